// Round 1
// baseline (17460.748 us; speedup 1.0000x reference)
//
#include <hip/hip_runtime.h>

#define N_NODES 50000
#define N_EDGES 800000
#define N_GRAPHS 128
#define FEAT 256            // HEADS*HID
#define JK 576              // 64 + 256 + 256

// ---------- helpers ----------
__device__ __forceinline__ unsigned enc_f(float x) {
    unsigned u = __float_as_uint(x);
    return (u & 0x80000000u) ? ~u : (u | 0x80000000u);
}
__device__ __forceinline__ float dec_f(unsigned u) {
    return (u & 0x80000000u) ? __uint_as_float(u ^ 0x80000000u) : __uint_as_float(~u);
}

// ---------- GEMM: Y[N,256] = X[N,K] @ W[K,256] ----------
// block = 256 threads, 16 rows per block, one output column per thread.
__global__ void gemm_kernel(const float* __restrict__ X, const float* __restrict__ W,
                            float* __restrict__ Y, int N, int K) {
    extern __shared__ float xs[];          // 16*K floats
    int n0 = blockIdx.x * 16;
    int t  = threadIdx.x;
    int total = 16 * K;
    for (int i = t; i < total; i += 256) {
        int r = i / K, k = i - r * K;
        int n = n0 + r;
        xs[i] = (n < N) ? X[(size_t)n * K + k] : 0.f;
    }
    __syncthreads();
    float acc[16];
#pragma unroll
    for (int r = 0; r < 16; r++) acc[r] = 0.f;
    int c = t;                              // 0..255
    for (int k = 0; k < K; k++) {
        float wv = W[k * 256 + c];
#pragma unroll
        for (int r = 0; r < 16; r++) acc[r] += xs[r * K + k] * wv;
    }
    for (int r = 0; r < 16; r++) {
        int n = n0 + r;
        if (n < N) Y[(size_t)n * 256 + c] = acc[r];
    }
}

// ---------- per-node attention logits: es[n,h], ed[n,h] ----------
// one wave per node; lane l holds feats l*4..l*4+3, head = l>>4.
__global__ void esed_kernel(const float* __restrict__ H, const float* __restrict__ a_s,
                            const float* __restrict__ a_d, float* __restrict__ es,
                            float* __restrict__ ed) {
    int gid  = blockIdx.x * blockDim.x + threadIdx.x;
    int node = gid >> 6;
    int lane = threadIdx.x & 63;
    if (node >= N_NODES) return;
    const float4 v = *(const float4*)&H[(size_t)node * 256 + lane * 4];
    const float4 a = *(const float4*)&a_s[lane * 4];
    const float4 b = *(const float4*)&a_d[lane * 4];
    float ps = v.x * a.x + v.y * a.y + v.z * a.z + v.w * a.w;
    float pd = v.x * b.x + v.y * b.y + v.z * b.z + v.w * b.w;
#pragma unroll
    for (int off = 1; off < 16; off <<= 1) {
        ps += __shfl_xor(ps, off);
        pd += __shfl_xor(pd, off);
    }
    if ((lane & 15) == 0) {
        int h = lane >> 4;
        es[node * 4 + h] = ps;
        ed[node * 4 + h] = pd;
    }
}

__global__ void init_menc(unsigned* __restrict__ m, int n) {
    int i = blockIdx.x * blockDim.x + threadIdx.x;
    if (i < n) m[i] = 0x007FFFFFu;   // enc(-inf)
}

// ---------- edge pass A: e = leaky_relu(es[src]+ed[dst]); segment max ----------
__global__ void edge_att_a(const int* __restrict__ src, const int* __restrict__ dst,
                           const float* __restrict__ es, const float* __restrict__ ed,
                           float* __restrict__ eedge, unsigned* __restrict__ menc) {
    int t = blockIdx.x * blockDim.x + threadIdx.x;
    if (t >= N_EDGES * 4) return;
    int e = t >> 2, h = t & 3;
    int s = src[e], d = dst[e];
    float v = es[s * 4 + h] + ed[d * 4 + h];
    v = v > 0.f ? v : 0.2f * v;
    eedge[t] = v;
    atomicMax(&menc[d * 4 + h], enc_f(v));
}

// ---------- edge pass B: e = exp(e - m[dst]); segment sum -> denom ----------
__global__ void edge_att_b(const int* __restrict__ dst, float* __restrict__ eedge,
                           const unsigned* __restrict__ menc, float* __restrict__ denom) {
    int t = blockIdx.x * blockDim.x + threadIdx.x;
    if (t >= N_EDGES * 4) return;
    int e = t >> 2, h = t & 3;
    int d = dst[e];
    float m  = dec_f(menc[d * 4 + h]);
    float ex = expf(eedge[t] - m);
    eedge[t] = ex;
    atomicAdd(&denom[d * 4 + h], ex);
}

// ---------- edge aggregate: out[dst] += h[src] * alpha ----------
// one wave per edge, float4 per lane.
__global__ void edge_aggregate(const int* __restrict__ src, const int* __restrict__ dst,
                               const float* __restrict__ eedge, const float* __restrict__ denom,
                               const float* __restrict__ H, float* __restrict__ out) {
    int gid  = blockIdx.x * blockDim.x + threadIdx.x;
    int e    = gid >> 6;
    int lane = threadIdx.x & 63;
    if (e >= N_EDGES) return;
    int s = src[e], d = dst[e];
    int h = lane >> 4;
    float dn = denom[d * 4 + h];
    dn = dn > 0.f ? dn : 1.f;
    float alpha = eedge[e * 4 + h] / dn;
    float4 v = *(const float4*)&H[(size_t)s * 256 + lane * 4];
    float* o = &out[(size_t)d * 256 + lane * 4];
    atomicAdd(o + 0, v.x * alpha);
    atomicAdd(o + 1, v.y * alpha);
    atomicAdd(o + 2, v.z * alpha);
    atomicAdd(o + 3, v.w * alpha);
}

__global__ void bias_relu(float* __restrict__ buf, const float* __restrict__ b) {
    int i = blockIdx.x * blockDim.x + threadIdx.x;
    if (i >= N_NODES * 256) return;
    float v = buf[i] + b[i & 255];
    buf[i] = v > 0.f ? v : 0.f;
}

// ---------- label prop ----------
__global__ void deg_kernel(const int* __restrict__ dst, float* __restrict__ deg) {
    int t = blockIdx.x * blockDim.x + threadIdx.x;
    if (t < N_EDGES) atomicAdd(&deg[dst[t]], 1.f);
}
__global__ void dis_kernel(const float* __restrict__ deg, float* __restrict__ dis) {
    int i = blockIdx.x * blockDim.x + threadIdx.x;
    if (i >= N_NODES) return;
    float d = deg[i];
    dis[i] = d > 0.f ? 1.f / sqrtf(d) : 0.f;
}
// out[dst] += in[src] * (dis[src]*dis[dst]); wave per edge
__global__ void lp_scatter(const int* __restrict__ src, const int* __restrict__ dst,
                           const float* __restrict__ dis, const float* __restrict__ in,
                           float* __restrict__ out) {
    int gid  = blockIdx.x * blockDim.x + threadIdx.x;
    int e    = gid >> 6;
    int lane = threadIdx.x & 63;
    if (e >= N_EDGES) return;
    int s = src[e], d = dst[e];
    float nrm = dis[s] * dis[d];
    float4 v = *(const float4*)&in[(size_t)s * 256 + lane * 4];
    float* o = &out[(size_t)d * 256 + lane * 4];
    atomicAdd(o + 0, v.x * nrm);
    atomicAdd(o + 1, v.y * nrm);
    atomicAdd(o + 2, v.z * nrm);
    atomicAdd(o + 3, v.w * nrm);
}
// out = clamp(0.5*out + 0.5*res, 0, 1)
__global__ void lp_combine(float* __restrict__ out, const float* __restrict__ res) {
    int i = blockIdx.x * blockDim.x + threadIdx.x;
    if (i >= N_NODES * 256) return;
    float v = 0.5f * out[i] + 0.5f * res[i];
    v = v < 0.f ? 0.f : (v > 1.f ? 1.f : v);
    out[i] = v;
}

// ---------- pooling ----------
__global__ void cnt_kernel(const int* __restrict__ batch, float* __restrict__ cnt) {
    int i = blockIdx.x * blockDim.x + threadIdx.x;
    if (i < N_NODES) atomicAdd(&cnt[batch[i]], 1.f);
}
// wave per node; C = 64 or 256
__global__ void pool_kernel(const float* __restrict__ buf, const int* __restrict__ batch,
                            float* __restrict__ gsum, int C, int colOff) {
    int gid  = blockIdx.x * blockDim.x + threadIdx.x;
    int node = gid >> 6;
    int lane = threadIdx.x & 63;
    if (node >= N_NODES) return;
    int g = batch[node];
    for (int j = lane; j < C; j += 64)
        atomicAdd(&gsum[g * JK + colOff + j], buf[(size_t)node * C + j]);
}
__global__ void gmean_kernel(const float* __restrict__ gsum, const float* __restrict__ cnt,
                             float* __restrict__ g) {
    int i = blockIdx.x * blockDim.x + threadIdx.x;
    if (i >= N_GRAPHS * JK) return;
    int gi = i / JK;
    float c = cnt[gi];
    g[i] = gsum[i] / (c > 1.f ? c : 1.f);
}

// ---------- small dense layers ----------
__global__ void dense_kernel(const float* __restrict__ in, const float* __restrict__ W,
                             const float* __restrict__ b, float* __restrict__ out,
                             int G, int K, int M, int in_stride, int out_stride, int do_relu) {
    int i = blockIdx.x * blockDim.x + threadIdx.x;
    if (i >= G * M) return;
    int g = i / M, m = i - g * M;
    float acc = b[m];
    for (int k = 0; k < K; k++) acc += in[g * in_stride + k] * W[k * M + m];
    if (do_relu) acc = acc > 0.f ? acc : 0.f;
    out[g * out_stride + m] = acc;
}

// ---------- launch ----------
extern "C" void kernel_launch(void* const* d_in, const int* in_sizes, int n_in,
                              void* d_out, int out_size, void* d_ws, size_t ws_size,
                              hipStream_t stream) {
    const float* x     = (const float*)d_in[0];
    const int*   ei    = (const int*)d_in[1];
    const int*   batch = (const int*)d_in[2];
    const float* clin  = (const float*)d_in[3];
    const float* W1  = (const float*)d_in[4];
    const float* a1s = (const float*)d_in[5];
    const float* a1d = (const float*)d_in[6];
    const float* b1  = (const float*)d_in[7];
    const float* W2  = (const float*)d_in[8];
    const float* a2s = (const float*)d_in[9];
    const float* a2d = (const float*)d_in[10];
    const float* b2  = (const float*)d_in[11];
    const float* pp_w1 = (const float*)d_in[12];
    const float* pp_b1 = (const float*)d_in[13];
    const float* pp_w2 = (const float*)d_in[14];
    const float* pp_b2 = (const float*)d_in[15];
    const float* cl_w1 = (const float*)d_in[16];
    const float* cl_b1 = (const float*)d_in[17];
    const float* cl_w2 = (const float*)d_in[18];
    const float* cl_b2 = (const float*)d_in[19];
    const float* h_w1  = (const float*)d_in[20];
    const float* h_b1  = (const float*)d_in[21];
    const float* h_w2  = (const float*)d_in[22];
    const float* h_b2  = (const float*)d_in[23];
    const float* h_w3  = (const float*)d_in[24];
    const float* h_b3  = (const float*)d_in[25];

    const int* src = ei;
    const int* dst = ei + N_EDGES;

    // workspace carve-up (256B aligned)
    char* p = (char*)d_ws;
    auto carve = [&](size_t bytes) -> char* {
        char* r = p;
        p += (bytes + 255) & ~(size_t)255;
        return r;
    };
    const size_t NB = (size_t)N_NODES * 256 * 4;
    float*    bufA  = (float*)carve(NB);
    float*    bufB  = (float*)carve(NB);
    float*    bufC  = (float*)carve(NB);
    float*    eedge = (float*)carve((size_t)N_EDGES * 4 * 4);
    float*    es    = (float*)carve((size_t)N_NODES * 4 * 4);
    float*    ed    = (float*)carve((size_t)N_NODES * 4 * 4);
    unsigned* menc  = (unsigned*)carve((size_t)N_NODES * 4 * 4);
    float*    denom = (float*)carve((size_t)N_NODES * 4 * 4);
    float*    deg   = (float*)carve((size_t)N_NODES * 4);
    float*    dis   = (float*)carve((size_t)N_NODES * 4);
    float*    gsum  = (float*)carve((size_t)N_GRAPHS * JK * 4);
    float*    cnt   = (float*)carve((size_t)N_GRAPHS * 4);
    float*    gbuf  = (float*)carve((size_t)N_GRAPHS * JK * 4);
    float*    t1    = (float*)carve((size_t)N_GRAPHS * 256 * 4);
    float*    zbuf  = (float*)carve((size_t)N_GRAPHS * 160 * 4);
    float*    t2    = (float*)carve((size_t)N_GRAPHS * 64 * 4);
    float*    t3    = (float*)carve((size_t)N_GRAPHS * 64 * 4);
    float*    t4    = (float*)carve((size_t)N_GRAPHS * 32 * 4);

    const int TB = 256;
    const int gN      = (N_NODES + TB - 1) / TB;
    const int gE      = (N_EDGES + TB - 1) / TB;
    const int gE4     = (N_EDGES * 4 + TB - 1) / TB;
    const int gN4     = (N_NODES * 4 + TB - 1) / TB;
    const int gNF     = (N_NODES * 256 + TB - 1) / TB;   // elementwise over node feats
    const int gNwave  = (N_NODES * 64 + TB - 1) / TB;    // wave per node
    const int gEwave  = (N_EDGES * 64 + TB - 1) / TB;    // wave per edge
    const int gGemm   = (N_NODES + 15) / 16;

    // ---- graph-wide precompute ----
    hipMemsetAsync(deg, 0, (size_t)N_NODES * 4, stream);
    hipMemsetAsync(gsum, 0, (size_t)N_GRAPHS * JK * 4, stream);
    hipMemsetAsync(cnt, 0, (size_t)N_GRAPHS * 4, stream);
    deg_kernel<<<gE, TB, 0, stream>>>(dst, deg);
    dis_kernel<<<gN, TB, 0, stream>>>(deg, dis);
    cnt_kernel<<<gN, TB, 0, stream>>>(batch, cnt);

    // ---- GAT layer 1 ----
    gemm_kernel<<<gGemm, TB, 16 * 64 * 4, stream>>>(x, W1, bufA, N_NODES, 64);
    esed_kernel<<<gNwave, TB, 0, stream>>>(bufA, a1s, a1d, es, ed);
    init_menc<<<gN4, TB, 0, stream>>>(menc, N_NODES * 4);
    hipMemsetAsync(denom, 0, (size_t)N_NODES * 4 * 4, stream);
    edge_att_a<<<gE4, TB, 0, stream>>>(src, dst, es, ed, eedge, menc);
    edge_att_b<<<gE4, TB, 0, stream>>>(dst, eedge, menc, denom);
    hipMemsetAsync(bufB, 0, NB, stream);
    edge_aggregate<<<gEwave, TB, 0, stream>>>(src, dst, eedge, denom, bufA, bufB);
    bias_relu<<<gNF, TB, 0, stream>>>(bufB, b1);          // bufB = h1a

    // ---- label prop 1 ----
    hipMemsetAsync(bufC, 0, NB, stream);
    lp_scatter<<<gEwave, TB, 0, stream>>>(src, dst, dis, bufB, bufC);
    lp_combine<<<gNF, TB, 0, stream>>>(bufC, bufB);
    hipMemsetAsync(bufA, 0, NB, stream);
    lp_scatter<<<gEwave, TB, 0, stream>>>(src, dst, dis, bufC, bufA);
    lp_combine<<<gNF, TB, 0, stream>>>(bufA, bufB);       // bufA = h1_final

    // ---- GAT layer 2 ----
    gemm_kernel<<<gGemm, TB, 16 * 256 * 4, stream>>>(bufA, W2, bufB, N_NODES, 256);
    esed_kernel<<<gNwave, TB, 0, stream>>>(bufB, a2s, a2d, es, ed);
    init_menc<<<gN4, TB, 0, stream>>>(menc, N_NODES * 4);
    hipMemsetAsync(denom, 0, (size_t)N_NODES * 4 * 4, stream);
    edge_att_a<<<gE4, TB, 0, stream>>>(src, dst, es, ed, eedge, menc);
    edge_att_b<<<gE4, TB, 0, stream>>>(dst, eedge, menc, denom);
    hipMemsetAsync(bufC, 0, NB, stream);
    edge_aggregate<<<gEwave, TB, 0, stream>>>(src, dst, eedge, denom, bufB, bufC);
    bias_relu<<<gNF, TB, 0, stream>>>(bufC, b2);          // bufC = h2a

    // pool h0 and h1 before bufA gets reused
    pool_kernel<<<gNwave, TB, 0, stream>>>(x, batch, gsum, 64, 0);
    pool_kernel<<<gNwave, TB, 0, stream>>>(bufA, batch, gsum, 256, 64);

    // ---- label prop 2 ----
    hipMemsetAsync(bufB, 0, NB, stream);
    lp_scatter<<<gEwave, TB, 0, stream>>>(src, dst, dis, bufC, bufB);
    lp_combine<<<gNF, TB, 0, stream>>>(bufB, bufC);
    hipMemsetAsync(bufA, 0, NB, stream);
    lp_scatter<<<gEwave, TB, 0, stream>>>(src, dst, dis, bufB, bufA);
    lp_combine<<<gNF, TB, 0, stream>>>(bufA, bufC);       // bufA = h2_final

    pool_kernel<<<gNwave, TB, 0, stream>>>(bufA, batch, gsum, 256, 320);

    // ---- graph mean + MLP head ----
    gmean_kernel<<<(N_GRAPHS * JK + TB - 1) / TB, TB, 0, stream>>>(gsum, cnt, gbuf);

    dense_kernel<<<(N_GRAPHS * 256 + TB - 1) / TB, TB, 0, stream>>>(gbuf, pp_w1, pp_b1, t1,
        N_GRAPHS, JK, 256, JK, 256, 1);
    dense_kernel<<<(N_GRAPHS * 128 + TB - 1) / TB, TB, 0, stream>>>(t1, pp_w2, pp_b2, zbuf,
        N_GRAPHS, 256, 128, 256, 160, 0);
    dense_kernel<<<(N_GRAPHS * 64 + TB - 1) / TB, TB, 0, stream>>>(clin, cl_w1, cl_b1, t2,
        N_GRAPHS, 32, 64, 32, 64, 1);
    dense_kernel<<<(N_GRAPHS * 32 + TB - 1) / TB, TB, 0, stream>>>(t2, cl_w2, cl_b2, zbuf + 128,
        N_GRAPHS, 64, 32, 64, 160, 0);
    dense_kernel<<<(N_GRAPHS * 64 + TB - 1) / TB, TB, 0, stream>>>(zbuf, h_w1, h_b1, t3,
        N_GRAPHS, 160, 64, 160, 64, 1);
    dense_kernel<<<(N_GRAPHS * 32 + TB - 1) / TB, TB, 0, stream>>>(t3, h_w2, h_b2, t4,
        N_GRAPHS, 64, 32, 64, 32, 1);
    dense_kernel<<<(N_GRAPHS * 2 + TB - 1) / TB, TB, 0, stream>>>(t4, h_w3, h_b3, (float*)d_out,
        N_GRAPHS, 32, 2, 32, 2, 0);
}

// Round 2
// 2051.056 us; speedup vs baseline: 8.5131x; 8.5131x over previous
//
#include <hip/hip_runtime.h>

#define N_NODES 50000
#define N_EDGES 800000
#define N_GRAPHS 128
#define JK 576              // 64 + 256 + 256

// ---------- GEMM: Y[N,256] = X[N,K] @ W[K,256] ----------
// block = 256 threads, 16 rows per block, one output column per thread.
__global__ void gemm_kernel(const float* __restrict__ X, const float* __restrict__ W,
                            float* __restrict__ Y, int N, int K) {
    extern __shared__ float xs[];          // 16*K floats
    int n0 = blockIdx.x * 16;
    int t  = threadIdx.x;
    int total = 16 * K;
    for (int i = t; i < total; i += 256) {
        int r = i / K, k = i - r * K;
        int n = n0 + r;
        xs[i] = (n < N) ? X[(size_t)n * K + k] : 0.f;
    }
    __syncthreads();
    float acc[16];
#pragma unroll
    for (int r = 0; r < 16; r++) acc[r] = 0.f;
    int c = t;                              // 0..255
    for (int k = 0; k < K; k++) {
        float wv = W[k * 256 + c];
#pragma unroll
        for (int r = 0; r < 16; r++) acc[r] += xs[r * K + k] * wv;
    }
    for (int r = 0; r < 16; r++) {
        int n = n0 + r;
        if (n < N) Y[(size_t)n * 256 + c] = acc[r];
    }
}

// ---------- CSR build ----------
__global__ void deg_kernel(const int* __restrict__ dst, int* __restrict__ deg) {
    int t = blockIdx.x * blockDim.x + threadIdx.x;
    if (t < N_EDGES) atomicAdd(&deg[dst[t]], 1);
}
__global__ void dis_kernel(const int* __restrict__ deg, float* __restrict__ dis) {
    int i = blockIdx.x * blockDim.x + threadIdx.x;
    if (i >= N_NODES) return;
    int d = deg[i];
    dis[i] = d > 0 ? rsqrtf((float)d) : 0.f;
}
// exclusive scan of deg[N_NODES] -> off[N_NODES+1], single block of 1024.
__global__ __launch_bounds__(1024) void scan_kernel(const int* __restrict__ deg,
                                                    int* __restrict__ off) {
    __shared__ int part[1024];
    int t = threadIdx.x;
    const int CH = (N_NODES + 1023) / 1024;
    int base = t * CH;
    int s = 0;
    for (int i = 0; i < CH; i++) {
        int n = base + i;
        if (n < N_NODES) s += deg[n];
    }
    part[t] = s;
    __syncthreads();
    for (int o = 1; o < 1024; o <<= 1) {
        int v = (t >= o) ? part[t - o] : 0;
        __syncthreads();
        part[t] += v;
        __syncthreads();
    }
    int run = (t == 0) ? 0 : part[t - 1];
    for (int i = 0; i < CH; i++) {
        int n = base + i;
        if (n < N_NODES) { off[n] = run; run += deg[n]; }
    }
    if (t == 1023) off[N_NODES] = run;
}
__global__ void csr_fill(const int* __restrict__ src, const int* __restrict__ dst,
                         const int* __restrict__ off, int* __restrict__ cursor,
                         int* __restrict__ csr_src) {
    int e = blockIdx.x * blockDim.x + threadIdx.x;
    if (e >= N_EDGES) return;
    int d = dst[e];
    int pos = off[d] + atomicAdd(&cursor[d], 1);
    csr_src[pos] = src[e];
}

// ---------- per-node attention logits: es[n,h], ed[n,h] ----------
__global__ void esed_kernel(const float* __restrict__ H, const float* __restrict__ a_s,
                            const float* __restrict__ a_d, float* __restrict__ es,
                            float* __restrict__ ed) {
    int gid  = blockIdx.x * blockDim.x + threadIdx.x;
    int node = gid >> 6;
    int lane = threadIdx.x & 63;
    if (node >= N_NODES) return;
    const float4 v = *(const float4*)&H[(size_t)node * 256 + lane * 4];
    const float4 a = *(const float4*)&a_s[lane * 4];
    const float4 b = *(const float4*)&a_d[lane * 4];
    float ps = v.x * a.x + v.y * a.y + v.z * a.z + v.w * a.w;
    float pd = v.x * b.x + v.y * b.y + v.z * b.z + v.w * b.w;
#pragma unroll
    for (int off = 1; off < 16; off <<= 1) {
        ps += __shfl_xor(ps, off);
        pd += __shfl_xor(pd, off);
    }
    if ((lane & 15) == 0) {
        int h = lane >> 4;
        es[node * 4 + h] = ps;
        ed[node * 4 + h] = pd;
    }
}

// ---------- attention softmax over incoming edges (no atomics) ----------
// thread per (node, head). pass1: v -> alpha_csr, track max. pass2: exp+sum.
__global__ void att_csr(const int* __restrict__ off, const int* __restrict__ csr_src,
                        const float* __restrict__ es, const float* __restrict__ ed,
                        float* __restrict__ alpha_csr, float* __restrict__ rdenom) {
    int t = blockIdx.x * blockDim.x + threadIdx.x;
    if (t >= N_NODES * 4) return;
    int n = t >> 2, h = t & 3;
    int p0 = off[n], p1 = off[n + 1];
    float edv = ed[n * 4 + h];
    float m = -1e30f;
    for (int p = p0; p < p1; p++) {
        float v = es[csr_src[p] * 4 + h] + edv;
        v = v > 0.f ? v : 0.2f * v;
        alpha_csr[p * 4 + h] = v;
        m = fmaxf(m, v);
    }
    float sum = 0.f;
    for (int p = p0; p < p1; p++) {
        float ex = expf(alpha_csr[p * 4 + h] - m);
        alpha_csr[p * 4 + h] = ex;
        sum += ex;
    }
    rdenom[t] = sum > 0.f ? 1.f / sum : 1.f;
}

// ---------- GAT aggregate: wave per node, fused bias + relu ----------
__global__ void gat_agg_csr(const int* __restrict__ off, const int* __restrict__ csr_src,
                            const float* __restrict__ alpha_csr, const float* __restrict__ rdenom,
                            const float* __restrict__ H, const float* __restrict__ bias,
                            float* __restrict__ out) {
    int gid  = blockIdx.x * blockDim.x + threadIdx.x;
    int n    = gid >> 6;
    int lane = threadIdx.x & 63;
    if (n >= N_NODES) return;
    int h = lane >> 4;
    float rd = rdenom[n * 4 + h];
    int p0 = off[n], p1 = off[n + 1];
    float4 acc = {0.f, 0.f, 0.f, 0.f};
    for (int p = p0; p < p1; p++) {
        int s = csr_src[p];
        float a = alpha_csr[p * 4 + h] * rd;
        float4 v = *(const float4*)&H[(size_t)s * 256 + lane * 4];
        acc.x += v.x * a; acc.y += v.y * a; acc.z += v.z * a; acc.w += v.w * a;
    }
    float4 bv = *(const float4*)&bias[lane * 4];
    acc.x += bv.x; acc.y += bv.y; acc.z += bv.z; acc.w += bv.w;
    acc.x = acc.x > 0.f ? acc.x : 0.f;
    acc.y = acc.y > 0.f ? acc.y : 0.f;
    acc.z = acc.z > 0.f ? acc.z : 0.f;
    acc.w = acc.w > 0.f ? acc.w : 0.f;
    *(float4*)&out[(size_t)n * 256 + lane * 4] = acc;
}

// ---------- label prop step: wave per node, fused combine + clamp ----------
__global__ void lp_csr(const int* __restrict__ off, const int* __restrict__ csr_src,
                       const float* __restrict__ dis, const float* __restrict__ in,
                       const float* __restrict__ res, float* __restrict__ out) {
    int gid  = blockIdx.x * blockDim.x + threadIdx.x;
    int n    = gid >> 6;
    int lane = threadIdx.x & 63;
    if (n >= N_NODES) return;
    float disd = dis[n];
    int p0 = off[n], p1 = off[n + 1];
    float4 acc = {0.f, 0.f, 0.f, 0.f};
    for (int p = p0; p < p1; p++) {
        int s = csr_src[p];
        float nrm = dis[s] * disd;
        float4 v = *(const float4*)&in[(size_t)s * 256 + lane * 4];
        acc.x += v.x * nrm; acc.y += v.y * nrm; acc.z += v.z * nrm; acc.w += v.w * nrm;
    }
    float4 r = *(const float4*)&res[(size_t)n * 256 + lane * 4];
    acc.x = 0.5f * acc.x + 0.5f * r.x;
    acc.y = 0.5f * acc.y + 0.5f * r.y;
    acc.z = 0.5f * acc.z + 0.5f * r.z;
    acc.w = 0.5f * acc.w + 0.5f * r.w;
    acc.x = fminf(fmaxf(acc.x, 0.f), 1.f);
    acc.y = fminf(fmaxf(acc.y, 0.f), 1.f);
    acc.z = fminf(fmaxf(acc.z, 0.f), 1.f);
    acc.w = fminf(fmaxf(acc.w, 0.f), 1.f);
    *(float4*)&out[(size_t)n * 256 + lane * 4] = acc;
}

// ---------- pooling via sorted-batch segments ----------
__global__ void bounds_kernel(const int* __restrict__ batch, int* __restrict__ gstart) {
    int n = blockIdx.x * blockDim.x + threadIdx.x;
    if (n >= N_NODES) return;
    int b = batch[n];
    int prev = (n == 0) ? -1 : batch[n - 1];
    for (int g = prev + 1; g <= b; g++) gstart[g] = n;
    if (n == N_NODES - 1)
        for (int g = b + 1; g <= N_GRAPHS; g++) gstart[g] = N_NODES;
}
// block per graph; contiguous node range; C cols of `buf` -> gbuf[:, colOff..]
__global__ void pool_seg(const float* __restrict__ buf, const int* __restrict__ gstart,
                         float* __restrict__ gbuf, int C, int colOff) {
    int g = blockIdx.x;
    int n0 = gstart[g], n1 = gstart[g + 1];
    float inv = (n1 > n0) ? 1.f / (float)(n1 - n0) : 1.f;
    for (int c = threadIdx.x; c < C; c += blockDim.x) {
        float s = 0.f;
        for (int n = n0; n < n1; n++) s += buf[(size_t)n * C + c];
        gbuf[g * JK + colOff + c] = s * inv;
    }
}

// ---------- small dense layers ----------
__global__ void dense_kernel(const float* __restrict__ in, const float* __restrict__ W,
                             const float* __restrict__ b, float* __restrict__ out,
                             int G, int K, int M, int in_stride, int out_stride, int do_relu) {
    int i = blockIdx.x * blockDim.x + threadIdx.x;
    if (i >= G * M) return;
    int g = i / M, m = i - g * M;
    float acc = b[m];
    for (int k = 0; k < K; k++) acc += in[g * in_stride + k] * W[k * M + m];
    if (do_relu) acc = acc > 0.f ? acc : 0.f;
    out[g * out_stride + m] = acc;
}

// ---------- launch ----------
extern "C" void kernel_launch(void* const* d_in, const int* in_sizes, int n_in,
                              void* d_out, int out_size, void* d_ws, size_t ws_size,
                              hipStream_t stream) {
    const float* x     = (const float*)d_in[0];
    const int*   ei    = (const int*)d_in[1];
    const int*   batch = (const int*)d_in[2];
    const float* clin  = (const float*)d_in[3];
    const float* W1  = (const float*)d_in[4];
    const float* a1s = (const float*)d_in[5];
    const float* a1d = (const float*)d_in[6];
    const float* b1  = (const float*)d_in[7];
    const float* W2  = (const float*)d_in[8];
    const float* a2s = (const float*)d_in[9];
    const float* a2d = (const float*)d_in[10];
    const float* b2  = (const float*)d_in[11];
    const float* pp_w1 = (const float*)d_in[12];
    const float* pp_b1 = (const float*)d_in[13];
    const float* pp_w2 = (const float*)d_in[14];
    const float* pp_b2 = (const float*)d_in[15];
    const float* cl_w1 = (const float*)d_in[16];
    const float* cl_b1 = (const float*)d_in[17];
    const float* cl_w2 = (const float*)d_in[18];
    const float* cl_b2 = (const float*)d_in[19];
    const float* h_w1  = (const float*)d_in[20];
    const float* h_b1  = (const float*)d_in[21];
    const float* h_w2  = (const float*)d_in[22];
    const float* h_b2  = (const float*)d_in[23];
    const float* h_w3  = (const float*)d_in[24];
    const float* h_b3  = (const float*)d_in[25];

    const int* src = ei;
    const int* dst = ei + N_EDGES;

    // workspace carve-up (256B aligned)
    char* p = (char*)d_ws;
    auto carve = [&](size_t bytes) -> char* {
        char* r = p;
        p += (bytes + 255) & ~(size_t)255;
        return r;
    };
    const size_t NB = (size_t)N_NODES * 256 * 4;
    float* bufA = (float*)carve(NB);
    float* bufB = (float*)carve(NB);
    float* bufC = (float*)carve(NB);
    float* alpha_csr = (float*)carve((size_t)N_EDGES * 4 * 4);
    int*   csr_src   = (int*)carve((size_t)N_EDGES * 4);
    int*   off       = (int*)carve((size_t)(N_NODES + 1) * 4);
    int*   deg       = (int*)carve((size_t)N_NODES * 4);
    int*   cursor    = (int*)carve((size_t)N_NODES * 4);
    float* dis       = (float*)carve((size_t)N_NODES * 4);
    float* es        = (float*)carve((size_t)N_NODES * 4 * 4);
    float* ed        = (float*)carve((size_t)N_NODES * 4 * 4);
    float* rdenom    = (float*)carve((size_t)N_NODES * 4 * 4);
    int*   gstart    = (int*)carve((size_t)(N_GRAPHS + 1) * 4);
    float* gbuf      = (float*)carve((size_t)N_GRAPHS * JK * 4);
    float* t1        = (float*)carve((size_t)N_GRAPHS * 256 * 4);
    float* zbuf      = (float*)carve((size_t)N_GRAPHS * 160 * 4);
    float* t2        = (float*)carve((size_t)N_GRAPHS * 64 * 4);
    float* t3        = (float*)carve((size_t)N_GRAPHS * 64 * 4);
    float* t4        = (float*)carve((size_t)N_GRAPHS * 32 * 4);

    const int TB = 256;
    const int gN     = (N_NODES + TB - 1) / TB;
    const int gE     = (N_EDGES + TB - 1) / TB;
    const int gN4    = (N_NODES * 4 + TB - 1) / TB;
    const int gNwave = (N_NODES * 64 + TB - 1) / TB;     // wave per node
    const int gGemm  = (N_NODES + 15) / 16;

    // ---- CSR + degree + pooling bounds ----
    hipMemsetAsync(deg, 0, (size_t)N_NODES * 4, stream);
    hipMemsetAsync(cursor, 0, (size_t)N_NODES * 4, stream);
    deg_kernel<<<gE, TB, 0, stream>>>(dst, deg);
    dis_kernel<<<gN, TB, 0, stream>>>(deg, dis);
    scan_kernel<<<1, 1024, 0, stream>>>(deg, off);
    csr_fill<<<gE, TB, 0, stream>>>(src, dst, off, cursor, csr_src);
    bounds_kernel<<<gN, TB, 0, stream>>>(batch, gstart);

    // ---- GAT layer 1 ----
    gemm_kernel<<<gGemm, TB, 16 * 64 * 4, stream>>>(x, W1, bufA, N_NODES, 64);
    esed_kernel<<<gNwave, TB, 0, stream>>>(bufA, a1s, a1d, es, ed);
    att_csr<<<gN4, TB, 0, stream>>>(off, csr_src, es, ed, alpha_csr, rdenom);
    gat_agg_csr<<<gNwave, TB, 0, stream>>>(off, csr_src, alpha_csr, rdenom, bufA, b1, bufB); // bufB = h1a

    // ---- label prop 1 ----
    lp_csr<<<gNwave, TB, 0, stream>>>(off, csr_src, dis, bufB, bufB, bufC);
    lp_csr<<<gNwave, TB, 0, stream>>>(off, csr_src, dis, bufC, bufB, bufA);  // bufA = h1_final

    // pool h1 now so bufA can be recycled later
    pool_seg<<<N_GRAPHS, TB, 0, stream>>>(bufA, gstart, gbuf, 256, 64);

    // ---- GAT layer 2 ----
    gemm_kernel<<<gGemm, TB, 16 * 256 * 4, stream>>>(bufA, W2, bufB, N_NODES, 256);
    esed_kernel<<<gNwave, TB, 0, stream>>>(bufB, a2s, a2d, es, ed);
    att_csr<<<gN4, TB, 0, stream>>>(off, csr_src, es, ed, alpha_csr, rdenom);
    gat_agg_csr<<<gNwave, TB, 0, stream>>>(off, csr_src, alpha_csr, rdenom, bufB, b2, bufC); // bufC = h2a

    // ---- label prop 2 ----
    lp_csr<<<gNwave, TB, 0, stream>>>(off, csr_src, dis, bufC, bufC, bufA);
    lp_csr<<<gNwave, TB, 0, stream>>>(off, csr_src, dis, bufA, bufC, bufB);  // bufB = h2_final

    // ---- pooling (x and h2) ----
    pool_seg<<<N_GRAPHS, TB, 0, stream>>>(x, gstart, gbuf, 64, 0);
    pool_seg<<<N_GRAPHS, TB, 0, stream>>>(bufB, gstart, gbuf, 256, 320);

    // ---- MLP head ----
    dense_kernel<<<(N_GRAPHS * 256 + TB - 1) / TB, TB, 0, stream>>>(gbuf, pp_w1, pp_b1, t1,
        N_GRAPHS, JK, 256, JK, 256, 1);
    dense_kernel<<<(N_GRAPHS * 128 + TB - 1) / TB, TB, 0, stream>>>(t1, pp_w2, pp_b2, zbuf,
        N_GRAPHS, 256, 128, 256, 160, 0);
    dense_kernel<<<(N_GRAPHS * 64 + TB - 1) / TB, TB, 0, stream>>>(clin, cl_w1, cl_b1, t2,
        N_GRAPHS, 32, 64, 32, 64, 1);
    dense_kernel<<<(N_GRAPHS * 32 + TB - 1) / TB, TB, 0, stream>>>(t2, cl_w2, cl_b2, zbuf + 128,
        N_GRAPHS, 64, 32, 64, 160, 0);
    dense_kernel<<<(N_GRAPHS * 64 + TB - 1) / TB, TB, 0, stream>>>(zbuf, h_w1, h_b1, t3,
        N_GRAPHS, 160, 64, 160, 64, 1);
    dense_kernel<<<(N_GRAPHS * 32 + TB - 1) / TB, TB, 0, stream>>>(t3, h_w2, h_b2, t4,
        N_GRAPHS, 64, 32, 64, 32, 1);
    dense_kernel<<<(N_GRAPHS * 2 + TB - 1) / TB, TB, 0, stream>>>(t4, h_w3, h_b3, (float*)d_out,
        N_GRAPHS, 32, 2, 32, 2, 0);
}

// Round 3
// 1714.679 us; speedup vs baseline: 10.1831x; 1.1962x over previous
//
#include <hip/hip_runtime.h>

#define N_NODES 50000
#define N_EDGES 800000
#define N_GRAPHS 128
#define JK 576              // 64 + 256 + 256
#define CAP 192             // max cached in-degree per node (Poisson(16); max~45)

// ---------- tiled GEMM: C[M x NC*gridY?] = A[M x K] @ B[K x NC] ----------
// 64-row x NC-col block tile, 256 threads, each thread 4 x (NC/16) outputs.
// blockIdx.y * head_stride is added to A,B,C,bias base (block-diag per-head GEMM).
template<int NC>
__global__ __launch_bounds__(256)
void gemm_tile(const float* __restrict__ A, int lda,
               const float* __restrict__ B, int ldb,
               float* __restrict__ C, int ldc,
               int M, int K,
               const float* __restrict__ bias, int do_relu, int head_stride) {
    __shared__ float As[16][68];       // [k][row], padded: b128-aligned, conflict-free
    __shared__ float Bs[16][NC];       // [k][col]
    const int off = blockIdx.y * head_stride;
    A += off; B += off; C += off;
    const float* bptr = bias ? bias + off : nullptr;
    const int m0 = blockIdx.x * 64;
    const int t  = threadIdx.x;
    const int tx = t & 15, ty = t >> 4;
    constexpr int CJ = NC / 64;        // float4 col-groups per thread
    float acc[4][CJ * 4];
#pragma unroll
    for (int r = 0; r < 4; r++)
#pragma unroll
        for (int j = 0; j < CJ * 4; j++) acc[r][j] = 0.f;

    const int sr = t >> 2;             // staging row 0..63
    const int sk = (t & 3) << 2;       // staging k 0,4,8,12

    for (int k0 = 0; k0 < K; k0 += 16) {
        float4 av4 = make_float4(0.f, 0.f, 0.f, 0.f);
        int gm = m0 + sr;
        if (gm < M) av4 = *(const float4*)&A[(size_t)gm * lda + k0 + sk];
        float4 bstg[CJ];
#pragma unroll
        for (int j = 0; j < CJ; j++)
            bstg[j] = *(const float4*)&B[(size_t)(k0 + ty) * ldb + tx * 4 + j * 64];
        __syncthreads();
        As[sk + 0][sr] = av4.x; As[sk + 1][sr] = av4.y;
        As[sk + 2][sr] = av4.z; As[sk + 3][sr] = av4.w;
#pragma unroll
        for (int j = 0; j < CJ; j++)
            *(float4*)&Bs[ty][tx * 4 + j * 64] = bstg[j];
        __syncthreads();
#pragma unroll
        for (int k = 0; k < 16; k++) {
            float4 a4 = *(const float4*)&As[k][ty * 4];
#pragma unroll
            for (int j = 0; j < CJ; j++) {
                float4 b4 = *(const float4*)&Bs[k][tx * 4 + j * 64];
                acc[0][j*4+0] += a4.x * b4.x; acc[0][j*4+1] += a4.x * b4.y;
                acc[0][j*4+2] += a4.x * b4.z; acc[0][j*4+3] += a4.x * b4.w;
                acc[1][j*4+0] += a4.y * b4.x; acc[1][j*4+1] += a4.y * b4.y;
                acc[1][j*4+2] += a4.y * b4.z; acc[1][j*4+3] += a4.y * b4.w;
                acc[2][j*4+0] += a4.z * b4.x; acc[2][j*4+1] += a4.z * b4.y;
                acc[2][j*4+2] += a4.z * b4.z; acc[2][j*4+3] += a4.z * b4.w;
                acc[3][j*4+0] += a4.w * b4.x; acc[3][j*4+1] += a4.w * b4.y;
                acc[3][j*4+2] += a4.w * b4.z; acc[3][j*4+3] += a4.w * b4.w;
            }
        }
    }
#pragma unroll
    for (int r = 0; r < 4; r++) {
        int row = m0 + ty * 4 + r;
        if (row >= M) continue;
#pragma unroll
        for (int j = 0; j < CJ; j++) {
            float4 o = make_float4(acc[r][j*4+0], acc[r][j*4+1], acc[r][j*4+2], acc[r][j*4+3]);
            if (bptr) {
                float4 bb = *(const float4*)&bptr[tx * 4 + j * 64];
                o.x += bb.x; o.y += bb.y; o.z += bb.z; o.w += bb.w;
            }
            if (do_relu) {
                o.x = fmaxf(o.x, 0.f); o.y = fmaxf(o.y, 0.f);
                o.z = fmaxf(o.z, 0.f); o.w = fmaxf(o.w, 0.f);
            }
            *(float4*)&C[(size_t)row * ldc + tx * 4 + j * 64] = o;
        }
    }
}

// ---------- CSR build ----------
__global__ void deg_kernel(const int* __restrict__ dst, int* __restrict__ deg) {
    int t = blockIdx.x * blockDim.x + threadIdx.x;
    if (t < N_EDGES) atomicAdd(&deg[dst[t]], 1);
}
__global__ void dis_kernel(const int* __restrict__ deg, float* __restrict__ dis) {
    int i = blockIdx.x * blockDim.x + threadIdx.x;
    if (i >= N_NODES) return;
    int d = deg[i];
    dis[i] = d > 0 ? rsqrtf((float)d) : 0.f;
}
__global__ __launch_bounds__(1024) void scan_kernel(const int* __restrict__ deg,
                                                    int* __restrict__ off) {
    __shared__ int part[1024];
    int t = threadIdx.x;
    const int CH = (N_NODES + 1023) / 1024;
    int base = t * CH;
    int s = 0;
    for (int i = 0; i < CH; i++) {
        int n = base + i;
        if (n < N_NODES) s += deg[n];
    }
    part[t] = s;
    __syncthreads();
    for (int o = 1; o < 1024; o <<= 1) {
        int v = (t >= o) ? part[t - o] : 0;
        __syncthreads();
        part[t] += v;
        __syncthreads();
    }
    int run = (t == 0) ? 0 : part[t - 1];
    for (int i = 0; i < CH; i++) {
        int n = base + i;
        if (n < N_NODES) { off[n] = run; run += deg[n]; }
    }
    if (t == 1023) off[N_NODES] = run;
}
// fill CSR src list + per-edge label-prop norm (dis[src]*dis[dst]) in CSR order
__global__ void csr_fill(const int* __restrict__ src, const int* __restrict__ dst,
                         const int* __restrict__ off, int* __restrict__ cursor,
                         const float* __restrict__ dis, int* __restrict__ csr_src,
                         float* __restrict__ wnorm) {
    int e = blockIdx.x * blockDim.x + threadIdx.x;
    if (e >= N_EDGES) return;
    int s = src[e], d = dst[e];
    int pos = off[d] + atomicAdd(&cursor[d], 1);
    csr_src[pos] = s;
    wnorm[pos] = dis[s] * dis[d];
}

// ---------- precontract W @ a  ->  w_es[c,h], w_ed[c,h] (c = K rows of W) ----------
__global__ void prep_w(const float* __restrict__ W, const float* __restrict__ as_,
                       const float* __restrict__ ad_, float* __restrict__ wes,
                       float* __restrict__ wed, int K) {
    int t = blockIdx.x * blockDim.x + threadIdx.x;
    if (t >= K * 4) return;
    int c = t >> 2, h = t & 3;
    float se = 0.f, sd = 0.f;
    for (int j = 0; j < 64; j++) {
        float w = W[(size_t)c * 256 + h * 64 + j];
        se += w * as_[h * 64 + j];
        sd += w * ad_[h * 64 + j];
    }
    wes[c * 4 + h] = se;
    wed[c * 4 + h] = sd;
}

// ---------- es/ed from K=64 input (x) : wave per node ----------
__global__ void esed_x(const float* __restrict__ X, const float* __restrict__ wes,
                       const float* __restrict__ wed, float* __restrict__ es,
                       float* __restrict__ ed) {
    int gid = blockIdx.x * blockDim.x + threadIdx.x;
    int n = gid >> 6, lane = threadIdx.x & 63;
    if (n >= N_NODES) return;
    float xv = X[(size_t)n * 64 + lane];
    float4 a = *(const float4*)&wes[lane * 4];
    float4 b = *(const float4*)&wed[lane * 4];
    float4 ps = make_float4(xv * a.x, xv * a.y, xv * a.z, xv * a.w);
    float4 pd = make_float4(xv * b.x, xv * b.y, xv * b.z, xv * b.w);
#pragma unroll
    for (int o = 1; o < 64; o <<= 1) {
        ps.x += __shfl_xor(ps.x, o); ps.y += __shfl_xor(ps.y, o);
        ps.z += __shfl_xor(ps.z, o); ps.w += __shfl_xor(ps.w, o);
        pd.x += __shfl_xor(pd.x, o); pd.y += __shfl_xor(pd.y, o);
        pd.z += __shfl_xor(pd.z, o); pd.w += __shfl_xor(pd.w, o);
    }
    if (lane == 0) {
        *(float4*)&es[n * 4] = ps;
        *(float4*)&ed[n * 4] = pd;
    }
}

// ---------- es/ed from K=256 input (h1) : wave per node ----------
__global__ void esed_h(const float* __restrict__ H, const float* __restrict__ wes,
                       const float* __restrict__ wed, float* __restrict__ es,
                       float* __restrict__ ed) {
    int gid = blockIdx.x * blockDim.x + threadIdx.x;
    int n = gid >> 6, lane = threadIdx.x & 63;
    if (n >= N_NODES) return;
    float4 xv = *(const float4*)&H[(size_t)n * 256 + lane * 4];
    float xs[4] = {xv.x, xv.y, xv.z, xv.w};
    float4 ps = make_float4(0.f, 0.f, 0.f, 0.f);
    float4 pd = make_float4(0.f, 0.f, 0.f, 0.f);
#pragma unroll
    for (int r = 0; r < 4; r++) {
        int c = lane * 4 + r;
        float4 a = *(const float4*)&wes[c * 4];
        float4 b = *(const float4*)&wed[c * 4];
        ps.x += xs[r] * a.x; ps.y += xs[r] * a.y; ps.z += xs[r] * a.z; ps.w += xs[r] * a.w;
        pd.x += xs[r] * b.x; pd.y += xs[r] * b.y; pd.z += xs[r] * b.z; pd.w += xs[r] * b.w;
    }
#pragma unroll
    for (int o = 1; o < 64; o <<= 1) {
        ps.x += __shfl_xor(ps.x, o); ps.y += __shfl_xor(ps.y, o);
        ps.z += __shfl_xor(ps.z, o); ps.w += __shfl_xor(ps.w, o);
        pd.x += __shfl_xor(pd.x, o); pd.y += __shfl_xor(pd.y, o);
        pd.z += __shfl_xor(pd.z, o); pd.w += __shfl_xor(pd.w, o);
    }
    if (lane == 0) {
        *(float4*)&es[n * 4] = ps;
        *(float4*)&ed[n * 4] = pd;
    }
}

// ---------- GAT1 fused softmax + x-aggregation: wave per node ----------
// aggx[n,h,c] = (1/sum_h) * sum_e exp(leaky(es[src]+ed[n]))_h * x[src,c]
__global__ __launch_bounds__(256)
void gat1_fused(const int* __restrict__ off, const int* __restrict__ csr_src,
                const float* __restrict__ es, const float* __restrict__ ed,
                const float* __restrict__ x, float* __restrict__ aggx,
                float* __restrict__ alpha_fb) {
    __shared__ float elds[4][CAP * 4];
    int wav = threadIdx.x >> 6, lane = threadIdx.x & 63;
    int n = blockIdx.x * 4 + wav;
    bool active = n < N_NODES;
    int p0 = 0, p1 = 0;
    float4 ed4 = make_float4(0.f, 0.f, 0.f, 0.f);
    if (active) { p0 = off[n]; p1 = off[n + 1]; ed4 = *(const float4*)&ed[n * 4]; }
    float4 sum = make_float4(0.f, 0.f, 0.f, 0.f);
    for (int p = p0 + lane; p < p1; p += 64) {
        int s = csr_src[p];
        float4 e4 = *(const float4*)&es[s * 4];
        e4.x += ed4.x; e4.y += ed4.y; e4.z += ed4.z; e4.w += ed4.w;
        e4.x = e4.x > 0.f ? e4.x : 0.2f * e4.x;
        e4.y = e4.y > 0.f ? e4.y : 0.2f * e4.y;
        e4.z = e4.z > 0.f ? e4.z : 0.2f * e4.z;
        e4.w = e4.w > 0.f ? e4.w : 0.2f * e4.w;
        e4.x = __expf(e4.x); e4.y = __expf(e4.y); e4.z = __expf(e4.z); e4.w = __expf(e4.w);
        int q = p - p0;
        if (q < CAP) *(float4*)&elds[wav][q * 4] = e4;
        else         *(float4*)&alpha_fb[(size_t)p * 4] = e4;
        sum.x += e4.x; sum.y += e4.y; sum.z += e4.z; sum.w += e4.w;
    }
#pragma unroll
    for (int o = 1; o < 64; o <<= 1) {
        sum.x += __shfl_xor(sum.x, o); sum.y += __shfl_xor(sum.y, o);
        sum.z += __shfl_xor(sum.z, o); sum.w += __shfl_xor(sum.w, o);
    }
    float4 rs;
    rs.x = sum.x > 0.f ? 1.f / sum.x : 0.f;
    rs.y = sum.y > 0.f ? 1.f / sum.y : 0.f;
    rs.z = sum.z > 0.f ? 1.f / sum.z : 0.f;
    rs.w = sum.w > 0.f ? 1.f / sum.w : 0.f;
    __syncthreads();
    if (!active) return;
    float4 acc = make_float4(0.f, 0.f, 0.f, 0.f);
    for (int p = p0; p < p1; p++) {
        int s = csr_src[p];
        int q = p - p0;
        float4 e4 = (q < CAP) ? *(const float4*)&elds[wav][q * 4]
                              : *(const float4*)&alpha_fb[(size_t)p * 4];
        float xv = x[(size_t)s * 64 + lane];
        acc.x += e4.x * xv; acc.y += e4.y * xv; acc.z += e4.z * xv; acc.w += e4.w * xv;
    }
    acc.x *= rs.x; acc.y *= rs.y; acc.z *= rs.z; acc.w *= rs.w;
    aggx[(size_t)n * 256 +   0 + lane] = acc.x;
    aggx[(size_t)n * 256 +  64 + lane] = acc.y;
    aggx[(size_t)n * 256 + 128 + lane] = acc.z;
    aggx[(size_t)n * 256 + 192 + lane] = acc.w;
}

// ---------- GAT2 fused softmax + h2-aggregation + bias + relu: wave per node ----------
__global__ __launch_bounds__(256)
void gat2_fused(const int* __restrict__ off, const int* __restrict__ csr_src,
                const float* __restrict__ es, const float* __restrict__ ed,
                const float* __restrict__ H2, const float* __restrict__ bias,
                float* __restrict__ out, float* __restrict__ alpha_fb) {
    __shared__ float elds[4][CAP * 4];
    int wav = threadIdx.x >> 6, lane = threadIdx.x & 63;
    int n = blockIdx.x * 4 + wav;
    bool active = n < N_NODES;
    int p0 = 0, p1 = 0;
    float4 ed4 = make_float4(0.f, 0.f, 0.f, 0.f);
    if (active) { p0 = off[n]; p1 = off[n + 1]; ed4 = *(const float4*)&ed[n * 4]; }
    float4 sum = make_float4(0.f, 0.f, 0.f, 0.f);
    for (int p = p0 + lane; p < p1; p += 64) {
        int s = csr_src[p];
        float4 e4 = *(const float4*)&es[s * 4];
        e4.x += ed4.x; e4.y += ed4.y; e4.z += ed4.z; e4.w += ed4.w;
        e4.x = e4.x > 0.f ? e4.x : 0.2f * e4.x;
        e4.y = e4.y > 0.f ? e4.y : 0.2f * e4.y;
        e4.z = e4.z > 0.f ? e4.z : 0.2f * e4.z;
        e4.w = e4.w > 0.f ? e4.w : 0.2f * e4.w;
        e4.x = __expf(e4.x); e4.y = __expf(e4.y); e4.z = __expf(e4.z); e4.w = __expf(e4.w);
        int q = p - p0;
        if (q < CAP) *(float4*)&elds[wav][q * 4] = e4;
        else         *(float4*)&alpha_fb[(size_t)p * 4] = e4;
        sum.x += e4.x; sum.y += e4.y; sum.z += e4.z; sum.w += e4.w;
    }
#pragma unroll
    for (int o = 1; o < 64; o <<= 1) {
        sum.x += __shfl_xor(sum.x, o); sum.y += __shfl_xor(sum.y, o);
        sum.z += __shfl_xor(sum.z, o); sum.w += __shfl_xor(sum.w, o);
    }
    int h = lane >> 4;
    float sh = (h == 0) ? sum.x : (h == 1) ? sum.y : (h == 2) ? sum.z : sum.w;
    float rsh = sh > 0.f ? 1.f / sh : 0.f;
    __syncthreads();
    if (!active) return;
    float4 acc = make_float4(0.f, 0.f, 0.f, 0.f);
    for (int p = p0; p < p1; p++) {
        int s = csr_src[p];
        int q = p - p0;
        float4 e4 = (q < CAP) ? *(const float4*)&elds[wav][q * 4]
                              : *(const float4*)&alpha_fb[(size_t)p * 4];
        float al = (h == 0) ? e4.x : (h == 1) ? e4.y : (h == 2) ? e4.z : e4.w;
        float4 v = *(const float4*)&H2[(size_t)s * 256 + lane * 4];
        acc.x += al * v.x; acc.y += al * v.y; acc.z += al * v.z; acc.w += al * v.w;
    }
    float4 bb = *(const float4*)&bias[lane * 4];
    acc.x = fmaxf(acc.x * rsh + bb.x, 0.f);
    acc.y = fmaxf(acc.y * rsh + bb.y, 0.f);
    acc.z = fmaxf(acc.z * rsh + bb.z, 0.f);
    acc.w = fmaxf(acc.w * rsh + bb.w, 0.f);
    *(float4*)&out[(size_t)n * 256 + lane * 4] = acc;
}

// ---------- label prop step: wave per node, fused combine + clamp ----------
__global__ void lp_csr(const int* __restrict__ off, const int* __restrict__ csr_src,
                       const float* __restrict__ wnorm, const float* __restrict__ in,
                       const float* __restrict__ res, float* __restrict__ out) {
    int gid = blockIdx.x * blockDim.x + threadIdx.x;
    int n = gid >> 6, lane = threadIdx.x & 63;
    if (n >= N_NODES) return;
    int p0 = off[n], p1 = off[n + 1];
    float4 acc = make_float4(0.f, 0.f, 0.f, 0.f);
    for (int p = p0; p < p1; p++) {
        int s = csr_src[p];
        float nr = wnorm[p];
        float4 v = *(const float4*)&in[(size_t)s * 256 + lane * 4];
        acc.x += v.x * nr; acc.y += v.y * nr; acc.z += v.z * nr; acc.w += v.w * nr;
    }
    float4 r = *(const float4*)&res[(size_t)n * 256 + lane * 4];
    acc.x = fminf(fmaxf(0.5f * acc.x + 0.5f * r.x, 0.f), 1.f);
    acc.y = fminf(fmaxf(0.5f * acc.y + 0.5f * r.y, 0.f), 1.f);
    acc.z = fminf(fmaxf(0.5f * acc.z + 0.5f * r.z, 0.f), 1.f);
    acc.w = fminf(fmaxf(0.5f * acc.w + 0.5f * r.w, 0.f), 1.f);
    *(float4*)&out[(size_t)n * 256 + lane * 4] = acc;
}

// ---------- pooling ----------
__global__ void bounds_kernel(const int* __restrict__ batch, int* __restrict__ gstart) {
    int n = blockIdx.x * blockDim.x + threadIdx.x;
    if (n >= N_NODES) return;
    int b = batch[n];
    int prev = (n == 0) ? -1 : batch[n - 1];
    for (int g = prev + 1; g <= b; g++) gstart[g] = n;
    if (n == N_NODES - 1)
        for (int g = b + 1; g <= N_GRAPHS; g++) gstart[g] = N_NODES;
}
// grid (N_GRAPHS, 4): quarter-segment partial sums -> atomicAdd into psum
__global__ void pool_partial(const float* __restrict__ buf, const int* __restrict__ gstart,
                             float* __restrict__ psum, int C, int colOff) {
    int g = blockIdx.x, q = blockIdx.y;
    int n0 = gstart[g], n1 = gstart[g + 1];
    int len = n1 - n0;
    int ns = n0 + (len * q) / 4, ne = n0 + (len * (q + 1)) / 4;
    int cp = threadIdx.x % C;
    int np = threadIdx.x / C;
    int NP = 256 / C;
    float s = 0.f;
    for (int n = ns + np; n < ne; n += NP) s += buf[(size_t)n * C + cp];
    atomicAdd(&psum[g * JK + colOff + cp], s);
}
__global__ void gmean_kernel(const float* __restrict__ psum, const int* __restrict__ gstart,
                             float* __restrict__ g) {
    int i = blockIdx.x * blockDim.x + threadIdx.x;
    if (i >= N_GRAPHS * JK) return;
    int gi = i / JK;
    int len = gstart[gi + 1] - gstart[gi];
    g[i] = psum[i] / (float)(len > 1 ? len : 1);
}

// ---------- small dense layers ----------
__global__ void dense_kernel(const float* __restrict__ in, const float* __restrict__ W,
                             const float* __restrict__ b, float* __restrict__ out,
                             int G, int K, int M, int in_stride, int out_stride, int do_relu) {
    int i = blockIdx.x * blockDim.x + threadIdx.x;
    if (i >= G * M) return;
    int g = i / M, m = i - g * M;
    float acc = b[m];
    for (int k = 0; k < K; k++) acc += in[g * in_stride + k] * W[k * M + m];
    if (do_relu) acc = acc > 0.f ? acc : 0.f;
    out[g * out_stride + m] = acc;
}

// ---------- launch ----------
extern "C" void kernel_launch(void* const* d_in, const int* in_sizes, int n_in,
                              void* d_out, int out_size, void* d_ws, size_t ws_size,
                              hipStream_t stream) {
    const float* x     = (const float*)d_in[0];
    const int*   ei    = (const int*)d_in[1];
    const int*   batch = (const int*)d_in[2];
    const float* clin  = (const float*)d_in[3];
    const float* W1  = (const float*)d_in[4];
    const float* a1s = (const float*)d_in[5];
    const float* a1d = (const float*)d_in[6];
    const float* b1  = (const float*)d_in[7];
    const float* W2  = (const float*)d_in[8];
    const float* a2s = (const float*)d_in[9];
    const float* a2d = (const float*)d_in[10];
    const float* b2  = (const float*)d_in[11];
    const float* pp_w1 = (const float*)d_in[12];
    const float* pp_b1 = (const float*)d_in[13];
    const float* pp_w2 = (const float*)d_in[14];
    const float* pp_b2 = (const float*)d_in[15];
    const float* cl_w1 = (const float*)d_in[16];
    const float* cl_b1 = (const float*)d_in[17];
    const float* cl_w2 = (const float*)d_in[18];
    const float* cl_b2 = (const float*)d_in[19];
    const float* h_w1  = (const float*)d_in[20];
    const float* h_b1  = (const float*)d_in[21];
    const float* h_w2  = (const float*)d_in[22];
    const float* h_b2  = (const float*)d_in[23];
    const float* h_w3  = (const float*)d_in[24];
    const float* h_b3  = (const float*)d_in[25];

    const int* src = ei;
    const int* dst = ei + N_EDGES;

    char* p = (char*)d_ws;
    auto carve = [&](size_t bytes) -> char* {
        char* r = p;
        p += (bytes + 255) & ~(size_t)255;
        return r;
    };
    const size_t NB = (size_t)N_NODES * 256 * 4;
    float* bufA = (float*)carve(NB);
    float* bufB = (float*)carve(NB);
    float* bufC = (float*)carve(NB);
    float* alpha_fb  = (float*)carve((size_t)N_EDGES * 4 * 4);  // overflow fallback (deg>CAP)
    int*   csr_src   = (int*)carve((size_t)N_EDGES * 4);
    float* wnorm     = (float*)carve((size_t)N_EDGES * 4);
    int*   off       = (int*)carve((size_t)(N_NODES + 1) * 4);
    int*   deg       = (int*)carve((size_t)N_NODES * 4);
    int*   cursor    = (int*)carve((size_t)N_NODES * 4);
    float* dis       = (float*)carve((size_t)N_NODES * 4);
    float* es        = (float*)carve((size_t)N_NODES * 4 * 4);
    float* ed        = (float*)carve((size_t)N_NODES * 4 * 4);
    float* wes1      = (float*)carve((size_t)64 * 4 * 4);
    float* wed1      = (float*)carve((size_t)64 * 4 * 4);
    float* wes2      = (float*)carve((size_t)256 * 4 * 4);
    float* wed2      = (float*)carve((size_t)256 * 4 * 4);
    int*   gstart    = (int*)carve((size_t)(N_GRAPHS + 1) * 4);
    float* psum      = (float*)carve((size_t)N_GRAPHS * JK * 4);
    float* gbuf      = (float*)carve((size_t)N_GRAPHS * JK * 4);
    float* t1        = (float*)carve((size_t)N_GRAPHS * 256 * 4);
    float* zbuf      = (float*)carve((size_t)N_GRAPHS * 160 * 4);
    float* t2        = (float*)carve((size_t)N_GRAPHS * 64 * 4);
    float* t3        = (float*)carve((size_t)N_GRAPHS * 64 * 4);
    float* t4        = (float*)carve((size_t)N_GRAPHS * 32 * 4);

    const int TB = 256;
    const int gN     = (N_NODES + TB - 1) / TB;
    const int gE     = (N_EDGES + TB - 1) / TB;
    const int gNwave = (N_NODES * 64 + TB - 1) / TB;   // wave per node
    const int gFuse  = (N_NODES + 3) / 4;              // 4 waves per block
    const int gRow   = (N_NODES + 63) / 64;            // GEMM row tiles

    // ---- CSR + degree + pooling bounds + weight precontractions ----
    hipMemsetAsync(deg, 0, (size_t)N_NODES * 4, stream);
    hipMemsetAsync(cursor, 0, (size_t)N_NODES * 4, stream);
    hipMemsetAsync(psum, 0, (size_t)N_GRAPHS * JK * 4, stream);
    deg_kernel<<<gE, TB, 0, stream>>>(dst, deg);
    dis_kernel<<<gN, TB, 0, stream>>>(deg, dis);
    scan_kernel<<<1, 1024, 0, stream>>>(deg, off);
    csr_fill<<<gE, TB, 0, stream>>>(src, dst, off, cursor, dis, csr_src, wnorm);
    bounds_kernel<<<gN, TB, 0, stream>>>(batch, gstart);
    prep_w<<<1, 256, 0, stream>>>(W1, a1s, a1d, wes1, wed1, 64);
    prep_w<<<4, 256, 0, stream>>>(W2, a2s, a2d, wes2, wed2, 256);

    // ---- GAT layer 1 (aggregate x, then block-diag per-head GEMM) ----
    esed_x<<<gNwave, TB, 0, stream>>>(x, wes1, wed1, es, ed);
    gat1_fused<<<gFuse, TB, 0, stream>>>(off, csr_src, es, ed, x, bufA, alpha_fb);
    gemm_tile<64><<<dim3(gRow, 4), 256, 0, stream>>>(bufA, 256, W1, 256, bufC, 256,
                                                     N_NODES, 64, b1, 1, 64);   // bufC = h1a

    // ---- label prop 1 ----
    lp_csr<<<gNwave, TB, 0, stream>>>(off, csr_src, wnorm, bufC, bufC, bufB);
    lp_csr<<<gNwave, TB, 0, stream>>>(off, csr_src, wnorm, bufB, bufC, bufA);  // bufA = h1

    pool_partial<<<dim3(N_GRAPHS, 4), TB, 0, stream>>>(bufA, gstart, psum, 256, 64);

    // ---- GAT layer 2 ----
    gemm_tile<256><<<dim3(gRow, 1), 256, 0, stream>>>(bufA, 256, W2, 256, bufB, 256,
                                                      N_NODES, 256, nullptr, 0, 0); // bufB = h2
    esed_h<<<gNwave, TB, 0, stream>>>(bufA, wes2, wed2, es, ed);
    gat2_fused<<<gFuse, TB, 0, stream>>>(off, csr_src, es, ed, bufB, b2, bufC, alpha_fb); // bufC = h2a

    // ---- label prop 2 ----
    lp_csr<<<gNwave, TB, 0, stream>>>(off, csr_src, wnorm, bufC, bufC, bufB);
    lp_csr<<<gNwave, TB, 0, stream>>>(off, csr_src, wnorm, bufB, bufC, bufA);  // bufA = h2_final

    // ---- pooling (x, h2) + mean ----
    pool_partial<<<dim3(N_GRAPHS, 4), TB, 0, stream>>>(x, gstart, psum, 64, 0);
    pool_partial<<<dim3(N_GRAPHS, 4), TB, 0, stream>>>(bufA, gstart, psum, 256, 320);
    gmean_kernel<<<(N_GRAPHS * JK + TB - 1) / TB, TB, 0, stream>>>(psum, gstart, gbuf);

    // ---- MLP head ----
    dense_kernel<<<(N_GRAPHS * 256 + TB - 1) / TB, TB, 0, stream>>>(gbuf, pp_w1, pp_b1, t1,
        N_GRAPHS, JK, 256, JK, 256, 1);
    dense_kernel<<<(N_GRAPHS * 128 + TB - 1) / TB, TB, 0, stream>>>(t1, pp_w2, pp_b2, zbuf,
        N_GRAPHS, 256, 128, 256, 160, 0);
    dense_kernel<<<(N_GRAPHS * 64 + TB - 1) / TB, TB, 0, stream>>>(clin, cl_w1, cl_b1, t2,
        N_GRAPHS, 32, 64, 32, 64, 1);
    dense_kernel<<<(N_GRAPHS * 32 + TB - 1) / TB, TB, 0, stream>>>(t2, cl_w2, cl_b2, zbuf + 128,
        N_GRAPHS, 64, 32, 64, 160, 0);
    dense_kernel<<<(N_GRAPHS * 64 + TB - 1) / TB, TB, 0, stream>>>(zbuf, h_w1, h_b1, t3,
        N_GRAPHS, 160, 64, 160, 64, 1);
    dense_kernel<<<(N_GRAPHS * 32 + TB - 1) / TB, TB, 0, stream>>>(t3, h_w2, h_b2, t4,
        N_GRAPHS, 64, 32, 64, 32, 1);
    dense_kernel<<<(N_GRAPHS * 2 + TB - 1) / TB, TB, 0, stream>>>(t4, h_w3, h_b3, (float*)d_out,
        N_GRAPHS, 32, 2, 32, 2, 0);
}

// Round 4
// 1365.209 us; speedup vs baseline: 12.7898x; 1.2560x over previous
//
#include <hip/hip_runtime.h>

#define N_NODES 50000
#define N_EDGES 800000
#define N_GRAPHS 128
#define JK 576              // 64 + 256 + 256
#define CAP 192             // max cached in-degree per node (Poisson(16); max~45)

// ---------- tiled GEMM: C[M x NC] = A[M x K] @ B[K x NC] ----------
// 64-row x NC-col block tile, 256 threads, each thread 4 x (NC/16) outputs.
// blockIdx.y * head_stride is added to A,B,C,bias base (block-diag per-head GEMM).
template<int NC>
__global__ __launch_bounds__(256)
void gemm_tile(const float* __restrict__ A, int lda,
               const float* __restrict__ B, int ldb,
               float* __restrict__ C, int ldc,
               int M, int K,
               const float* __restrict__ bias, int do_relu, int head_stride) {
    __shared__ float As[16][68];       // [k][row], padded: b128-aligned, conflict-free
    __shared__ float Bs[16][NC];       // [k][col]
    const int off = blockIdx.y * head_stride;
    A += off; B += off; C += off;
    const float* bptr = bias ? bias + off : nullptr;
    const int m0 = blockIdx.x * 64;
    const int t  = threadIdx.x;
    const int tx = t & 15, ty = t >> 4;
    constexpr int CJ = NC / 64;        // float4 col-groups per thread
    float acc[4][CJ * 4];
#pragma unroll
    for (int r = 0; r < 4; r++)
#pragma unroll
        for (int j = 0; j < CJ * 4; j++) acc[r][j] = 0.f;

    const int sr = t >> 2;             // staging row 0..63
    const int sk = (t & 3) << 2;       // staging k 0,4,8,12

    for (int k0 = 0; k0 < K; k0 += 16) {
        float4 av4 = make_float4(0.f, 0.f, 0.f, 0.f);
        int gm = m0 + sr;
        if (gm < M) av4 = *(const float4*)&A[(size_t)gm * lda + k0 + sk];
        float4 bstg[CJ];
#pragma unroll
        for (int j = 0; j < CJ; j++)
            bstg[j] = *(const float4*)&B[(size_t)(k0 + ty) * ldb + tx * 4 + j * 64];
        __syncthreads();
        As[sk + 0][sr] = av4.x; As[sk + 1][sr] = av4.y;
        As[sk + 2][sr] = av4.z; As[sk + 3][sr] = av4.w;
#pragma unroll
        for (int j = 0; j < CJ; j++)
            *(float4*)&Bs[ty][tx * 4 + j * 64] = bstg[j];
        __syncthreads();
#pragma unroll
        for (int k = 0; k < 16; k++) {
            float4 a4 = *(const float4*)&As[k][ty * 4];
#pragma unroll
            for (int j = 0; j < CJ; j++) {
                float4 b4 = *(const float4*)&Bs[k][tx * 4 + j * 64];
                acc[0][j*4+0] += a4.x * b4.x; acc[0][j*4+1] += a4.x * b4.y;
                acc[0][j*4+2] += a4.x * b4.z; acc[0][j*4+3] += a4.x * b4.w;
                acc[1][j*4+0] += a4.y * b4.x; acc[1][j*4+1] += a4.y * b4.y;
                acc[1][j*4+2] += a4.y * b4.z; acc[1][j*4+3] += a4.y * b4.w;
                acc[2][j*4+0] += a4.z * b4.x; acc[2][j*4+1] += a4.z * b4.y;
                acc[2][j*4+2] += a4.z * b4.z; acc[2][j*4+3] += a4.z * b4.w;
                acc[3][j*4+0] += a4.w * b4.x; acc[3][j*4+1] += a4.w * b4.y;
                acc[3][j*4+2] += a4.w * b4.z; acc[3][j*4+3] += a4.w * b4.w;
            }
        }
    }
#pragma unroll
    for (int r = 0; r < 4; r++) {
        int row = m0 + ty * 4 + r;
        if (row >= M) continue;
#pragma unroll
        for (int j = 0; j < CJ; j++) {
            float4 o = make_float4(acc[r][j*4+0], acc[r][j*4+1], acc[r][j*4+2], acc[r][j*4+3]);
            if (bptr) {
                float4 bb = *(const float4*)&bptr[tx * 4 + j * 64];
                o.x += bb.x; o.y += bb.y; o.z += bb.z; o.w += bb.w;
            }
            if (do_relu) {
                o.x = fmaxf(o.x, 0.f); o.y = fmaxf(o.y, 0.f);
                o.z = fmaxf(o.z, 0.f); o.w = fmaxf(o.w, 0.f);
            }
            *(float4*)&C[(size_t)row * ldc + tx * 4 + j * 64] = o;
        }
    }
}

// ---------- CSR build ----------
__global__ void deg_kernel(const int* __restrict__ dst, int* __restrict__ deg) {
    int t = blockIdx.x * blockDim.x + threadIdx.x;
    if (t < N_EDGES) atomicAdd(&deg[dst[t]], 1);
}
__global__ void dis_kernel(const int* __restrict__ deg, float* __restrict__ dis) {
    int i = blockIdx.x * blockDim.x + threadIdx.x;
    if (i >= N_NODES) return;
    int d = deg[i];
    dis[i] = d > 0 ? rsqrtf((float)d) : 0.f;
}
__global__ __launch_bounds__(1024) void scan_kernel(const int* __restrict__ deg,
                                                    int* __restrict__ off) {
    __shared__ int part[1024];
    int t = threadIdx.x;
    const int CH = (N_NODES + 1023) / 1024;
    int base = t * CH;
    int s = 0;
    for (int i = 0; i < CH; i++) {
        int n = base + i;
        if (n < N_NODES) s += deg[n];
    }
    part[t] = s;
    __syncthreads();
    for (int o = 1; o < 1024; o <<= 1) {
        int v = (t >= o) ? part[t - o] : 0;
        __syncthreads();
        part[t] += v;
        __syncthreads();
    }
    int run = (t == 0) ? 0 : part[t - 1];
    for (int i = 0; i < CH; i++) {
        int n = base + i;
        if (n < N_NODES) { off[n] = run; run += deg[n]; }
    }
    if (t == 1023) off[N_NODES] = run;
}
// fill CSR src list + per-edge label-prop norm (dis[src]*dis[dst]) in CSR order
__global__ void csr_fill(const int* __restrict__ src, const int* __restrict__ dst,
                         const int* __restrict__ off, int* __restrict__ cursor,
                         const float* __restrict__ dis, int* __restrict__ csr_src,
                         float* __restrict__ wnorm) {
    int e = blockIdx.x * blockDim.x + threadIdx.x;
    if (e >= N_EDGES) return;
    int s = src[e], d = dst[e];
    int pos = off[d] + atomicAdd(&cursor[d], 1);
    csr_src[pos] = s;
    wnorm[pos] = dis[s] * dis[d];
}

// ---------- precontract W @ a  ->  w_es[c,h], w_ed[c,h] (c = K rows of W) ----------
__global__ void prep_w(const float* __restrict__ W, const float* __restrict__ as_,
                       const float* __restrict__ ad_, float* __restrict__ wes,
                       float* __restrict__ wed, int K) {
    int t = blockIdx.x * blockDim.x + threadIdx.x;
    if (t >= K * 4) return;
    int c = t >> 2, h = t & 3;
    float se = 0.f, sd = 0.f;
    for (int j = 0; j < 64; j++) {
        float w = W[(size_t)c * 256 + h * 64 + j];
        se += w * as_[h * 64 + j];
        sd += w * ad_[h * 64 + j];
    }
    wes[c * 4 + h] = se;
    wed[c * 4 + h] = sd;
}

// ---------- es/ed from K=64 input (x) : wave per node ----------
__global__ void esed_x(const float* __restrict__ X, const float* __restrict__ wes,
                       const float* __restrict__ wed, float* __restrict__ es,
                       float* __restrict__ ed) {
    int gid = blockIdx.x * blockDim.x + threadIdx.x;
    int n = gid >> 6, lane = threadIdx.x & 63;
    if (n >= N_NODES) return;
    float xv = X[(size_t)n * 64 + lane];
    float4 a = *(const float4*)&wes[lane * 4];
    float4 b = *(const float4*)&wed[lane * 4];
    float4 ps = make_float4(xv * a.x, xv * a.y, xv * a.z, xv * a.w);
    float4 pd = make_float4(xv * b.x, xv * b.y, xv * b.z, xv * b.w);
#pragma unroll
    for (int o = 1; o < 64; o <<= 1) {
        ps.x += __shfl_xor(ps.x, o); ps.y += __shfl_xor(ps.y, o);
        ps.z += __shfl_xor(ps.z, o); ps.w += __shfl_xor(ps.w, o);
        pd.x += __shfl_xor(pd.x, o); pd.y += __shfl_xor(pd.y, o);
        pd.z += __shfl_xor(pd.z, o); pd.w += __shfl_xor(pd.w, o);
    }
    if (lane == 0) {
        *(float4*)&es[n * 4] = ps;
        *(float4*)&ed[n * 4] = pd;
    }
}

// ---------- es/ed from K=256 input (h1) : wave per node ----------
__global__ void esed_h(const float* __restrict__ H, const float* __restrict__ wes,
                       const float* __restrict__ wed, float* __restrict__ es,
                       float* __restrict__ ed) {
    int gid = blockIdx.x * blockDim.x + threadIdx.x;
    int n = gid >> 6, lane = threadIdx.x & 63;
    if (n >= N_NODES) return;
    float4 xv = *(const float4*)&H[(size_t)n * 256 + lane * 4];
    float xs[4] = {xv.x, xv.y, xv.z, xv.w};
    float4 ps = make_float4(0.f, 0.f, 0.f, 0.f);
    float4 pd = make_float4(0.f, 0.f, 0.f, 0.f);
#pragma unroll
    for (int r = 0; r < 4; r++) {
        int c = lane * 4 + r;
        float4 a = *(const float4*)&wes[c * 4];
        float4 b = *(const float4*)&wed[c * 4];
        ps.x += xs[r] * a.x; ps.y += xs[r] * a.y; ps.z += xs[r] * a.z; ps.w += xs[r] * a.w;
        pd.x += xs[r] * b.x; pd.y += xs[r] * b.y; pd.z += xs[r] * b.z; pd.w += xs[r] * b.w;
    }
#pragma unroll
    for (int o = 1; o < 64; o <<= 1) {
        ps.x += __shfl_xor(ps.x, o); ps.y += __shfl_xor(ps.y, o);
        ps.z += __shfl_xor(ps.z, o); ps.w += __shfl_xor(ps.w, o);
        pd.x += __shfl_xor(pd.x, o); pd.y += __shfl_xor(pd.y, o);
        pd.w += __shfl_xor(pd.w, o); pd.z += __shfl_xor(pd.z, o);
    }
    if (lane == 0) {
        *(float4*)&es[n * 4] = ps;
        *(float4*)&ed[n * 4] = pd;
    }
}

// ---------- GAT1 fused softmax + x-aggregation: wave per node ----------
__global__ __launch_bounds__(256)
void gat1_fused(const int* __restrict__ off, const int* __restrict__ csr_src,
                const float* __restrict__ es, const float* __restrict__ ed,
                const float* __restrict__ x, float* __restrict__ aggx,
                float* __restrict__ alpha_fb) {
    __shared__ float elds[4][CAP * 4];
    int wav = threadIdx.x >> 6, lane = threadIdx.x & 63;
    int n = blockIdx.x * 4 + wav;
    bool active = n < N_NODES;
    int p0 = 0, p1 = 0;
    float4 ed4 = make_float4(0.f, 0.f, 0.f, 0.f);
    if (active) { p0 = off[n]; p1 = off[n + 1]; ed4 = *(const float4*)&ed[n * 4]; }
    float4 sum = make_float4(0.f, 0.f, 0.f, 0.f);
    for (int p = p0 + lane; p < p1; p += 64) {
        int s = csr_src[p];
        float4 e4 = *(const float4*)&es[s * 4];
        e4.x += ed4.x; e4.y += ed4.y; e4.z += ed4.z; e4.w += ed4.w;
        e4.x = e4.x > 0.f ? e4.x : 0.2f * e4.x;
        e4.y = e4.y > 0.f ? e4.y : 0.2f * e4.y;
        e4.z = e4.z > 0.f ? e4.z : 0.2f * e4.z;
        e4.w = e4.w > 0.f ? e4.w : 0.2f * e4.w;
        e4.x = __expf(e4.x); e4.y = __expf(e4.y); e4.z = __expf(e4.z); e4.w = __expf(e4.w);
        int q = p - p0;
        if (q < CAP) *(float4*)&elds[wav][q * 4] = e4;
        else         *(float4*)&alpha_fb[(size_t)p * 4] = e4;
        sum.x += e4.x; sum.y += e4.y; sum.z += e4.z; sum.w += e4.w;
    }
#pragma unroll
    for (int o = 1; o < 64; o <<= 1) {
        sum.x += __shfl_xor(sum.x, o); sum.y += __shfl_xor(sum.y, o);
        sum.z += __shfl_xor(sum.z, o); sum.w += __shfl_xor(sum.w, o);
    }
    float4 rs;
    rs.x = sum.x > 0.f ? 1.f / sum.x : 0.f;
    rs.y = sum.y > 0.f ? 1.f / sum.y : 0.f;
    rs.z = sum.z > 0.f ? 1.f / sum.z : 0.f;
    rs.w = sum.w > 0.f ? 1.f / sum.w : 0.f;
    __syncthreads();
    if (!active) return;
    float4 acc = make_float4(0.f, 0.f, 0.f, 0.f);
    for (int p = p0; p < p1; p++) {
        int s = csr_src[p];
        int q = p - p0;
        float4 e4 = (q < CAP) ? *(const float4*)&elds[wav][q * 4]
                              : *(const float4*)&alpha_fb[(size_t)p * 4];
        float xv = x[(size_t)s * 64 + lane];
        acc.x += e4.x * xv; acc.y += e4.y * xv; acc.z += e4.z * xv; acc.w += e4.w * xv;
    }
    acc.x *= rs.x; acc.y *= rs.y; acc.z *= rs.z; acc.w *= rs.w;
    aggx[(size_t)n * 256 +   0 + lane] = acc.x;
    aggx[(size_t)n * 256 +  64 + lane] = acc.y;
    aggx[(size_t)n * 256 + 128 + lane] = acc.z;
    aggx[(size_t)n * 256 + 192 + lane] = acc.w;
}

// ---------- GAT2 fused softmax + h2-aggregation + bias + relu: wave per node ----------
__global__ __launch_bounds__(256)
void gat2_fused(const int* __restrict__ off, const int* __restrict__ csr_src,
                const float* __restrict__ es, const float* __restrict__ ed,
                const float* __restrict__ H2, const float* __restrict__ bias,
                float* __restrict__ out, float* __restrict__ alpha_fb) {
    __shared__ float elds[4][CAP * 4];
    int wav = threadIdx.x >> 6, lane = threadIdx.x & 63;
    int n = blockIdx.x * 4 + wav;
    bool active = n < N_NODES;
    int p0 = 0, p1 = 0;
    float4 ed4 = make_float4(0.f, 0.f, 0.f, 0.f);
    if (active) { p0 = off[n]; p1 = off[n + 1]; ed4 = *(const float4*)&ed[n * 4]; }
    float4 sum = make_float4(0.f, 0.f, 0.f, 0.f);
    for (int p = p0 + lane; p < p1; p += 64) {
        int s = csr_src[p];
        float4 e4 = *(const float4*)&es[s * 4];
        e4.x += ed4.x; e4.y += ed4.y; e4.z += ed4.z; e4.w += ed4.w;
        e4.x = e4.x > 0.f ? e4.x : 0.2f * e4.x;
        e4.y = e4.y > 0.f ? e4.y : 0.2f * e4.y;
        e4.z = e4.z > 0.f ? e4.z : 0.2f * e4.z;
        e4.w = e4.w > 0.f ? e4.w : 0.2f * e4.w;
        e4.x = __expf(e4.x); e4.y = __expf(e4.y); e4.z = __expf(e4.z); e4.w = __expf(e4.w);
        int q = p - p0;
        if (q < CAP) *(float4*)&elds[wav][q * 4] = e4;
        else         *(float4*)&alpha_fb[(size_t)p * 4] = e4;
        sum.x += e4.x; sum.y += e4.y; sum.z += e4.z; sum.w += e4.w;
    }
#pragma unroll
    for (int o = 1; o < 64; o <<= 1) {
        sum.x += __shfl_xor(sum.x, o); sum.y += __shfl_xor(sum.y, o);
        sum.z += __shfl_xor(sum.z, o); sum.w += __shfl_xor(sum.w, o);
    }
    int h = lane >> 4;
    float sh = (h == 0) ? sum.x : (h == 1) ? sum.y : (h == 2) ? sum.z : sum.w;
    float rsh = sh > 0.f ? 1.f / sh : 0.f;
    __syncthreads();
    if (!active) return;
    float4 acc = make_float4(0.f, 0.f, 0.f, 0.f);
    for (int p = p0; p < p1; p++) {
        int s = csr_src[p];
        int q = p - p0;
        float4 e4 = (q < CAP) ? *(const float4*)&elds[wav][q * 4]
                              : *(const float4*)&alpha_fb[(size_t)p * 4];
        float al = (h == 0) ? e4.x : (h == 1) ? e4.y : (h == 2) ? e4.z : e4.w;
        float4 v = *(const float4*)&H2[(size_t)s * 256 + lane * 4];
        acc.x += al * v.x; acc.y += al * v.y; acc.z += al * v.z; acc.w += al * v.w;
    }
    float4 bb = *(const float4*)&bias[lane * 4];
    acc.x = fmaxf(acc.x * rsh + bb.x, 0.f);
    acc.y = fmaxf(acc.y * rsh + bb.y, 0.f);
    acc.z = fmaxf(acc.z * rsh + bb.z, 0.f);
    acc.w = fmaxf(acc.w * rsh + bb.w, 0.f);
    *(float4*)&out[(size_t)n * 256 + lane * 4] = acc;
}

// ---------- label prop step: wave per node, fused combine + clamp ----------
__global__ void lp_csr(const int* __restrict__ off, const int* __restrict__ csr_src,
                       const float* __restrict__ wnorm, const float* __restrict__ in,
                       const float* __restrict__ res, float* __restrict__ out) {
    int gid = blockIdx.x * blockDim.x + threadIdx.x;
    int n = gid >> 6, lane = threadIdx.x & 63;
    if (n >= N_NODES) return;
    int p0 = off[n], p1 = off[n + 1];
    float4 acc = make_float4(0.f, 0.f, 0.f, 0.f);
    for (int p = p0; p < p1; p++) {
        int s = csr_src[p];
        float nr = wnorm[p];
        float4 v = *(const float4*)&in[(size_t)s * 256 + lane * 4];
        acc.x += v.x * nr; acc.y += v.y * nr; acc.z += v.z * nr; acc.w += v.w * nr;
    }
    float4 r = *(const float4*)&res[(size_t)n * 256 + lane * 4];
    acc.x = fminf(fmaxf(0.5f * acc.x + 0.5f * r.x, 0.f), 1.f);
    acc.y = fminf(fmaxf(0.5f * acc.y + 0.5f * r.y, 0.f), 1.f);
    acc.z = fminf(fmaxf(0.5f * acc.z + 0.5f * r.z, 0.f), 1.f);
    acc.w = fminf(fmaxf(0.5f * acc.w + 0.5f * r.w, 0.f), 1.f);
    *(float4*)&out[(size_t)n * 256 + lane * 4] = acc;
}

// ---------- pooling ----------
__global__ void bounds_kernel(const int* __restrict__ batch, int* __restrict__ gstart) {
    int n = blockIdx.x * blockDim.x + threadIdx.x;
    if (n >= N_NODES) return;
    int b = batch[n];
    int prev = (n == 0) ? -1 : batch[n - 1];
    for (int g = prev + 1; g <= b; g++) gstart[g] = n;
    if (n == N_NODES - 1)
        for (int g = b + 1; g <= N_GRAPHS; g++) gstart[g] = N_NODES;
}
// grid (N_GRAPHS, 4): quarter-segment partial sums -> atomicAdd into psum
__global__ void pool_partial(const float* __restrict__ buf, const int* __restrict__ gstart,
                             float* __restrict__ psum, int C, int colOff) {
    int g = blockIdx.x, q = blockIdx.y;
    int n0 = gstart[g], n1 = gstart[g + 1];
    int len = n1 - n0;
    int ns = n0 + (len * q) / 4, ne = n0 + (len * (q + 1)) / 4;
    int cp = threadIdx.x % C;
    int np = threadIdx.x / C;
    int NP = 256 / C;
    float s = 0.f;
    for (int n = ns + np; n < ne; n += NP) s += buf[(size_t)n * C + cp];
    atomicAdd(&psum[g * JK + colOff + cp], s);
}
__global__ void gmean_kernel(const float* __restrict__ psum, const int* __restrict__ gstart,
                             float* __restrict__ g) {
    int i = blockIdx.x * blockDim.x + threadIdx.x;
    if (i >= N_GRAPHS * JK) return;
    int gi = i / JK;
    int len = gstart[gi + 1] - gstart[gi];
    g[i] = psum[i] / (float)(len > 1 ? len : 1);
}

// ---------- MLP head, layer 1: [G,576] @ [576,256] + b, relu ----------
// grid (4, G), block = 64 (one wave). K-loop unrolled, input row in LDS.
__global__ __launch_bounds__(64)
void head_d1(const float* __restrict__ gbuf, const float* __restrict__ W,
             const float* __restrict__ bias, float* __restrict__ out) {
    __shared__ float zin[JK];
    int g = blockIdx.y, mc = blockIdx.x, lane = threadIdx.x;
    for (int k = lane; k < JK; k += 64) zin[k] = gbuf[g * JK + k];
    __syncthreads();
    int m = mc * 64 + lane;
    float acc = bias[m];
#pragma unroll 8
    for (int k = 0; k < JK; k++) acc += zin[k] * W[k * 256 + m];
    out[g * 256 + m] = fmaxf(acc, 0.f);
}

// ---------- MLP head, rest: fused d2 + clin-MLP + 3-layer head ----------
// block per graph, 256 threads, activations in LDS.
__global__ __launch_bounds__(256)
void head_rest(const float* __restrict__ t1, const float* __restrict__ clin,
               const float* __restrict__ pp_w2, const float* __restrict__ pp_b2,
               const float* __restrict__ cl_w1, const float* __restrict__ cl_b1,
               const float* __restrict__ cl_w2, const float* __restrict__ cl_b2,
               const float* __restrict__ h_w1, const float* __restrict__ h_b1,
               const float* __restrict__ h_w2, const float* __restrict__ h_b2,
               const float* __restrict__ h_w3, const float* __restrict__ h_b3,
               float* __restrict__ out) {
    __shared__ float z1[256];    // relu'd t1 row
    __shared__ float zcl[32];    // clin row
    __shared__ float zc[64];     // clin hidden
    __shared__ float z[160];     // concat v_graph(128) | v_clin(32)
    __shared__ float z3[64];
    __shared__ float z4[32];
    __shared__ float part[128];  // K-split partials for d2
    int g = blockIdx.x, t = threadIdx.x;
    z1[t] = t1[g * 256 + t];
    if (t < 32) zcl[t] = clin[g * 32 + t];
    __syncthreads();
    // d2: 128 outputs, K=256 split across 2 halves of the block (no relu)
    int m = t & 127, half = t >> 7;
    {
        float acc = 0.f;
        int k0 = half * 128;
#pragma unroll 8
        for (int k = k0; k < k0 + 128; k++) acc += z1[k] * pp_w2[k * 128 + m];
        if (half) part[m] = acc;
        __syncthreads();
        if (!half) z[m] = acc + part[m] + pp_b2[m];
    }
    // cl1: 64 outputs, K=32, relu
    if (t < 64) {
        float acc = cl_b1[t];
#pragma unroll
        for (int k = 0; k < 32; k++) acc += zcl[k] * cl_w1[k * 64 + t];
        zc[t] = fmaxf(acc, 0.f);
    }
    __syncthreads();
    // cl2: 32 outputs, K=64 (no relu)
    if (t < 32) {
        float acc = cl_b2[t];
#pragma unroll
        for (int k = 0; k < 64; k++) acc += zc[k] * cl_w2[k * 32 + t];
        z[128 + t] = acc;
    }
    __syncthreads();
    // h1: 64 outputs, K=160, relu
    if (t < 64) {
        float acc = h_b1[t];
#pragma unroll 8
        for (int k = 0; k < 160; k++) acc += z[k] * h_w1[k * 64 + t];
        z3[t] = fmaxf(acc, 0.f);
    }
    __syncthreads();
    // h2: 32 outputs, K=64, relu
    if (t < 32) {
        float acc = h_b2[t];
#pragma unroll
        for (int k = 0; k < 64; k++) acc += z3[k] * h_w2[k * 32 + t];
        z4[t] = fmaxf(acc, 0.f);
    }
    __syncthreads();
    // h3: 2 outputs, K=32
    if (t < 2) {
        float acc = h_b3[t];
#pragma unroll
        for (int k = 0; k < 32; k++) acc += z4[k] * h_w3[k * 2 + t];
        out[g * 2 + t] = acc;
    }
}

// ---------- launch ----------
extern "C" void kernel_launch(void* const* d_in, const int* in_sizes, int n_in,
                              void* d_out, int out_size, void* d_ws, size_t ws_size,
                              hipStream_t stream) {
    const float* x     = (const float*)d_in[0];
    const int*   ei    = (const int*)d_in[1];
    const int*   batch = (const int*)d_in[2];
    const float* clin  = (const float*)d_in[3];
    const float* W1  = (const float*)d_in[4];
    const float* a1s = (const float*)d_in[5];
    const float* a1d = (const float*)d_in[6];
    const float* b1  = (const float*)d_in[7];
    const float* W2  = (const float*)d_in[8];
    const float* a2s = (const float*)d_in[9];
    const float* a2d = (const float*)d_in[10];
    const float* b2  = (const float*)d_in[11];
    const float* pp_w1 = (const float*)d_in[12];
    const float* pp_b1 = (const float*)d_in[13];
    const float* pp_w2 = (const float*)d_in[14];
    const float* pp_b2 = (const float*)d_in[15];
    const float* cl_w1 = (const float*)d_in[16];
    const float* cl_b1 = (const float*)d_in[17];
    const float* cl_w2 = (const float*)d_in[18];
    const float* cl_b2 = (const float*)d_in[19];
    const float* h_w1  = (const float*)d_in[20];
    const float* h_b1  = (const float*)d_in[21];
    const float* h_w2  = (const float*)d_in[22];
    const float* h_b2  = (const float*)d_in[23];
    const float* h_w3  = (const float*)d_in[24];
    const float* h_b3  = (const float*)d_in[25];

    const int* src = ei;
    const int* dst = ei + N_EDGES;

    char* p = (char*)d_ws;
    auto carve = [&](size_t bytes) -> char* {
        char* r = p;
        p += (bytes + 255) & ~(size_t)255;
        return r;
    };
    const size_t NB = (size_t)N_NODES * 256 * 4;
    float* bufA = (float*)carve(NB);
    float* bufB = (float*)carve(NB);
    float* bufC = (float*)carve(NB);
    float* alpha_fb  = (float*)carve((size_t)N_EDGES * 4 * 4);  // overflow fallback (deg>CAP)
    int*   csr_src   = (int*)carve((size_t)N_EDGES * 4);
    float* wnorm     = (float*)carve((size_t)N_EDGES * 4);
    int*   off       = (int*)carve((size_t)(N_NODES + 1) * 4);
    int*   deg       = (int*)carve((size_t)N_NODES * 4);
    int*   cursor    = (int*)carve((size_t)N_NODES * 4);
    float* dis       = (float*)carve((size_t)N_NODES * 4);
    float* es        = (float*)carve((size_t)N_NODES * 4 * 4);
    float* ed        = (float*)carve((size_t)N_NODES * 4 * 4);
    float* wes1      = (float*)carve((size_t)64 * 4 * 4);
    float* wed1      = (float*)carve((size_t)64 * 4 * 4);
    float* wes2      = (float*)carve((size_t)256 * 4 * 4);
    float* wed2      = (float*)carve((size_t)256 * 4 * 4);
    int*   gstart    = (int*)carve((size_t)(N_GRAPHS + 1) * 4);
    float* psum      = (float*)carve((size_t)N_GRAPHS * JK * 4);
    float* gbuf      = (float*)carve((size_t)N_GRAPHS * JK * 4);
    float* t1        = (float*)carve((size_t)N_GRAPHS * 256 * 4);

    const int TB = 256;
    const int gN     = (N_NODES + TB - 1) / TB;
    const int gE     = (N_EDGES + TB - 1) / TB;
    const int gNwave = (N_NODES * 64 + TB - 1) / TB;   // wave per node
    const int gFuse  = (N_NODES + 3) / 4;              // 4 waves per block
    const int gRow   = (N_NODES + 63) / 64;            // GEMM row tiles

    // ---- CSR + degree + pooling bounds + weight precontractions ----
    hipMemsetAsync(deg, 0, (size_t)N_NODES * 4, stream);
    hipMemsetAsync(cursor, 0, (size_t)N_NODES * 4, stream);
    hipMemsetAsync(psum, 0, (size_t)N_GRAPHS * JK * 4, stream);
    deg_kernel<<<gE, TB, 0, stream>>>(dst, deg);
    dis_kernel<<<gN, TB, 0, stream>>>(deg, dis);
    scan_kernel<<<1, 1024, 0, stream>>>(deg, off);
    csr_fill<<<gE, TB, 0, stream>>>(src, dst, off, cursor, dis, csr_src, wnorm);
    bounds_kernel<<<gN, TB, 0, stream>>>(batch, gstart);
    prep_w<<<1, 256, 0, stream>>>(W1, a1s, a1d, wes1, wed1, 64);
    prep_w<<<4, 256, 0, stream>>>(W2, a2s, a2d, wes2, wed2, 256);

    // ---- GAT layer 1 (aggregate x, then block-diag per-head GEMM) ----
    esed_x<<<gNwave, TB, 0, stream>>>(x, wes1, wed1, es, ed);
    gat1_fused<<<gFuse, TB, 0, stream>>>(off, csr_src, es, ed, x, bufA, alpha_fb);
    gemm_tile<64><<<dim3(gRow, 4), 256, 0, stream>>>(bufA, 256, W1, 256, bufC, 256,
                                                     N_NODES, 64, b1, 1, 64);   // bufC = h1a

    // ---- label prop 1 ----
    lp_csr<<<gNwave, TB, 0, stream>>>(off, csr_src, wnorm, bufC, bufC, bufB);
    lp_csr<<<gNwave, TB, 0, stream>>>(off, csr_src, wnorm, bufB, bufC, bufA);  // bufA = h1

    pool_partial<<<dim3(N_GRAPHS, 4), TB, 0, stream>>>(bufA, gstart, psum, 256, 64);

    // ---- GAT layer 2 ----
    gemm_tile<256><<<dim3(gRow, 1), 256, 0, stream>>>(bufA, 256, W2, 256, bufB, 256,
                                                      N_NODES, 256, nullptr, 0, 0); // bufB = h2
    esed_h<<<gNwave, TB, 0, stream>>>(bufA, wes2, wed2, es, ed);
    gat2_fused<<<gFuse, TB, 0, stream>>>(off, csr_src, es, ed, bufB, b2, bufC, alpha_fb); // bufC = h2a

    // ---- label prop 2 ----
    lp_csr<<<gNwave, TB, 0, stream>>>(off, csr_src, wnorm, bufC, bufC, bufB);
    lp_csr<<<gNwave, TB, 0, stream>>>(off, csr_src, wnorm, bufB, bufC, bufA);  // bufA = h2_final

    // ---- pooling (x, h2) + mean ----
    pool_partial<<<dim3(N_GRAPHS, 4), TB, 0, stream>>>(x, gstart, psum, 64, 0);
    pool_partial<<<dim3(N_GRAPHS, 4), TB, 0, stream>>>(bufA, gstart, psum, 256, 320);
    gmean_kernel<<<(N_GRAPHS * JK + TB - 1) / TB, TB, 0, stream>>>(psum, gstart, gbuf);

    // ---- MLP head (2 kernels) ----
    head_d1<<<dim3(4, N_GRAPHS), 64, 0, stream>>>(gbuf, pp_w1, pp_b1, t1);
    head_rest<<<N_GRAPHS, 256, 0, stream>>>(t1, clin, pp_w2, pp_b2, cl_w1, cl_b1,
                                            cl_w2, cl_b2, h_w1, h_b1, h_w2, h_b2,
                                            h_w3, h_b3, (float*)d_out);
}

// Round 5
// 1233.936 us; speedup vs baseline: 14.1504x; 1.1064x over previous
//
#include <hip/hip_runtime.h>

#define N_NODES 50000
#define N_EDGES 800000
#define N_GRAPHS 128
#define JK 576              // 64 + 256 + 256
#define CAP 192             // max cached in-degree per node (Poisson(16); max~45)

// ---------- bf16 pack/unpack helpers ----------
__device__ __forceinline__ unsigned f2_to_bf2(float a, float b) {
    unsigned ua = __float_as_uint(a), ub = __float_as_uint(b);
    ua = (ua + 0x7fffu + ((ua >> 16) & 1u)) >> 16;       // RNE
    ub = (ub + 0x7fffu + ((ub >> 16) & 1u)) >> 16;
    return ua | (ub << 16);
}
__device__ __forceinline__ uint2 f4_to_bf4(float4 v) {
    return make_uint2(f2_to_bf2(v.x, v.y), f2_to_bf2(v.z, v.w));
}
__device__ __forceinline__ float4 bf4_to_f4(uint2 u) {
    float4 r;
    r.x = __uint_as_float(u.x << 16);
    r.y = __uint_as_float(u.x & 0xffff0000u);
    r.z = __uint_as_float(u.y << 16);
    r.w = __uint_as_float(u.y & 0xffff0000u);
    return r;
}

// ---------- tiled GEMM: C[M x NC] = A[M x K] @ B[K x NC], software-pipelined ----------
// 64-row x NC-col tile, 256 threads, 4 x (NC/16) outputs/thread.
// blockIdx.y * head_stride added to A,B,C,bias (block-diag per-head GEMM).
// Optional bf16 copy of C written to Cbf (packed pairs).
template<int NC>
__global__ __launch_bounds__(256)
void gemm_tile(const float* __restrict__ A, int lda,
               const float* __restrict__ B, int ldb,
               float* __restrict__ C, int ldc, unsigned* __restrict__ Cbf,
               int M, int K,
               const float* __restrict__ bias, int do_relu, int head_stride) {
    __shared__ float As[16][68];
    __shared__ float Bs[16][NC];
    const int off = blockIdx.y * head_stride;
    A += off; B += off; C += off;
    const float* bptr = bias ? bias + off : nullptr;
    unsigned* cbf = Cbf ? Cbf + (off >> 1) : nullptr;
    const int m0 = blockIdx.x * 64;
    const int t  = threadIdx.x;
    const int tx = t & 15, ty = t >> 4;
    constexpr int CJ = NC / 64;
    float acc[4][CJ * 4];
#pragma unroll
    for (int r = 0; r < 4; r++)
#pragma unroll
        for (int j = 0; j < CJ * 4; j++) acc[r][j] = 0.f;

    const int sr = t >> 2;
    const int sk = (t & 3) << 2;

    float4 av4;
    float4 bstg[CJ];
    auto load_tile = [&](int k0) {
        av4 = make_float4(0.f, 0.f, 0.f, 0.f);
        int gm = m0 + sr;
        if (gm < M) av4 = *(const float4*)&A[(size_t)gm * lda + k0 + sk];
#pragma unroll
        for (int j = 0; j < CJ; j++)
            bstg[j] = *(const float4*)&B[(size_t)(k0 + ty) * ldb + tx * 4 + j * 64];
    };
    load_tile(0);

    for (int k0 = 0; k0 < K; k0 += 16) {
        __syncthreads();
        As[sk + 0][sr] = av4.x; As[sk + 1][sr] = av4.y;
        As[sk + 2][sr] = av4.z; As[sk + 3][sr] = av4.w;
#pragma unroll
        for (int j = 0; j < CJ; j++)
            *(float4*)&Bs[ty][tx * 4 + j * 64] = bstg[j];
        __syncthreads();
        if (k0 + 16 < K) load_tile(k0 + 16);    // prefetch overlaps compute
#pragma unroll
        for (int k = 0; k < 16; k++) {
            float4 a4 = *(const float4*)&As[k][ty * 4];
#pragma unroll
            for (int j = 0; j < CJ; j++) {
                float4 b4 = *(const float4*)&Bs[k][tx * 4 + j * 64];
                acc[0][j*4+0] += a4.x * b4.x; acc[0][j*4+1] += a4.x * b4.y;
                acc[0][j*4+2] += a4.x * b4.z; acc[0][j*4+3] += a4.x * b4.w;
                acc[1][j*4+0] += a4.y * b4.x; acc[1][j*4+1] += a4.y * b4.y;
                acc[1][j*4+2] += a4.y * b4.z; acc[1][j*4+3] += a4.y * b4.w;
                acc[2][j*4+0] += a4.z * b4.x; acc[2][j*4+1] += a4.z * b4.y;
                acc[2][j*4+2] += a4.z * b4.z; acc[2][j*4+3] += a4.z * b4.w;
                acc[3][j*4+0] += a4.w * b4.x; acc[3][j*4+1] += a4.w * b4.y;
                acc[3][j*4+2] += a4.w * b4.z; acc[3][j*4+3] += a4.w * b4.w;
            }
        }
    }
#pragma unroll
    for (int r = 0; r < 4; r++) {
        int row = m0 + ty * 4 + r;
        if (row >= M) continue;
#pragma unroll
        for (int j = 0; j < CJ; j++) {
            float4 o = make_float4(acc[r][j*4+0], acc[r][j*4+1], acc[r][j*4+2], acc[r][j*4+3]);
            if (bptr) {
                float4 bb = *(const float4*)&bptr[tx * 4 + j * 64];
                o.x += bb.x; o.y += bb.y; o.z += bb.z; o.w += bb.w;
            }
            if (do_relu) {
                o.x = fmaxf(o.x, 0.f); o.y = fmaxf(o.y, 0.f);
                o.z = fmaxf(o.z, 0.f); o.w = fmaxf(o.w, 0.f);
            }
            size_t eidx = (size_t)row * ldc + tx * 4 + j * 64;
            *(float4*)&C[eidx] = o;
            if (cbf) *(uint2*)&cbf[eidx >> 1] = f4_to_bf4(o);
        }
    }
}

// ---------- CSR build ----------
__global__ void deg_kernel(const int* __restrict__ dst, int* __restrict__ deg) {
    int t = blockIdx.x * blockDim.x + threadIdx.x;
    if (t < N_EDGES) atomicAdd(&deg[dst[t]], 1);
}
__global__ void dis_kernel(const int* __restrict__ deg, float* __restrict__ dis) {
    int i = blockIdx.x * blockDim.x + threadIdx.x;
    if (i >= N_NODES) return;
    int d = deg[i];
    dis[i] = d > 0 ? rsqrtf((float)d) : 0.f;
}
__global__ __launch_bounds__(1024) void scan_kernel(const int* __restrict__ deg,
                                                    int* __restrict__ off) {
    __shared__ int part[1024];
    int t = threadIdx.x;
    const int CH = (N_NODES + 1023) / 1024;
    int base = t * CH;
    int s = 0;
    for (int i = 0; i < CH; i++) {
        int n = base + i;
        if (n < N_NODES) s += deg[n];
    }
    part[t] = s;
    __syncthreads();
    for (int o = 1; o < 1024; o <<= 1) {
        int v = (t >= o) ? part[t - o] : 0;
        __syncthreads();
        part[t] += v;
        __syncthreads();
    }
    int run = (t == 0) ? 0 : part[t - 1];
    for (int i = 0; i < CH; i++) {
        int n = base + i;
        if (n < N_NODES) { off[n] = run; run += deg[n]; }
    }
    if (t == 1023) off[N_NODES] = run;
}
__global__ void csr_fill(const int* __restrict__ src, const int* __restrict__ dst,
                         const int* __restrict__ off, int* __restrict__ cursor,
                         const float* __restrict__ dis, int* __restrict__ csr_src,
                         float* __restrict__ wnorm) {
    int e = blockIdx.x * blockDim.x + threadIdx.x;
    if (e >= N_EDGES) return;
    int s = src[e], d = dst[e];
    int pos = off[d] + atomicAdd(&cursor[d], 1);
    csr_src[pos] = s;
    wnorm[pos] = dis[s] * dis[d];
}

// ---------- precontract W @ a ----------
__global__ void prep_w(const float* __restrict__ W, const float* __restrict__ as_,
                       const float* __restrict__ ad_, float* __restrict__ wes,
                       float* __restrict__ wed, int K) {
    int t = blockIdx.x * blockDim.x + threadIdx.x;
    if (t >= K * 4) return;
    int c = t >> 2, h = t & 3;
    float se = 0.f, sd = 0.f;
    for (int j = 0; j < 64; j++) {
        float w = W[(size_t)c * 256 + h * 64 + j];
        se += w * as_[h * 64 + j];
        sd += w * ad_[h * 64 + j];
    }
    wes[c * 4 + h] = se;
    wed[c * 4 + h] = sd;
}

// ---------- es/ed from K=64 input (x) ----------
__global__ void esed_x(const float* __restrict__ X, const float* __restrict__ wes,
                       const float* __restrict__ wed, float* __restrict__ es,
                       float* __restrict__ ed) {
    int gid = blockIdx.x * blockDim.x + threadIdx.x;
    int n = gid >> 6, lane = threadIdx.x & 63;
    if (n >= N_NODES) return;
    float xv = X[(size_t)n * 64 + lane];
    float4 a = *(const float4*)&wes[lane * 4];
    float4 b = *(const float4*)&wed[lane * 4];
    float4 ps = make_float4(xv * a.x, xv * a.y, xv * a.z, xv * a.w);
    float4 pd = make_float4(xv * b.x, xv * b.y, xv * b.z, xv * b.w);
#pragma unroll
    for (int o = 1; o < 64; o <<= 1) {
        ps.x += __shfl_xor(ps.x, o); ps.y += __shfl_xor(ps.y, o);
        ps.z += __shfl_xor(ps.z, o); ps.w += __shfl_xor(ps.w, o);
        pd.x += __shfl_xor(pd.x, o); pd.y += __shfl_xor(pd.y, o);
        pd.z += __shfl_xor(pd.z, o); pd.w += __shfl_xor(pd.w, o);
    }
    if (lane == 0) {
        *(float4*)&es[n * 4] = ps;
        *(float4*)&ed[n * 4] = pd;
    }
}

// ---------- es/ed from K=256 input (h1) ----------
__global__ void esed_h(const float* __restrict__ H, const float* __restrict__ wes,
                       const float* __restrict__ wed, float* __restrict__ es,
                       float* __restrict__ ed) {
    int gid = blockIdx.x * blockDim.x + threadIdx.x;
    int n = gid >> 6, lane = threadIdx.x & 63;
    if (n >= N_NODES) return;
    float4 xv = *(const float4*)&H[(size_t)n * 256 + lane * 4];
    float xs[4] = {xv.x, xv.y, xv.z, xv.w};
    float4 ps = make_float4(0.f, 0.f, 0.f, 0.f);
    float4 pd = make_float4(0.f, 0.f, 0.f, 0.f);
#pragma unroll
    for (int r = 0; r < 4; r++) {
        int c = lane * 4 + r;
        float4 a = *(const float4*)&wes[c * 4];
        float4 b = *(const float4*)&wed[c * 4];
        ps.x += xs[r] * a.x; ps.y += xs[r] * a.y; ps.z += xs[r] * a.z; ps.w += xs[r] * a.w;
        pd.x += xs[r] * b.x; pd.y += xs[r] * b.y; pd.z += xs[r] * b.z; pd.w += xs[r] * b.w;
    }
#pragma unroll
    for (int o = 1; o < 64; o <<= 1) {
        ps.x += __shfl_xor(ps.x, o); ps.y += __shfl_xor(ps.y, o);
        ps.z += __shfl_xor(ps.z, o); ps.w += __shfl_xor(ps.w, o);
        pd.x += __shfl_xor(pd.x, o); pd.y += __shfl_xor(pd.y, o);
        pd.z += __shfl_xor(pd.z, o); pd.w += __shfl_xor(pd.w, o);
    }
    if (lane == 0) {
        *(float4*)&es[n * 4] = ps;
        *(float4*)&ed[n * 4] = pd;
    }
}

// ---------- GAT1 fused softmax + x-aggregation (x fp32 gather, 64 feats) ----------
__global__ __launch_bounds__(256)
void gat1_fused(const int* __restrict__ off, const int* __restrict__ csr_src,
                const float* __restrict__ es, const float* __restrict__ ed,
                const float* __restrict__ x, float* __restrict__ aggx,
                float* __restrict__ alpha_fb) {
    __shared__ float elds[4][CAP * 4];
    int wav = threadIdx.x >> 6, lane = threadIdx.x & 63;
    int n = blockIdx.x * 4 + wav;
    bool active = n < N_NODES;
    int p0 = 0, p1 = 0;
    float4 ed4 = make_float4(0.f, 0.f, 0.f, 0.f);
    if (active) { p0 = off[n]; p1 = off[n + 1]; ed4 = *(const float4*)&ed[n * 4]; }
    float4 sum = make_float4(0.f, 0.f, 0.f, 0.f);
    for (int p = p0 + lane; p < p1; p += 64) {
        int s = csr_src[p];
        float4 e4 = *(const float4*)&es[s * 4];
        e4.x += ed4.x; e4.y += ed4.y; e4.z += ed4.z; e4.w += ed4.w;
        e4.x = e4.x > 0.f ? e4.x : 0.2f * e4.x;
        e4.y = e4.y > 0.f ? e4.y : 0.2f * e4.y;
        e4.z = e4.z > 0.f ? e4.z : 0.2f * e4.z;
        e4.w = e4.w > 0.f ? e4.w : 0.2f * e4.w;
        e4.x = __expf(e4.x); e4.y = __expf(e4.y); e4.z = __expf(e4.z); e4.w = __expf(e4.w);
        int q = p - p0;
        if (q < CAP) *(float4*)&elds[wav][q * 4] = e4;
        else         *(float4*)&alpha_fb[(size_t)p * 4] = e4;
        sum.x += e4.x; sum.y += e4.y; sum.z += e4.z; sum.w += e4.w;
    }
#pragma unroll
    for (int o = 1; o < 64; o <<= 1) {
        sum.x += __shfl_xor(sum.x, o); sum.y += __shfl_xor(sum.y, o);
        sum.z += __shfl_xor(sum.z, o); sum.w += __shfl_xor(sum.w, o);
    }
    float4 rs;
    rs.x = sum.x > 0.f ? 1.f / sum.x : 0.f;
    rs.y = sum.y > 0.f ? 1.f / sum.y : 0.f;
    rs.z = sum.z > 0.f ? 1.f / sum.z : 0.f;
    rs.w = sum.w > 0.f ? 1.f / sum.w : 0.f;
    __syncthreads();
    if (!active) return;
    float4 acc = make_float4(0.f, 0.f, 0.f, 0.f);
    for (int p = p0; p < p1; p++) {
        int s = csr_src[p];
        int q = p - p0;
        float4 e4 = (q < CAP) ? *(const float4*)&elds[wav][q * 4]
                              : *(const float4*)&alpha_fb[(size_t)p * 4];
        float xv = x[(size_t)s * 64 + lane];
        acc.x += e4.x * xv; acc.y += e4.y * xv; acc.z += e4.z * xv; acc.w += e4.w * xv;
    }
    acc.x *= rs.x; acc.y *= rs.y; acc.z *= rs.z; acc.w *= rs.w;
    aggx[(size_t)n * 256 +   0 + lane] = acc.x;
    aggx[(size_t)n * 256 +  64 + lane] = acc.y;
    aggx[(size_t)n * 256 + 128 + lane] = acc.z;
    aggx[(size_t)n * 256 + 192 + lane] = acc.w;
}

// ---------- GAT2 fused softmax + bf16-gather aggregation + bias + relu ----------
__global__ __launch_bounds__(256)
void gat2_fused(const int* __restrict__ off, const int* __restrict__ csr_src,
                const float* __restrict__ es, const float* __restrict__ ed,
                const unsigned* __restrict__ H2bf, const float* __restrict__ bias,
                float* __restrict__ out, unsigned* __restrict__ outbf,
                float* __restrict__ alpha_fb) {
    __shared__ float elds[4][CAP * 4];
    int wav = threadIdx.x >> 6, lane = threadIdx.x & 63;
    int n = blockIdx.x * 4 + wav;
    bool active = n < N_NODES;
    int p0 = 0, p1 = 0;
    float4 ed4 = make_float4(0.f, 0.f, 0.f, 0.f);
    if (active) { p0 = off[n]; p1 = off[n + 1]; ed4 = *(const float4*)&ed[n * 4]; }
    float4 sum = make_float4(0.f, 0.f, 0.f, 0.f);
    for (int p = p0 + lane; p < p1; p += 64) {
        int s = csr_src[p];
        float4 e4 = *(const float4*)&es[s * 4];
        e4.x += ed4.x; e4.y += ed4.y; e4.z += ed4.z; e4.w += ed4.w;
        e4.x = e4.x > 0.f ? e4.x : 0.2f * e4.x;
        e4.y = e4.y > 0.f ? e4.y : 0.2f * e4.y;
        e4.z = e4.z > 0.f ? e4.z : 0.2f * e4.z;
        e4.w = e4.w > 0.f ? e4.w : 0.2f * e4.w;
        e4.x = __expf(e4.x); e4.y = __expf(e4.y); e4.z = __expf(e4.z); e4.w = __expf(e4.w);
        int q = p - p0;
        if (q < CAP) *(float4*)&elds[wav][q * 4] = e4;
        else         *(float4*)&alpha_fb[(size_t)p * 4] = e4;
        sum.x += e4.x; sum.y += e4.y; sum.z += e4.z; sum.w += e4.w;
    }
#pragma unroll
    for (int o = 1; o < 64; o <<= 1) {
        sum.x += __shfl_xor(sum.x, o); sum.y += __shfl_xor(sum.y, o);
        sum.z += __shfl_xor(sum.z, o); sum.w += __shfl_xor(sum.w, o);
    }
    int h = lane >> 4;
    float sh = (h == 0) ? sum.x : (h == 1) ? sum.y : (h == 2) ? sum.z : sum.w;
    float rsh = sh > 0.f ? 1.f / sh : 0.f;
    __syncthreads();
    if (!active) return;
    float4 acc = make_float4(0.f, 0.f, 0.f, 0.f);
    for (int p = p0; p < p1; p++) {
        int s = csr_src[p];
        int q = p - p0;
        float4 e4 = (q < CAP) ? *(const float4*)&elds[wav][q * 4]
                              : *(const float4*)&alpha_fb[(size_t)p * 4];
        float al = (h == 0) ? e4.x : (h == 1) ? e4.y : (h == 2) ? e4.z : e4.w;
        float4 v = bf4_to_f4(*(const uint2*)&H2bf[(size_t)s * 128 + lane * 2]);
        acc.x += al * v.x; acc.y += al * v.y; acc.z += al * v.z; acc.w += al * v.w;
    }
    float4 bb = *(const float4*)&bias[lane * 4];
    acc.x = fmaxf(acc.x * rsh + bb.x, 0.f);
    acc.y = fmaxf(acc.y * rsh + bb.y, 0.f);
    acc.z = fmaxf(acc.z * rsh + bb.z, 0.f);
    acc.w = fmaxf(acc.w * rsh + bb.w, 0.f);
    *(float4*)&out[(size_t)n * 256 + lane * 4] = acc;
    *(uint2*)&outbf[(size_t)n * 128 + lane * 2] = f4_to_bf4(acc);
}

// ---------- label prop step: bf16 gather, fp32 residual/compute, dual write ----------
__global__ void lp_csr(const int* __restrict__ off, const int* __restrict__ csr_src,
                       const float* __restrict__ wnorm, const unsigned* __restrict__ in_bf,
                       const float* __restrict__ res, float* __restrict__ out,
                       unsigned* __restrict__ out_bf) {
    int gid = blockIdx.x * blockDim.x + threadIdx.x;
    int n = gid >> 6, lane = threadIdx.x & 63;
    if (n >= N_NODES) return;
    int p0 = off[n], p1 = off[n + 1];
    float4 acc = make_float4(0.f, 0.f, 0.f, 0.f);
    for (int p = p0; p < p1; p++) {
        int s = csr_src[p];
        float nr = wnorm[p];
        float4 v = bf4_to_f4(*(const uint2*)&in_bf[(size_t)s * 128 + lane * 2]);
        acc.x += v.x * nr; acc.y += v.y * nr; acc.z += v.z * nr; acc.w += v.w * nr;
    }
    float4 r = *(const float4*)&res[(size_t)n * 256 + lane * 4];
    acc.x = fminf(fmaxf(0.5f * acc.x + 0.5f * r.x, 0.f), 1.f);
    acc.y = fminf(fmaxf(0.5f * acc.y + 0.5f * r.y, 0.f), 1.f);
    acc.z = fminf(fmaxf(0.5f * acc.z + 0.5f * r.z, 0.f), 1.f);
    acc.w = fminf(fmaxf(0.5f * acc.w + 0.5f * r.w, 0.f), 1.f);
    *(float4*)&out[(size_t)n * 256 + lane * 4] = acc;
    if (out_bf) *(uint2*)&out_bf[(size_t)n * 128 + lane * 2] = f4_to_bf4(acc);
}

// ---------- pooling ----------
__global__ void bounds_kernel(const int* __restrict__ batch, int* __restrict__ gstart) {
    int n = blockIdx.x * blockDim.x + threadIdx.x;
    if (n >= N_NODES) return;
    int b = batch[n];
    int prev = (n == 0) ? -1 : batch[n - 1];
    for (int g = prev + 1; g <= b; g++) gstart[g] = n;
    if (n == N_NODES - 1)
        for (int g = b + 1; g <= N_GRAPHS; g++) gstart[g] = N_NODES;
}
__global__ void pool_partial(const float* __restrict__ buf, const int* __restrict__ gstart,
                             float* __restrict__ psum, int C, int colOff) {
    int g = blockIdx.x, q = blockIdx.y;
    int n0 = gstart[g], n1 = gstart[g + 1];
    int len = n1 - n0;
    int ns = n0 + (len * q) / 4, ne = n0 + (len * (q + 1)) / 4;
    int cp = threadIdx.x % C;
    int np = threadIdx.x / C;
    int NP = 256 / C;
    float s = 0.f;
    for (int n = ns + np; n < ne; n += NP) s += buf[(size_t)n * C + cp];
    atomicAdd(&psum[g * JK + colOff + cp], s);
}
__global__ void gmean_kernel(const float* __restrict__ psum, const int* __restrict__ gstart,
                             float* __restrict__ g) {
    int i = blockIdx.x * blockDim.x + threadIdx.x;
    if (i >= N_GRAPHS * JK) return;
    int gi = i / JK;
    int len = gstart[gi + 1] - gstart[gi];
    g[i] = psum[i] / (float)(len > 1 ? len : 1);
}

// ---------- MLP head, layer 1 ----------
__global__ __launch_bounds__(64)
void head_d1(const float* __restrict__ gbuf, const float* __restrict__ W,
             const float* __restrict__ bias, float* __restrict__ out) {
    __shared__ float zin[JK];
    int g = blockIdx.y, mc = blockIdx.x, lane = threadIdx.x;
    for (int k = lane; k < JK; k += 64) zin[k] = gbuf[g * JK + k];
    __syncthreads();
    int m = mc * 64 + lane;
    float acc = bias[m];
#pragma unroll 8
    for (int k = 0; k < JK; k++) acc += zin[k] * W[k * 256 + m];
    out[g * 256 + m] = fmaxf(acc, 0.f);
}

// ---------- MLP head, rest ----------
__global__ __launch_bounds__(256)
void head_rest(const float* __restrict__ t1, const float* __restrict__ clin,
               const float* __restrict__ pp_w2, const float* __restrict__ pp_b2,
               const float* __restrict__ cl_w1, const float* __restrict__ cl_b1,
               const float* __restrict__ cl_w2, const float* __restrict__ cl_b2,
               const float* __restrict__ h_w1, const float* __restrict__ h_b1,
               const float* __restrict__ h_w2, const float* __restrict__ h_b2,
               const float* __restrict__ h_w3, const float* __restrict__ h_b3,
               float* __restrict__ out) {
    __shared__ float z1[256];
    __shared__ float zcl[32];
    __shared__ float zc[64];
    __shared__ float z[160];
    __shared__ float z3[64];
    __shared__ float z4[32];
    __shared__ float part[128];
    int g = blockIdx.x, t = threadIdx.x;
    z1[t] = t1[g * 256 + t];
    if (t < 32) zcl[t] = clin[g * 32 + t];
    __syncthreads();
    int m = t & 127, half = t >> 7;
    {
        float acc = 0.f;
        int k0 = half * 128;
#pragma unroll 8
        for (int k = k0; k < k0 + 128; k++) acc += z1[k] * pp_w2[k * 128 + m];
        if (half) part[m] = acc;
        __syncthreads();
        if (!half) z[m] = acc + part[m] + pp_b2[m];
    }
    if (t < 64) {
        float acc = cl_b1[t];
#pragma unroll
        for (int k = 0; k < 32; k++) acc += zcl[k] * cl_w1[k * 64 + t];
        zc[t] = fmaxf(acc, 0.f);
    }
    __syncthreads();
    if (t < 32) {
        float acc = cl_b2[t];
#pragma unroll
        for (int k = 0; k < 64; k++) acc += zc[k] * cl_w2[k * 32 + t];
        z[128 + t] = acc;
    }
    __syncthreads();
    if (t < 64) {
        float acc = h_b1[t];
#pragma unroll 8
        for (int k = 0; k < 160; k++) acc += z[k] * h_w1[k * 64 + t];
        z3[t] = fmaxf(acc, 0.f);
    }
    __syncthreads();
    if (t < 32) {
        float acc = h_b2[t];
#pragma unroll
        for (int k = 0; k < 64; k++) acc += z3[k] * h_w2[k * 32 + t];
        z4[t] = fmaxf(acc, 0.f);
    }
    __syncthreads();
    if (t < 2) {
        float acc = h_b3[t];
#pragma unroll
        for (int k = 0; k < 32; k++) acc += z4[k] * h_w3[k * 2 + t];
        out[g * 2 + t] = acc;
    }
}

// ---------- launch ----------
extern "C" void kernel_launch(void* const* d_in, const int* in_sizes, int n_in,
                              void* d_out, int out_size, void* d_ws, size_t ws_size,
                              hipStream_t stream) {
    const float* x     = (const float*)d_in[0];
    const int*   ei    = (const int*)d_in[1];
    const int*   batch = (const int*)d_in[2];
    const float* clin  = (const float*)d_in[3];
    const float* W1  = (const float*)d_in[4];
    const float* a1s = (const float*)d_in[5];
    const float* a1d = (const float*)d_in[6];
    const float* b1  = (const float*)d_in[7];
    const float* W2  = (const float*)d_in[8];
    const float* a2s = (const float*)d_in[9];
    const float* a2d = (const float*)d_in[10];
    const float* b2  = (const float*)d_in[11];
    const float* pp_w1 = (const float*)d_in[12];
    const float* pp_b1 = (const float*)d_in[13];
    const float* pp_w2 = (const float*)d_in[14];
    const float* pp_b2 = (const float*)d_in[15];
    const float* cl_w1 = (const float*)d_in[16];
    const float* cl_b1 = (const float*)d_in[17];
    const float* cl_w2 = (const float*)d_in[18];
    const float* cl_b2 = (const float*)d_in[19];
    const float* h_w1  = (const float*)d_in[20];
    const float* h_b1  = (const float*)d_in[21];
    const float* h_w2  = (const float*)d_in[22];
    const float* h_b2  = (const float*)d_in[23];
    const float* h_w3  = (const float*)d_in[24];
    const float* h_b3  = (const float*)d_in[25];

    const int* src = ei;
    const int* dst = ei + N_EDGES;

    char* p = (char*)d_ws;
    auto carve = [&](size_t bytes) -> char* {
        char* r = p;
        p += (bytes + 255) & ~(size_t)255;
        return r;
    };
    const size_t NB  = (size_t)N_NODES * 256 * 4;
    const size_t NBH = (size_t)N_NODES * 256 * 2;    // bf16 copy
    float*    bufA = (float*)carve(NB);
    float*    bufB = (float*)carve(NB);
    float*    bufC = (float*)carve(NB);
    unsigned* bf1  = (unsigned*)carve(NBH);
    unsigned* bf2  = (unsigned*)carve(NBH);
    float* alpha_fb  = (float*)carve((size_t)N_EDGES * 4 * 4);
    int*   csr_src   = (int*)carve((size_t)N_EDGES * 4);
    float* wnorm     = (float*)carve((size_t)N_EDGES * 4);
    int*   off       = (int*)carve((size_t)(N_NODES + 1) * 4);
    int*   deg       = (int*)carve((size_t)N_NODES * 4);
    int*   cursor    = (int*)carve((size_t)N_NODES * 4);
    float* dis       = (float*)carve((size_t)N_NODES * 4);
    float* es        = (float*)carve((size_t)N_NODES * 4 * 4);
    float* ed        = (float*)carve((size_t)N_NODES * 4 * 4);
    float* wes1      = (float*)carve((size_t)64 * 4 * 4);
    float* wed1      = (float*)carve((size_t)64 * 4 * 4);
    float* wes2      = (float*)carve((size_t)256 * 4 * 4);
    float* wed2      = (float*)carve((size_t)256 * 4 * 4);
    int*   gstart    = (int*)carve((size_t)(N_GRAPHS + 1) * 4);
    float* psum      = (float*)carve((size_t)N_GRAPHS * JK * 4);
    float* gbuf      = (float*)carve((size_t)N_GRAPHS * JK * 4);
    float* t1        = (float*)carve((size_t)N_GRAPHS * 256 * 4);

    const int TB = 256;
    const int gN     = (N_NODES + TB - 1) / TB;
    const int gE     = (N_EDGES + TB - 1) / TB;
    const int gNwave = (N_NODES * 64 + TB - 1) / TB;
    const int gFuse  = (N_NODES + 3) / 4;
    const int gRow   = (N_NODES + 63) / 64;

    // ---- CSR + degree + pooling bounds + weight precontractions ----
    hipMemsetAsync(deg, 0, (size_t)N_NODES * 4, stream);
    hipMemsetAsync(cursor, 0, (size_t)N_NODES * 4, stream);
    hipMemsetAsync(psum, 0, (size_t)N_GRAPHS * JK * 4, stream);
    deg_kernel<<<gE, TB, 0, stream>>>(dst, deg);
    dis_kernel<<<gN, TB, 0, stream>>>(deg, dis);
    scan_kernel<<<1, 1024, 0, stream>>>(deg, off);
    csr_fill<<<gE, TB, 0, stream>>>(src, dst, off, cursor, dis, csr_src, wnorm);
    bounds_kernel<<<gN, TB, 0, stream>>>(batch, gstart);
    prep_w<<<1, 256, 0, stream>>>(W1, a1s, a1d, wes1, wed1, 64);
    prep_w<<<4, 256, 0, stream>>>(W2, a2s, a2d, wes2, wed2, 256);

    // ---- GAT layer 1 (aggregate x, then block-diag per-head GEMM) ----
    esed_x<<<gNwave, TB, 0, stream>>>(x, wes1, wed1, es, ed);
    gat1_fused<<<gFuse, TB, 0, stream>>>(off, csr_src, es, ed, x, bufA, alpha_fb);
    gemm_tile<64><<<dim3(gRow, 4), 256, 0, stream>>>(bufA, 256, W1, 256, bufC, 256, bf1,
                                                     N_NODES, 64, b1, 1, 64);   // bufC = h1a (+bf1)

    // ---- label prop 1 ----
    lp_csr<<<gNwave, TB, 0, stream>>>(off, csr_src, wnorm, bf1, bufC, bufB, bf2);
    lp_csr<<<gNwave, TB, 0, stream>>>(off, csr_src, wnorm, bf2, bufC, bufA, nullptr); // bufA = h1

    pool_partial<<<dim3(N_GRAPHS, 4), TB, 0, stream>>>(bufA, gstart, psum, 256, 64);

    // ---- GAT layer 2 ----
    gemm_tile<256><<<dim3(gRow, 1), 256, 0, stream>>>(bufA, 256, W2, 256, bufB, 256, bf1,
                                                      N_NODES, 256, nullptr, 0, 0); // h2 -> bf1
    esed_h<<<gNwave, TB, 0, stream>>>(bufA, wes2, wed2, es, ed);
    gat2_fused<<<gFuse, TB, 0, stream>>>(off, csr_src, es, ed, bf1, b2, bufC, bf2, alpha_fb); // bufC = h2a (+bf2)

    // ---- label prop 2 ----
    lp_csr<<<gNwave, TB, 0, stream>>>(off, csr_src, wnorm, bf2, bufC, bufB, bf1);
    lp_csr<<<gNwave, TB, 0, stream>>>(off, csr_src, wnorm, bf1, bufC, bufA, nullptr); // bufA = h2_final

    // ---- pooling (x, h2) + mean ----
    pool_partial<<<dim3(N_GRAPHS, 4), TB, 0, stream>>>(x, gstart, psum, 64, 0);
    pool_partial<<<dim3(N_GRAPHS, 4), TB, 0, stream>>>(bufA, gstart, psum, 256, 320);
    gmean_kernel<<<(N_GRAPHS * JK + TB - 1) / TB, TB, 0, stream>>>(psum, gstart, gbuf);

    // ---- MLP head ----
    head_d1<<<dim3(4, N_GRAPHS), 64, 0, stream>>>(gbuf, pp_w1, pp_b1, t1);
    head_rest<<<N_GRAPHS, 256, 0, stream>>>(t1, clin, pp_w2, pp_b2, cl_w1, cl_b1,
                                            cl_w2, cl_b2, h_w1, h_b1, h_w2, h_b2,
                                            h_w3, h_b3, (float*)d_out);
}

// Round 6
// 1160.646 us; speedup vs baseline: 15.0440x; 1.0631x over previous
//
#include <hip/hip_runtime.h>

#define N_NODES 50000
#define N_EDGES 800000
#define N_GRAPHS 128
#define JK 576              // 64 + 256 + 256
#define CAP 192             // max cached in-degree per node (Poisson(16); max~45)

typedef __attribute__((ext_vector_type(8))) short bf16x8;
typedef __attribute__((ext_vector_type(4))) float f32x4;

// ---------- bf16 pack/unpack helpers ----------
__device__ __forceinline__ unsigned f2_to_bf2(float a, float b) {
    unsigned ua = __float_as_uint(a), ub = __float_as_uint(b);
    ua = (ua + 0x7fffu + ((ua >> 16) & 1u)) >> 16;       // RNE
    ub = (ub + 0x7fffu + ((ub >> 16) & 1u)) >> 16;
    return ua | (ub << 16);
}
__device__ __forceinline__ uint2 f4_to_bf4(float4 v) {
    return make_uint2(f2_to_bf2(v.x, v.y), f2_to_bf2(v.z, v.w));
}
__device__ __forceinline__ float4 bf4_to_f4(uint2 u) {
    float4 r;
    r.x = __uint_as_float(u.x << 16);
    r.y = __uint_as_float(u.x & 0xffff0000u);
    r.z = __uint_as_float(u.y << 16);
    r.w = __uint_as_float(u.y & 0xffff0000u);
    return r;
}

// ---------- MFMA GEMM: C[M,*] = A_bf16 @ B, B pre-transposed (n-major) bf16 ----------
// Block: 256 thr = 4 waves; tile 64 rows x BN cols; K-step 32 via 16x16x32 bf16 MFMA.
// Per-head (blockIdx.y) element offsets a_off/b_off/c_off for block-diagonal GEMMs.
template<int BN, int KK>
__global__ __launch_bounds__(256)
void mfma_gemm(const unsigned short* __restrict__ Abf, int lda,
               const unsigned short* __restrict__ BT,
               float* __restrict__ C, unsigned* __restrict__ Cbf, int ldc,
               int M, const float* __restrict__ bias, int relu,
               int a_off, int b_off, int c_off) {
    __shared__ unsigned short As[64][32];
    __shared__ unsigned short Bs[BN][32];
    const int t = threadIdx.x;
    const int wav = t >> 6, lane = t & 63;
    const int quad = lane >> 4, l15 = lane & 15;
    const int m0 = blockIdx.x * 64;
    const int head = blockIdx.y;
    Abf += (size_t)head * a_off;
    BT  += (size_t)head * b_off;
    const float* bptr = bias ? bias + (size_t)head * c_off : nullptr;
    float*    cp  = C   ? C   + (size_t)head * c_off : nullptr;
    unsigned* cbf = Cbf ? Cbf + (((size_t)head * c_off) >> 1) : nullptr;

    f32x4 acc[BN / 16];
#pragma unroll
    for (int i = 0; i < BN / 16; i++) acc[i] = (f32x4){0.f, 0.f, 0.f, 0.f};

    const int arow = t >> 2, aseg = t & 3;     // A staging: 64 rows x 32 k, 16B/thread
    for (int k0 = 0; k0 < KK; k0 += 32) {
        uint4 av = make_uint4(0, 0, 0, 0);
        int gm = m0 + arow;
        if (gm < M) av = *(const uint4*)&Abf[(size_t)gm * lda + k0 + aseg * 8];
        uint4 bv[BN == 256 ? 4 : 1];
        if (BN == 256) {
            const unsigned short* srcb = &BT[(size_t)t * KK + k0];
#pragma unroll
            for (int j = 0; j < 4; j++) bv[j] = *(const uint4*)&srcb[j * 8];
        } else {
            bv[0] = *(const uint4*)&BT[(size_t)arow * KK + k0 + aseg * 8];
        }
        __syncthreads();
        *(uint4*)&As[arow][aseg * 8] = av;
        if (BN == 256) {
#pragma unroll
            for (int j = 0; j < 4; j++) *(uint4*)&Bs[t][j * 8] = bv[j];
        } else {
            *(uint4*)&Bs[arow][aseg * 8] = bv[0];
        }
        __syncthreads();
        bf16x8 afrag = *(const bf16x8*)&As[wav * 16 + l15][quad * 8];
#pragma unroll
        for (int nt = 0; nt < BN / 16; nt++) {
            bf16x8 bfrag = *(const bf16x8*)&Bs[nt * 16 + l15][quad * 8];
            acc[nt] = __builtin_amdgcn_mfma_f32_16x16x32_bf16(afrag, bfrag, acc[nt], 0, 0, 0);
        }
    }
    // epilogue: D row = quad*4+reg (within wave's 16 rows), col = l15
    int rbase = m0 + wav * 16 + quad * 4;
#pragma unroll
    for (int nt = 0; nt < BN / 16; nt++) {
        int col = nt * 16 + l15;
        float bb = bptr ? bptr[col] : 0.f;
#pragma unroll
        for (int r = 0; r < 4; r++) {
            int row = rbase + r;
            float v = acc[nt][r] + bb;
            if (relu) v = fmaxf(v, 0.f);
            float vp = __shfl_xor(v, 1);
            if (row < M) {
                if (cp) cp[(size_t)row * ldc + col] = v;
                if (cbf && !(l15 & 1))
                    cbf[((size_t)row * ldc + col) >> 1] = f2_to_bf2(v, vp);
            }
        }
    }
}

// ---------- weight transpose + bf16 convert: WT[n][c] = bf16(W[c][n]) ----------
__global__ void conv_wT(const float* __restrict__ W, unsigned short* __restrict__ WT,
                        int IN, int OUT) {
    int i = blockIdx.x * blockDim.x + threadIdx.x;
    if (i >= IN * OUT) return;
    int n = i / IN, c = i - n * IN;
    unsigned u = __float_as_uint(W[(size_t)c * OUT + n]);
    u = (u + 0x7fffu + ((u >> 16) & 1u)) >> 16;
    WT[i] = (unsigned short)u;
}

// ---------- CSR build ----------
__global__ void deg_kernel(const int* __restrict__ dst, int* __restrict__ deg) {
    int t = blockIdx.x * blockDim.x + threadIdx.x;
    if (t < N_EDGES) atomicAdd(&deg[dst[t]], 1);
}
__global__ void dis_kernel(const int* __restrict__ deg, float* __restrict__ dis) {
    int i = blockIdx.x * blockDim.x + threadIdx.x;
    if (i >= N_NODES) return;
    int d = deg[i];
    dis[i] = d > 0 ? rsqrtf((float)d) : 0.f;
}
__global__ __launch_bounds__(1024) void scan_kernel(const int* __restrict__ deg,
                                                    int* __restrict__ off) {
    __shared__ int part[1024];
    int t = threadIdx.x;
    const int CH = (N_NODES + 1023) / 1024;
    int base = t * CH;
    int s = 0;
    for (int i = 0; i < CH; i++) {
        int n = base + i;
        if (n < N_NODES) s += deg[n];
    }
    part[t] = s;
    __syncthreads();
    for (int o = 1; o < 1024; o <<= 1) {
        int v = (t >= o) ? part[t - o] : 0;
        __syncthreads();
        part[t] += v;
        __syncthreads();
    }
    int run = (t == 0) ? 0 : part[t - 1];
    for (int i = 0; i < CH; i++) {
        int n = base + i;
        if (n < N_NODES) { off[n] = run; run += deg[n]; }
    }
    if (t == 1023) off[N_NODES] = run;
}
__global__ void csr_fill(const int* __restrict__ src, const int* __restrict__ dst,
                         const int* __restrict__ off, int* __restrict__ cursor,
                         const float* __restrict__ dis, int* __restrict__ csr_src,
                         float* __restrict__ wnorm) {
    int e = blockIdx.x * blockDim.x + threadIdx.x;
    if (e >= N_EDGES) return;
    int s = src[e], d = dst[e];
    int pos = off[d] + atomicAdd(&cursor[d], 1);
    csr_src[pos] = s;
    wnorm[pos] = dis[s] * dis[d];
}

// ---------- precontract W @ a ----------
__global__ void prep_w(const float* __restrict__ W, const float* __restrict__ as_,
                       const float* __restrict__ ad_, float* __restrict__ wes,
                       float* __restrict__ wed, int K) {
    int t = blockIdx.x * blockDim.x + threadIdx.x;
    if (t >= K * 4) return;
    int c = t >> 2, h = t & 3;
    float se = 0.f, sd = 0.f;
    for (int j = 0; j < 64; j++) {
        float w = W[(size_t)c * 256 + h * 64 + j];
        se += w * as_[h * 64 + j];
        sd += w * ad_[h * 64 + j];
    }
    wes[c * 4 + h] = se;
    wed[c * 4 + h] = sd;
}

// ---------- es/ed from K=64 input (x) ----------
__global__ void esed_x(const float* __restrict__ X, const float* __restrict__ wes,
                       const float* __restrict__ wed, float* __restrict__ es,
                       float* __restrict__ ed) {
    int gid = blockIdx.x * blockDim.x + threadIdx.x;
    int n = gid >> 6, lane = threadIdx.x & 63;
    if (n >= N_NODES) return;
    float xv = X[(size_t)n * 64 + lane];
    float4 a = *(const float4*)&wes[lane * 4];
    float4 b = *(const float4*)&wed[lane * 4];
    float4 ps = make_float4(xv * a.x, xv * a.y, xv * a.z, xv * a.w);
    float4 pd = make_float4(xv * b.x, xv * b.y, xv * b.z, xv * b.w);
#pragma unroll
    for (int o = 1; o < 64; o <<= 1) {
        ps.x += __shfl_xor(ps.x, o); ps.y += __shfl_xor(ps.y, o);
        ps.z += __shfl_xor(ps.z, o); ps.w += __shfl_xor(ps.w, o);
        pd.x += __shfl_xor(pd.x, o); pd.y += __shfl_xor(pd.y, o);
        pd.z += __shfl_xor(pd.z, o); pd.w += __shfl_xor(pd.w, o);
    }
    if (lane == 0) {
        *(float4*)&es[n * 4] = ps;
        *(float4*)&ed[n * 4] = pd;
    }
}

// ---------- es/ed from K=256 input (h1, fp32) ----------
__global__ void esed_h(const float* __restrict__ H, const float* __restrict__ wes,
                       const float* __restrict__ wed, float* __restrict__ es,
                       float* __restrict__ ed) {
    int gid = blockIdx.x * blockDim.x + threadIdx.x;
    int n = gid >> 6, lane = threadIdx.x & 63;
    if (n >= N_NODES) return;
    float4 xv = *(const float4*)&H[(size_t)n * 256 + lane * 4];
    float xs[4] = {xv.x, xv.y, xv.z, xv.w};
    float4 ps = make_float4(0.f, 0.f, 0.f, 0.f);
    float4 pd = make_float4(0.f, 0.f, 0.f, 0.f);
#pragma unroll
    for (int r = 0; r < 4; r++) {
        int c = lane * 4 + r;
        float4 a = *(const float4*)&wes[c * 4];
        float4 b = *(const float4*)&wed[c * 4];
        ps.x += xs[r] * a.x; ps.y += xs[r] * a.y; ps.z += xs[r] * a.z; ps.w += xs[r] * a.w;
        pd.x += xs[r] * b.x; pd.y += xs[r] * b.y; pd.z += xs[r] * b.z; pd.w += xs[r] * b.w;
    }
#pragma unroll
    for (int o = 1; o < 64; o <<= 1) {
        ps.x += __shfl_xor(ps.x, o); ps.y += __shfl_xor(ps.y, o);
        ps.z += __shfl_xor(ps.z, o); ps.w += __shfl_xor(ps.w, o);
        pd.x += __shfl_xor(pd.x, o); pd.y += __shfl_xor(pd.y, o);
        pd.z += __shfl_xor(pd.z, o); pd.w += __shfl_xor(pd.w, o);
    }
    if (lane == 0) {
        *(float4*)&es[n * 4] = ps;
        *(float4*)&ed[n * 4] = pd;
    }
}

// ---------- GAT1 fused softmax + x-aggregation -> bf16 output only ----------
__global__ __launch_bounds__(256)
void gat1_fused(const int* __restrict__ off, const int* __restrict__ csr_src,
                const float* __restrict__ es, const float* __restrict__ ed,
                const float* __restrict__ x, unsigned* __restrict__ aggx_bf,
                float* __restrict__ alpha_fb) {
    __shared__ float elds[4][CAP * 4];
    int wav = threadIdx.x >> 6, lane = threadIdx.x & 63;
    int n = blockIdx.x * 4 + wav;
    bool active = n < N_NODES;
    int p0 = 0, p1 = 0;
    float4 ed4 = make_float4(0.f, 0.f, 0.f, 0.f);
    if (active) { p0 = off[n]; p1 = off[n + 1]; ed4 = *(const float4*)&ed[n * 4]; }
    float4 sum = make_float4(0.f, 0.f, 0.f, 0.f);
    for (int p = p0 + lane; p < p1; p += 64) {
        int s = csr_src[p];
        float4 e4 = *(const float4*)&es[s * 4];
        e4.x += ed4.x; e4.y += ed4.y; e4.z += ed4.z; e4.w += ed4.w;
        e4.x = e4.x > 0.f ? e4.x : 0.2f * e4.x;
        e4.y = e4.y > 0.f ? e4.y : 0.2f * e4.y;
        e4.z = e4.z > 0.f ? e4.z : 0.2f * e4.z;
        e4.w = e4.w > 0.f ? e4.w : 0.2f * e4.w;
        e4.x = __expf(e4.x); e4.y = __expf(e4.y); e4.z = __expf(e4.z); e4.w = __expf(e4.w);
        int q = p - p0;
        if (q < CAP) *(float4*)&elds[wav][q * 4] = e4;
        else         *(float4*)&alpha_fb[(size_t)p * 4] = e4;
        sum.x += e4.x; sum.y += e4.y; sum.z += e4.z; sum.w += e4.w;
    }
#pragma unroll
    for (int o = 1; o < 64; o <<= 1) {
        sum.x += __shfl_xor(sum.x, o); sum.y += __shfl_xor(sum.y, o);
        sum.z += __shfl_xor(sum.z, o); sum.w += __shfl_xor(sum.w, o);
    }
    float4 rs;
    rs.x = sum.x > 0.f ? 1.f / sum.x : 0.f;
    rs.y = sum.y > 0.f ? 1.f / sum.y : 0.f;
    rs.z = sum.z > 0.f ? 1.f / sum.z : 0.f;
    rs.w = sum.w > 0.f ? 1.f / sum.w : 0.f;
    __syncthreads();
    if (!active) return;
    float4 acc = make_float4(0.f, 0.f, 0.f, 0.f);
    for (int p = p0; p < p1; p++) {
        int s = csr_src[p];
        int q = p - p0;
        float4 e4 = (q < CAP) ? *(const float4*)&elds[wav][q * 4]
                              : *(const float4*)&alpha_fb[(size_t)p * 4];
        float xv = x[(size_t)s * 64 + lane];
        acc.x += e4.x * xv; acc.y += e4.y * xv; acc.z += e4.z * xv; acc.w += e4.w * xv;
    }
    acc.x *= rs.x; acc.y *= rs.y; acc.z *= rs.z; acc.w *= rs.w;
    float px = __shfl_xor(acc.x, 1), py = __shfl_xor(acc.y, 1);
    float pz = __shfl_xor(acc.z, 1), pw = __shfl_xor(acc.w, 1);
    if (!(lane & 1)) {
        size_t b = (size_t)n * 128 + (lane >> 1);
        aggx_bf[b +  0] = f2_to_bf2(acc.x, px);
        aggx_bf[b + 32] = f2_to_bf2(acc.y, py);
        aggx_bf[b + 64] = f2_to_bf2(acc.z, pz);
        aggx_bf[b + 96] = f2_to_bf2(acc.w, pw);
    }
}

// ---------- GAT2 fused softmax + bf16-gather aggregation + bias + relu ----------
__global__ __launch_bounds__(256)
void gat2_fused(const int* __restrict__ off, const int* __restrict__ csr_src,
                const float* __restrict__ es, const float* __restrict__ ed,
                const unsigned* __restrict__ H2bf, const float* __restrict__ bias,
                float* __restrict__ out, unsigned* __restrict__ outbf,
                float* __restrict__ alpha_fb) {
    __shared__ float elds[4][CAP * 4];
    int wav = threadIdx.x >> 6, lane = threadIdx.x & 63;
    int n = blockIdx.x * 4 + wav;
    bool active = n < N_NODES;
    int p0 = 0, p1 = 0;
    float4 ed4 = make_float4(0.f, 0.f, 0.f, 0.f);
    if (active) { p0 = off[n]; p1 = off[n + 1]; ed4 = *(const float4*)&ed[n * 4]; }
    float4 sum = make_float4(0.f, 0.f, 0.f, 0.f);
    for (int p = p0 + lane; p < p1; p += 64) {
        int s = csr_src[p];
        float4 e4 = *(const float4*)&es[s * 4];
        e4.x += ed4.x; e4.y += ed4.y; e4.z += ed4.z; e4.w += ed4.w;
        e4.x = e4.x > 0.f ? e4.x : 0.2f * e4.x;
        e4.y = e4.y > 0.f ? e4.y : 0.2f * e4.y;
        e4.z = e4.z > 0.f ? e4.z : 0.2f * e4.z;
        e4.w = e4.w > 0.f ? e4.w : 0.2f * e4.w;
        e4.x = __expf(e4.x); e4.y = __expf(e4.y); e4.z = __expf(e4.z); e4.w = __expf(e4.w);
        int q = p - p0;
        if (q < CAP) *(float4*)&elds[wav][q * 4] = e4;
        else         *(float4*)&alpha_fb[(size_t)p * 4] = e4;
        sum.x += e4.x; sum.y += e4.y; sum.z += e4.z; sum.w += e4.w;
    }
#pragma unroll
    for (int o = 1; o < 64; o <<= 1) {
        sum.x += __shfl_xor(sum.x, o); sum.y += __shfl_xor(sum.y, o);
        sum.z += __shfl_xor(sum.z, o); sum.w += __shfl_xor(sum.w, o);
    }
    int h = lane >> 4;
    float sh = (h == 0) ? sum.x : (h == 1) ? sum.y : (h == 2) ? sum.z : sum.w;
    float rsh = sh > 0.f ? 1.f / sh : 0.f;
    __syncthreads();
    if (!active) return;
    float4 acc = make_float4(0.f, 0.f, 0.f, 0.f);
    for (int p = p0; p < p1; p++) {
        int s = csr_src[p];
        int q = p - p0;
        float4 e4 = (q < CAP) ? *(const float4*)&elds[wav][q * 4]
                              : *(const float4*)&alpha_fb[(size_t)p * 4];
        float al = (h == 0) ? e4.x : (h == 1) ? e4.y : (h == 2) ? e4.z : e4.w;
        float4 v = bf4_to_f4(*(const uint2*)&H2bf[(size_t)s * 128 + lane * 2]);
        acc.x += al * v.x; acc.y += al * v.y; acc.z += al * v.z; acc.w += al * v.w;
    }
    float4 bb = *(const float4*)&bias[lane * 4];
    acc.x = fmaxf(acc.x * rsh + bb.x, 0.f);
    acc.y = fmaxf(acc.y * rsh + bb.y, 0.f);
    acc.z = fmaxf(acc.z * rsh + bb.z, 0.f);
    acc.w = fmaxf(acc.w * rsh + bb.w, 0.f);
    *(float4*)&out[(size_t)n * 256 + lane * 4] = acc;
    *(uint2*)&outbf[(size_t)n * 128 + lane * 2] = f4_to_bf4(acc);
}

// ---------- label prop step: bf16 gather, fp32 residual, nullable outputs ----------
__global__ void lp_csr(const int* __restrict__ off, const int* __restrict__ csr_src,
                       const float* __restrict__ wnorm, const unsigned* __restrict__ in_bf,
                       const float* __restrict__ res, float* __restrict__ out,
                       unsigned* __restrict__ out_bf) {
    int gid = blockIdx.x * blockDim.x + threadIdx.x;
    int n = gid >> 6, lane = threadIdx.x & 63;
    if (n >= N_NODES) return;
    int p0 = off[n], p1 = off[n + 1];
    float4 acc = make_float4(0.f, 0.f, 0.f, 0.f);
    for (int p = p0; p < p1; p++) {
        int s = csr_src[p];
        float nr = wnorm[p];
        float4 v = bf4_to_f4(*(const uint2*)&in_bf[(size_t)s * 128 + lane * 2]);
        acc.x += v.x * nr; acc.y += v.y * nr; acc.z += v.z * nr; acc.w += v.w * nr;
    }
    float4 r = *(const float4*)&res[(size_t)n * 256 + lane * 4];
    acc.x = fminf(fmaxf(0.5f * acc.x + 0.5f * r.x, 0.f), 1.f);
    acc.y = fminf(fmaxf(0.5f * acc.y + 0.5f * r.y, 0.f), 1.f);
    acc.z = fminf(fmaxf(0.5f * acc.z + 0.5f * r.z, 0.f), 1.f);
    acc.w = fminf(fmaxf(0.5f * acc.w + 0.5f * r.w, 0.f), 1.f);
    if (out)    *(float4*)&out[(size_t)n * 256 + lane * 4] = acc;
    if (out_bf) *(uint2*)&out_bf[(size_t)n * 128 + lane * 2] = f4_to_bf4(acc);
}

// ---------- pooling ----------
__global__ void bounds_kernel(const int* __restrict__ batch, int* __restrict__ gstart) {
    int n = blockIdx.x * blockDim.x + threadIdx.x;
    if (n >= N_NODES) return;
    int b = batch[n];
    int prev = (n == 0) ? -1 : batch[n - 1];
    for (int g = prev + 1; g <= b; g++) gstart[g] = n;
    if (n == N_NODES - 1)
        for (int g = b + 1; g <= N_GRAPHS; g++) gstart[g] = N_NODES;
}
__global__ void pool_partial(const float* __restrict__ buf, const int* __restrict__ gstart,
                             float* __restrict__ psum, int C, int colOff) {
    int g = blockIdx.x, q = blockIdx.y;
    int n0 = gstart[g], n1 = gstart[g + 1];
    int len = n1 - n0;
    int ns = n0 + (len * q) / 4, ne = n0 + (len * (q + 1)) / 4;
    int cp = threadIdx.x % C;
    int np = threadIdx.x / C;
    int NP = 256 / C;
    float s = 0.f;
    for (int n = ns + np; n < ne; n += NP) s += buf[(size_t)n * C + cp];
    atomicAdd(&psum[g * JK + colOff + cp], s);
}
__global__ void gmean_kernel(const float* __restrict__ psum, const int* __restrict__ gstart,
                             float* __restrict__ g) {
    int i = blockIdx.x * blockDim.x + threadIdx.x;
    if (i >= N_GRAPHS * JK) return;
    int gi = i / JK;
    int len = gstart[gi + 1] - gstart[gi];
    g[i] = psum[i] / (float)(len > 1 ? len : 1);
}

// ---------- MLP head ----------
__global__ __launch_bounds__(64)
void head_d1(const float* __restrict__ gbuf, const float* __restrict__ W,
             const float* __restrict__ bias, float* __restrict__ out) {
    __shared__ float zin[JK];
    int g = blockIdx.y, mc = blockIdx.x, lane = threadIdx.x;
    for (int k = lane; k < JK; k += 64) zin[k] = gbuf[g * JK + k];
    __syncthreads();
    int m = mc * 64 + lane;
    float acc = bias[m];
#pragma unroll 8
    for (int k = 0; k < JK; k++) acc += zin[k] * W[k * 256 + m];
    out[g * 256 + m] = fmaxf(acc, 0.f);
}

__global__ __launch_bounds__(256)
void head_rest(const float* __restrict__ t1, const float* __restrict__ clin,
               const float* __restrict__ pp_w2, const float* __restrict__ pp_b2,
               const float* __restrict__ cl_w1, const float* __restrict__ cl_b1,
               const float* __restrict__ cl_w2, const float* __restrict__ cl_b2,
               const float* __restrict__ h_w1, const float* __restrict__ h_b1,
               const float* __restrict__ h_w2, const float* __restrict__ h_b2,
               const float* __restrict__ h_w3, const float* __restrict__ h_b3,
               float* __restrict__ out) {
    __shared__ float z1[256];
    __shared__ float zcl[32];
    __shared__ float zc[64];
    __shared__ float z[160];
    __shared__ float z3[64];
    __shared__ float z4[32];
    __shared__ float part[128];
    int g = blockIdx.x, t = threadIdx.x;
    z1[t] = t1[g * 256 + t];
    if (t < 32) zcl[t] = clin[g * 32 + t];
    __syncthreads();
    int m = t & 127, half = t >> 7;
    {
        float acc = 0.f;
        int k0 = half * 128;
#pragma unroll 8
        for (int k = k0; k < k0 + 128; k++) acc += z1[k] * pp_w2[k * 128 + m];
        if (half) part[m] = acc;
        __syncthreads();
        if (!half) z[m] = acc + part[m] + pp_b2[m];
    }
    if (t < 64) {
        float acc = cl_b1[t];
#pragma unroll
        for (int k = 0; k < 32; k++) acc += zcl[k] * cl_w1[k * 64 + t];
        zc[t] = fmaxf(acc, 0.f);
    }
    __syncthreads();
    if (t < 32) {
        float acc = cl_b2[t];
#pragma unroll
        for (int k = 0; k < 64; k++) acc += zc[k] * cl_w2[k * 32 + t];
        z[128 + t] = acc;
    }
    __syncthreads();
    if (t < 64) {
        float acc = h_b1[t];
#pragma unroll 8
        for (int k = 0; k < 160; k++) acc += z[k] * h_w1[k * 64 + t];
        z3[t] = fmaxf(acc, 0.f);
    }
    __syncthreads();
    if (t < 32) {
        float acc = h_b2[t];
#pragma unroll
        for (int k = 0; k < 64; k++) acc += z3[k] * h_w2[k * 32 + t];
        z4[t] = fmaxf(acc, 0.f);
    }
    __syncthreads();
    if (t < 2) {
        float acc = h_b3[t];
#pragma unroll
        for (int k = 0; k < 32; k++) acc += z4[k] * h_w3[k * 2 + t];
        out[g * 2 + t] = acc;
    }
}

// ---------- launch ----------
extern "C" void kernel_launch(void* const* d_in, const int* in_sizes, int n_in,
                              void* d_out, int out_size, void* d_ws, size_t ws_size,
                              hipStream_t stream) {
    const float* x     = (const float*)d_in[0];
    const int*   ei    = (const int*)d_in[1];
    const int*   batch = (const int*)d_in[2];
    const float* clin  = (const float*)d_in[3];
    const float* W1  = (const float*)d_in[4];
    const float* a1s = (const float*)d_in[5];
    const float* a1d = (const float*)d_in[6];
    const float* b1  = (const float*)d_in[7];
    const float* W2  = (const float*)d_in[8];
    const float* a2s = (const float*)d_in[9];
    const float* a2d = (const float*)d_in[10];
    const float* b2  = (const float*)d_in[11];
    const float* pp_w1 = (const float*)d_in[12];
    const float* pp_b1 = (const float*)d_in[13];
    const float* pp_w2 = (const float*)d_in[14];
    const float* pp_b2 = (const float*)d_in[15];
    const float* cl_w1 = (const float*)d_in[16];
    const float* cl_b1 = (const float*)d_in[17];
    const float* cl_w2 = (const float*)d_in[18];
    const float* cl_b2 = (const float*)d_in[19];
    const float* h_w1  = (const float*)d_in[20];
    const float* h_b1  = (const float*)d_in[21];
    const float* h_w2  = (const float*)d_in[22];
    const float* h_b2  = (const float*)d_in[23];
    const float* h_w3  = (const float*)d_in[24];
    const float* h_b3  = (const float*)d_in[25];

    const int* src = ei;
    const int* dst = ei + N_EDGES;

    char* p = (char*)d_ws;
    auto carve = [&](size_t bytes) -> char* {
        char* r = p;
        p += (bytes + 255) & ~(size_t)255;
        return r;
    };
    const size_t NB  = (size_t)N_NODES * 256 * 4;
    const size_t NBH = (size_t)N_NODES * 256 * 2;
    float*    bufA = (float*)carve(NB);      // fp32 h1 / h2_final
    float*    bufC = (float*)carve(NB);      // fp32 residual (h1a / h2a)
    unsigned* abf  = (unsigned*)carve(NBH);  // aggx bf16
    unsigned* bf1  = (unsigned*)carve(NBH);
    unsigned* bf2  = (unsigned*)carve(NBH);
    unsigned* bf3  = (unsigned*)carve(NBH);
    float* alpha_fb  = (float*)carve((size_t)N_EDGES * 4 * 4);
    int*   csr_src   = (int*)carve((size_t)N_EDGES * 4);
    float* wnorm     = (float*)carve((size_t)N_EDGES * 4);
    int*   off       = (int*)carve((size_t)(N_NODES + 1) * 4);
    int*   deg       = (int*)carve((size_t)N_NODES * 4);
    int*   cursor    = (int*)carve((size_t)N_NODES * 4);
    float* dis       = (float*)carve((size_t)N_NODES * 4);
    float* es        = (float*)carve((size_t)N_NODES * 4 * 4);
    float* ed        = (float*)carve((size_t)N_NODES * 4 * 4);
    float* wes1      = (float*)carve((size_t)64 * 4 * 4);
    float* wed1      = (float*)carve((size_t)64 * 4 * 4);
    float* wes2      = (float*)carve((size_t)256 * 4 * 4);
    float* wed2      = (float*)carve((size_t)256 * 4 * 4);
    unsigned short* W1T = (unsigned short*)carve((size_t)256 * 64 * 2);
    unsigned short* W2T = (unsigned short*)carve((size_t)256 * 256 * 2);
    int*   gstart    = (int*)carve((size_t)(N_GRAPHS + 1) * 4);
    float* psum      = (float*)carve((size_t)N_GRAPHS * JK * 4);
    float* gbuf      = (float*)carve((size_t)N_GRAPHS * JK * 4);
    float* t1        = (float*)carve((size_t)N_GRAPHS * 256 * 4);

    const int TB = 256;
    const int gN     = (N_NODES + TB - 1) / TB;
    const int gE     = (N_EDGES + TB - 1) / TB;
    const int gNwave = (N_NODES * 64 + TB - 1) / TB;
    const int gFuse  = (N_NODES + 3) / 4;
    const int gRow   = (N_NODES + 63) / 64;

    // ---- CSR + degree + pooling bounds + weight prep ----
    hipMemsetAsync(deg, 0, (size_t)N_NODES * 4, stream);
    hipMemsetAsync(cursor, 0, (size_t)N_NODES * 4, stream);
    hipMemsetAsync(psum, 0, (size_t)N_GRAPHS * JK * 4, stream);
    deg_kernel<<<gE, TB, 0, stream>>>(dst, deg);
    dis_kernel<<<gN, TB, 0, stream>>>(deg, dis);
    scan_kernel<<<1, 1024, 0, stream>>>(deg, off);
    csr_fill<<<gE, TB, 0, stream>>>(src, dst, off, cursor, dis, csr_src, wnorm);
    bounds_kernel<<<gN, TB, 0, stream>>>(batch, gstart);
    prep_w<<<1, 256, 0, stream>>>(W1, a1s, a1d, wes1, wed1, 64);
    prep_w<<<4, 256, 0, stream>>>(W2, a2s, a2d, wes2, wed2, 256);
    conv_wT<<<(256 * 64 + TB - 1) / TB, TB, 0, stream>>>(W1, W1T, 64, 256);
    conv_wT<<<(256 * 256 + TB - 1) / TB, TB, 0, stream>>>(W2, W2T, 256, 256);

    // ---- GAT layer 1: aggregate x -> bf16, then block-diag MFMA GEMM ----
    esed_x<<<gNwave, TB, 0, stream>>>(x, wes1, wed1, es, ed);
    gat1_fused<<<gFuse, TB, 0, stream>>>(off, csr_src, es, ed, x, abf, alpha_fb);
    mfma_gemm<64, 64><<<dim3(gRow, 4), 256, 0, stream>>>(
        (const unsigned short*)abf, 256, W1T, bufC, bf1, 256, N_NODES, b1, 1,
        64, 64 * 64, 64);                                   // bufC = h1a fp32, bf1 = h1a bf16

    // ---- label prop 1 (fp32 write only where consumed) ----
    lp_csr<<<gNwave, TB, 0, stream>>>(off, csr_src, wnorm, bf1, bufC, nullptr, bf2);
    lp_csr<<<gNwave, TB, 0, stream>>>(off, csr_src, wnorm, bf2, bufC, bufA, bf3); // h1: bufA fp32 + bf3

    pool_partial<<<dim3(N_GRAPHS, 4), TB, 0, stream>>>(bufA, gstart, psum, 256, 64);

    // ---- GAT layer 2: MFMA GEMM (bf16 out only), fused attention ----
    mfma_gemm<256, 256><<<dim3(gRow, 1), 256, 0, stream>>>(
        (const unsigned short*)bf3, 256, W2T, nullptr, bf1, 256, N_NODES, nullptr, 0,
        0, 0, 0);                                           // bf1 = h2 bf16
    esed_h<<<gNwave, TB, 0, stream>>>(bufA, wes2, wed2, es, ed);
    gat2_fused<<<gFuse, TB, 0, stream>>>(off, csr_src, es, ed, bf1, b2, bufC, bf2, alpha_fb);

    // ---- label prop 2 ----
    lp_csr<<<gNwave, TB, 0, stream>>>(off, csr_src, wnorm, bf2, bufC, nullptr, bf1);
    lp_csr<<<gNwave, TB, 0, stream>>>(off, csr_src, wnorm, bf1, bufC, bufA, nullptr); // bufA = h2_final

    // ---- pooling (x, h2) + mean ----
    pool_partial<<<dim3(N_GRAPHS, 4), TB, 0, stream>>>(x, gstart, psum, 64, 0);
    pool_partial<<<dim3(N_GRAPHS, 4), TB, 0, stream>>>(bufA, gstart, psum, 256, 320);
    gmean_kernel<<<(N_GRAPHS * JK + TB - 1) / TB, TB, 0, stream>>>(psum, gstart, gbuf);

    // ---- MLP head ----
    head_d1<<<dim3(4, N_GRAPHS), 64, 0, stream>>>(gbuf, pp_w1, pp_b1, t1);
    head_rest<<<N_GRAPHS, 256, 0, stream>>>(t1, clin, pp_w2, pp_b2, cl_w1, cl_b1,
                                            cl_w2, cl_b2, h_w1, h_b1, h_w2, h_b2,
                                            h_w3, h_b3, (float*)d_out);
}

// Round 7
// 945.629 us; speedup vs baseline: 18.4647x; 1.2274x over previous
//
#include <hip/hip_runtime.h>

#define N_NODES 50000
#define N_EDGES 800000
#define N_GRAPHS 128
#define JK 576              // 64 + 256 + 256
#define CAP 192             // max cached in-degree per node (Poisson(16); max~45)

typedef __attribute__((ext_vector_type(8))) short bf16x8;
typedef __attribute__((ext_vector_type(4))) float f32x4;

// ---------- bf16 pack/unpack helpers ----------
__device__ __forceinline__ unsigned f2_to_bf2(float a, float b) {
    unsigned ua = __float_as_uint(a), ub = __float_as_uint(b);
    ua = (ua + 0x7fffu + ((ua >> 16) & 1u)) >> 16;       // RNE
    ub = (ub + 0x7fffu + ((ub >> 16) & 1u)) >> 16;
    return ua | (ub << 16);
}
__device__ __forceinline__ uint2 f4_to_bf4(float4 v) {
    return make_uint2(f2_to_bf2(v.x, v.y), f2_to_bf2(v.z, v.w));
}
__device__ __forceinline__ float4 bf4_to_f4(uint2 u) {
    float4 r;
    r.x = __uint_as_float(u.x << 16);
    r.y = __uint_as_float(u.x & 0xffff0000u);
    r.z = __uint_as_float(u.y << 16);
    r.w = __uint_as_float(u.y & 0xffff0000u);
    return r;
}

// ---------- MFMA GEMM: bf16 out = A_bf16 @ B (BT n-major bf16), fp32 acc ----------
template<int BN, int KK>
__global__ __launch_bounds__(256)
void mfma_gemm(const unsigned short* __restrict__ Abf, int lda,
               const unsigned short* __restrict__ BT,
               unsigned* __restrict__ Cbf, int ldc,
               int M, const float* __restrict__ bias, int relu,
               int a_off, int b_off, int c_off) {
    __shared__ unsigned short As[64][32];
    __shared__ unsigned short Bs[BN][32];
    const int t = threadIdx.x;
    const int wav = t >> 6, lane = t & 63;
    const int quad = lane >> 4, l15 = lane & 15;
    const int m0 = blockIdx.x * 64;
    const int head = blockIdx.y;
    Abf += (size_t)head * a_off;
    BT  += (size_t)head * b_off;
    const float* bptr = bias ? bias + (size_t)head * c_off : nullptr;
    unsigned* cbf = Cbf + (((size_t)head * c_off) >> 1);

    f32x4 acc[BN / 16];
#pragma unroll
    for (int i = 0; i < BN / 16; i++) acc[i] = (f32x4){0.f, 0.f, 0.f, 0.f};

    const int arow = t >> 2, aseg = t & 3;
    for (int k0 = 0; k0 < KK; k0 += 32) {
        uint4 av = make_uint4(0, 0, 0, 0);
        int gm = m0 + arow;
        if (gm < M) av = *(const uint4*)&Abf[(size_t)gm * lda + k0 + aseg * 8];
        uint4 bv[BN == 256 ? 4 : 1];
        if (BN == 256) {
            const unsigned short* srcb = &BT[(size_t)t * KK + k0];
#pragma unroll
            for (int j = 0; j < 4; j++) bv[j] = *(const uint4*)&srcb[j * 8];
        } else {
            bv[0] = *(const uint4*)&BT[(size_t)arow * KK + k0 + aseg * 8];
        }
        __syncthreads();
        *(uint4*)&As[arow][aseg * 8] = av;
        if (BN == 256) {
#pragma unroll
            for (int j = 0; j < 4; j++) *(uint4*)&Bs[t][j * 8] = bv[j];
        } else {
            *(uint4*)&Bs[arow][aseg * 8] = bv[0];
        }
        __syncthreads();
        bf16x8 afrag = *(const bf16x8*)&As[wav * 16 + l15][quad * 8];
#pragma unroll
        for (int nt = 0; nt < BN / 16; nt++) {
            bf16x8 bfrag = *(const bf16x8*)&Bs[nt * 16 + l15][quad * 8];
            acc[nt] = __builtin_amdgcn_mfma_f32_16x16x32_bf16(afrag, bfrag, acc[nt], 0, 0, 0);
        }
    }
    int rbase = m0 + wav * 16 + quad * 4;
#pragma unroll
    for (int nt = 0; nt < BN / 16; nt++) {
        int col = nt * 16 + l15;
        float bb = bptr ? bptr[col] : 0.f;
#pragma unroll
        for (int r = 0; r < 4; r++) {
            int row = rbase + r;
            float v = acc[nt][r] + bb;
            if (relu) v = fmaxf(v, 0.f);
            float vp = __shfl_xor(v, 1);
            if (row < M && !(l15 & 1))
                cbf[((size_t)row * ldc + col) >> 1] = f2_to_bf2(v, vp);
        }
    }
}

// ---------- weight transpose + bf16 convert ----------
__global__ void conv_wT(const float* __restrict__ W, unsigned short* __restrict__ WT,
                        int IN, int OUT) {
    int i = blockIdx.x * blockDim.x + threadIdx.x;
    if (i >= IN * OUT) return;
    int n = i / IN, c = i - n * IN;
    unsigned u = __float_as_uint(W[(size_t)c * OUT + n]);
    u = (u + 0x7fffu + ((u >> 16) & 1u)) >> 16;
    WT[i] = (unsigned short)u;
}

// ---------- CSR build ----------
__global__ void deg_kernel(const int* __restrict__ dst, int* __restrict__ deg) {
    int t = blockIdx.x * blockDim.x + threadIdx.x;
    if (t < N_EDGES) atomicAdd(&deg[dst[t]], 1);
}
__global__ void dis_kernel(const int* __restrict__ deg, float* __restrict__ dis) {
    int i = blockIdx.x * blockDim.x + threadIdx.x;
    if (i >= N_NODES) return;
    int d = deg[i];
    dis[i] = d > 0 ? rsqrtf((float)d) : 0.f;
}
__global__ __launch_bounds__(1024) void scan_kernel(const int* __restrict__ deg,
                                                    int* __restrict__ off) {
    __shared__ int part[1024];
    int t = threadIdx.x;
    const int CH = (N_NODES + 1023) / 1024;
    int base = t * CH;
    int s = 0;
    for (int i = 0; i < CH; i++) {
        int n = base + i;
        if (n < N_NODES) s += deg[n];
    }
    part[t] = s;
    __syncthreads();
    for (int o = 1; o < 1024; o <<= 1) {
        int v = (t >= o) ? part[t - o] : 0;
        __syncthreads();
        part[t] += v;
        __syncthreads();
    }
    int run = (t == 0) ? 0 : part[t - 1];
    for (int i = 0; i < CH; i++) {
        int n = base + i;
        if (n < N_NODES) { off[n] = run; run += deg[n]; }
    }
    if (t == 1023) off[N_NODES] = run;
}
__global__ void csr_fill(const int* __restrict__ src, const int* __restrict__ dst,
                         const int* __restrict__ off, int* __restrict__ cursor,
                         int* __restrict__ csr_src) {
    int e = blockIdx.x * blockDim.x + threadIdx.x;
    if (e >= N_EDGES) return;
    int s = src[e], d = dst[e];
    int pos = off[d] + atomicAdd(&cursor[d], 1);
    csr_src[pos] = s;
}

// ---------- precontract W @ a ----------
__global__ void prep_w(const float* __restrict__ W, const float* __restrict__ as_,
                       const float* __restrict__ ad_, float* __restrict__ wes,
                       float* __restrict__ wed, int K) {
    int t = blockIdx.x * blockDim.x + threadIdx.x;
    if (t >= K * 4) return;
    int c = t >> 2, h = t & 3;
    float se = 0.f, sd = 0.f;
    for (int j = 0; j < 64; j++) {
        float w = W[(size_t)c * 256 + h * 64 + j];
        se += w * as_[h * 64 + j];
        sd += w * ad_[h * 64 + j];
    }
    wes[c * 4 + h] = se;
    wed[c * 4 + h] = sd;
}

// ---------- es/ed from K=64 fp32 input (x) ----------
__global__ void esed_x(const float* __restrict__ X, const float* __restrict__ wes,
                       const float* __restrict__ wed, float* __restrict__ es,
                       float* __restrict__ ed) {
    int gid = blockIdx.x * blockDim.x + threadIdx.x;
    int n = gid >> 6, lane = threadIdx.x & 63;
    if (n >= N_NODES) return;
    float xv = X[(size_t)n * 64 + lane];
    float4 a = *(const float4*)&wes[lane * 4];
    float4 b = *(const float4*)&wed[lane * 4];
    float4 ps = make_float4(xv * a.x, xv * a.y, xv * a.z, xv * a.w);
    float4 pd = make_float4(xv * b.x, xv * b.y, xv * b.z, xv * b.w);
#pragma unroll
    for (int o = 1; o < 64; o <<= 1) {
        ps.x += __shfl_xor(ps.x, o); ps.y += __shfl_xor(ps.y, o);
        ps.z += __shfl_xor(ps.z, o); ps.w += __shfl_xor(ps.w, o);
        pd.x += __shfl_xor(pd.x, o); pd.y += __shfl_xor(pd.y, o);
        pd.z += __shfl_xor(pd.z, o); pd.w += __shfl_xor(pd.w, o);
    }
    if (lane == 0) {
        *(float4*)&es[n * 4] = ps;
        *(float4*)&ed[n * 4] = pd;
    }
}

// ---------- es/ed from K=256 bf16 input (h1) ----------
__global__ void esed_h(const unsigned* __restrict__ Hbf, const float* __restrict__ wes,
                       const float* __restrict__ wed, float* __restrict__ es,
                       float* __restrict__ ed) {
    int gid = blockIdx.x * blockDim.x + threadIdx.x;
    int n = gid >> 6, lane = threadIdx.x & 63;
    if (n >= N_NODES) return;
    float4 xv = bf4_to_f4(*(const uint2*)&Hbf[(size_t)n * 128 + lane * 2]);
    float xs[4] = {xv.x, xv.y, xv.z, xv.w};
    float4 ps = make_float4(0.f, 0.f, 0.f, 0.f);
    float4 pd = make_float4(0.f, 0.f, 0.f, 0.f);
#pragma unroll
    for (int r = 0; r < 4; r++) {
        int c = lane * 4 + r;
        float4 a = *(const float4*)&wes[c * 4];
        float4 b = *(const float4*)&wed[c * 4];
        ps.x += xs[r] * a.x; ps.y += xs[r] * a.y; ps.z += xs[r] * a.z; ps.w += xs[r] * a.w;
        pd.x += xs[r] * b.x; pd.y += xs[r] * b.y; pd.z += xs[r] * b.z; pd.w += xs[r] * b.w;
    }
#pragma unroll
    for (int o = 1; o < 64; o <<= 1) {
        ps.x += __shfl_xor(ps.x, o); ps.y += __shfl_xor(ps.y, o);
        ps.z += __shfl_xor(ps.z, o); ps.w += __shfl_xor(ps.w, o);
        pd.x += __shfl_xor(pd.x, o); pd.y += __shfl_xor(pd.y, o);
        pd.z += __shfl_xor(pd.z, o); pd.w += __shfl_xor(pd.w, o);
    }
    if (lane == 0) {
        *(float4*)&es[n * 4] = ps;
        *(float4*)&ed[n * 4] = pd;
    }
}

// ---------- GAT1: fused softmax + x-aggregation (float4/lane, 4 edges/iter) ----------
__global__ __launch_bounds__(256)
void gat1_fused(const int* __restrict__ off, const int* __restrict__ csr_src,
                const float* __restrict__ es, const float* __restrict__ ed,
                const float* __restrict__ x, unsigned* __restrict__ aggx_bf,
                float* __restrict__ alpha_fb) {
    __shared__ float elds[4][CAP * 4];
    int wav = threadIdx.x >> 6, lane = threadIdx.x & 63;
    int n = blockIdx.x * 4 + wav;
    bool active = n < N_NODES;
    int p0 = 0, p1 = 0;
    float4 ed4 = make_float4(0.f, 0.f, 0.f, 0.f);
    if (active) { p0 = off[n]; p1 = off[n + 1]; ed4 = *(const float4*)&ed[n * 4]; }
    float4 sum = make_float4(0.f, 0.f, 0.f, 0.f);
    for (int p = p0 + lane; p < p1; p += 64) {
        int s = csr_src[p];
        float4 e4 = *(const float4*)&es[s * 4];
        e4.x += ed4.x; e4.y += ed4.y; e4.z += ed4.z; e4.w += ed4.w;
        e4.x = e4.x > 0.f ? e4.x : 0.2f * e4.x;
        e4.y = e4.y > 0.f ? e4.y : 0.2f * e4.y;
        e4.z = e4.z > 0.f ? e4.z : 0.2f * e4.z;
        e4.w = e4.w > 0.f ? e4.w : 0.2f * e4.w;
        e4.x = __expf(e4.x); e4.y = __expf(e4.y); e4.z = __expf(e4.z); e4.w = __expf(e4.w);
        int q = p - p0;
        if (q < CAP) *(float4*)&elds[wav][q * 4] = e4;
        else         *(float4*)&alpha_fb[(size_t)p * 4] = e4;
        sum.x += e4.x; sum.y += e4.y; sum.z += e4.z; sum.w += e4.w;
    }
#pragma unroll
    for (int o = 1; o < 64; o <<= 1) {
        sum.x += __shfl_xor(sum.x, o); sum.y += __shfl_xor(sum.y, o);
        sum.z += __shfl_xor(sum.z, o); sum.w += __shfl_xor(sum.w, o);
    }
    float4 rs;
    rs.x = sum.x > 0.f ? 1.f / sum.x : 0.f;
    rs.y = sum.y > 0.f ? 1.f / sum.y : 0.f;
    rs.z = sum.z > 0.f ? 1.f / sum.z : 0.f;
    rs.w = sum.w > 0.f ? 1.f / sum.w : 0.f;
    __syncthreads();
    if (!active) return;
    // phase 2: 4 edges per iteration, 16 lanes x float4 per edge
    int eg = lane >> 4, l15 = lane & 15;
    float4 a0 = make_float4(0.f, 0.f, 0.f, 0.f);
    float4 a1 = a0, a2 = a0, a3 = a0;
    for (int p = p0; p < p1; p += 4) {
        int pe = p + eg;
        float4 e4 = make_float4(0.f, 0.f, 0.f, 0.f);
        int s = 0;
        if (pe < p1) {
            int q = pe - p0;
            e4 = (q < CAP) ? *(const float4*)&elds[wav][q * 4]
                           : *(const float4*)&alpha_fb[(size_t)pe * 4];
            s = csr_src[pe];
        }
        float4 xv = *(const float4*)&x[(size_t)s * 64 + l15 * 4];
        a0.x += e4.x * xv.x; a0.y += e4.x * xv.y; a0.z += e4.x * xv.z; a0.w += e4.x * xv.w;
        a1.x += e4.y * xv.x; a1.y += e4.y * xv.y; a1.z += e4.y * xv.z; a1.w += e4.y * xv.w;
        a2.x += e4.z * xv.x; a2.y += e4.z * xv.y; a2.z += e4.z * xv.z; a2.w += e4.z * xv.w;
        a3.x += e4.w * xv.x; a3.y += e4.w * xv.y; a3.z += e4.w * xv.z; a3.w += e4.w * xv.w;
    }
#pragma unroll
    for (int o = 16; o < 64; o <<= 1) {
        a0.x += __shfl_xor(a0.x, o); a0.y += __shfl_xor(a0.y, o);
        a0.z += __shfl_xor(a0.z, o); a0.w += __shfl_xor(a0.w, o);
        a1.x += __shfl_xor(a1.x, o); a1.y += __shfl_xor(a1.y, o);
        a1.z += __shfl_xor(a1.z, o); a1.w += __shfl_xor(a1.w, o);
        a2.x += __shfl_xor(a2.x, o); a2.y += __shfl_xor(a2.y, o);
        a2.z += __shfl_xor(a2.z, o); a2.w += __shfl_xor(a2.w, o);
        a3.x += __shfl_xor(a3.x, o); a3.y += __shfl_xor(a3.y, o);
        a3.z += __shfl_xor(a3.z, o); a3.w += __shfl_xor(a3.w, o);
    }
    if (eg == 0) {
        a0.x *= rs.x; a0.y *= rs.x; a0.z *= rs.x; a0.w *= rs.x;
        a1.x *= rs.y; a1.y *= rs.y; a1.z *= rs.y; a1.w *= rs.y;
        a2.x *= rs.z; a2.y *= rs.z; a2.z *= rs.z; a2.w *= rs.z;
        a3.x *= rs.w; a3.y *= rs.w; a3.z *= rs.w; a3.w *= rs.w;
        size_t b = (size_t)n * 128 + l15 * 2;
        *(uint2*)&aggx_bf[b +  0] = f4_to_bf4(a0);
        *(uint2*)&aggx_bf[b + 32] = f4_to_bf4(a1);
        *(uint2*)&aggx_bf[b + 64] = f4_to_bf4(a2);
        *(uint2*)&aggx_bf[b + 96] = f4_to_bf4(a3);
    }
}

// ---------- GAT2: fused softmax + bf16 gather (uint4/lane, 2 edges/iter) ----------
__global__ __launch_bounds__(256)
void gat2_fused(const int* __restrict__ off, const int* __restrict__ csr_src,
                const float* __restrict__ es, const float* __restrict__ ed,
                const unsigned* __restrict__ H2bf, const float* __restrict__ bias,
                unsigned* __restrict__ outbf, float* __restrict__ alpha_fb) {
    __shared__ float elds[4][CAP * 4];
    int wav = threadIdx.x >> 6, lane = threadIdx.x & 63;
    int n = blockIdx.x * 4 + wav;
    bool active = n < N_NODES;
    int p0 = 0, p1 = 0;
    float4 ed4 = make_float4(0.f, 0.f, 0.f, 0.f);
    if (active) { p0 = off[n]; p1 = off[n + 1]; ed4 = *(const float4*)&ed[n * 4]; }
    float4 sum = make_float4(0.f, 0.f, 0.f, 0.f);
    for (int p = p0 + lane; p < p1; p += 64) {
        int s = csr_src[p];
        float4 e4 = *(const float4*)&es[s * 4];
        e4.x += ed4.x; e4.y += ed4.y; e4.z += ed4.z; e4.w += ed4.w;
        e4.x = e4.x > 0.f ? e4.x : 0.2f * e4.x;
        e4.y = e4.y > 0.f ? e4.y : 0.2f * e4.y;
        e4.z = e4.z > 0.f ? e4.z : 0.2f * e4.z;
        e4.w = e4.w > 0.f ? e4.w : 0.2f * e4.w;
        e4.x = __expf(e4.x); e4.y = __expf(e4.y); e4.z = __expf(e4.z); e4.w = __expf(e4.w);
        int q = p - p0;
        if (q < CAP) *(float4*)&elds[wav][q * 4] = e4;
        else         *(float4*)&alpha_fb[(size_t)p * 4] = e4;
        sum.x += e4.x; sum.y += e4.y; sum.z += e4.z; sum.w += e4.w;
    }
#pragma unroll
    for (int o = 1; o < 64; o <<= 1) {
        sum.x += __shfl_xor(sum.x, o); sum.y += __shfl_xor(sum.y, o);
        sum.z += __shfl_xor(sum.z, o); sum.w += __shfl_xor(sum.w, o);
    }
    __syncthreads();
    if (!active) return;
    // phase 2: 2 edges per iteration, 32 lanes x uint4 (8 bf16 feats) per edge
    int half = lane >> 5, l = lane & 31;
    int hh = l >> 3;                         // head for feats l*8..l*8+7
    float sh = (hh == 0) ? sum.x : (hh == 1) ? sum.y : (hh == 2) ? sum.z : sum.w;
    float rsh = sh > 0.f ? 1.f / sh : 0.f;
    float acc[8];
#pragma unroll
    for (int j = 0; j < 8; j++) acc[j] = 0.f;
    for (int p = p0; p < p1; p += 2) {
        int pe = p + half;
        float al = 0.f; int s = 0;
        if (pe < p1) {
            s = csr_src[pe];
            int q = pe - p0;
            al = (q < CAP) ? elds[wav][q * 4 + hh] : alpha_fb[(size_t)pe * 4 + hh];
        }
        uint4 rv = *(const uint4*)&H2bf[(size_t)s * 128 + l * 4];
        float4 f0 = bf4_to_f4(make_uint2(rv.x, rv.y));
        float4 f1 = bf4_to_f4(make_uint2(rv.z, rv.w));
        acc[0] += al * f0.x; acc[1] += al * f0.y; acc[2] += al * f0.z; acc[3] += al * f0.w;
        acc[4] += al * f1.x; acc[5] += al * f1.y; acc[6] += al * f1.z; acc[7] += al * f1.w;
    }
#pragma unroll
    for (int j = 0; j < 8; j++) acc[j] += __shfl_xor(acc[j], 32);
    if (half == 0) {
        float4 b0 = *(const float4*)&bias[l * 8];
        float4 b1 = *(const float4*)&bias[l * 8 + 4];
        float4 o0, o1;
        o0.x = fmaxf(acc[0] * rsh + b0.x, 0.f);
        o0.y = fmaxf(acc[1] * rsh + b0.y, 0.f);
        o0.z = fmaxf(acc[2] * rsh + b0.z, 0.f);
        o0.w = fmaxf(acc[3] * rsh + b0.w, 0.f);
        o1.x = fmaxf(acc[4] * rsh + b1.x, 0.f);
        o1.y = fmaxf(acc[5] * rsh + b1.y, 0.f);
        o1.z = fmaxf(acc[6] * rsh + b1.z, 0.f);
        o1.w = fmaxf(acc[7] * rsh + b1.w, 0.f);
        uint2 w0 = f4_to_bf4(o0), w1 = f4_to_bf4(o1);
        uint4 w = make_uint4(w0.x, w0.y, w1.x, w1.y);
        *(uint4*)&outbf[(size_t)n * 128 + l * 4] = w;
    }
}

// ---------- label prop: bf16 gather (uint4/lane, 2 edges/iter), bf16 residual ----------
__global__ void lp_csr(const int* __restrict__ off, const int* __restrict__ csr_src,
                       const float* __restrict__ dis, const unsigned* __restrict__ in_bf,
                       const unsigned* __restrict__ res_bf, unsigned* __restrict__ out_bf) {
    int gid = blockIdx.x * blockDim.x + threadIdx.x;
    int n = gid >> 6, lane = threadIdx.x & 63;
    if (n >= N_NODES) return;
    int half = lane >> 5, l = lane & 31;
    int p0 = off[n], p1 = off[n + 1];
    float disd = dis[n];
    float acc[8];
#pragma unroll
    for (int j = 0; j < 8; j++) acc[j] = 0.f;
    for (int p = p0; p < p1; p += 2) {
        int pe = p + half;
        float nr = 0.f; int s = 0;
        if (pe < p1) { s = csr_src[pe]; nr = dis[s] * disd; }
        uint4 rv = *(const uint4*)&in_bf[(size_t)s * 128 + l * 4];
        float4 f0 = bf4_to_f4(make_uint2(rv.x, rv.y));
        float4 f1 = bf4_to_f4(make_uint2(rv.z, rv.w));
        acc[0] += nr * f0.x; acc[1] += nr * f0.y; acc[2] += nr * f0.z; acc[3] += nr * f0.w;
        acc[4] += nr * f1.x; acc[5] += nr * f1.y; acc[6] += nr * f1.z; acc[7] += nr * f1.w;
    }
#pragma unroll
    for (int j = 0; j < 8; j++) acc[j] += __shfl_xor(acc[j], 32);
    if (half == 0) {
        uint4 rr = *(const uint4*)&res_bf[(size_t)n * 128 + l * 4];
        float4 r0 = bf4_to_f4(make_uint2(rr.x, rr.y));
        float4 r1 = bf4_to_f4(make_uint2(rr.z, rr.w));
        float4 o0, o1;
        o0.x = fminf(fmaxf(0.5f * acc[0] + 0.5f * r0.x, 0.f), 1.f);
        o0.y = fminf(fmaxf(0.5f * acc[1] + 0.5f * r0.y, 0.f), 1.f);
        o0.z = fminf(fmaxf(0.5f * acc[2] + 0.5f * r0.z, 0.f), 1.f);
        o0.w = fminf(fmaxf(0.5f * acc[3] + 0.5f * r0.w, 0.f), 1.f);
        o1.x = fminf(fmaxf(0.5f * acc[4] + 0.5f * r1.x, 0.f), 1.f);
        o1.y = fminf(fmaxf(0.5f * acc[5] + 0.5f * r1.y, 0.f), 1.f);
        o1.z = fminf(fmaxf(0.5f * acc[6] + 0.5f * r1.z, 0.f), 1.f);
        o1.w = fminf(fmaxf(0.5f * acc[7] + 0.5f * r1.w, 0.f), 1.f);
        uint2 w0 = f4_to_bf4(o0), w1 = f4_to_bf4(o1);
        uint4 w = make_uint4(w0.x, w0.y, w1.x, w1.y);
        *(uint4*)&out_bf[(size_t)n * 128 + l * 4] = w;
    }
}

// ---------- pooling ----------
__global__ void bounds_kernel(const int* __restrict__ batch, int* __restrict__ gstart) {
    int n = blockIdx.x * blockDim.x + threadIdx.x;
    if (n >= N_NODES) return;
    int b = batch[n];
    int prev = (n == 0) ? -1 : batch[n - 1];
    for (int g = prev + 1; g <= b; g++) gstart[g] = n;
    if (n == N_NODES - 1)
        for (int g = b + 1; g <= N_GRAPHS; g++) gstart[g] = N_NODES;
}
__global__ void pool_partial(const float* __restrict__ buf, const int* __restrict__ gstart,
                             float* __restrict__ psum, int C, int colOff) {
    int g = blockIdx.x, q = blockIdx.y;
    int n0 = gstart[g], n1 = gstart[g + 1];
    int len = n1 - n0;
    int ns = n0 + (len * q) / 4, ne = n0 + (len * (q + 1)) / 4;
    int cp = threadIdx.x % C;
    int np = threadIdx.x / C;
    int NP = 256 / C;
    float s = 0.f;
    for (int n = ns + np; n < ne; n += NP) s += buf[(size_t)n * C + cp];
    atomicAdd(&psum[g * JK + colOff + cp], s);
}
// bf16 pool for 256-feat buffers (row = 128 uints)
__global__ void pool_bf(const unsigned* __restrict__ buf, const int* __restrict__ gstart,
                        float* __restrict__ psum, int colOff) {
    int g = blockIdx.x, q = blockIdx.y;
    int n0 = gstart[g], n1 = gstart[g + 1];
    int len = n1 - n0;
    int ns = n0 + (len * q) / 4, ne = n0 + (len * (q + 1)) / 4;
    int cp = threadIdx.x & 127;
    int np = threadIdx.x >> 7;
    float s0 = 0.f, s1 = 0.f;
    for (int n = ns + np; n < ne; n += 2) {
        unsigned u = buf[(size_t)n * 128 + cp];
        s0 += __uint_as_float(u << 16);
        s1 += __uint_as_float(u & 0xffff0000u);
    }
    atomicAdd(&psum[g * JK + colOff + cp * 2 + 0], s0);
    atomicAdd(&psum[g * JK + colOff + cp * 2 + 1], s1);
}
__global__ void gmean_kernel(const float* __restrict__ psum, const int* __restrict__ gstart,
                             float* __restrict__ g) {
    int i = blockIdx.x * blockDim.x + threadIdx.x;
    if (i >= N_GRAPHS * JK) return;
    int gi = i / JK;
    int len = gstart[gi + 1] - gstart[gi];
    g[i] = psum[i] / (float)(len > 1 ? len : 1);
}

// ---------- MLP head ----------
__global__ __launch_bounds__(64)
void head_d1(const float* __restrict__ gbuf, const float* __restrict__ W,
             const float* __restrict__ bias, float* __restrict__ out) {
    __shared__ float zin[JK];
    int g = blockIdx.y, mc = blockIdx.x, lane = threadIdx.x;
    for (int k = lane; k < JK; k += 64) zin[k] = gbuf[g * JK + k];
    __syncthreads();
    int m = mc * 64 + lane;
    float acc = bias[m];
#pragma unroll 8
    for (int k = 0; k < JK; k++) acc += zin[k] * W[k * 256 + m];
    out[g * 256 + m] = fmaxf(acc, 0.f);
}

__global__ __launch_bounds__(256)
void head_rest(const float* __restrict__ t1, const float* __restrict__ clin,
               const float* __restrict__ pp_w2, const float* __restrict__ pp_b2,
               const float* __restrict__ cl_w1, const float* __restrict__ cl_b1,
               const float* __restrict__ cl_w2, const float* __restrict__ cl_b2,
               const float* __restrict__ h_w1, const float* __restrict__ h_b1,
               const float* __restrict__ h_w2, const float* __restrict__ h_b2,
               const float* __restrict__ h_w3, const float* __restrict__ h_b3,
               float* __restrict__ out) {
    __shared__ float z1[256];
    __shared__ float zcl[32];
    __shared__ float zc[64];
    __shared__ float z[160];
    __shared__ float z3[64];
    __shared__ float z4[32];
    __shared__ float part[128];
    int g = blockIdx.x, t = threadIdx.x;
    z1[t] = t1[g * 256 + t];
    if (t < 32) zcl[t] = clin[g * 32 + t];
    __syncthreads();
    int m = t & 127, half = t >> 7;
    {
        float acc = 0.f;
        int k0 = half * 128;
#pragma unroll 8
        for (int k = k0; k < k0 + 128; k++) acc += z1[k] * pp_w2[k * 128 + m];
        if (half) part[m] = acc;
        __syncthreads();
        if (!half) z[m] = acc + part[m] + pp_b2[m];
    }
    if (t < 64) {
        float acc = cl_b1[t];
#pragma unroll
        for (int k = 0; k < 32; k++) acc += zcl[k] * cl_w1[k * 64 + t];
        zc[t] = fmaxf(acc, 0.f);
    }
    __syncthreads();
    if (t < 32) {
        float acc = cl_b2[t];
#pragma unroll
        for (int k = 0; k < 64; k++) acc += zc[k] * cl_w2[k * 32 + t];
        z[128 + t] = acc;
    }
    __syncthreads();
    if (t < 64) {
        float acc = h_b1[t];
#pragma unroll 8
        for (int k = 0; k < 160; k++) acc += z[k] * h_w1[k * 64 + t];
        z3[t] = fmaxf(acc, 0.f);
    }
    __syncthreads();
    if (t < 32) {
        float acc = h_b2[t];
#pragma unroll
        for (int k = 0; k < 64; k++) acc += z3[k] * h_w2[k * 32 + t];
        z4[t] = fmaxf(acc, 0.f);
    }
    __syncthreads();
    if (t < 2) {
        float acc = h_b3[t];
#pragma unroll
        for (int k = 0; k < 32; k++) acc += z4[k] * h_w3[k * 2 + t];
        out[g * 2 + t] = acc;
    }
}

// ---------- launch ----------
extern "C" void kernel_launch(void* const* d_in, const int* in_sizes, int n_in,
                              void* d_out, int out_size, void* d_ws, size_t ws_size,
                              hipStream_t stream) {
    const float* x     = (const float*)d_in[0];
    const int*   ei    = (const int*)d_in[1];
    const int*   batch = (const int*)d_in[2];
    const float* clin  = (const float*)d_in[3];
    const float* W1  = (const float*)d_in[4];
    const float* a1s = (const float*)d_in[5];
    const float* a1d = (const float*)d_in[6];
    const float* b1  = (const float*)d_in[7];
    const float* W2  = (const float*)d_in[8];
    const float* a2s = (const float*)d_in[9];
    const float* a2d = (const float*)d_in[10];
    const float* b2  = (const float*)d_in[11];
    const float* pp_w1 = (const float*)d_in[12];
    const float* pp_b1 = (const float*)d_in[13];
    const float* pp_w2 = (const float*)d_in[14];
    const float* pp_b2 = (const float*)d_in[15];
    const float* cl_w1 = (const float*)d_in[16];
    const float* cl_b1 = (const float*)d_in[17];
    const float* cl_w2 = (const float*)d_in[18];
    const float* cl_b2 = (const float*)d_in[19];
    const float* h_w1  = (const float*)d_in[20];
    const float* h_b1  = (const float*)d_in[21];
    const float* h_w2  = (const float*)d_in[22];
    const float* h_b2  = (const float*)d_in[23];
    const float* h_w3  = (const float*)d_in[24];
    const float* h_b3  = (const float*)d_in[25];

    const int* src = ei;
    const int* dst = ei + N_EDGES;

    char* p = (char*)d_ws;
    auto carve = [&](size_t bytes) -> char* {
        char* r = p;
        p += (bytes + 255) & ~(size_t)255;
        return r;
    };
    const size_t NBH = (size_t)N_NODES * 256 * 2;    // bf16 node buffer
    unsigned* abf  = (unsigned*)carve(NBH);          // aggx, later h2_final
    unsigned* bf1  = (unsigned*)carve(NBH);
    unsigned* bf2  = (unsigned*)carve(NBH);
    unsigned* bf3  = (unsigned*)carve(NBH);
    float* alpha_fb  = (float*)carve((size_t)N_EDGES * 4 * 4);
    int*   csr_src   = (int*)carve((size_t)N_EDGES * 4);
    int*   off       = (int*)carve((size_t)(N_NODES + 1) * 4);
    int*   deg       = (int*)carve((size_t)N_NODES * 4);
    int*   cursor    = (int*)carve((size_t)N_NODES * 4);
    float* dis       = (float*)carve((size_t)N_NODES * 4);
    float* es        = (float*)carve((size_t)N_NODES * 4 * 4);
    float* ed        = (float*)carve((size_t)N_NODES * 4 * 4);
    float* wes1      = (float*)carve((size_t)64 * 4 * 4);
    float* wed1      = (float*)carve((size_t)64 * 4 * 4);
    float* wes2      = (float*)carve((size_t)256 * 4 * 4);
    float* wed2      = (float*)carve((size_t)256 * 4 * 4);
    unsigned short* W1T = (unsigned short*)carve((size_t)256 * 64 * 2);
    unsigned short* W2T = (unsigned short*)carve((size_t)256 * 256 * 2);
    int*   gstart    = (int*)carve((size_t)(N_GRAPHS + 1) * 4);
    float* psum      = (float*)carve((size_t)N_GRAPHS * JK * 4);
    float* gbuf      = (float*)carve((size_t)N_GRAPHS * JK * 4);
    float* t1        = (float*)carve((size_t)N_GRAPHS * 256 * 4);

    const int TB = 256;
    const int gN     = (N_NODES + TB - 1) / TB;
    const int gE     = (N_EDGES + TB - 1) / TB;
    const int gNwave = (N_NODES * 64 + TB - 1) / TB;
    const int gFuse  = (N_NODES + 3) / 4;
    const int gRow   = (N_NODES + 63) / 64;

    // ---- CSR + degree + pooling bounds + weight prep ----
    hipMemsetAsync(deg, 0, (size_t)N_NODES * 4, stream);
    hipMemsetAsync(cursor, 0, (size_t)N_NODES * 4, stream);
    hipMemsetAsync(psum, 0, (size_t)N_GRAPHS * JK * 4, stream);
    deg_kernel<<<gE, TB, 0, stream>>>(dst, deg);
    dis_kernel<<<gN, TB, 0, stream>>>(deg, dis);
    scan_kernel<<<1, 1024, 0, stream>>>(deg, off);
    csr_fill<<<gE, TB, 0, stream>>>(src, dst, off, cursor, csr_src);
    bounds_kernel<<<gN, TB, 0, stream>>>(batch, gstart);
    prep_w<<<1, 256, 0, stream>>>(W1, a1s, a1d, wes1, wed1, 64);
    prep_w<<<4, 256, 0, stream>>>(W2, a2s, a2d, wes2, wed2, 256);
    conv_wT<<<(256 * 64 + TB - 1) / TB, TB, 0, stream>>>(W1, W1T, 64, 256);
    conv_wT<<<(256 * 256 + TB - 1) / TB, TB, 0, stream>>>(W2, W2T, 256, 256);

    // ---- GAT layer 1 ----
    esed_x<<<gNwave, TB, 0, stream>>>(x, wes1, wed1, es, ed);
    gat1_fused<<<gFuse, TB, 0, stream>>>(off, csr_src, es, ed, x, abf, alpha_fb);
    mfma_gemm<64, 64><<<dim3(gRow, 4), 256, 0, stream>>>(
        (const unsigned short*)abf, 256, W1T, bf1, 256, N_NODES, b1, 1,
        64, 64 * 64, 64);                                   // bf1 = h1a

    // ---- label prop 1 (residual = bf1) ----
    lp_csr<<<gNwave, TB, 0, stream>>>(off, csr_src, dis, bf1, bf1, bf2);
    lp_csr<<<gNwave, TB, 0, stream>>>(off, csr_src, dis, bf2, bf1, bf3);   // bf3 = h1

    pool_bf<<<dim3(N_GRAPHS, 4), TB, 0, stream>>>(bf3, gstart, psum, 64);

    // ---- GAT layer 2 ----
    mfma_gemm<256, 256><<<dim3(gRow, 1), 256, 0, stream>>>(
        (const unsigned short*)bf3, 256, W2T, bf1, 256, N_NODES, nullptr, 0,
        0, 0, 0);                                           // bf1 = h2
    esed_h<<<gNwave, TB, 0, stream>>>(bf3, wes2, wed2, es, ed);
    gat2_fused<<<gFuse, TB, 0, stream>>>(off, csr_src, es, ed, bf1, b2, bf2, alpha_fb); // bf2 = h2a

    // ---- label prop 2 (residual = bf2) ----
    lp_csr<<<gNwave, TB, 0, stream>>>(off, csr_src, dis, bf2, bf2, bf1);
    lp_csr<<<gNwave, TB, 0, stream>>>(off, csr_src, dis, bf1, bf2, abf);   // abf = h2_final

    // ---- pooling (x fp32, h2 bf16) + mean ----
    pool_partial<<<dim3(N_GRAPHS, 4), TB, 0, stream>>>(x, gstart, psum, 64, 0);
    pool_bf<<<dim3(N_GRAPHS, 4), TB, 0, stream>>>(abf, gstart, psum, 320);
    gmean_kernel<<<(N_GRAPHS * JK + TB - 1) / TB, TB, 0, stream>>>(psum, gstart, gbuf);

    // ---- MLP head ----
    head_d1<<<dim3(4, N_GRAPHS), 64, 0, stream>>>(gbuf, pp_w1, pp_b1, t1);
    head_rest<<<N_GRAPHS, 256, 0, stream>>>(t1, clin, pp_w2, pp_b2, cl_w1, cl_b1,
                                            cl_w2, cl_b2, h_w1, h_b1, h_w2, h_b2,
                                            h_w3, h_b3, (float*)d_out);
}

// Round 8
// 878.323 us; speedup vs baseline: 19.8796x; 1.0766x over previous
//
#include <hip/hip_runtime.h>

#define N_NODES 50000
#define N_EDGES 800000
#define N_GRAPHS 128
#define JK 576              // 64 + 256 + 256
#define CAP 192             // max cached in-degree per node (Poisson(16); max~45)
#define NSB ((N_NODES + 255) / 256)   // scan blocks = 196

typedef __attribute__((ext_vector_type(8))) short bf16x8;
typedef __attribute__((ext_vector_type(4))) float f32x4;

// ---------- bf16 pack/unpack helpers ----------
__device__ __forceinline__ unsigned f2_to_bf2(float a, float b) {
    unsigned ua = __float_as_uint(a), ub = __float_as_uint(b);
    ua = (ua + 0x7fffu + ((ua >> 16) & 1u)) >> 16;       // RNE
    ub = (ub + 0x7fffu + ((ub >> 16) & 1u)) >> 16;
    return ua | (ub << 16);
}
__device__ __forceinline__ uint2 f4_to_bf4(float4 v) {
    return make_uint2(f2_to_bf2(v.x, v.y), f2_to_bf2(v.z, v.w));
}
__device__ __forceinline__ float4 bf4_to_f4(uint2 u) {
    float4 r;
    r.x = __uint_as_float(u.x << 16);
    r.y = __uint_as_float(u.x & 0xffff0000u);
    r.z = __uint_as_float(u.y << 16);
    r.w = __uint_as_float(u.y & 0xffff0000u);
    return r;
}

// ---------- MFMA GEMM: bf16 out = A_bf16 @ B (BT n-major bf16), fp32 acc ----------
template<int BN, int KK>
__global__ __launch_bounds__(256)
void mfma_gemm(const unsigned short* __restrict__ Abf, int lda,
               const unsigned short* __restrict__ BT,
               unsigned* __restrict__ Cbf, int ldc,
               int M, const float* __restrict__ bias, int relu,
               int a_off, int b_off, int c_off) {
    __shared__ unsigned short As[64][32];
    __shared__ unsigned short Bs[BN][32];
    const int t = threadIdx.x;
    const int wav = t >> 6, lane = t & 63;
    const int quad = lane >> 4, l15 = lane & 15;
    const int m0 = blockIdx.x * 64;
    const int head = blockIdx.y;
    Abf += (size_t)head * a_off;
    BT  += (size_t)head * b_off;
    const float* bptr = bias ? bias + (size_t)head * c_off : nullptr;
    unsigned* cbf = Cbf + (((size_t)head * c_off) >> 1);

    f32x4 acc[BN / 16];
#pragma unroll
    for (int i = 0; i < BN / 16; i++) acc[i] = (f32x4){0.f, 0.f, 0.f, 0.f};

    const int arow = t >> 2, aseg = t & 3;
    for (int k0 = 0; k0 < KK; k0 += 32) {
        uint4 av = make_uint4(0, 0, 0, 0);
        int gm = m0 + arow;
        if (gm < M) av = *(const uint4*)&Abf[(size_t)gm * lda + k0 + aseg * 8];
        uint4 bv[BN == 256 ? 4 : 1];
        if (BN == 256) {
            const unsigned short* srcb = &BT[(size_t)t * KK + k0];
#pragma unroll
            for (int j = 0; j < 4; j++) bv[j] = *(const uint4*)&srcb[j * 8];
        } else {
            bv[0] = *(const uint4*)&BT[(size_t)arow * KK + k0 + aseg * 8];
        }
        __syncthreads();
        *(uint4*)&As[arow][aseg * 8] = av;
        if (BN == 256) {
#pragma unroll
            for (int j = 0; j < 4; j++) *(uint4*)&Bs[t][j * 8] = bv[j];
        } else {
            *(uint4*)&Bs[arow][aseg * 8] = bv[0];
        }
        __syncthreads();
        bf16x8 afrag = *(const bf16x8*)&As[wav * 16 + l15][quad * 8];
#pragma unroll
        for (int nt = 0; nt < BN / 16; nt++) {
            bf16x8 bfrag = *(const bf16x8*)&Bs[nt * 16 + l15][quad * 8];
            acc[nt] = __builtin_amdgcn_mfma_f32_16x16x32_bf16(afrag, bfrag, acc[nt], 0, 0, 0);
        }
    }
    int rbase = m0 + wav * 16 + quad * 4;
#pragma unroll
    for (int nt = 0; nt < BN / 16; nt++) {
        int col = nt * 16 + l15;
        float bb = bptr ? bptr[col] : 0.f;
#pragma unroll
        for (int r = 0; r < 4; r++) {
            int row = rbase + r;
            float v = acc[nt][r] + bb;
            if (relu) v = fmaxf(v, 0.f);
            float vp = __shfl_xor(v, 1);
            if (row < M && !(l15 & 1))
                cbf[((size_t)row * ldc + col) >> 1] = f2_to_bf2(v, vp);
        }
    }
}

// ---------- weight transpose + bf16 convert ----------
__global__ void conv_wT(const float* __restrict__ W, unsigned short* __restrict__ WT,
                        int IN, int OUT) {
    int i = blockIdx.x * blockDim.x + threadIdx.x;
    if (i >= IN * OUT) return;
    int n = i / IN, c = i - n * IN;
    unsigned u = __float_as_uint(W[(size_t)c * OUT + n]);
    u = (u + 0x7fffu + ((u >> 16) & 1u)) >> 16;
    WT[i] = (unsigned short)u;
}

// ---------- CSR build ----------
__global__ void deg_kernel(const int* __restrict__ dst, int* __restrict__ deg) {
    int t = blockIdx.x * blockDim.x + threadIdx.x;
    if (t < N_EDGES) atomicAdd(&deg[dst[t]], 1);
}
__global__ void dis_kernel(const int* __restrict__ deg, float* __restrict__ dis) {
    int i = blockIdx.x * blockDim.x + threadIdx.x;
    if (i >= N_NODES) return;
    int d = deg[i];
    dis[i] = d > 0 ? rsqrtf((float)d) : 0.f;
}
// ---- hierarchical scan: per-block sums -> block prefix -> per-node offsets ----
__global__ __launch_bounds__(256) void scan_bsum(const int* __restrict__ deg,
                                                 int* __restrict__ bsum) {
    __shared__ int sd[256];
    int n = blockIdx.x * 256 + threadIdx.x;
    sd[threadIdx.x] = (n < N_NODES) ? deg[n] : 0;
    __syncthreads();
    for (int o = 128; o > 0; o >>= 1) {
        if (threadIdx.x < o) sd[threadIdx.x] += sd[threadIdx.x + o];
        __syncthreads();
    }
    if (threadIdx.x == 0) bsum[blockIdx.x] = sd[0];
}
__global__ __launch_bounds__(256) void scan_bpre(const int* __restrict__ bsum,
                                                 int* __restrict__ bpre,
                                                 int* __restrict__ off_last) {
    __shared__ int sd[256];
    int t = threadIdx.x;
    int v = (t < NSB) ? bsum[t] : 0;
    sd[t] = v;
    __syncthreads();
    for (int o = 1; o < 256; o <<= 1) {
        int u = (t >= o) ? sd[t - o] : 0;
        __syncthreads();
        sd[t] += u;
        __syncthreads();
    }
    if (t < NSB) bpre[t] = sd[t] - v;     // exclusive block prefix
    if (t == 255) *off_last = sd[255];    // total = N_EDGES
}
__global__ __launch_bounds__(256) void scan_off(const int* __restrict__ deg,
                                                const int* __restrict__ bpre,
                                                int* __restrict__ off) {
    __shared__ int sd[256];
    int n = blockIdx.x * 256 + threadIdx.x;
    int t = threadIdx.x;
    int v = (n < N_NODES) ? deg[n] : 0;
    sd[t] = v;
    __syncthreads();
    for (int o = 1; o < 256; o <<= 1) {
        int u = (t >= o) ? sd[t - o] : 0;
        __syncthreads();
        sd[t] += u;
        __syncthreads();
    }
    if (n < N_NODES) off[n] = bpre[blockIdx.x] + sd[t] - v;
}
__global__ void csr_fill(const int* __restrict__ src, const int* __restrict__ dst,
                         const int* __restrict__ off, int* __restrict__ cursor,
                         int* __restrict__ csr_src) {
    int e = blockIdx.x * blockDim.x + threadIdx.x;
    if (e >= N_EDGES) return;
    int s = src[e], d = dst[e];
    int pos = off[d] + atomicAdd(&cursor[d], 1);
    csr_src[pos] = s;
}

// ---------- precontract W @ a ----------
__global__ void prep_w(const float* __restrict__ W, const float* __restrict__ as_,
                       const float* __restrict__ ad_, float* __restrict__ wes,
                       float* __restrict__ wed, int K) {
    int t = blockIdx.x * blockDim.x + threadIdx.x;
    if (t >= K * 4) return;
    int c = t >> 2, h = t & 3;
    float se = 0.f, sd = 0.f;
    for (int j = 0; j < 64; j++) {
        float w = W[(size_t)c * 256 + h * 64 + j];
        se += w * as_[h * 64 + j];
        sd += w * ad_[h * 64 + j];
    }
    wes[c * 4 + h] = se;
    wed[c * 4 + h] = sd;
}

// ---------- es/ed from K=64 fp32 input (x) ----------
__global__ void esed_x(const float* __restrict__ X, const float* __restrict__ wes,
                       const float* __restrict__ wed, float* __restrict__ es,
                       float* __restrict__ ed) {
    int gid = blockIdx.x * blockDim.x + threadIdx.x;
    int n = gid >> 6, lane = threadIdx.x & 63;
    if (n >= N_NODES) return;
    float xv = X[(size_t)n * 64 + lane];
    float4 a = *(const float4*)&wes[lane * 4];
    float4 b = *(const float4*)&wed[lane * 4];
    float4 ps = make_float4(xv * a.x, xv * a.y, xv * a.z, xv * a.w);
    float4 pd = make_float4(xv * b.x, xv * b.y, xv * b.z, xv * b.w);
#pragma unroll
    for (int o = 1; o < 64; o <<= 1) {
        ps.x += __shfl_xor(ps.x, o); ps.y += __shfl_xor(ps.y, o);
        ps.z += __shfl_xor(ps.z, o); ps.w += __shfl_xor(ps.w, o);
        pd.x += __shfl_xor(pd.x, o); pd.y += __shfl_xor(pd.y, o);
        pd.z += __shfl_xor(pd.z, o); pd.w += __shfl_xor(pd.w, o);
    }
    if (lane == 0) {
        *(float4*)&es[n * 4] = ps;
        *(float4*)&ed[n * 4] = pd;
    }
}

// ---------- es/ed from K=256 bf16 input (h1) ----------
__global__ void esed_h(const unsigned* __restrict__ Hbf, const float* __restrict__ wes,
                       const float* __restrict__ wed, float* __restrict__ es,
                       float* __restrict__ ed) {
    int gid = blockIdx.x * blockDim.x + threadIdx.x;
    int n = gid >> 6, lane = threadIdx.x & 63;
    if (n >= N_NODES) return;
    float4 xv = bf4_to_f4(*(const uint2*)&Hbf[(size_t)n * 128 + lane * 2]);
    float xs[4] = {xv.x, xv.y, xv.z, xv.w};
    float4 ps = make_float4(0.f, 0.f, 0.f, 0.f);
    float4 pd = make_float4(0.f, 0.f, 0.f, 0.f);
#pragma unroll
    for (int r = 0; r < 4; r++) {
        int c = lane * 4 + r;
        float4 a = *(const float4*)&wes[c * 4];
        float4 b = *(const float4*)&wed[c * 4];
        ps.x += xs[r] * a.x; ps.y += xs[r] * a.y; ps.z += xs[r] * a.z; ps.w += xs[r] * a.w;
        pd.x += xs[r] * b.x; pd.y += xs[r] * b.y; pd.z += xs[r] * b.z; pd.w += xs[r] * b.w;
    }
#pragma unroll
    for (int o = 1; o < 64; o <<= 1) {
        ps.x += __shfl_xor(ps.x, o); ps.y += __shfl_xor(ps.y, o);
        ps.z += __shfl_xor(ps.z, o); ps.w += __shfl_xor(ps.w, o);
        pd.x += __shfl_xor(pd.x, o); pd.y += __shfl_xor(pd.y, o);
        pd.z += __shfl_xor(pd.z, o); pd.w += __shfl_xor(pd.w, o);
    }
    if (lane == 0) {
        *(float4*)&es[n * 4] = ps;
        *(float4*)&ed[n * 4] = pd;
    }
}

// ---------- GAT1: fused softmax + x-aggregation (float4/lane, 4 edges/iter) ----------
__global__ __launch_bounds__(256)
void gat1_fused(const int* __restrict__ off, const int* __restrict__ csr_src,
                const float* __restrict__ es, const float* __restrict__ ed,
                const float* __restrict__ x, unsigned* __restrict__ aggx_bf,
                float* __restrict__ alpha_fb) {
    __shared__ float elds[4][CAP * 4];
    int wav = threadIdx.x >> 6, lane = threadIdx.x & 63;
    int n = blockIdx.x * 4 + wav;
    bool active = n < N_NODES;
    int p0 = 0, p1 = 0;
    float4 ed4 = make_float4(0.f, 0.f, 0.f, 0.f);
    if (active) { p0 = off[n]; p1 = off[n + 1]; ed4 = *(const float4*)&ed[n * 4]; }
    float4 sum = make_float4(0.f, 0.f, 0.f, 0.f);
    for (int p = p0 + lane; p < p1; p += 64) {
        int s = csr_src[p];
        float4 e4 = *(const float4*)&es[s * 4];
        e4.x += ed4.x; e4.y += ed4.y; e4.z += ed4.z; e4.w += ed4.w;
        e4.x = e4.x > 0.f ? e4.x : 0.2f * e4.x;
        e4.y = e4.y > 0.f ? e4.y : 0.2f * e4.y;
        e4.z = e4.z > 0.f ? e4.z : 0.2f * e4.z;
        e4.w = e4.w > 0.f ? e4.w : 0.2f * e4.w;
        e4.x = __expf(e4.x); e4.y = __expf(e4.y); e4.z = __expf(e4.z); e4.w = __expf(e4.w);
        int q = p - p0;
        if (q < CAP) *(float4*)&elds[wav][q * 4] = e4;
        else         *(float4*)&alpha_fb[(size_t)p * 4] = e4;
        sum.x += e4.x; sum.y += e4.y; sum.z += e4.z; sum.w += e4.w;
    }
#pragma unroll
    for (int o = 1; o < 64; o <<= 1) {
        sum.x += __shfl_xor(sum.x, o); sum.y += __shfl_xor(sum.y, o);
        sum.z += __shfl_xor(sum.z, o); sum.w += __shfl_xor(sum.w, o);
    }
    float4 rs;
    rs.x = sum.x > 0.f ? 1.f / sum.x : 0.f;
    rs.y = sum.y > 0.f ? 1.f / sum.y : 0.f;
    rs.z = sum.z > 0.f ? 1.f / sum.z : 0.f;
    rs.w = sum.w > 0.f ? 1.f / sum.w : 0.f;
    __syncthreads();
    if (!active) return;
    int eg = lane >> 4, l15 = lane & 15;
    float4 a0 = make_float4(0.f, 0.f, 0.f, 0.f);
    float4 a1 = a0, a2 = a0, a3 = a0;
    for (int p = p0; p < p1; p += 4) {
        int pe = p + eg;
        float4 e4 = make_float4(0.f, 0.f, 0.f, 0.f);
        int s = 0;
        if (pe < p1) {
            int q = pe - p0;
            e4 = (q < CAP) ? *(const float4*)&elds[wav][q * 4]
                           : *(const float4*)&alpha_fb[(size_t)pe * 4];
            s = csr_src[pe];
        }
        float4 xv = *(const float4*)&x[(size_t)s * 64 + l15 * 4];
        a0.x += e4.x * xv.x; a0.y += e4.x * xv.y; a0.z += e4.x * xv.z; a0.w += e4.x * xv.w;
        a1.x += e4.y * xv.x; a1.y += e4.y * xv.y; a1.z += e4.y * xv.z; a1.w += e4.y * xv.w;
        a2.x += e4.z * xv.x; a2.y += e4.z * xv.y; a2.z += e4.z * xv.z; a2.w += e4.z * xv.w;
        a3.x += e4.w * xv.x; a3.y += e4.w * xv.y; a3.z += e4.w * xv.z; a3.w += e4.w * xv.w;
    }
#pragma unroll
    for (int o = 16; o < 64; o <<= 1) {
        a0.x += __shfl_xor(a0.x, o); a0.y += __shfl_xor(a0.y, o);
        a0.z += __shfl_xor(a0.z, o); a0.w += __shfl_xor(a0.w, o);
        a1.x += __shfl_xor(a1.x, o); a1.y += __shfl_xor(a1.y, o);
        a1.z += __shfl_xor(a1.z, o); a1.w += __shfl_xor(a1.w, o);
        a2.x += __shfl_xor(a2.x, o); a2.y += __shfl_xor(a2.y, o);
        a2.z += __shfl_xor(a2.z, o); a2.w += __shfl_xor(a2.w, o);
        a3.x += __shfl_xor(a3.x, o); a3.y += __shfl_xor(a3.y, o);
        a3.z += __shfl_xor(a3.z, o); a3.w += __shfl_xor(a3.w, o);
    }
    if (eg == 0) {
        a0.x *= rs.x; a0.y *= rs.x; a0.z *= rs.x; a0.w *= rs.x;
        a1.x *= rs.y; a1.y *= rs.y; a1.z *= rs.y; a1.w *= rs.y;
        a2.x *= rs.z; a2.y *= rs.z; a2.z *= rs.z; a2.w *= rs.z;
        a3.x *= rs.w; a3.y *= rs.w; a3.z *= rs.w; a3.w *= rs.w;
        size_t b = (size_t)n * 128 + l15 * 2;
        *(uint2*)&aggx_bf[b +  0] = f4_to_bf4(a0);
        *(uint2*)&aggx_bf[b + 32] = f4_to_bf4(a1);
        *(uint2*)&aggx_bf[b + 64] = f4_to_bf4(a2);
        *(uint2*)&aggx_bf[b + 96] = f4_to_bf4(a3);
    }
}

// ---------- GAT2: fused softmax + bf16 gather (uint4/lane, 2 edges/iter) ----------
__global__ __launch_bounds__(256)
void gat2_fused(const int* __restrict__ off, const int* __restrict__ csr_src,
                const float* __restrict__ es, const float* __restrict__ ed,
                const unsigned* __restrict__ H2bf, const float* __restrict__ bias,
                unsigned* __restrict__ outbf, float* __restrict__ alpha_fb) {
    __shared__ float elds[4][CAP * 4];
    int wav = threadIdx.x >> 6, lane = threadIdx.x & 63;
    int n = blockIdx.x * 4 + wav;
    bool active = n < N_NODES;
    int p0 = 0, p1 = 0;
    float4 ed4 = make_float4(0.f, 0.f, 0.f, 0.f);
    if (active) { p0 = off[n]; p1 = off[n + 1]; ed4 = *(const float4*)&ed[n * 4]; }
    float4 sum = make_float4(0.f, 0.f, 0.f, 0.f);
    for (int p = p0 + lane; p < p1; p += 64) {
        int s = csr_src[p];
        float4 e4 = *(const float4*)&es[s * 4];
        e4.x += ed4.x; e4.y += ed4.y; e4.z += ed4.z; e4.w += ed4.w;
        e4.x = e4.x > 0.f ? e4.x : 0.2f * e4.x;
        e4.y = e4.y > 0.f ? e4.y : 0.2f * e4.y;
        e4.z = e4.z > 0.f ? e4.z : 0.2f * e4.z;
        e4.w = e4.w > 0.f ? e4.w : 0.2f * e4.w;
        e4.x = __expf(e4.x); e4.y = __expf(e4.y); e4.z = __expf(e4.z); e4.w = __expf(e4.w);
        int q = p - p0;
        if (q < CAP) *(float4*)&elds[wav][q * 4] = e4;
        else         *(float4*)&alpha_fb[(size_t)p * 4] = e4;
        sum.x += e4.x; sum.y += e4.y; sum.z += e4.z; sum.w += e4.w;
    }
#pragma unroll
    for (int o = 1; o < 64; o <<= 1) {
        sum.x += __shfl_xor(sum.x, o); sum.y += __shfl_xor(sum.y, o);
        sum.z += __shfl_xor(sum.z, o); sum.w += __shfl_xor(sum.w, o);
    }
    __syncthreads();
    if (!active) return;
    int half = lane >> 5, l = lane & 31;
    int hh = l >> 3;
    float sh = (hh == 0) ? sum.x : (hh == 1) ? sum.y : (hh == 2) ? sum.z : sum.w;
    float rsh = sh > 0.f ? 1.f / sh : 0.f;
    float acc[8];
#pragma unroll
    for (int j = 0; j < 8; j++) acc[j] = 0.f;
    for (int p = p0; p < p1; p += 2) {
        int pe = p + half;
        float al = 0.f; int s = 0;
        if (pe < p1) {
            s = csr_src[pe];
            int q = pe - p0;
            al = (q < CAP) ? elds[wav][q * 4 + hh] : alpha_fb[(size_t)pe * 4 + hh];
        }
        uint4 rv = *(const uint4*)&H2bf[(size_t)s * 128 + l * 4];
        float4 f0 = bf4_to_f4(make_uint2(rv.x, rv.y));
        float4 f1 = bf4_to_f4(make_uint2(rv.z, rv.w));
        acc[0] += al * f0.x; acc[1] += al * f0.y; acc[2] += al * f0.z; acc[3] += al * f0.w;
        acc[4] += al * f1.x; acc[5] += al * f1.y; acc[6] += al * f1.z; acc[7] += al * f1.w;
    }
#pragma unroll
    for (int j = 0; j < 8; j++) acc[j] += __shfl_xor(acc[j], 32);
    if (half == 0) {
        float4 b0 = *(const float4*)&bias[l * 8];
        float4 b1 = *(const float4*)&bias[l * 8 + 4];
        float4 o0, o1;
        o0.x = fmaxf(acc[0] * rsh + b0.x, 0.f);
        o0.y = fmaxf(acc[1] * rsh + b0.y, 0.f);
        o0.z = fmaxf(acc[2] * rsh + b0.z, 0.f);
        o0.w = fmaxf(acc[3] * rsh + b0.w, 0.f);
        o1.x = fmaxf(acc[4] * rsh + b1.x, 0.f);
        o1.y = fmaxf(acc[5] * rsh + b1.y, 0.f);
        o1.z = fmaxf(acc[6] * rsh + b1.z, 0.f);
        o1.w = fmaxf(acc[7] * rsh + b1.w, 0.f);
        uint2 w0 = f4_to_bf4(o0), w1 = f4_to_bf4(o1);
        uint4 w = make_uint4(w0.x, w0.y, w1.x, w1.y);
        *(uint4*)&outbf[(size_t)n * 128 + l * 4] = w;
    }
}

// ---------- label prop: bf16 gather (uint4/lane, 2 edges/iter), bf16 residual ----------
__global__ void lp_csr(const int* __restrict__ off, const int* __restrict__ csr_src,
                       const float* __restrict__ dis, const unsigned* __restrict__ in_bf,
                       const unsigned* __restrict__ res_bf, unsigned* __restrict__ out_bf) {
    int gid = blockIdx.x * blockDim.x + threadIdx.x;
    int n = gid >> 6, lane = threadIdx.x & 63;
    if (n >= N_NODES) return;
    int half = lane >> 5, l = lane & 31;
    int p0 = off[n], p1 = off[n + 1];
    float disd = dis[n];
    float acc[8];
#pragma unroll
    for (int j = 0; j < 8; j++) acc[j] = 0.f;
    for (int p = p0; p < p1; p += 2) {
        int pe = p + half;
        float nr = 0.f; int s = 0;
        if (pe < p1) { s = csr_src[pe]; nr = dis[s] * disd; }
        uint4 rv = *(const uint4*)&in_bf[(size_t)s * 128 + l * 4];
        float4 f0 = bf4_to_f4(make_uint2(rv.x, rv.y));
        float4 f1 = bf4_to_f4(make_uint2(rv.z, rv.w));
        acc[0] += nr * f0.x; acc[1] += nr * f0.y; acc[2] += nr * f0.z; acc[3] += nr * f0.w;
        acc[4] += nr * f1.x; acc[5] += nr * f1.y; acc[6] += nr * f1.z; acc[7] += nr * f1.w;
    }
#pragma unroll
    for (int j = 0; j < 8; j++) acc[j] += __shfl_xor(acc[j], 32);
    if (half == 0) {
        uint4 rr = *(const uint4*)&res_bf[(size_t)n * 128 + l * 4];
        float4 r0 = bf4_to_f4(make_uint2(rr.x, rr.y));
        float4 r1 = bf4_to_f4(make_uint2(rr.z, rr.w));
        float4 o0, o1;
        o0.x = fminf(fmaxf(0.5f * acc[0] + 0.5f * r0.x, 0.f), 1.f);
        o0.y = fminf(fmaxf(0.5f * acc[1] + 0.5f * r0.y, 0.f), 1.f);
        o0.z = fminf(fmaxf(0.5f * acc[2] + 0.5f * r0.z, 0.f), 1.f);
        o0.w = fminf(fmaxf(0.5f * acc[3] + 0.5f * r0.w, 0.f), 1.f);
        o1.x = fminf(fmaxf(0.5f * acc[4] + 0.5f * r1.x, 0.f), 1.f);
        o1.y = fminf(fmaxf(0.5f * acc[5] + 0.5f * r1.y, 0.f), 1.f);
        o1.z = fminf(fmaxf(0.5f * acc[6] + 0.5f * r1.z, 0.f), 1.f);
        o1.w = fminf(fmaxf(0.5f * acc[7] + 0.5f * r1.w, 0.f), 1.f);
        uint2 w0 = f4_to_bf4(o0), w1 = f4_to_bf4(o1);
        uint4 w = make_uint4(w0.x, w0.y, w1.x, w1.y);
        *(uint4*)&out_bf[(size_t)n * 128 + l * 4] = w;
    }
}

// ---------- pooling ----------
__global__ void bounds_kernel(const int* __restrict__ batch, int* __restrict__ gstart) {
    int n = blockIdx.x * blockDim.x + threadIdx.x;
    if (n >= N_NODES) return;
    int b = batch[n];
    int prev = (n == 0) ? -1 : batch[n - 1];
    for (int g = prev + 1; g <= b; g++) gstart[g] = n;
    if (n == N_NODES - 1)
        for (int g = b + 1; g <= N_GRAPHS; g++) gstart[g] = N_NODES;
}
__global__ void pool_partial(const float* __restrict__ buf, const int* __restrict__ gstart,
                             float* __restrict__ psum, int C, int colOff) {
    int g = blockIdx.x, q = blockIdx.y;
    int n0 = gstart[g], n1 = gstart[g + 1];
    int len = n1 - n0;
    int ns = n0 + (len * q) / 4, ne = n0 + (len * (q + 1)) / 4;
    int cp = threadIdx.x % C;
    int np = threadIdx.x / C;
    int NP = 256 / C;
    float s = 0.f;
    for (int n = ns + np; n < ne; n += NP) s += buf[(size_t)n * C + cp];
    atomicAdd(&psum[g * JK + colOff + cp], s);
}
__global__ void pool_bf(const unsigned* __restrict__ buf, const int* __restrict__ gstart,
                        float* __restrict__ psum, int colOff) {
    int g = blockIdx.x, q = blockIdx.y;
    int n0 = gstart[g], n1 = gstart[g + 1];
    int len = n1 - n0;
    int ns = n0 + (len * q) / 4, ne = n0 + (len * (q + 1)) / 4;
    int cp = threadIdx.x & 127;
    int np = threadIdx.x >> 7;
    float s0 = 0.f, s1 = 0.f;
    for (int n = ns + np; n < ne; n += 2) {
        unsigned u = buf[(size_t)n * 128 + cp];
        s0 += __uint_as_float(u << 16);
        s1 += __uint_as_float(u & 0xffff0000u);
    }
    atomicAdd(&psum[g * JK + colOff + cp * 2 + 0], s0);
    atomicAdd(&psum[g * JK + colOff + cp * 2 + 1], s1);
}
__global__ void gmean_kernel(const float* __restrict__ psum, const int* __restrict__ gstart,
                             float* __restrict__ g) {
    int i = blockIdx.x * blockDim.x + threadIdx.x;
    if (i >= N_GRAPHS * JK) return;
    int gi = i / JK;
    int len = gstart[gi + 1] - gstart[gi];
    g[i] = psum[i] / (float)(len > 1 ? len : 1);
}

// ---------- MLP head ----------
__global__ __launch_bounds__(64)
void head_d1(const float* __restrict__ gbuf, const float* __restrict__ W,
             const float* __restrict__ bias, float* __restrict__ out) {
    __shared__ float zin[JK];
    int g = blockIdx.y, mc = blockIdx.x, lane = threadIdx.x;
    for (int k = lane; k < JK; k += 64) zin[k] = gbuf[g * JK + k];
    __syncthreads();
    int m = mc * 64 + lane;
    float acc = bias[m];
#pragma unroll 8
    for (int k = 0; k < JK; k++) acc += zin[k] * W[k * 256 + m];
    out[g * 256 + m] = fmaxf(acc, 0.f);
}

__global__ __launch_bounds__(256)
void head_rest(const float* __restrict__ t1, const float* __restrict__ clin,
               const float* __restrict__ pp_w2, const float* __restrict__ pp_b2,
               const float* __restrict__ cl_w1, const float* __restrict__ cl_b1,
               const float* __restrict__ cl_w2, const float* __restrict__ cl_b2,
               const float* __restrict__ h_w1, const float* __restrict__ h_b1,
               const float* __restrict__ h_w2, const float* __restrict__ h_b2,
               const float* __restrict__ h_w3, const float* __restrict__ h_b3,
               float* __restrict__ out) {
    __shared__ float z1[256];
    __shared__ float zcl[32];
    __shared__ float zc[64];
    __shared__ float z[160];
    __shared__ float z3[64];
    __shared__ float z4[32];
    __shared__ float part[128];
    int g = blockIdx.x, t = threadIdx.x;
    z1[t] = t1[g * 256 + t];
    if (t < 32) zcl[t] = clin[g * 32 + t];
    __syncthreads();
    int m = t & 127, half = t >> 7;
    {
        float acc = 0.f;
        int k0 = half * 128;
#pragma unroll 8
        for (int k = k0; k < k0 + 128; k++) acc += z1[k] * pp_w2[k * 128 + m];
        if (half) part[m] = acc;
        __syncthreads();
        if (!half) z[m] = acc + part[m] + pp_b2[m];
    }
    if (t < 64) {
        float acc = cl_b1[t];
#pragma unroll
        for (int k = 0; k < 32; k++) acc += zcl[k] * cl_w1[k * 64 + t];
        zc[t] = fmaxf(acc, 0.f);
    }
    __syncthreads();
    if (t < 32) {
        float acc = cl_b2[t];
#pragma unroll
        for (int k = 0; k < 64; k++) acc += zc[k] * cl_w2[k * 32 + t];
        z[128 + t] = acc;
    }
    __syncthreads();
    if (t < 64) {
        float acc = h_b1[t];
#pragma unroll 8
        for (int k = 0; k < 160; k++) acc += z[k] * h_w1[k * 64 + t];
        z3[t] = fmaxf(acc, 0.f);
    }
    __syncthreads();
    if (t < 32) {
        float acc = h_b2[t];
#pragma unroll
        for (int k = 0; k < 64; k++) acc += z3[k] * h_w2[k * 32 + t];
        z4[t] = fmaxf(acc, 0.f);
    }
    __syncthreads();
    if (t < 2) {
        float acc = h_b3[t];
#pragma unroll
        for (int k = 0; k < 32; k++) acc += z4[k] * h_w3[k * 2 + t];
        out[g * 2 + t] = acc;
    }
}

// ---------- launch ----------
extern "C" void kernel_launch(void* const* d_in, const int* in_sizes, int n_in,
                              void* d_out, int out_size, void* d_ws, size_t ws_size,
                              hipStream_t stream) {
    const float* x     = (const float*)d_in[0];
    const int*   ei    = (const int*)d_in[1];
    const int*   batch = (const int*)d_in[2];
    const float* clin  = (const float*)d_in[3];
    const float* W1  = (const float*)d_in[4];
    const float* a1s = (const float*)d_in[5];
    const float* a1d = (const float*)d_in[6];
    const float* b1  = (const float*)d_in[7];
    const float* W2  = (const float*)d_in[8];
    const float* a2s = (const float*)d_in[9];
    const float* a2d = (const float*)d_in[10];
    const float* b2  = (const float*)d_in[11];
    const float* pp_w1 = (const float*)d_in[12];
    const float* pp_b1 = (const float*)d_in[13];
    const float* pp_w2 = (const float*)d_in[14];
    const float* pp_b2 = (const float*)d_in[15];
    const float* cl_w1 = (const float*)d_in[16];
    const float* cl_b1 = (const float*)d_in[17];
    const float* cl_w2 = (const float*)d_in[18];
    const float* cl_b2 = (const float*)d_in[19];
    const float* h_w1  = (const float*)d_in[20];
    const float* h_b1  = (const float*)d_in[21];
    const float* h_w2  = (const float*)d_in[22];
    const float* h_b2  = (const float*)d_in[23];
    const float* h_w3  = (const float*)d_in[24];
    const float* h_b3  = (const float*)d_in[25];

    const int* src = ei;
    const int* dst = ei + N_EDGES;

    char* p = (char*)d_ws;
    auto carve = [&](size_t bytes) -> char* {
        char* r = p;
        p += (bytes + 255) & ~(size_t)255;
        return r;
    };
    const size_t NBH = (size_t)N_NODES * 256 * 2;    // bf16 node buffer
    unsigned* abf  = (unsigned*)carve(NBH);          // aggx, later h2_final
    unsigned* bf1  = (unsigned*)carve(NBH);
    unsigned* bf2  = (unsigned*)carve(NBH);
    unsigned* bf3  = (unsigned*)carve(NBH);
    float* alpha_fb  = (float*)carve((size_t)N_EDGES * 4 * 4);
    int*   csr_src   = (int*)carve((size_t)N_EDGES * 4);
    int*   off       = (int*)carve((size_t)(N_NODES + 1) * 4);
    int*   deg       = (int*)carve((size_t)N_NODES * 4);
    int*   cursor    = (int*)carve((size_t)N_NODES * 4);
    int*   bsum      = (int*)carve((size_t)NSB * 4);
    int*   bpre      = (int*)carve((size_t)NSB * 4);
    float* dis       = (float*)carve((size_t)N_NODES * 4);
    float* es        = (float*)carve((size_t)N_NODES * 4 * 4);
    float* ed        = (float*)carve((size_t)N_NODES * 4 * 4);
    float* wes1      = (float*)carve((size_t)64 * 4 * 4);
    float* wed1      = (float*)carve((size_t)64 * 4 * 4);
    float* wes2      = (float*)carve((size_t)256 * 4 * 4);
    float* wed2      = (float*)carve((size_t)256 * 4 * 4);
    unsigned short* W1T = (unsigned short*)carve((size_t)256 * 64 * 2);
    unsigned short* W2T = (unsigned short*)carve((size_t)256 * 256 * 2);
    int*   gstart    = (int*)carve((size_t)(N_GRAPHS + 1) * 4);
    float* psum      = (float*)carve((size_t)N_GRAPHS * JK * 4);
    float* gbuf      = (float*)carve((size_t)N_GRAPHS * JK * 4);
    float* t1        = (float*)carve((size_t)N_GRAPHS * 256 * 4);

    const int TB = 256;
    const int gN     = (N_NODES + TB - 1) / TB;
    const int gE     = (N_EDGES + TB - 1) / TB;
    const int gNwave = (N_NODES * 64 + TB - 1) / TB;
    const int gFuse  = (N_NODES + 3) / 4;
    const int gRow   = (N_NODES + 63) / 64;

    // ---- CSR + degree + pooling bounds + weight prep ----
    hipMemsetAsync(deg, 0, (size_t)N_NODES * 4, stream);
    hipMemsetAsync(cursor, 0, (size_t)N_NODES * 4, stream);
    hipMemsetAsync(psum, 0, (size_t)N_GRAPHS * JK * 4, stream);
    deg_kernel<<<gE, TB, 0, stream>>>(dst, deg);
    dis_kernel<<<gN, TB, 0, stream>>>(deg, dis);
    scan_bsum<<<NSB, 256, 0, stream>>>(deg, bsum);
    scan_bpre<<<1, 256, 0, stream>>>(bsum, bpre, &off[N_NODES]);
    scan_off<<<NSB, 256, 0, stream>>>(deg, bpre, off);
    csr_fill<<<gE, TB, 0, stream>>>(src, dst, off, cursor, csr_src);
    bounds_kernel<<<gN, TB, 0, stream>>>(batch, gstart);
    prep_w<<<1, 256, 0, stream>>>(W1, a1s, a1d, wes1, wed1, 64);
    prep_w<<<4, 256, 0, stream>>>(W2, a2s, a2d, wes2, wed2, 256);
    conv_wT<<<(256 * 64 + TB - 1) / TB, TB, 0, stream>>>(W1, W1T, 64, 256);
    conv_wT<<<(256 * 256 + TB - 1) / TB, TB, 0, stream>>>(W2, W2T, 256, 256);

    // ---- GAT layer 1 ----
    esed_x<<<gNwave, TB, 0, stream>>>(x, wes1, wed1, es, ed);
    gat1_fused<<<gFuse, TB, 0, stream>>>(off, csr_src, es, ed, x, abf, alpha_fb);
    mfma_gemm<64, 64><<<dim3(gRow, 4), 256, 0, stream>>>(
        (const unsigned short*)abf, 256, W1T, bf1, 256, N_NODES, b1, 1,
        64, 64 * 64, 64);                                   // bf1 = h1a

    // ---- label prop 1 (residual = bf1) ----
    lp_csr<<<gNwave, TB, 0, stream>>>(off, csr_src, dis, bf1, bf1, bf2);
    lp_csr<<<gNwave, TB, 0, stream>>>(off, csr_src, dis, bf2, bf1, bf3);   // bf3 = h1

    pool_bf<<<dim3(N_GRAPHS, 4), TB, 0, stream>>>(bf3, gstart, psum, 64);

    // ---- GAT layer 2 ----
    mfma_gemm<256, 256><<<dim3(gRow, 1), 256, 0, stream>>>(
        (const unsigned short*)bf3, 256, W2T, bf1, 256, N_NODES, nullptr, 0,
        0, 0, 0);                                           // bf1 = h2
    esed_h<<<gNwave, TB, 0, stream>>>(bf3, wes2, wed2, es, ed);
    gat2_fused<<<gFuse, TB, 0, stream>>>(off, csr_src, es, ed, bf1, b2, bf2, alpha_fb); // bf2 = h2a

    // ---- label prop 2 (residual = bf2) ----
    lp_csr<<<gNwave, TB, 0, stream>>>(off, csr_src, dis, bf2, bf2, bf1);
    lp_csr<<<gNwave, TB, 0, stream>>>(off, csr_src, dis, bf1, bf2, abf);   // abf = h2_final

    // ---- pooling (x fp32, h2 bf16) + mean ----
    pool_partial<<<dim3(N_GRAPHS, 4), TB, 0, stream>>>(x, gstart, psum, 64, 0);
    pool_bf<<<dim3(N_GRAPHS, 4), TB, 0, stream>>>(abf, gstart, psum, 320);
    gmean_kernel<<<(N_GRAPHS * JK + TB - 1) / TB, TB, 0, stream>>>(psum, gstart, gbuf);

    // ---- MLP head ----
    head_d1<<<dim3(4, N_GRAPHS), 64, 0, stream>>>(gbuf, pp_w1, pp_b1, t1);
    head_rest<<<N_GRAPHS, 256, 0, stream>>>(t1, clin, pp_w2, pp_b2, cl_w1, cl_b1,
                                            cl_w2, cl_b2, h_w1, h_b1, h_w2, h_b2,
                                            h_w3, h_b3, (float*)d_out);
}

// Round 9
// 834.318 us; speedup vs baseline: 20.9282x; 1.0527x over previous
//
#include <hip/hip_runtime.h>

#define N_NODES 50000
#define N_EDGES 800000
#define N_GRAPHS 128
#define JK 576              // 64 + 256 + 256
#define CAP 192             // max cached in-degree per node (Poisson(16); max~45)
#define NSB ((N_NODES + 255) / 256)   // scan blocks = 196

typedef __attribute__((ext_vector_type(8))) short bf16x8;
typedef __attribute__((ext_vector_type(4))) float f32x4;

// ---------- bf16 pack/unpack helpers ----------
__device__ __forceinline__ unsigned f2_to_bf2(float a, float b) {
    unsigned ua = __float_as_uint(a), ub = __float_as_uint(b);
    ua = (ua + 0x7fffu + ((ua >> 16) & 1u)) >> 16;       // RNE
    ub = (ub + 0x7fffu + ((ub >> 16) & 1u)) >> 16;
    return ua | (ub << 16);
}
__device__ __forceinline__ uint2 f4_to_bf4(float4 v) {
    return make_uint2(f2_to_bf2(v.x, v.y), f2_to_bf2(v.z, v.w));
}
__device__ __forceinline__ float4 bf4_to_f4(uint2 u) {
    float4 r;
    r.x = __uint_as_float(u.x << 16);
    r.y = __uint_as_float(u.x & 0xffff0000u);
    r.z = __uint_as_float(u.y << 16);
    r.w = __uint_as_float(u.y & 0xffff0000u);
    return r;
}

// ---------- MFMA GEMM: bf16 out = A_bf16 @ B (BT n-major bf16), fp32 acc ----------
template<int BN, int KK>
__global__ __launch_bounds__(256)
void mfma_gemm(const unsigned short* __restrict__ Abf, int lda,
               const unsigned short* __restrict__ BT,
               unsigned* __restrict__ Cbf, int ldc,
               int M, const float* __restrict__ bias, int relu,
               int a_off, int b_off, int c_off) {
    __shared__ unsigned short As[64][32];
    __shared__ unsigned short Bs[BN][32];
    const int t = threadIdx.x;
    const int wav = t >> 6, lane = t & 63;
    const int quad = lane >> 4, l15 = lane & 15;
    const int m0 = blockIdx.x * 64;
    const int head = blockIdx.y;
    Abf += (size_t)head * a_off;
    BT  += (size_t)head * b_off;
    const float* bptr = bias ? bias + (size_t)head * c_off : nullptr;
    unsigned* cbf = Cbf + (((size_t)head * c_off) >> 1);

    f32x4 acc[BN / 16];
#pragma unroll
    for (int i = 0; i < BN / 16; i++) acc[i] = (f32x4){0.f, 0.f, 0.f, 0.f};

    const int arow = t >> 2, aseg = t & 3;
    for (int k0 = 0; k0 < KK; k0 += 32) {
        uint4 av = make_uint4(0, 0, 0, 0);
        int gm = m0 + arow;
        if (gm < M) av = *(const uint4*)&Abf[(size_t)gm * lda + k0 + aseg * 8];
        uint4 bv[BN == 256 ? 4 : 1];
        if (BN == 256) {
            const unsigned short* srcb = &BT[(size_t)t * KK + k0];
#pragma unroll
            for (int j = 0; j < 4; j++) bv[j] = *(const uint4*)&srcb[j * 8];
        } else {
            bv[0] = *(const uint4*)&BT[(size_t)arow * KK + k0 + aseg * 8];
        }
        __syncthreads();
        *(uint4*)&As[arow][aseg * 8] = av;
        if (BN == 256) {
#pragma unroll
            for (int j = 0; j < 4; j++) *(uint4*)&Bs[t][j * 8] = bv[j];
        } else {
            *(uint4*)&Bs[arow][aseg * 8] = bv[0];
        }
        __syncthreads();
        bf16x8 afrag = *(const bf16x8*)&As[wav * 16 + l15][quad * 8];
#pragma unroll
        for (int nt = 0; nt < BN / 16; nt++) {
            bf16x8 bfrag = *(const bf16x8*)&Bs[nt * 16 + l15][quad * 8];
            acc[nt] = __builtin_amdgcn_mfma_f32_16x16x32_bf16(afrag, bfrag, acc[nt], 0, 0, 0);
        }
    }
    int rbase = m0 + wav * 16 + quad * 4;
#pragma unroll
    for (int nt = 0; nt < BN / 16; nt++) {
        int col = nt * 16 + l15;
        float bb = bptr ? bptr[col] : 0.f;
#pragma unroll
        for (int r = 0; r < 4; r++) {
            int row = rbase + r;
            float v = acc[nt][r] + bb;
            if (relu) v = fmaxf(v, 0.f);
            float vp = __shfl_xor(v, 1);
            if (row < M && !(l15 & 1))
                cbf[((size_t)row * ldc + col) >> 1] = f2_to_bf2(v, vp);
        }
    }
}

// ---------- weight transpose + bf16 convert ----------
__global__ void conv_wT(const float* __restrict__ W, unsigned short* __restrict__ WT,
                        int IN, int OUT) {
    int i = blockIdx.x * blockDim.x + threadIdx.x;
    if (i >= IN * OUT) return;
    int n = i / IN, c = i - n * IN;
    unsigned u = __float_as_uint(W[(size_t)c * OUT + n]);
    u = (u + 0x7fffu + ((u >> 16) & 1u)) >> 16;
    WT[i] = (unsigned short)u;
}

// ---------- CSR build ----------
__global__ void deg_kernel(const int* __restrict__ dst, int* __restrict__ deg) {
    int t = blockIdx.x * blockDim.x + threadIdx.x;
    if (t < N_EDGES) atomicAdd(&deg[dst[t]], 1);
}
__global__ void dis_kernel(const int* __restrict__ deg, float* __restrict__ dis) {
    int i = blockIdx.x * blockDim.x + threadIdx.x;
    if (i >= N_NODES) return;
    int d = deg[i];
    dis[i] = d > 0 ? rsqrtf((float)d) : 0.f;
}
// ---- hierarchical scan ----
__global__ __launch_bounds__(256) void scan_bsum(const int* __restrict__ deg,
                                                 int* __restrict__ bsum) {
    __shared__ int sd[256];
    int n = blockIdx.x * 256 + threadIdx.x;
    sd[threadIdx.x] = (n < N_NODES) ? deg[n] : 0;
    __syncthreads();
    for (int o = 128; o > 0; o >>= 1) {
        if (threadIdx.x < o) sd[threadIdx.x] += sd[threadIdx.x + o];
        __syncthreads();
    }
    if (threadIdx.x == 0) bsum[blockIdx.x] = sd[0];
}
__global__ __launch_bounds__(256) void scan_bpre(const int* __restrict__ bsum,
                                                 int* __restrict__ bpre,
                                                 int* __restrict__ off_last) {
    __shared__ int sd[256];
    int t = threadIdx.x;
    int v = (t < NSB) ? bsum[t] : 0;
    sd[t] = v;
    __syncthreads();
    for (int o = 1; o < 256; o <<= 1) {
        int u = (t >= o) ? sd[t - o] : 0;
        __syncthreads();
        sd[t] += u;
        __syncthreads();
    }
    if (t < NSB) bpre[t] = sd[t] - v;
    if (t == 255) *off_last = sd[255];
}
__global__ __launch_bounds__(256) void scan_off(const int* __restrict__ deg,
                                                const int* __restrict__ bpre,
                                                int* __restrict__ off) {
    __shared__ int sd[256];
    int n = blockIdx.x * 256 + threadIdx.x;
    int t = threadIdx.x;
    int v = (n < N_NODES) ? deg[n] : 0;
    sd[t] = v;
    __syncthreads();
    for (int o = 1; o < 256; o <<= 1) {
        int u = (t >= o) ? sd[t - o] : 0;
        __syncthreads();
        sd[t] += u;
        __syncthreads();
    }
    if (n < N_NODES) off[n] = bpre[blockIdx.x] + sd[t] - v;
}
__global__ void csr_fill(const int* __restrict__ src, const int* __restrict__ dst,
                         const int* __restrict__ off, int* __restrict__ cursor,
                         int* __restrict__ csr_src) {
    int e = blockIdx.x * blockDim.x + threadIdx.x;
    if (e >= N_EDGES) return;
    int s = src[e], d = dst[e];
    int pos = off[d] + atomicAdd(&cursor[d], 1);
    csr_src[pos] = s;
}

// ---------- precontract W @ a ----------
__global__ void prep_w(const float* __restrict__ W, const float* __restrict__ as_,
                       const float* __restrict__ ad_, float* __restrict__ wes,
                       float* __restrict__ wed, int K) {
    int t = blockIdx.x * blockDim.x + threadIdx.x;
    if (t >= K * 4) return;
    int c = t >> 2, h = t & 3;
    float se = 0.f, sd = 0.f;
    for (int j = 0; j < 64; j++) {
        float w = W[(size_t)c * 256 + h * 64 + j];
        se += w * as_[h * 64 + j];
        sd += w * ad_[h * 64 + j];
    }
    wes[c * 4 + h] = se;
    wed[c * 4 + h] = sd;
}

// ---------- es/ed from K=64 fp32 input (x) ----------
__global__ void esed_x(const float* __restrict__ X, const float* __restrict__ wes,
                       const float* __restrict__ wed, float* __restrict__ es,
                       float* __restrict__ ed) {
    int gid = blockIdx.x * blockDim.x + threadIdx.x;
    int n = gid >> 6, lane = threadIdx.x & 63;
    if (n >= N_NODES) return;
    float xv = X[(size_t)n * 64 + lane];
    float4 a = *(const float4*)&wes[lane * 4];
    float4 b = *(const float4*)&wed[lane * 4];
    float4 ps = make_float4(xv * a.x, xv * a.y, xv * a.z, xv * a.w);
    float4 pd = make_float4(xv * b.x, xv * b.y, xv * b.z, xv * b.w);
#pragma unroll
    for (int o = 1; o < 64; o <<= 1) {
        ps.x += __shfl_xor(ps.x, o); ps.y += __shfl_xor(ps.y, o);
        ps.z += __shfl_xor(ps.z, o); ps.w += __shfl_xor(ps.w, o);
        pd.x += __shfl_xor(pd.x, o); pd.y += __shfl_xor(pd.y, o);
        pd.z += __shfl_xor(pd.z, o); pd.w += __shfl_xor(pd.w, o);
    }
    if (lane == 0) {
        *(float4*)&es[n * 4] = ps;
        *(float4*)&ed[n * 4] = pd;
    }
}

// ---------- es/ed from K=256 bf16 input (h1) ----------
__global__ void esed_h(const unsigned* __restrict__ Hbf, const float* __restrict__ wes,
                       const float* __restrict__ wed, float* __restrict__ es,
                       float* __restrict__ ed) {
    int gid = blockIdx.x * blockDim.x + threadIdx.x;
    int n = gid >> 6, lane = threadIdx.x & 63;
    if (n >= N_NODES) return;
    float4 xv = bf4_to_f4(*(const uint2*)&Hbf[(size_t)n * 128 + lane * 2]);
    float xs[4] = {xv.x, xv.y, xv.z, xv.w};
    float4 ps = make_float4(0.f, 0.f, 0.f, 0.f);
    float4 pd = make_float4(0.f, 0.f, 0.f, 0.f);
#pragma unroll
    for (int r = 0; r < 4; r++) {
        int c = lane * 4 + r;
        float4 a = *(const float4*)&wes[c * 4];
        float4 b = *(const float4*)&wed[c * 4];
        ps.x += xs[r] * a.x; ps.y += xs[r] * a.y; ps.z += xs[r] * a.z; ps.w += xs[r] * a.w;
        pd.x += xs[r] * b.x; pd.y += xs[r] * b.y; pd.z += xs[r] * b.z; pd.w += xs[r] * b.w;
    }
#pragma unroll
    for (int o = 1; o < 64; o <<= 1) {
        ps.x += __shfl_xor(ps.x, o); ps.y += __shfl_xor(ps.y, o);
        ps.z += __shfl_xor(ps.z, o); ps.w += __shfl_xor(ps.w, o);
        pd.x += __shfl_xor(pd.x, o); pd.y += __shfl_xor(pd.y, o);
        pd.z += __shfl_xor(pd.z, o); pd.w += __shfl_xor(pd.w, o);
    }
    if (lane == 0) {
        *(float4*)&es[n * 4] = ps;
        *(float4*)&ed[n * 4] = pd;
    }
}

// ---------- GAT1: fused softmax + x-aggregation (pipelined gather) ----------
__global__ __launch_bounds__(256)
void gat1_fused(const int* __restrict__ off, const int* __restrict__ csr_src,
                const float* __restrict__ es, const float* __restrict__ ed,
                const float* __restrict__ x, unsigned* __restrict__ aggx_bf,
                float* __restrict__ alpha_fb) {
    __shared__ float elds[4][CAP * 4];
    int wav = threadIdx.x >> 6, lane = threadIdx.x & 63;
    int n = blockIdx.x * 4 + wav;
    bool active = n < N_NODES;
    int p0 = 0, p1 = 0;
    float4 ed4 = make_float4(0.f, 0.f, 0.f, 0.f);
    if (active) { p0 = off[n]; p1 = off[n + 1]; ed4 = *(const float4*)&ed[n * 4]; }
    float4 sum = make_float4(0.f, 0.f, 0.f, 0.f);
    for (int p = p0 + lane; p < p1; p += 64) {
        int s = csr_src[p];
        float4 e4 = *(const float4*)&es[s * 4];
        e4.x += ed4.x; e4.y += ed4.y; e4.z += ed4.z; e4.w += ed4.w;
        e4.x = e4.x > 0.f ? e4.x : 0.2f * e4.x;
        e4.y = e4.y > 0.f ? e4.y : 0.2f * e4.y;
        e4.z = e4.z > 0.f ? e4.z : 0.2f * e4.z;
        e4.w = e4.w > 0.f ? e4.w : 0.2f * e4.w;
        e4.x = __expf(e4.x); e4.y = __expf(e4.y); e4.z = __expf(e4.z); e4.w = __expf(e4.w);
        int q = p - p0;
        if (q < CAP) *(float4*)&elds[wav][q * 4] = e4;
        else         *(float4*)&alpha_fb[(size_t)p * 4] = e4;
        sum.x += e4.x; sum.y += e4.y; sum.z += e4.z; sum.w += e4.w;
    }
#pragma unroll
    for (int o = 1; o < 64; o <<= 1) {
        sum.x += __shfl_xor(sum.x, o); sum.y += __shfl_xor(sum.y, o);
        sum.z += __shfl_xor(sum.z, o); sum.w += __shfl_xor(sum.w, o);
    }
    float4 rs;
    rs.x = sum.x > 0.f ? 1.f / sum.x : 0.f;
    rs.y = sum.y > 0.f ? 1.f / sum.y : 0.f;
    rs.z = sum.z > 0.f ? 1.f / sum.z : 0.f;
    rs.w = sum.w > 0.f ? 1.f / sum.w : 0.f;
    __syncthreads();
    if (!active) return;
    // phase 2: 4 edges/iter, 16 lanes x float4 per edge, 2-deep pipeline
    int eg = lane >> 4, l15 = lane & 15;
    float4 a0 = make_float4(0.f, 0.f, 0.f, 0.f);
    float4 a1 = a0, a2 = a0, a3 = a0;
    int pe = p0 + eg;
    float4 eA = make_float4(0.f, 0.f, 0.f, 0.f);
    float4 xA = eA;
    if (pe < p1) {
        int q = pe - p0;
        eA = (q < CAP) ? *(const float4*)&elds[wav][q * 4]
                       : *(const float4*)&alpha_fb[(size_t)pe * 4];
        xA = *(const float4*)&x[(size_t)csr_src[pe] * 64 + l15 * 4];
    }
    while (pe < p1) {
        int pn = pe + 4;
        float4 eB = make_float4(0.f, 0.f, 0.f, 0.f);
        float4 xB = eB;
        if (pn < p1) {
            int q = pn - p0;
            eB = (q < CAP) ? *(const float4*)&elds[wav][q * 4]
                           : *(const float4*)&alpha_fb[(size_t)pn * 4];
            xB = *(const float4*)&x[(size_t)csr_src[pn] * 64 + l15 * 4];
        }
        a0.x += eA.x * xA.x; a0.y += eA.x * xA.y; a0.z += eA.x * xA.z; a0.w += eA.x * xA.w;
        a1.x += eA.y * xA.x; a1.y += eA.y * xA.y; a1.z += eA.y * xA.z; a1.w += eA.y * xA.w;
        a2.x += eA.z * xA.x; a2.y += eA.z * xA.y; a2.z += eA.z * xA.z; a2.w += eA.z * xA.w;
        a3.x += eA.w * xA.x; a3.y += eA.w * xA.y; a3.z += eA.w * xA.z; a3.w += eA.w * xA.w;
        eA = eB; xA = xB; pe = pn;
    }
#pragma unroll
    for (int o = 16; o < 64; o <<= 1) {
        a0.x += __shfl_xor(a0.x, o); a0.y += __shfl_xor(a0.y, o);
        a0.z += __shfl_xor(a0.z, o); a0.w += __shfl_xor(a0.w, o);
        a1.x += __shfl_xor(a1.x, o); a1.y += __shfl_xor(a1.y, o);
        a1.z += __shfl_xor(a1.z, o); a1.w += __shfl_xor(a1.w, o);
        a2.x += __shfl_xor(a2.x, o); a2.y += __shfl_xor(a2.y, o);
        a2.z += __shfl_xor(a2.z, o); a2.w += __shfl_xor(a2.w, o);
        a3.x += __shfl_xor(a3.x, o); a3.y += __shfl_xor(a3.y, o);
        a3.z += __shfl_xor(a3.z, o); a3.w += __shfl_xor(a3.w, o);
    }
    if (eg == 0) {
        a0.x *= rs.x; a0.y *= rs.x; a0.z *= rs.x; a0.w *= rs.x;
        a1.x *= rs.y; a1.y *= rs.y; a1.z *= rs.y; a1.w *= rs.y;
        a2.x *= rs.z; a2.y *= rs.z; a2.z *= rs.z; a2.w *= rs.z;
        a3.x *= rs.w; a3.y *= rs.w; a3.z *= rs.w; a3.w *= rs.w;
        size_t b = (size_t)n * 128 + l15 * 2;
        *(uint2*)&aggx_bf[b +  0] = f4_to_bf4(a0);
        *(uint2*)&aggx_bf[b + 32] = f4_to_bf4(a1);
        *(uint2*)&aggx_bf[b + 64] = f4_to_bf4(a2);
        *(uint2*)&aggx_bf[b + 96] = f4_to_bf4(a3);
    }
}

// ---------- GAT2: fused softmax + bf16 gather (pipelined) ----------
__global__ __launch_bounds__(256)
void gat2_fused(const int* __restrict__ off, const int* __restrict__ csr_src,
                const float* __restrict__ es, const float* __restrict__ ed,
                const unsigned* __restrict__ H2bf, const float* __restrict__ bias,
                unsigned* __restrict__ outbf, float* __restrict__ alpha_fb) {
    __shared__ float elds[4][CAP * 4];
    int wav = threadIdx.x >> 6, lane = threadIdx.x & 63;
    int n = blockIdx.x * 4 + wav;
    bool active = n < N_NODES;
    int p0 = 0, p1 = 0;
    float4 ed4 = make_float4(0.f, 0.f, 0.f, 0.f);
    if (active) { p0 = off[n]; p1 = off[n + 1]; ed4 = *(const float4*)&ed[n * 4]; }
    float4 sum = make_float4(0.f, 0.f, 0.f, 0.f);
    for (int p = p0 + lane; p < p1; p += 64) {
        int s = csr_src[p];
        float4 e4 = *(const float4*)&es[s * 4];
        e4.x += ed4.x; e4.y += ed4.y; e4.z += ed4.z; e4.w += ed4.w;
        e4.x = e4.x > 0.f ? e4.x : 0.2f * e4.x;
        e4.y = e4.y > 0.f ? e4.y : 0.2f * e4.y;
        e4.z = e4.z > 0.f ? e4.z : 0.2f * e4.z;
        e4.w = e4.w > 0.f ? e4.w : 0.2f * e4.w;
        e4.x = __expf(e4.x); e4.y = __expf(e4.y); e4.z = __expf(e4.z); e4.w = __expf(e4.w);
        int q = p - p0;
        if (q < CAP) *(float4*)&elds[wav][q * 4] = e4;
        else         *(float4*)&alpha_fb[(size_t)p * 4] = e4;
        sum.x += e4.x; sum.y += e4.y; sum.z += e4.z; sum.w += e4.w;
    }
#pragma unroll
    for (int o = 1; o < 64; o <<= 1) {
        sum.x += __shfl_xor(sum.x, o); sum.y += __shfl_xor(sum.y, o);
        sum.z += __shfl_xor(sum.z, o); sum.w += __shfl_xor(sum.w, o);
    }
    __syncthreads();
    if (!active) return;
    int half = lane >> 5, l = lane & 31;
    int hh = l >> 3;
    float sh = (hh == 0) ? sum.x : (hh == 1) ? sum.y : (hh == 2) ? sum.z : sum.w;
    float rsh = sh > 0.f ? 1.f / sh : 0.f;
    float acc[8];
#pragma unroll
    for (int j = 0; j < 8; j++) acc[j] = 0.f;
    int pe = p0 + half;
    float aA = 0.f;
    uint4 rA = make_uint4(0, 0, 0, 0);
    if (pe < p1) {
        int q = pe - p0;
        aA = (q < CAP) ? elds[wav][q * 4 + hh] : alpha_fb[(size_t)pe * 4 + hh];
        rA = *(const uint4*)&H2bf[(size_t)csr_src[pe] * 128 + l * 4];
    }
    while (pe < p1) {
        int pn = pe + 2;
        float aB = 0.f;
        uint4 rB = make_uint4(0, 0, 0, 0);
        if (pn < p1) {
            int q = pn - p0;
            aB = (q < CAP) ? elds[wav][q * 4 + hh] : alpha_fb[(size_t)pn * 4 + hh];
            rB = *(const uint4*)&H2bf[(size_t)csr_src[pn] * 128 + l * 4];
        }
        float4 f0 = bf4_to_f4(make_uint2(rA.x, rA.y));
        float4 f1 = bf4_to_f4(make_uint2(rA.z, rA.w));
        acc[0] += aA * f0.x; acc[1] += aA * f0.y; acc[2] += aA * f0.z; acc[3] += aA * f0.w;
        acc[4] += aA * f1.x; acc[5] += aA * f1.y; acc[6] += aA * f1.z; acc[7] += aA * f1.w;
        aA = aB; rA = rB; pe = pn;
    }
#pragma unroll
    for (int j = 0; j < 8; j++) acc[j] += __shfl_xor(acc[j], 32);
    if (half == 0) {
        float4 b0 = *(const float4*)&bias[l * 8];
        float4 b1 = *(const float4*)&bias[l * 8 + 4];
        float4 o0, o1;
        o0.x = fmaxf(acc[0] * rsh + b0.x, 0.f);
        o0.y = fmaxf(acc[1] * rsh + b0.y, 0.f);
        o0.z = fmaxf(acc[2] * rsh + b0.z, 0.f);
        o0.w = fmaxf(acc[3] * rsh + b0.w, 0.f);
        o1.x = fmaxf(acc[4] * rsh + b1.x, 0.f);
        o1.y = fmaxf(acc[5] * rsh + b1.y, 0.f);
        o1.z = fmaxf(acc[6] * rsh + b1.z, 0.f);
        o1.w = fmaxf(acc[7] * rsh + b1.w, 0.f);
        uint2 w0 = f4_to_bf4(o0), w1 = f4_to_bf4(o1);
        uint4 w = make_uint4(w0.x, w0.y, w1.x, w1.y);
        *(uint4*)&outbf[(size_t)n * 128 + l * 4] = w;
    }
}

// ---------- label prop: bf16 gather, 2-deep pipelined ----------
__global__ void lp_csr(const int* __restrict__ off, const int* __restrict__ csr_src,
                       const float* __restrict__ dis, const unsigned* __restrict__ in_bf,
                       const unsigned* __restrict__ res_bf, unsigned* __restrict__ out_bf) {
    int gid = blockIdx.x * blockDim.x + threadIdx.x;
    int n = gid >> 6, lane = threadIdx.x & 63;
    if (n >= N_NODES) return;
    int half = lane >> 5, l = lane & 31;
    int p0 = off[n], p1 = off[n + 1];
    float disd = dis[n];
    float acc[8];
#pragma unroll
    for (int j = 0; j < 8; j++) acc[j] = 0.f;
    int pe = p0 + half;
    float nA = 0.f;
    uint4 rA = make_uint4(0, 0, 0, 0);
    if (pe < p1) {
        int s = csr_src[pe];
        nA = dis[s] * disd;
        rA = *(const uint4*)&in_bf[(size_t)s * 128 + l * 4];
    }
    while (pe < p1) {
        int pn = pe + 2;
        float nB = 0.f;
        uint4 rB = make_uint4(0, 0, 0, 0);
        if (pn < p1) {
            int s = csr_src[pn];
            nB = dis[s] * disd;
            rB = *(const uint4*)&in_bf[(size_t)s * 128 + l * 4];
        }
        float4 f0 = bf4_to_f4(make_uint2(rA.x, rA.y));
        float4 f1 = bf4_to_f4(make_uint2(rA.z, rA.w));
        acc[0] += nA * f0.x; acc[1] += nA * f0.y; acc[2] += nA * f0.z; acc[3] += nA * f0.w;
        acc[4] += nA * f1.x; acc[5] += nA * f1.y; acc[6] += nA * f1.z; acc[7] += nA * f1.w;
        nA = nB; rA = rB; pe = pn;
    }
#pragma unroll
    for (int j = 0; j < 8; j++) acc[j] += __shfl_xor(acc[j], 32);
    if (half == 0) {
        uint4 rr = *(const uint4*)&res_bf[(size_t)n * 128 + l * 4];
        float4 r0 = bf4_to_f4(make_uint2(rr.x, rr.y));
        float4 r1 = bf4_to_f4(make_uint2(rr.z, rr.w));
        float4 o0, o1;
        o0.x = fminf(fmaxf(0.5f * acc[0] + 0.5f * r0.x, 0.f), 1.f);
        o0.y = fminf(fmaxf(0.5f * acc[1] + 0.5f * r0.y, 0.f), 1.f);
        o0.z = fminf(fmaxf(0.5f * acc[2] + 0.5f * r0.z, 0.f), 1.f);
        o0.w = fminf(fmaxf(0.5f * acc[3] + 0.5f * r0.w, 0.f), 1.f);
        o1.x = fminf(fmaxf(0.5f * acc[4] + 0.5f * r1.x, 0.f), 1.f);
        o1.y = fminf(fmaxf(0.5f * acc[5] + 0.5f * r1.y, 0.f), 1.f);
        o1.z = fminf(fmaxf(0.5f * acc[6] + 0.5f * r1.z, 0.f), 1.f);
        o1.w = fminf(fmaxf(0.5f * acc[7] + 0.5f * r1.w, 0.f), 1.f);
        uint2 w0 = f4_to_bf4(o0), w1 = f4_to_bf4(o1);
        uint4 w = make_uint4(w0.x, w0.y, w1.x, w1.y);
        *(uint4*)&out_bf[(size_t)n * 128 + l * 4] = w;
    }
}

// ---------- pooling ----------
__global__ void bounds_kernel(const int* __restrict__ batch, int* __restrict__ gstart) {
    int n = blockIdx.x * blockDim.x + threadIdx.x;
    if (n >= N_NODES) return;
    int b = batch[n];
    int prev = (n == 0) ? -1 : batch[n - 1];
    for (int g = prev + 1; g <= b; g++) gstart[g] = n;
    if (n == N_NODES - 1)
        for (int g = b + 1; g <= N_GRAPHS; g++) gstart[g] = N_NODES;
}
__global__ void pool_partial(const float* __restrict__ buf, const int* __restrict__ gstart,
                             float* __restrict__ psum, int C, int colOff) {
    int g = blockIdx.x, q = blockIdx.y;
    int n0 = gstart[g], n1 = gstart[g + 1];
    int len = n1 - n0;
    int ns = n0 + (len * q) / 4, ne = n0 + (len * (q + 1)) / 4;
    int cp = threadIdx.x % C;
    int np = threadIdx.x / C;
    int NP = 256 / C;
    float s = 0.f;
    for (int n = ns + np; n < ne; n += NP) s += buf[(size_t)n * C + cp];
    atomicAdd(&psum[g * JK + colOff + cp], s);
}
__global__ void pool_bf(const unsigned* __restrict__ buf, const int* __restrict__ gstart,
                        float* __restrict__ psum, int colOff) {
    int g = blockIdx.x, q = blockIdx.y;
    int n0 = gstart[g], n1 = gstart[g + 1];
    int len = n1 - n0;
    int ns = n0 + (len * q) / 4, ne = n0 + (len * (q + 1)) / 4;
    int cp = threadIdx.x & 127;
    int np = threadIdx.x >> 7;
    float s0 = 0.f, s1 = 0.f;
    for (int n = ns + np; n < ne; n += 2) {
        unsigned u = buf[(size_t)n * 128 + cp];
        s0 += __uint_as_float(u << 16);
        s1 += __uint_as_float(u & 0xffff0000u);
    }
    atomicAdd(&psum[g * JK + colOff + cp * 2 + 0], s0);
    atomicAdd(&psum[g * JK + colOff + cp * 2 + 1], s1);
}
__global__ void gmean_kernel(const float* __restrict__ psum, const int* __restrict__ gstart,
                             float* __restrict__ g) {
    int i = blockIdx.x * blockDim.x + threadIdx.x;
    if (i >= N_GRAPHS * JK) return;
    int gi = i / JK;
    int len = gstart[gi + 1] - gstart[gi];
    g[i] = psum[i] / (float)(len > 1 ? len : 1);
}

// ---------- MLP head ----------
__global__ __launch_bounds__(64)
void head_d1(const float* __restrict__ gbuf, const float* __restrict__ W,
             const float* __restrict__ bias, float* __restrict__ out) {
    __shared__ float zin[JK];
    int g = blockIdx.y, mc = blockIdx.x, lane = threadIdx.x;
    for (int k = lane; k < JK; k += 64) zin[k] = gbuf[g * JK + k];
    __syncthreads();
    int m = mc * 64 + lane;
    float acc = bias[m];
#pragma unroll 8
    for (int k = 0; k < JK; k++) acc += zin[k] * W[k * 256 + m];
    out[g * 256 + m] = fmaxf(acc, 0.f);
}

__global__ __launch_bounds__(256)
void head_rest(const float* __restrict__ t1, const float* __restrict__ clin,
               const float* __restrict__ pp_w2, const float* __restrict__ pp_b2,
               const float* __restrict__ cl_w1, const float* __restrict__ cl_b1,
               const float* __restrict__ cl_w2, const float* __restrict__ cl_b2,
               const float* __restrict__ h_w1, const float* __restrict__ h_b1,
               const float* __restrict__ h_w2, const float* __restrict__ h_b2,
               const float* __restrict__ h_w3, const float* __restrict__ h_b3,
               float* __restrict__ out) {
    __shared__ float z1[256];
    __shared__ float zcl[32];
    __shared__ float zc[64];
    __shared__ float z[160];
    __shared__ float z3[64];
    __shared__ float z4[32];
    __shared__ float part[128];
    int g = blockIdx.x, t = threadIdx.x;
    z1[t] = t1[g * 256 + t];
    if (t < 32) zcl[t] = clin[g * 32 + t];
    __syncthreads();
    int m = t & 127, half = t >> 7;
    {
        float acc = 0.f;
        int k0 = half * 128;
#pragma unroll 8
        for (int k = k0; k < k0 + 128; k++) acc += z1[k] * pp_w2[k * 128 + m];
        if (half) part[m] = acc;
        __syncthreads();
        if (!half) z[m] = acc + part[m] + pp_b2[m];
    }
    if (t < 64) {
        float acc = cl_b1[t];
#pragma unroll
        for (int k = 0; k < 32; k++) acc += zcl[k] * cl_w1[k * 64 + t];
        zc[t] = fmaxf(acc, 0.f);
    }
    __syncthreads();
    if (t < 32) {
        float acc = cl_b2[t];
#pragma unroll
        for (int k = 0; k < 64; k++) acc += zc[k] * cl_w2[k * 32 + t];
        z[128 + t] = acc;
    }
    __syncthreads();
    if (t < 64) {
        float acc = h_b1[t];
#pragma unroll 8
        for (int k = 0; k < 160; k++) acc += z[k] * h_w1[k * 64 + t];
        z3[t] = fmaxf(acc, 0.f);
    }
    __syncthreads();
    if (t < 32) {
        float acc = h_b2[t];
#pragma unroll
        for (int k = 0; k < 64; k++) acc += z3[k] * h_w2[k * 32 + t];
        z4[t] = fmaxf(acc, 0.f);
    }
    __syncthreads();
    if (t < 2) {
        float acc = h_b3[t];
#pragma unroll
        for (int k = 0; k < 32; k++) acc += z4[k] * h_w3[k * 2 + t];
        out[g * 2 + t] = acc;
    }
}

// ---------- launch ----------
extern "C" void kernel_launch(void* const* d_in, const int* in_sizes, int n_in,
                              void* d_out, int out_size, void* d_ws, size_t ws_size,
                              hipStream_t stream) {
    const float* x     = (const float*)d_in[0];
    const int*   ei    = (const int*)d_in[1];
    const int*   batch = (const int*)d_in[2];
    const float* clin  = (const float*)d_in[3];
    const float* W1  = (const float*)d_in[4];
    const float* a1s = (const float*)d_in[5];
    const float* a1d = (const float*)d_in[6];
    const float* b1  = (const float*)d_in[7];
    const float* W2  = (const float*)d_in[8];
    const float* a2s = (const float*)d_in[9];
    const float* a2d = (const float*)d_in[10];
    const float* b2  = (const float*)d_in[11];
    const float* pp_w1 = (const float*)d_in[12];
    const float* pp_b1 = (const float*)d_in[13];
    const float* pp_w2 = (const float*)d_in[14];
    const float* pp_b2 = (const float*)d_in[15];
    const float* cl_w1 = (const float*)d_in[16];
    const float* cl_b1 = (const float*)d_in[17];
    const float* cl_w2 = (const float*)d_in[18];
    const float* cl_b2 = (const float*)d_in[19];
    const float* h_w1  = (const float*)d_in[20];
    const float* h_b1  = (const float*)d_in[21];
    const float* h_w2  = (const float*)d_in[22];
    const float* h_b2  = (const float*)d_in[23];
    const float* h_w3  = (const float*)d_in[24];
    const float* h_b3  = (const float*)d_in[25];

    const int* src = ei;
    const int* dst = ei + N_EDGES;

    char* p = (char*)d_ws;
    auto carve = [&](size_t bytes) -> char* {
        char* r = p;
        p += (bytes + 255) & ~(size_t)255;
        return r;
    };
    const size_t NBH = (size_t)N_NODES * 256 * 2;    // bf16 node buffer
    unsigned* abf  = (unsigned*)carve(NBH);          // aggx, later h2_final
    unsigned* bf1  = (unsigned*)carve(NBH);
    unsigned* bf2  = (unsigned*)carve(NBH);
    unsigned* bf3  = (unsigned*)carve(NBH);
    float* alpha_fb  = (float*)carve((size_t)N_EDGES * 4 * 4);
    int*   csr_src   = (int*)carve((size_t)N_EDGES * 4);
    int*   off       = (int*)carve((size_t)(N_NODES + 1) * 4);
    int*   deg       = (int*)carve((size_t)N_NODES * 4);
    int*   cursor    = (int*)carve((size_t)N_NODES * 4);
    int*   bsum      = (int*)carve((size_t)NSB * 4);
    int*   bpre      = (int*)carve((size_t)NSB * 4);
    float* dis       = (float*)carve((size_t)N_NODES * 4);
    float* es        = (float*)carve((size_t)N_NODES * 4 * 4);
    float* ed        = (float*)carve((size_t)N_NODES * 4 * 4);
    float* wes1      = (float*)carve((size_t)64 * 4 * 4);
    float* wed1      = (float*)carve((size_t)64 * 4 * 4);
    float* wes2      = (float*)carve((size_t)256 * 4 * 4);
    float* wed2      = (float*)carve((size_t)256 * 4 * 4);
    unsigned short* W1T = (unsigned short*)carve((size_t)256 * 64 * 2);
    unsigned short* W2T = (unsigned short*)carve((size_t)256 * 256 * 2);
    int*   gstart    = (int*)carve((size_t)(N_GRAPHS + 1) * 4);
    float* psum      = (float*)carve((size_t)N_GRAPHS * JK * 4);
    float* gbuf      = (float*)carve((size_t)N_GRAPHS * JK * 4);
    float* t1        = (float*)carve((size_t)N_GRAPHS * 256 * 4);

    const int TB = 256;
    const int gN     = (N_NODES + TB - 1) / TB;
    const int gE     = (N_EDGES + TB - 1) / TB;
    const int gNwave = (N_NODES * 64 + TB - 1) / TB;
    const int gFuse  = (N_NODES + 3) / 4;
    const int gRow   = (N_NODES + 63) / 64;

    // ---- CSR + degree + pooling bounds + weight prep ----
    hipMemsetAsync(deg, 0, (size_t)N_NODES * 4, stream);
    hipMemsetAsync(cursor, 0, (size_t)N_NODES * 4, stream);
    hipMemsetAsync(psum, 0, (size_t)N_GRAPHS * JK * 4, stream);
    deg_kernel<<<gE, TB, 0, stream>>>(dst, deg);
    dis_kernel<<<gN, TB, 0, stream>>>(deg, dis);
    scan_bsum<<<NSB, 256, 0, stream>>>(deg, bsum);
    scan_bpre<<<1, 256, 0, stream>>>(bsum, bpre, &off[N_NODES]);
    scan_off<<<NSB, 256, 0, stream>>>(deg, bpre, off);
    csr_fill<<<gE, TB, 0, stream>>>(src, dst, off, cursor, csr_src);
    bounds_kernel<<<gN, TB, 0, stream>>>(batch, gstart);
    prep_w<<<1, 256, 0, stream>>>(W1, a1s, a1d, wes1, wed1, 64);
    prep_w<<<4, 256, 0, stream>>>(W2, a2s, a2d, wes2, wed2, 256);
    conv_wT<<<(256 * 64 + TB - 1) / TB, TB, 0, stream>>>(W1, W1T, 64, 256);
    conv_wT<<<(256 * 256 + TB - 1) / TB, TB, 0, stream>>>(W2, W2T, 256, 256);

    // ---- GAT layer 1 ----
    esed_x<<<gNwave, TB, 0, stream>>>(x, wes1, wed1, es, ed);
    gat1_fused<<<gFuse, TB, 0, stream>>>(off, csr_src, es, ed, x, abf, alpha_fb);
    mfma_gemm<64, 64><<<dim3(gRow, 4), 256, 0, stream>>>(
        (const unsigned short*)abf, 256, W1T, bf1, 256, N_NODES, b1, 1,
        64, 64 * 64, 64);                                   // bf1 = h1a

    // ---- label prop 1 (residual = bf1) ----
    lp_csr<<<gNwave, TB, 0, stream>>>(off, csr_src, dis, bf1, bf1, bf2);
    lp_csr<<<gNwave, TB, 0, stream>>>(off, csr_src, dis, bf2, bf1, bf3);   // bf3 = h1

    pool_bf<<<dim3(N_GRAPHS, 4), TB, 0, stream>>>(bf3, gstart, psum, 64);

    // ---- GAT layer 2 ----
    mfma_gemm<256, 256><<<dim3(gRow, 1), 256, 0, stream>>>(
        (const unsigned short*)bf3, 256, W2T, bf1, 256, N_NODES, nullptr, 0,
        0, 0, 0);                                           // bf1 = h2
    esed_h<<<gNwave, TB, 0, stream>>>(bf3, wes2, wed2, es, ed);
    gat2_fused<<<gFuse, TB, 0, stream>>>(off, csr_src, es, ed, bf1, b2, bf2, alpha_fb); // bf2 = h2a

    // ---- label prop 2 (residual = bf2) ----
    lp_csr<<<gNwave, TB, 0, stream>>>(off, csr_src, dis, bf2, bf2, bf1);
    lp_csr<<<gNwave, TB, 0, stream>>>(off, csr_src, dis, bf1, bf2, abf);   // abf = h2_final

    // ---- pooling (x fp32, h2 bf16) + mean ----
    pool_partial<<<dim3(N_GRAPHS, 4), TB, 0, stream>>>(x, gstart, psum, 64, 0);
    pool_bf<<<dim3(N_GRAPHS, 4), TB, 0, stream>>>(abf, gstart, psum, 320);
    gmean_kernel<<<(N_GRAPHS * JK + TB - 1) / TB, TB, 0, stream>>>(psum, gstart, gbuf);

    // ---- MLP head ----
    head_d1<<<dim3(4, N_GRAPHS), 64, 0, stream>>>(gbuf, pp_w1, pp_b1, t1);
    head_rest<<<N_GRAPHS, 256, 0, stream>>>(t1, clin, pp_w2, pp_b2, cl_w1, cl_b1,
                                            cl_w2, cl_b2, h_w1, h_b1, h_w2, h_b2,
                                            h_w3, h_b3, (float*)d_out);
}

// Round 10
// 798.335 us; speedup vs baseline: 21.8714x; 1.0451x over previous
//
#include <hip/hip_runtime.h>

#define N_NODES 50000
#define N_EDGES 800000
#define N_GRAPHS 128
#define JK 576              // 64 + 256 + 256
#define CAP 192             // max cached in-degree per node (Poisson(16); max~45)
#define NSB ((N_NODES + 255) / 256)   // scan blocks = 196

typedef __attribute__((ext_vector_type(8))) short bf16x8;
typedef __attribute__((ext_vector_type(4))) float f32x4;

// ---------- bf16 pack/unpack helpers ----------
__device__ __forceinline__ unsigned f2_to_bf2(float a, float b) {
    unsigned ua = __float_as_uint(a), ub = __float_as_uint(b);
    ua = (ua + 0x7fffu + ((ua >> 16) & 1u)) >> 16;       // RNE
    ub = (ub + 0x7fffu + ((ub >> 16) & 1u)) >> 16;
    return ua | (ub << 16);
}
__device__ __forceinline__ uint2 f4_to_bf4(float4 v) {
    return make_uint2(f2_to_bf2(v.x, v.y), f2_to_bf2(v.z, v.w));
}
__device__ __forceinline__ float4 bf4_to_f4(uint2 u) {
    float4 r;
    r.x = __uint_as_float(u.x << 16);
    r.y = __uint_as_float(u.x & 0xffff0000u);
    r.z = __uint_as_float(u.y << 16);
    r.w = __uint_as_float(u.y & 0xffff0000u);
    return r;
}

// ---------- MFMA GEMM: bf16 out = A_bf16 @ B (BT n-major bf16), fp32 acc ----------
template<int BN, int KK>
__global__ __launch_bounds__(256)
void mfma_gemm(const unsigned short* __restrict__ Abf, int lda,
               const unsigned short* __restrict__ BT,
               unsigned* __restrict__ Cbf, int ldc,
               int M, const float* __restrict__ bias, int relu,
               int a_off, int b_off, int c_off) {
    __shared__ unsigned short As[64][32];
    __shared__ unsigned short Bs[BN][32];
    const int t = threadIdx.x;
    const int wav = t >> 6, lane = t & 63;
    const int quad = lane >> 4, l15 = lane & 15;
    const int m0 = blockIdx.x * 64;
    const int head = blockIdx.y;
    Abf += (size_t)head * a_off;
    BT  += (size_t)head * b_off;
    const float* bptr = bias ? bias + (size_t)head * c_off : nullptr;
    unsigned* cbf = Cbf + (((size_t)head * c_off) >> 1);

    f32x4 acc[BN / 16];
#pragma unroll
    for (int i = 0; i < BN / 16; i++) acc[i] = (f32x4){0.f, 0.f, 0.f, 0.f};

    const int arow = t >> 2, aseg = t & 3;
    for (int k0 = 0; k0 < KK; k0 += 32) {
        uint4 av = make_uint4(0, 0, 0, 0);
        int gm = m0 + arow;
        if (gm < M) av = *(const uint4*)&Abf[(size_t)gm * lda + k0 + aseg * 8];
        uint4 bv[BN == 256 ? 4 : 1];
        if (BN == 256) {
            const unsigned short* srcb = &BT[(size_t)t * KK + k0];
#pragma unroll
            for (int j = 0; j < 4; j++) bv[j] = *(const uint4*)&srcb[j * 8];
        } else {
            bv[0] = *(const uint4*)&BT[(size_t)arow * KK + k0 + aseg * 8];
        }
        __syncthreads();
        *(uint4*)&As[arow][aseg * 8] = av;
        if (BN == 256) {
#pragma unroll
            for (int j = 0; j < 4; j++) *(uint4*)&Bs[t][j * 8] = bv[j];
        } else {
            *(uint4*)&Bs[arow][aseg * 8] = bv[0];
        }
        __syncthreads();
        bf16x8 afrag = *(const bf16x8*)&As[wav * 16 + l15][quad * 8];
#pragma unroll
        for (int nt = 0; nt < BN / 16; nt++) {
            bf16x8 bfrag = *(const bf16x8*)&Bs[nt * 16 + l15][quad * 8];
            acc[nt] = __builtin_amdgcn_mfma_f32_16x16x32_bf16(afrag, bfrag, acc[nt], 0, 0, 0);
        }
    }
    int rbase = m0 + wav * 16 + quad * 4;
#pragma unroll
    for (int nt = 0; nt < BN / 16; nt++) {
        int col = nt * 16 + l15;
        float bb = bptr ? bptr[col] : 0.f;
#pragma unroll
        for (int r = 0; r < 4; r++) {
            int row = rbase + r;
            float v = acc[nt][r] + bb;
            if (relu) v = fmaxf(v, 0.f);
            float vp = __shfl_xor(v, 1);
            if (row < M && !(l15 & 1))
                cbf[((size_t)row * ldc + col) >> 1] = f2_to_bf2(v, vp);
        }
    }
}

// ---------- weight transpose + bf16 convert ----------
__global__ void conv_wT(const float* __restrict__ W, unsigned short* __restrict__ WT,
                        int IN, int OUT) {
    int i = blockIdx.x * blockDim.x + threadIdx.x;
    if (i >= IN * OUT) return;
    int n = i / IN, c = i - n * IN;
    unsigned u = __float_as_uint(W[(size_t)c * OUT + n]);
    u = (u + 0x7fffu + ((u >> 16) & 1u)) >> 16;
    WT[i] = (unsigned short)u;
}

// ---------- CSR build ----------
__global__ void deg_kernel(const int* __restrict__ dst, int* __restrict__ deg) {
    int t = blockIdx.x * blockDim.x + threadIdx.x;
    if (t < N_EDGES) atomicAdd(&deg[dst[t]], 1);
}
__global__ void dis_kernel(const int* __restrict__ deg, float* __restrict__ dis) {
    int i = blockIdx.x * blockDim.x + threadIdx.x;
    if (i >= N_NODES) return;
    int d = deg[i];
    dis[i] = d > 0 ? rsqrtf((float)d) : 0.f;
}
// ---- hierarchical scan ----
__global__ __launch_bounds__(256) void scan_bsum(const int* __restrict__ deg,
                                                 int* __restrict__ bsum) {
    __shared__ int sd[256];
    int n = blockIdx.x * 256 + threadIdx.x;
    sd[threadIdx.x] = (n < N_NODES) ? deg[n] : 0;
    __syncthreads();
    for (int o = 128; o > 0; o >>= 1) {
        if (threadIdx.x < o) sd[threadIdx.x] += sd[threadIdx.x + o];
        __syncthreads();
    }
    if (threadIdx.x == 0) bsum[blockIdx.x] = sd[0];
}
__global__ __launch_bounds__(256) void scan_bpre(const int* __restrict__ bsum,
                                                 int* __restrict__ bpre,
                                                 int* __restrict__ off_last) {
    __shared__ int sd[256];
    int t = threadIdx.x;
    int v = (t < NSB) ? bsum[t] : 0;
    sd[t] = v;
    __syncthreads();
    for (int o = 1; o < 256; o <<= 1) {
        int u = (t >= o) ? sd[t - o] : 0;
        __syncthreads();
        sd[t] += u;
        __syncthreads();
    }
    if (t < NSB) bpre[t] = sd[t] - v;
    if (t == 255) *off_last = sd[255];
}
__global__ __launch_bounds__(256) void scan_off(const int* __restrict__ deg,
                                                const int* __restrict__ bpre,
                                                int* __restrict__ off) {
    __shared__ int sd[256];
    int n = blockIdx.x * 256 + threadIdx.x;
    int t = threadIdx.x;
    int v = (n < N_NODES) ? deg[n] : 0;
    sd[t] = v;
    __syncthreads();
    for (int o = 1; o < 256; o <<= 1) {
        int u = (t >= o) ? sd[t - o] : 0;
        __syncthreads();
        sd[t] += u;
        __syncthreads();
    }
    if (n < N_NODES) off[n] = bpre[blockIdx.x] + sd[t] - v;
}
__global__ void csr_fill(const int* __restrict__ src, const int* __restrict__ dst,
                         const int* __restrict__ off, int* __restrict__ cursor,
                         int* __restrict__ csr_src) {
    int e = blockIdx.x * blockDim.x + threadIdx.x;
    if (e >= N_EDGES) return;
    int s = src[e], d = dst[e];
    int pos = off[d] + atomicAdd(&cursor[d], 1);
    csr_src[pos] = s;
}

// ---------- precontract W @ a ----------
__global__ void prep_w(const float* __restrict__ W, const float* __restrict__ as_,
                       const float* __restrict__ ad_, float* __restrict__ wes,
                       float* __restrict__ wed, int K) {
    int t = blockIdx.x * blockDim.x + threadIdx.x;
    if (t >= K * 4) return;
    int c = t >> 2, h = t & 3;
    float se = 0.f, sd = 0.f;
    for (int j = 0; j < 64; j++) {
        float w = W[(size_t)c * 256 + h * 64 + j];
        se += w * as_[h * 64 + j];
        sd += w * ad_[h * 64 + j];
    }
    wes[c * 4 + h] = se;
    wed[c * 4 + h] = sd;
}

// ---------- es/ed from K=64 fp32 input (x) ----------
__global__ void esed_x(const float* __restrict__ X, const float* __restrict__ wes,
                       const float* __restrict__ wed, float* __restrict__ es,
                       float* __restrict__ ed) {
    int gid = blockIdx.x * blockDim.x + threadIdx.x;
    int n = gid >> 6, lane = threadIdx.x & 63;
    if (n >= N_NODES) return;
    float xv = X[(size_t)n * 64 + lane];
    float4 a = *(const float4*)&wes[lane * 4];
    float4 b = *(const float4*)&wed[lane * 4];
    float4 ps = make_float4(xv * a.x, xv * a.y, xv * a.z, xv * a.w);
    float4 pd = make_float4(xv * b.x, xv * b.y, xv * b.z, xv * b.w);
#pragma unroll
    for (int o = 1; o < 64; o <<= 1) {
        ps.x += __shfl_xor(ps.x, o); ps.y += __shfl_xor(ps.y, o);
        ps.z += __shfl_xor(ps.z, o); ps.w += __shfl_xor(ps.w, o);
        pd.x += __shfl_xor(pd.x, o); pd.y += __shfl_xor(pd.y, o);
        pd.z += __shfl_xor(pd.z, o); pd.w += __shfl_xor(pd.w, o);
    }
    if (lane == 0) {
        *(float4*)&es[n * 4] = ps;
        *(float4*)&ed[n * 4] = pd;
    }
}

// ---------- es/ed from K=256 bf16 input (h1) ----------
__global__ void esed_h(const unsigned* __restrict__ Hbf, const float* __restrict__ wes,
                       const float* __restrict__ wed, float* __restrict__ es,
                       float* __restrict__ ed) {
    int gid = blockIdx.x * blockDim.x + threadIdx.x;
    int n = gid >> 6, lane = threadIdx.x & 63;
    if (n >= N_NODES) return;
    float4 xv = bf4_to_f4(*(const uint2*)&Hbf[(size_t)n * 128 + lane * 2]);
    float xs[4] = {xv.x, xv.y, xv.z, xv.w};
    float4 ps = make_float4(0.f, 0.f, 0.f, 0.f);
    float4 pd = make_float4(0.f, 0.f, 0.f, 0.f);
#pragma unroll
    for (int r = 0; r < 4; r++) {
        int c = lane * 4 + r;
        float4 a = *(const float4*)&wes[c * 4];
        float4 b = *(const float4*)&wed[c * 4];
        ps.x += xs[r] * a.x; ps.y += xs[r] * a.y; ps.z += xs[r] * a.z; ps.w += xs[r] * a.w;
        pd.x += xs[r] * b.x; pd.y += xs[r] * b.y; pd.z += xs[r] * b.z; pd.w += xs[r] * b.w;
    }
#pragma unroll
    for (int o = 1; o < 64; o <<= 1) {
        ps.x += __shfl_xor(ps.x, o); ps.y += __shfl_xor(ps.y, o);
        ps.z += __shfl_xor(ps.z, o); ps.w += __shfl_xor(ps.w, o);
        pd.x += __shfl_xor(pd.x, o); pd.y += __shfl_xor(pd.y, o);
        pd.z += __shfl_xor(pd.z, o); pd.w += __shfl_xor(pd.w, o);
    }
    if (lane == 0) {
        *(float4*)&es[n * 4] = ps;
        *(float4*)&ed[n * 4] = pd;
    }
}

// ---------- GAT1: fused softmax + x-aggregation (LDS idx, chain-free prefetch) ----------
__global__ __launch_bounds__(256)
void gat1_fused(const int* __restrict__ off, const int* __restrict__ csr_src,
                const float* __restrict__ es, const float* __restrict__ ed,
                const float* __restrict__ x, unsigned* __restrict__ aggx_bf,
                float* __restrict__ alpha_fb) {
    __shared__ float elds[4][CAP * 4];
    __shared__ int   sidx[4][CAP];
    int wav = threadIdx.x >> 6, lane = threadIdx.x & 63;
    int n = blockIdx.x * 4 + wav;
    bool active = n < N_NODES;
    int p0 = 0, p1 = 0;
    float4 ed4 = make_float4(0.f, 0.f, 0.f, 0.f);
    if (active) { p0 = off[n]; p1 = off[n + 1]; ed4 = *(const float4*)&ed[n * 4]; }
    float4 sum = make_float4(0.f, 0.f, 0.f, 0.f);
    for (int p = p0 + lane; p < p1; p += 64) {
        int s = csr_src[p];
        float4 e4 = *(const float4*)&es[s * 4];
        e4.x += ed4.x; e4.y += ed4.y; e4.z += ed4.z; e4.w += ed4.w;
        e4.x = e4.x > 0.f ? e4.x : 0.2f * e4.x;
        e4.y = e4.y > 0.f ? e4.y : 0.2f * e4.y;
        e4.z = e4.z > 0.f ? e4.z : 0.2f * e4.z;
        e4.w = e4.w > 0.f ? e4.w : 0.2f * e4.w;
        e4.x = __expf(e4.x); e4.y = __expf(e4.y); e4.z = __expf(e4.z); e4.w = __expf(e4.w);
        int q = p - p0;
        if (q < CAP) { *(float4*)&elds[wav][q * 4] = e4; sidx[wav][q] = s; }
        else         *(float4*)&alpha_fb[(size_t)p * 4] = e4;
        sum.x += e4.x; sum.y += e4.y; sum.z += e4.z; sum.w += e4.w;
    }
#pragma unroll
    for (int o = 1; o < 64; o <<= 1) {
        sum.x += __shfl_xor(sum.x, o); sum.y += __shfl_xor(sum.y, o);
        sum.z += __shfl_xor(sum.z, o); sum.w += __shfl_xor(sum.w, o);
    }
    float4 rs;
    rs.x = sum.x > 0.f ? 1.f / sum.x : 0.f;
    rs.y = sum.y > 0.f ? 1.f / sum.y : 0.f;
    rs.z = sum.z > 0.f ? 1.f / sum.z : 0.f;
    rs.w = sum.w > 0.f ? 1.f / sum.w : 0.f;
    if (!active) return;
    // phase 2: 4 edges/iter, 16 lanes x float4 per edge, 2-deep chain-free pipeline
    int eg = lane >> 4, l15 = lane & 15;
    int deg = p1 - p0;
    float4 a0 = make_float4(0.f, 0.f, 0.f, 0.f);
    float4 a1 = a0, a2 = a0, a3 = a0;
    int q = eg;
    float4 eA = make_float4(0.f, 0.f, 0.f, 0.f);
    float4 xA = eA;
    if (q < deg) {
        int s;
        if (q < CAP) { s = sidx[wav][q]; eA = *(const float4*)&elds[wav][q * 4]; }
        else { s = csr_src[p0 + q]; eA = *(const float4*)&alpha_fb[(size_t)(p0 + q) * 4]; }
        xA = *(const float4*)&x[(size_t)s * 64 + l15 * 4];
    }
    while (q < deg) {
        int qn = q + 4;
        float4 eB = make_float4(0.f, 0.f, 0.f, 0.f);
        float4 xB = eB;
        if (qn < deg) {
            int s;
            if (qn < CAP) { s = sidx[wav][qn]; eB = *(const float4*)&elds[wav][qn * 4]; }
            else { s = csr_src[p0 + qn]; eB = *(const float4*)&alpha_fb[(size_t)(p0 + qn) * 4]; }
            xB = *(const float4*)&x[(size_t)s * 64 + l15 * 4];
        }
        a0.x += eA.x * xA.x; a0.y += eA.x * xA.y; a0.z += eA.x * xA.z; a0.w += eA.x * xA.w;
        a1.x += eA.y * xA.x; a1.y += eA.y * xA.y; a1.z += eA.y * xA.z; a1.w += eA.y * xA.w;
        a2.x += eA.z * xA.x; a2.y += eA.z * xA.y; a2.z += eA.z * xA.z; a2.w += eA.z * xA.w;
        a3.x += eA.w * xA.x; a3.y += eA.w * xA.y; a3.z += eA.w * xA.z; a3.w += eA.w * xA.w;
        eA = eB; xA = xB; q = qn;
    }
#pragma unroll
    for (int o = 16; o < 64; o <<= 1) {
        a0.x += __shfl_xor(a0.x, o); a0.y += __shfl_xor(a0.y, o);
        a0.z += __shfl_xor(a0.z, o); a0.w += __shfl_xor(a0.w, o);
        a1.x += __shfl_xor(a1.x, o); a1.y += __shfl_xor(a1.y, o);
        a1.z += __shfl_xor(a1.z, o); a1.w += __shfl_xor(a1.w, o);
        a2.x += __shfl_xor(a2.x, o); a2.y += __shfl_xor(a2.y, o);
        a2.z += __shfl_xor(a2.z, o); a2.w += __shfl_xor(a2.w, o);
        a3.x += __shfl_xor(a3.x, o); a3.y += __shfl_xor(a3.y, o);
        a3.z += __shfl_xor(a3.z, o); a3.w += __shfl_xor(a3.w, o);
    }
    if (eg == 0) {
        a0.x *= rs.x; a0.y *= rs.x; a0.z *= rs.x; a0.w *= rs.x;
        a1.x *= rs.y; a1.y *= rs.y; a1.z *= rs.y; a1.w *= rs.y;
        a2.x *= rs.z; a2.y *= rs.z; a2.z *= rs.z; a2.w *= rs.z;
        a3.x *= rs.w; a3.y *= rs.w; a3.z *= rs.w; a3.w *= rs.w;
        size_t b = (size_t)n * 128 + l15 * 2;
        *(uint2*)&aggx_bf[b +  0] = f4_to_bf4(a0);
        *(uint2*)&aggx_bf[b + 32] = f4_to_bf4(a1);
        *(uint2*)&aggx_bf[b + 64] = f4_to_bf4(a2);
        *(uint2*)&aggx_bf[b + 96] = f4_to_bf4(a3);
    }
}

// ---------- GAT2: fused softmax + bf16 gather (LDS idx, chain-free prefetch) ----------
__global__ __launch_bounds__(256)
void gat2_fused(const int* __restrict__ off, const int* __restrict__ csr_src,
                const float* __restrict__ es, const float* __restrict__ ed,
                const unsigned* __restrict__ H2bf, const float* __restrict__ bias,
                unsigned* __restrict__ outbf, float* __restrict__ alpha_fb) {
    __shared__ float elds[4][CAP * 4];
    __shared__ int   sidx[4][CAP];
    int wav = threadIdx.x >> 6, lane = threadIdx.x & 63;
    int n = blockIdx.x * 4 + wav;
    bool active = n < N_NODES;
    int p0 = 0, p1 = 0;
    float4 ed4 = make_float4(0.f, 0.f, 0.f, 0.f);
    if (active) { p0 = off[n]; p1 = off[n + 1]; ed4 = *(const float4*)&ed[n * 4]; }
    float4 sum = make_float4(0.f, 0.f, 0.f, 0.f);
    for (int p = p0 + lane; p < p1; p += 64) {
        int s = csr_src[p];
        float4 e4 = *(const float4*)&es[s * 4];
        e4.x += ed4.x; e4.y += ed4.y; e4.z += ed4.z; e4.w += ed4.w;
        e4.x = e4.x > 0.f ? e4.x : 0.2f * e4.x;
        e4.y = e4.y > 0.f ? e4.y : 0.2f * e4.y;
        e4.z = e4.z > 0.f ? e4.z : 0.2f * e4.z;
        e4.w = e4.w > 0.f ? e4.w : 0.2f * e4.w;
        e4.x = __expf(e4.x); e4.y = __expf(e4.y); e4.z = __expf(e4.z); e4.w = __expf(e4.w);
        int q = p - p0;
        if (q < CAP) { *(float4*)&elds[wav][q * 4] = e4; sidx[wav][q] = s; }
        else         *(float4*)&alpha_fb[(size_t)p * 4] = e4;
        sum.x += e4.x; sum.y += e4.y; sum.z += e4.z; sum.w += e4.w;
    }
#pragma unroll
    for (int o = 1; o < 64; o <<= 1) {
        sum.x += __shfl_xor(sum.x, o); sum.y += __shfl_xor(sum.y, o);
        sum.z += __shfl_xor(sum.z, o); sum.w += __shfl_xor(sum.w, o);
    }
    if (!active) return;
    int half = lane >> 5, l = lane & 31;
    int hh = l >> 3;
    float sh = (hh == 0) ? sum.x : (hh == 1) ? sum.y : (hh == 2) ? sum.z : sum.w;
    float rsh = sh > 0.f ? 1.f / sh : 0.f;
    int deg = p1 - p0;
    float acc[8];
#pragma unroll
    for (int j = 0; j < 8; j++) acc[j] = 0.f;
    int q = half;
    float aA = 0.f;
    uint4 rA = make_uint4(0, 0, 0, 0);
    if (q < deg) {
        int s;
        if (q < CAP) { s = sidx[wav][q]; aA = elds[wav][q * 4 + hh]; }
        else { s = csr_src[p0 + q]; aA = alpha_fb[(size_t)(p0 + q) * 4 + hh]; }
        rA = *(const uint4*)&H2bf[(size_t)s * 128 + l * 4];
    }
    while (q < deg) {
        int qn = q + 2;
        float aB = 0.f;
        uint4 rB = make_uint4(0, 0, 0, 0);
        if (qn < deg) {
            int s;
            if (qn < CAP) { s = sidx[wav][qn]; aB = elds[wav][qn * 4 + hh]; }
            else { s = csr_src[p0 + qn]; aB = alpha_fb[(size_t)(p0 + qn) * 4 + hh]; }
            rB = *(const uint4*)&H2bf[(size_t)s * 128 + l * 4];
        }
        float4 f0 = bf4_to_f4(make_uint2(rA.x, rA.y));
        float4 f1 = bf4_to_f4(make_uint2(rA.z, rA.w));
        acc[0] += aA * f0.x; acc[1] += aA * f0.y; acc[2] += aA * f0.z; acc[3] += aA * f0.w;
        acc[4] += aA * f1.x; acc[5] += aA * f1.y; acc[6] += aA * f1.z; acc[7] += aA * f1.w;
        aA = aB; rA = rB; q = qn;
    }
#pragma unroll
    for (int j = 0; j < 8; j++) acc[j] += __shfl_xor(acc[j], 32);
    if (half == 0) {
        float4 b0 = *(const float4*)&bias[l * 8];
        float4 b1 = *(const float4*)&bias[l * 8 + 4];
        float4 o0, o1;
        o0.x = fmaxf(acc[0] * rsh + b0.x, 0.f);
        o0.y = fmaxf(acc[1] * rsh + b0.y, 0.f);
        o0.z = fmaxf(acc[2] * rsh + b0.z, 0.f);
        o0.w = fmaxf(acc[3] * rsh + b0.w, 0.f);
        o1.x = fmaxf(acc[4] * rsh + b1.x, 0.f);
        o1.y = fmaxf(acc[5] * rsh + b1.y, 0.f);
        o1.z = fmaxf(acc[6] * rsh + b1.z, 0.f);
        o1.w = fmaxf(acc[7] * rsh + b1.w, 0.f);
        uint2 w0 = f4_to_bf4(o0), w1 = f4_to_bf4(o1);
        uint4 w = make_uint4(w0.x, w0.y, w1.x, w1.y);
        *(uint4*)&outbf[(size_t)n * 128 + l * 4] = w;
    }
}

// ---------- label prop: LDS idx+weight staging, chain-free 2-deep prefetch ----------
__global__ __launch_bounds__(256)
void lp_csr(const int* __restrict__ off, const int* __restrict__ csr_src,
            const float* __restrict__ dis, const unsigned* __restrict__ in_bf,
            const unsigned* __restrict__ res_bf, unsigned* __restrict__ out_bf) {
    __shared__ int   widx[4][CAP];
    __shared__ float wwt[4][CAP];
    int wav = threadIdx.x >> 6, lane = threadIdx.x & 63;
    int n = blockIdx.x * 4 + wav;
    if (n >= N_NODES) return;
    int p0 = off[n], p1 = off[n + 1];
    int deg = p1 - p0;
    float disd = dis[n];
    // phase 0: stage indices + weights in LDS (wave-synchronous, own slice)
    for (int q = lane; q < deg && q < CAP; q += 64) {
        int s = csr_src[p0 + q];
        widx[wav][q] = s;
        wwt[wav][q] = dis[s] * disd;
    }
    int half = lane >> 5, l = lane & 31;
    float acc[8];
#pragma unroll
    for (int j = 0; j < 8; j++) acc[j] = 0.f;
    int q = half;
    float nA = 0.f;
    uint4 rA = make_uint4(0, 0, 0, 0);
    if (q < deg) {
        int s;
        if (q < CAP) { s = widx[wav][q]; nA = wwt[wav][q]; }
        else { s = csr_src[p0 + q]; nA = dis[s] * disd; }
        rA = *(const uint4*)&in_bf[(size_t)s * 128 + l * 4];
    }
    while (q < deg) {
        int qn = q + 2;
        float nB = 0.f;
        uint4 rB = make_uint4(0, 0, 0, 0);
        if (qn < deg) {
            int s;
            if (qn < CAP) { s = widx[wav][qn]; nB = wwt[wav][qn]; }
            else { s = csr_src[p0 + qn]; nB = dis[s] * disd; }
            rB = *(const uint4*)&in_bf[(size_t)s * 128 + l * 4];
        }
        float4 f0 = bf4_to_f4(make_uint2(rA.x, rA.y));
        float4 f1 = bf4_to_f4(make_uint2(rA.z, rA.w));
        acc[0] += nA * f0.x; acc[1] += nA * f0.y; acc[2] += nA * f0.z; acc[3] += nA * f0.w;
        acc[4] += nA * f1.x; acc[5] += nA * f1.y; acc[6] += nA * f1.z; acc[7] += nA * f1.w;
        nA = nB; rA = rB; q = qn;
    }
#pragma unroll
    for (int j = 0; j < 8; j++) acc[j] += __shfl_xor(acc[j], 32);
    if (half == 0) {
        uint4 rr = *(const uint4*)&res_bf[(size_t)n * 128 + l * 4];
        float4 r0 = bf4_to_f4(make_uint2(rr.x, rr.y));
        float4 r1 = bf4_to_f4(make_uint2(rr.z, rr.w));
        float4 o0, o1;
        o0.x = fminf(fmaxf(0.5f * acc[0] + 0.5f * r0.x, 0.f), 1.f);
        o0.y = fminf(fmaxf(0.5f * acc[1] + 0.5f * r0.y, 0.f), 1.f);
        o0.z = fminf(fmaxf(0.5f * acc[2] + 0.5f * r0.z, 0.f), 1.f);
        o0.w = fminf(fmaxf(0.5f * acc[3] + 0.5f * r0.w, 0.f), 1.f);
        o1.x = fminf(fmaxf(0.5f * acc[4] + 0.5f * r1.x, 0.f), 1.f);
        o1.y = fminf(fmaxf(0.5f * acc[5] + 0.5f * r1.y, 0.f), 1.f);
        o1.z = fminf(fmaxf(0.5f * acc[6] + 0.5f * r1.z, 0.f), 1.f);
        o1.w = fminf(fmaxf(0.5f * acc[7] + 0.5f * r1.w, 0.f), 1.f);
        uint2 w0 = f4_to_bf4(o0), w1 = f4_to_bf4(o1);
        uint4 w = make_uint4(w0.x, w0.y, w1.x, w1.y);
        *(uint4*)&out_bf[(size_t)n * 128 + l * 4] = w;
    }
}

// ---------- pooling ----------
__global__ void bounds_kernel(const int* __restrict__ batch, int* __restrict__ gstart) {
    int n = blockIdx.x * blockDim.x + threadIdx.x;
    if (n >= N_NODES) return;
    int b = batch[n];
    int prev = (n == 0) ? -1 : batch[n - 1];
    for (int g = prev + 1; g <= b; g++) gstart[g] = n;
    if (n == N_NODES - 1)
        for (int g = b + 1; g <= N_GRAPHS; g++) gstart[g] = N_NODES;
}
__global__ void pool_partial(const float* __restrict__ buf, const int* __restrict__ gstart,
                             float* __restrict__ psum, int C, int colOff) {
    int g = blockIdx.x, q = blockIdx.y;
    int n0 = gstart[g], n1 = gstart[g + 1];
    int len = n1 - n0;
    int ns = n0 + (len * q) / 4, ne = n0 + (len * (q + 1)) / 4;
    int cp = threadIdx.x % C;
    int np = threadIdx.x / C;
    int NP = 256 / C;
    float s = 0.f;
    for (int n = ns + np; n < ne; n += NP) s += buf[(size_t)n * C + cp];
    atomicAdd(&psum[g * JK + colOff + cp], s);
}
__global__ void pool_bf(const unsigned* __restrict__ buf, const int* __restrict__ gstart,
                        float* __restrict__ psum, int colOff) {
    int g = blockIdx.x, q = blockIdx.y;
    int n0 = gstart[g], n1 = gstart[g + 1];
    int len = n1 - n0;
    int ns = n0 + (len * q) / 4, ne = n0 + (len * (q + 1)) / 4;
    int cp = threadIdx.x & 127;
    int np = threadIdx.x >> 7;
    float s0 = 0.f, s1 = 0.f;
    for (int n = ns + np; n < ne; n += 2) {
        unsigned u = buf[(size_t)n * 128 + cp];
        s0 += __uint_as_float(u << 16);
        s1 += __uint_as_float(u & 0xffff0000u);
    }
    atomicAdd(&psum[g * JK + colOff + cp * 2 + 0], s0);
    atomicAdd(&psum[g * JK + colOff + cp * 2 + 1], s1);
}
__global__ void gmean_kernel(const float* __restrict__ psum, const int* __restrict__ gstart,
                             float* __restrict__ g) {
    int i = blockIdx.x * blockDim.x + threadIdx.x;
    if (i >= N_GRAPHS * JK) return;
    int gi = i / JK;
    int len = gstart[gi + 1] - gstart[gi];
    g[i] = psum[i] / (float)(len > 1 ? len : 1);
}

// ---------- MLP head ----------
__global__ __launch_bounds__(64)
void head_d1(const float* __restrict__ gbuf, const float* __restrict__ W,
             const float* __restrict__ bias, float* __restrict__ out) {
    __shared__ float zin[JK];
    int g = blockIdx.y, mc = blockIdx.x, lane = threadIdx.x;
    for (int k = lane; k < JK; k += 64) zin[k] = gbuf[g * JK + k];
    __syncthreads();
    int m = mc * 64 + lane;
    float acc = bias[m];
#pragma unroll 8
    for (int k = 0; k < JK; k++) acc += zin[k] * W[k * 256 + m];
    out[g * 256 + m] = fmaxf(acc, 0.f);
}

__global__ __launch_bounds__(256)
void head_rest(const float* __restrict__ t1, const float* __restrict__ clin,
               const float* __restrict__ pp_w2, const float* __restrict__ pp_b2,
               const float* __restrict__ cl_w1, const float* __restrict__ cl_b1,
               const float* __restrict__ cl_w2, const float* __restrict__ cl_b2,
               const float* __restrict__ h_w1, const float* __restrict__ h_b1,
               const float* __restrict__ h_w2, const float* __restrict__ h_b2,
               const float* __restrict__ h_w3, const float* __restrict__ h_b3,
               float* __restrict__ out) {
    __shared__ float z1[256];
    __shared__ float zcl[32];
    __shared__ float zc[64];
    __shared__ float z[160];
    __shared__ float z3[64];
    __shared__ float z4[32];
    __shared__ float part[128];
    int g = blockIdx.x, t = threadIdx.x;
    z1[t] = t1[g * 256 + t];
    if (t < 32) zcl[t] = clin[g * 32 + t];
    __syncthreads();
    int m = t & 127, half = t >> 7;
    {
        float acc = 0.f;
        int k0 = half * 128;
#pragma unroll 8
        for (int k = k0; k < k0 + 128; k++) acc += z1[k] * pp_w2[k * 128 + m];
        if (half) part[m] = acc;
        __syncthreads();
        if (!half) z[m] = acc + part[m] + pp_b2[m];
    }
    if (t < 64) {
        float acc = cl_b1[t];
#pragma unroll
        for (int k = 0; k < 32; k++) acc += zcl[k] * cl_w1[k * 64 + t];
        zc[t] = fmaxf(acc, 0.f);
    }
    __syncthreads();
    if (t < 32) {
        float acc = cl_b2[t];
#pragma unroll
        for (int k = 0; k < 64; k++) acc += zc[k] * cl_w2[k * 32 + t];
        z[128 + t] = acc;
    }
    __syncthreads();
    if (t < 64) {
        float acc = h_b1[t];
#pragma unroll 8
        for (int k = 0; k < 160; k++) acc += z[k] * h_w1[k * 64 + t];
        z3[t] = fmaxf(acc, 0.f);
    }
    __syncthreads();
    if (t < 32) {
        float acc = h_b2[t];
#pragma unroll
        for (int k = 0; k < 64; k++) acc += z3[k] * h_w2[k * 32 + t];
        z4[t] = fmaxf(acc, 0.f);
    }
    __syncthreads();
    if (t < 2) {
        float acc = h_b3[t];
#pragma unroll
        for (int k = 0; k < 32; k++) acc += z4[k] * h_w3[k * 2 + t];
        out[g * 2 + t] = acc;
    }
}

// ---------- launch ----------
extern "C" void kernel_launch(void* const* d_in, const int* in_sizes, int n_in,
                              void* d_out, int out_size, void* d_ws, size_t ws_size,
                              hipStream_t stream) {
    const float* x     = (const float*)d_in[0];
    const int*   ei    = (const int*)d_in[1];
    const int*   batch = (const int*)d_in[2];
    const float* clin  = (const float*)d_in[3];
    const float* W1  = (const float*)d_in[4];
    const float* a1s = (const float*)d_in[5];
    const float* a1d = (const float*)d_in[6];
    const float* b1  = (const float*)d_in[7];
    const float* W2  = (const float*)d_in[8];
    const float* a2s = (const float*)d_in[9];
    const float* a2d = (const float*)d_in[10];
    const float* b2  = (const float*)d_in[11];
    const float* pp_w1 = (const float*)d_in[12];
    const float* pp_b1 = (const float*)d_in[13];
    const float* pp_w2 = (const float*)d_in[14];
    const float* pp_b2 = (const float*)d_in[15];
    const float* cl_w1 = (const float*)d_in[16];
    const float* cl_b1 = (const float*)d_in[17];
    const float* cl_w2 = (const float*)d_in[18];
    const float* cl_b2 = (const float*)d_in[19];
    const float* h_w1  = (const float*)d_in[20];
    const float* h_b1  = (const float*)d_in[21];
    const float* h_w2  = (const float*)d_in[22];
    const float* h_b2  = (const float*)d_in[23];
    const float* h_w3  = (const float*)d_in[24];
    const float* h_b3  = (const float*)d_in[25];

    const int* src = ei;
    const int* dst = ei + N_EDGES;

    char* p = (char*)d_ws;
    auto carve = [&](size_t bytes) -> char* {
        char* r = p;
        p += (bytes + 255) & ~(size_t)255;
        return r;
    };
    const size_t NBH = (size_t)N_NODES * 256 * 2;    // bf16 node buffer
    unsigned* abf  = (unsigned*)carve(NBH);          // aggx, later h2_final
    unsigned* bf1  = (unsigned*)carve(NBH);
    unsigned* bf2  = (unsigned*)carve(NBH);
    unsigned* bf3  = (unsigned*)carve(NBH);
    float* alpha_fb  = (float*)carve((size_t)N_EDGES * 4 * 4);
    int*   csr_src   = (int*)carve((size_t)N_EDGES * 4);
    int*   off       = (int*)carve((size_t)(N_NODES + 1) * 4);
    int*   deg       = (int*)carve((size_t)N_NODES * 4);
    int*   cursor    = (int*)carve((size_t)N_NODES * 4);
    int*   bsum      = (int*)carve((size_t)NSB * 4);
    int*   bpre      = (int*)carve((size_t)NSB * 4);
    float* dis       = (float*)carve((size_t)N_NODES * 4);
    float* es        = (float*)carve((size_t)N_NODES * 4 * 4);
    float* ed        = (float*)carve((size_t)N_NODES * 4 * 4);
    float* wes1      = (float*)carve((size_t)64 * 4 * 4);
    float* wed1      = (float*)carve((size_t)64 * 4 * 4);
    float* wes2      = (float*)carve((size_t)256 * 4 * 4);
    float* wed2      = (float*)carve((size_t)256 * 4 * 4);
    unsigned short* W1T = (unsigned short*)carve((size_t)256 * 64 * 2);
    unsigned short* W2T = (unsigned short*)carve((size_t)256 * 256 * 2);
    int*   gstart    = (int*)carve((size_t)(N_GRAPHS + 1) * 4);
    float* psum      = (float*)carve((size_t)N_GRAPHS * JK * 4);
    float* gbuf      = (float*)carve((size_t)N_GRAPHS * JK * 4);
    float* t1        = (float*)carve((size_t)N_GRAPHS * 256 * 4);

    const int TB = 256;
    const int gN     = (N_NODES + TB - 1) / TB;
    const int gE     = (N_EDGES + TB - 1) / TB;
    const int gNwave = (N_NODES * 64 + TB - 1) / TB;
    const int gFuse  = (N_NODES + 3) / 4;
    const int gRow   = (N_NODES + 63) / 64;

    // ---- CSR + degree + pooling bounds + weight prep ----
    hipMemsetAsync(deg, 0, (size_t)N_NODES * 4, stream);
    hipMemsetAsync(cursor, 0, (size_t)N_NODES * 4, stream);
    hipMemsetAsync(psum, 0, (size_t)N_GRAPHS * JK * 4, stream);
    deg_kernel<<<gE, TB, 0, stream>>>(dst, deg);
    dis_kernel<<<gN, TB, 0, stream>>>(deg, dis);
    scan_bsum<<<NSB, 256, 0, stream>>>(deg, bsum);
    scan_bpre<<<1, 256, 0, stream>>>(bsum, bpre, &off[N_NODES]);
    scan_off<<<NSB, 256, 0, stream>>>(deg, bpre, off);
    csr_fill<<<gE, TB, 0, stream>>>(src, dst, off, cursor, csr_src);
    bounds_kernel<<<gN, TB, 0, stream>>>(batch, gstart);
    prep_w<<<1, 256, 0, stream>>>(W1, a1s, a1d, wes1, wed1, 64);
    prep_w<<<4, 256, 0, stream>>>(W2, a2s, a2d, wes2, wed2, 256);
    conv_wT<<<(256 * 64 + TB - 1) / TB, TB, 0, stream>>>(W1, W1T, 64, 256);
    conv_wT<<<(256 * 256 + TB - 1) / TB, TB, 0, stream>>>(W2, W2T, 256, 256);

    // ---- GAT layer 1 ----
    esed_x<<<gNwave, TB, 0, stream>>>(x, wes1, wed1, es, ed);
    gat1_fused<<<gFuse, TB, 0, stream>>>(off, csr_src, es, ed, x, abf, alpha_fb);
    mfma_gemm<64, 64><<<dim3(gRow, 4), 256, 0, stream>>>(
        (const unsigned short*)abf, 256, W1T, bf1, 256, N_NODES, b1, 1,
        64, 64 * 64, 64);                                   // bf1 = h1a

    // ---- label prop 1 (residual = bf1) ----
    lp_csr<<<gFuse, TB, 0, stream>>>(off, csr_src, dis, bf1, bf1, bf2);
    lp_csr<<<gFuse, TB, 0, stream>>>(off, csr_src, dis, bf2, bf1, bf3);   // bf3 = h1

    pool_bf<<<dim3(N_GRAPHS, 4), TB, 0, stream>>>(bf3, gstart, psum, 64);

    // ---- GAT layer 2 ----
    mfma_gemm<256, 256><<<dim3(gRow, 1), 256, 0, stream>>>(
        (const unsigned short*)bf3, 256, W2T, bf1, 256, N_NODES, nullptr, 0,
        0, 0, 0);                                           // bf1 = h2
    esed_h<<<gNwave, TB, 0, stream>>>(bf3, wes2, wed2, es, ed);
    gat2_fused<<<gFuse, TB, 0, stream>>>(off, csr_src, es, ed, bf1, b2, bf2, alpha_fb); // bf2 = h2a

    // ---- label prop 2 (residual = bf2) ----
    lp_csr<<<gFuse, TB, 0, stream>>>(off, csr_src, dis, bf2, bf2, bf1);
    lp_csr<<<gFuse, TB, 0, stream>>>(off, csr_src, dis, bf1, bf2, abf);   // abf = h2_final

    // ---- pooling (x fp32, h2 bf16) + mean ----
    pool_partial<<<dim3(N_GRAPHS, 4), TB, 0, stream>>>(x, gstart, psum, 64, 0);
    pool_bf<<<dim3(N_GRAPHS, 4), TB, 0, stream>>>(abf, gstart, psum, 320);
    gmean_kernel<<<(N_GRAPHS * JK + TB - 1) / TB, TB, 0, stream>>>(psum, gstart, gbuf);

    // ---- MLP head ----
    head_d1<<<dim3(4, N_GRAPHS), 64, 0, stream>>>(gbuf, pp_w1, pp_b1, t1);
    head_rest<<<N_GRAPHS, 256, 0, stream>>>(t1, clin, pp_w2, pp_b2, cl_w1, cl_b1,
                                            cl_w2, cl_b2, h_w1, h_b1, h_w2, h_b2,
                                            h_w3, h_b3, (float*)d_out);
}

// Round 11
// 784.331 us; speedup vs baseline: 22.2620x; 1.0179x over previous
//
#include <hip/hip_runtime.h>

#define N_NODES 50000
#define N_EDGES 800000
#define N_GRAPHS 128
#define JK 576              // 64 + 256 + 256
#define CAP 192             // max cached in-degree per node (Poisson(16); max~45)
#define NSB ((N_NODES + 255) / 256)   // scan blocks = 196

typedef __attribute__((ext_vector_type(8))) short bf16x8;
typedef __attribute__((ext_vector_type(4))) float f32x4;

// ---------- bf16 pack/unpack helpers ----------
__device__ __forceinline__ unsigned f2_to_bf2(float a, float b) {
    unsigned ua = __float_as_uint(a), ub = __float_as_uint(b);
    ua = (ua + 0x7fffu + ((ua >> 16) & 1u)) >> 16;       // RNE
    ub = (ub + 0x7fffu + ((ub >> 16) & 1u)) >> 16;
    return ua | (ub << 16);
}
__device__ __forceinline__ uint2 f4_to_bf4(float4 v) {
    return make_uint2(f2_to_bf2(v.x, v.y), f2_to_bf2(v.z, v.w));
}
__device__ __forceinline__ float4 bf4_to_f4(uint2 u) {
    float4 r;
    r.x = __uint_as_float(u.x << 16);
    r.y = __uint_as_float(u.x & 0xffff0000u);
    r.z = __uint_as_float(u.y << 16);
    r.w = __uint_as_float(u.y & 0xffff0000u);
    return r;
}

// ---------- MFMA GEMM: bf16 out = A_bf16 @ B (BT n-major bf16), fp32 acc ----------
template<int BN, int KK>
__global__ __launch_bounds__(256)
void mfma_gemm(const unsigned short* __restrict__ Abf, int lda,
               const unsigned short* __restrict__ BT,
               unsigned* __restrict__ Cbf, int ldc,
               int M, const float* __restrict__ bias, int relu,
               int a_off, int b_off, int c_off) {
    __shared__ unsigned short As[64][32];
    __shared__ unsigned short Bs[BN][32];
    const int t = threadIdx.x;
    const int wav = t >> 6, lane = t & 63;
    const int quad = lane >> 4, l15 = lane & 15;
    const int m0 = blockIdx.x * 64;
    const int head = blockIdx.y;
    Abf += (size_t)head * a_off;
    BT  += (size_t)head * b_off;
    const float* bptr = bias ? bias + (size_t)head * c_off : nullptr;
    unsigned* cbf = Cbf + (((size_t)head * c_off) >> 1);

    f32x4 acc[BN / 16];
#pragma unroll
    for (int i = 0; i < BN / 16; i++) acc[i] = (f32x4){0.f, 0.f, 0.f, 0.f};

    const int arow = t >> 2, aseg = t & 3;
    for (int k0 = 0; k0 < KK; k0 += 32) {
        uint4 av = make_uint4(0, 0, 0, 0);
        int gm = m0 + arow;
        if (gm < M) av = *(const uint4*)&Abf[(size_t)gm * lda + k0 + aseg * 8];
        uint4 bv[BN == 256 ? 4 : 1];
        if (BN == 256) {
            const unsigned short* srcb = &BT[(size_t)t * KK + k0];
#pragma unroll
            for (int j = 0; j < 4; j++) bv[j] = *(const uint4*)&srcb[j * 8];
        } else {
            bv[0] = *(const uint4*)&BT[(size_t)arow * KK + k0 + aseg * 8];
        }
        __syncthreads();
        *(uint4*)&As[arow][aseg * 8] = av;
        if (BN == 256) {
#pragma unroll
            for (int j = 0; j < 4; j++) *(uint4*)&Bs[t][j * 8] = bv[j];
        } else {
            *(uint4*)&Bs[arow][aseg * 8] = bv[0];
        }
        __syncthreads();
        bf16x8 afrag = *(const bf16x8*)&As[wav * 16 + l15][quad * 8];
#pragma unroll
        for (int nt = 0; nt < BN / 16; nt++) {
            bf16x8 bfrag = *(const bf16x8*)&Bs[nt * 16 + l15][quad * 8];
            acc[nt] = __builtin_amdgcn_mfma_f32_16x16x32_bf16(afrag, bfrag, acc[nt], 0, 0, 0);
        }
    }
    int rbase = m0 + wav * 16 + quad * 4;
#pragma unroll
    for (int nt = 0; nt < BN / 16; nt++) {
        int col = nt * 16 + l15;
        float bb = bptr ? bptr[col] : 0.f;
#pragma unroll
        for (int r = 0; r < 4; r++) {
            int row = rbase + r;
            float v = acc[nt][r] + bb;
            if (relu) v = fmaxf(v, 0.f);
            float vp = __shfl_xor(v, 1);
            if (row < M && !(l15 & 1))
                cbf[((size_t)row * ldc + col) >> 1] = f2_to_bf2(v, vp);
        }
    }
}

// ---------- CSR build ----------
__global__ void deg_kernel(const int* __restrict__ dst, int* __restrict__ deg) {
    int t = blockIdx.x * blockDim.x + threadIdx.x;
    if (t < N_EDGES) atomicAdd(&deg[dst[t]], 1);
}
// ---- fused misc prep: dis | bounds | prep_w1 | prep_w2 | W1T | W2T | xbf ----
#define S1 50000
#define S2 100000
#define S3 100256
#define S4 101280
#define S5 117664
#define S6 183200
#define S7 1783200   // S6 + 50000*32
__global__ void prep_misc(const int* __restrict__ deg, float* __restrict__ dis,
                          const int* __restrict__ batch, int* __restrict__ gstart,
                          const float* __restrict__ W1, const float* __restrict__ a1s,
                          const float* __restrict__ a1d, float* __restrict__ wes1,
                          float* __restrict__ wed1,
                          const float* __restrict__ W2, const float* __restrict__ a2s,
                          const float* __restrict__ a2d, float* __restrict__ wes2,
                          float* __restrict__ wed2,
                          unsigned short* __restrict__ W1T, unsigned short* __restrict__ W2T,
                          const float* __restrict__ x, unsigned* __restrict__ xbf) {
    int i = blockIdx.x * blockDim.x + threadIdx.x;
    if (i >= S7) return;
    if (i >= S6) {                       // x -> bf16 (pairs)
        int j = i - S6;
        float2 v = *(const float2*)&x[(size_t)j * 2];
        xbf[j] = f2_to_bf2(v.x, v.y);
    } else if (i >= S5) {                // W2T
        int t2 = i - S5;
        int n = t2 >> 8, c = t2 & 255;
        unsigned u = __float_as_uint(W2[(size_t)c * 256 + n]);
        u = (u + 0x7fffu + ((u >> 16) & 1u)) >> 16;
        W2T[t2] = (unsigned short)u;
    } else if (i >= S4) {                // W1T
        int t2 = i - S4;
        int n = t2 >> 6, c = t2 & 63;
        unsigned u = __float_as_uint(W1[(size_t)c * 256 + n]);
        u = (u + 0x7fffu + ((u >> 16) & 1u)) >> 16;
        W1T[t2] = (unsigned short)u;
    } else if (i >= S3) {                // prep_w2
        int t2 = i - S3;
        int c = t2 >> 2, h = t2 & 3;
        float se = 0.f, sd = 0.f;
        for (int j = 0; j < 64; j++) {
            float w = W2[(size_t)c * 256 + h * 64 + j];
            se += w * a2s[h * 64 + j];
            sd += w * a2d[h * 64 + j];
        }
        wes2[c * 4 + h] = se;
        wed2[c * 4 + h] = sd;
    } else if (i >= S2) {                // prep_w1
        int t2 = i - S2;
        int c = t2 >> 2, h = t2 & 3;
        float se = 0.f, sd = 0.f;
        for (int j = 0; j < 64; j++) {
            float w = W1[(size_t)c * 256 + h * 64 + j];
            se += w * a1s[h * 64 + j];
            sd += w * a1d[h * 64 + j];
        }
        wes1[c * 4 + h] = se;
        wed1[c * 4 + h] = sd;
    } else if (i >= S1) {                // bounds
        int n = i - S1;
        int b = batch[n];
        int prev = (n == 0) ? -1 : batch[n - 1];
        for (int g = prev + 1; g <= b; g++) gstart[g] = n;
        if (n == N_NODES - 1)
            for (int g = b + 1; g <= N_GRAPHS; g++) gstart[g] = N_NODES;
    } else {                             // dis
        int d = deg[i];
        dis[i] = d > 0 ? rsqrtf((float)d) : 0.f;
    }
}
// ---- hierarchical scan ----
__global__ __launch_bounds__(256) void scan_bsum(const int* __restrict__ deg,
                                                 int* __restrict__ bsum) {
    __shared__ int sd[256];
    int n = blockIdx.x * 256 + threadIdx.x;
    sd[threadIdx.x] = (n < N_NODES) ? deg[n] : 0;
    __syncthreads();
    for (int o = 128; o > 0; o >>= 1) {
        if (threadIdx.x < o) sd[threadIdx.x] += sd[threadIdx.x + o];
        __syncthreads();
    }
    if (threadIdx.x == 0) bsum[blockIdx.x] = sd[0];
}
__global__ __launch_bounds__(256) void scan_bpre(const int* __restrict__ bsum,
                                                 int* __restrict__ bpre,
                                                 int* __restrict__ off_last) {
    __shared__ int sd[256];
    int t = threadIdx.x;
    int v = (t < NSB) ? bsum[t] : 0;
    sd[t] = v;
    __syncthreads();
    for (int o = 1; o < 256; o <<= 1) {
        int u = (t >= o) ? sd[t - o] : 0;
        __syncthreads();
        sd[t] += u;
        __syncthreads();
    }
    if (t < NSB) bpre[t] = sd[t] - v;
    if (t == 255) *off_last = sd[255];
}
__global__ __launch_bounds__(256) void scan_off(const int* __restrict__ deg,
                                                const int* __restrict__ bpre,
                                                int* __restrict__ off) {
    __shared__ int sd[256];
    int n = blockIdx.x * 256 + threadIdx.x;
    int t = threadIdx.x;
    int v = (n < N_NODES) ? deg[n] : 0;
    sd[t] = v;
    __syncthreads();
    for (int o = 1; o < 256; o <<= 1) {
        int u = (t >= o) ? sd[t - o] : 0;
        __syncthreads();
        sd[t] += u;
        __syncthreads();
    }
    if (n < N_NODES) off[n] = bpre[blockIdx.x] + sd[t] - v;
}
__global__ void csr_fill(const int* __restrict__ src, const int* __restrict__ dst,
                         const int* __restrict__ off, int* __restrict__ cursor,
                         int* __restrict__ csr_src) {
    int e = blockIdx.x * blockDim.x + threadIdx.x;
    if (e >= N_EDGES) return;
    int s = src[e], d = dst[e];
    int pos = off[d] + atomicAdd(&cursor[d], 1);
    csr_src[pos] = s;
}

// ---------- es/ed from K=64 fp32 input (x) ----------
__global__ void esed_x(const float* __restrict__ X, const float* __restrict__ wes,
                       const float* __restrict__ wed, float* __restrict__ es,
                       float* __restrict__ ed) {
    int gid = blockIdx.x * blockDim.x + threadIdx.x;
    int n = gid >> 6, lane = threadIdx.x & 63;
    if (n >= N_NODES) return;
    float xv = X[(size_t)n * 64 + lane];
    float4 a = *(const float4*)&wes[lane * 4];
    float4 b = *(const float4*)&wed[lane * 4];
    float4 ps = make_float4(xv * a.x, xv * a.y, xv * a.z, xv * a.w);
    float4 pd = make_float4(xv * b.x, xv * b.y, xv * b.z, xv * b.w);
#pragma unroll
    for (int o = 1; o < 64; o <<= 1) {
        ps.x += __shfl_xor(ps.x, o); ps.y += __shfl_xor(ps.y, o);
        ps.z += __shfl_xor(ps.z, o); ps.w += __shfl_xor(ps.w, o);
        pd.x += __shfl_xor(pd.x, o); pd.y += __shfl_xor(pd.y, o);
        pd.z += __shfl_xor(pd.z, o); pd.w += __shfl_xor(pd.w, o);
    }
    if (lane == 0) {
        *(float4*)&es[n * 4] = ps;
        *(float4*)&ed[n * 4] = pd;
    }
}

// ---------- es/ed from K=256 bf16 input (h1) ----------
__global__ void esed_h(const unsigned* __restrict__ Hbf, const float* __restrict__ wes,
                       const float* __restrict__ wed, float* __restrict__ es,
                       float* __restrict__ ed) {
    int gid = blockIdx.x * blockDim.x + threadIdx.x;
    int n = gid >> 6, lane = threadIdx.x & 63;
    if (n >= N_NODES) return;
    float4 xv = bf4_to_f4(*(const uint2*)&Hbf[(size_t)n * 128 + lane * 2]);
    float xs[4] = {xv.x, xv.y, xv.z, xv.w};
    float4 ps = make_float4(0.f, 0.f, 0.f, 0.f);
    float4 pd = make_float4(0.f, 0.f, 0.f, 0.f);
#pragma unroll
    for (int r = 0; r < 4; r++) {
        int c = lane * 4 + r;
        float4 a = *(const float4*)&wes[c * 4];
        float4 b = *(const float4*)&wed[c * 4];
        ps.x += xs[r] * a.x; ps.y += xs[r] * a.y; ps.z += xs[r] * a.z; ps.w += xs[r] * a.w;
        pd.x += xs[r] * b.x; pd.y += xs[r] * b.y; pd.z += xs[r] * b.z; pd.w += xs[r] * b.w;
    }
#pragma unroll
    for (int o = 1; o < 64; o <<= 1) {
        ps.x += __shfl_xor(ps.x, o); ps.y += __shfl_xor(ps.y, o);
        ps.z += __shfl_xor(ps.z, o); ps.w += __shfl_xor(ps.w, o);
        pd.x += __shfl_xor(pd.x, o); pd.y += __shfl_xor(pd.y, o);
        pd.z += __shfl_xor(pd.z, o); pd.w += __shfl_xor(pd.w, o);
    }
    if (lane == 0) {
        *(float4*)&es[n * 4] = ps;
        *(float4*)&ed[n * 4] = pd;
    }
}

// ---------- GAT1: fused softmax + bf16-x aggregation (depth-4 pipeline) ----------
__global__ __launch_bounds__(256)
void gat1_fused(const int* __restrict__ off, const int* __restrict__ csr_src,
                const float* __restrict__ es, const float* __restrict__ ed,
                const unsigned* __restrict__ xbf, unsigned* __restrict__ aggx_bf,
                float* __restrict__ alpha_fb) {
    __shared__ float elds[4][CAP * 4];
    __shared__ int   sidx[4][CAP];
    int wav = threadIdx.x >> 6, lane = threadIdx.x & 63;
    int n = blockIdx.x * 4 + wav;
    bool active = n < N_NODES;
    int p0 = 0, p1 = 0;
    float4 ed4 = make_float4(0.f, 0.f, 0.f, 0.f);
    if (active) { p0 = off[n]; p1 = off[n + 1]; ed4 = *(const float4*)&ed[n * 4]; }
    float4 sum = make_float4(0.f, 0.f, 0.f, 0.f);
    for (int p = p0 + lane; p < p1; p += 64) {
        int s = csr_src[p];
        float4 e4 = *(const float4*)&es[s * 4];
        e4.x += ed4.x; e4.y += ed4.y; e4.z += ed4.z; e4.w += ed4.w;
        e4.x = e4.x > 0.f ? e4.x : 0.2f * e4.x;
        e4.y = e4.y > 0.f ? e4.y : 0.2f * e4.y;
        e4.z = e4.z > 0.f ? e4.z : 0.2f * e4.z;
        e4.w = e4.w > 0.f ? e4.w : 0.2f * e4.w;
        e4.x = __expf(e4.x); e4.y = __expf(e4.y); e4.z = __expf(e4.z); e4.w = __expf(e4.w);
        int q = p - p0;
        if (q < CAP) { *(float4*)&elds[wav][q * 4] = e4; sidx[wav][q] = s; }
        else         *(float4*)&alpha_fb[(size_t)p * 4] = e4;
        sum.x += e4.x; sum.y += e4.y; sum.z += e4.z; sum.w += e4.w;
    }
#pragma unroll
    for (int o = 1; o < 64; o <<= 1) {
        sum.x += __shfl_xor(sum.x, o); sum.y += __shfl_xor(sum.y, o);
        sum.z += __shfl_xor(sum.z, o); sum.w += __shfl_xor(sum.w, o);
    }
    float4 rs;
    rs.x = sum.x > 0.f ? 1.f / sum.x : 0.f;
    rs.y = sum.y > 0.f ? 1.f / sum.y : 0.f;
    rs.z = sum.z > 0.f ? 1.f / sum.z : 0.f;
    rs.w = sum.w > 0.f ? 1.f / sum.w : 0.f;
    if (!active) return;
    int eg = lane >> 4, l15 = lane & 15;
    int deg = p1 - p0;
    float4 a0 = make_float4(0.f, 0.f, 0.f, 0.f);
    float4 a1 = a0, a2 = a0, a3 = a0;
    auto fetch = [&](int qq, float4& e4, float4& xv) {
        e4 = make_float4(0.f, 0.f, 0.f, 0.f);
        xv = e4;
        if (qq < deg) {
            int s;
            if (qq < CAP) { s = sidx[wav][qq]; e4 = *(const float4*)&elds[wav][qq * 4]; }
            else { s = csr_src[p0 + qq]; e4 = *(const float4*)&alpha_fb[(size_t)(p0 + qq) * 4]; }
            xv = bf4_to_f4(*(const uint2*)&xbf[(size_t)s * 32 + l15 * 2]);
        }
    };
    int q = eg;
    float4 eA, xA, eB, xB, eC, xC;
    fetch(q, eA, xA);
    fetch(q + 4, eB, xB);
    fetch(q + 8, eC, xC);
    while (q < deg) {
        float4 eD, xD;
        fetch(q + 12, eD, xD);
        a0.x += eA.x * xA.x; a0.y += eA.x * xA.y; a0.z += eA.x * xA.z; a0.w += eA.x * xA.w;
        a1.x += eA.y * xA.x; a1.y += eA.y * xA.y; a1.z += eA.y * xA.z; a1.w += eA.y * xA.w;
        a2.x += eA.z * xA.x; a2.y += eA.z * xA.y; a2.z += eA.z * xA.z; a2.w += eA.z * xA.w;
        a3.x += eA.w * xA.x; a3.y += eA.w * xA.y; a3.z += eA.w * xA.z; a3.w += eA.w * xA.w;
        eA = eB; xA = xB; eB = eC; xB = xC; eC = eD; xC = xD;
        q += 4;
    }
#pragma unroll
    for (int o = 16; o < 64; o <<= 1) {
        a0.x += __shfl_xor(a0.x, o); a0.y += __shfl_xor(a0.y, o);
        a0.z += __shfl_xor(a0.z, o); a0.w += __shfl_xor(a0.w, o);
        a1.x += __shfl_xor(a1.x, o); a1.y += __shfl_xor(a1.y, o);
        a1.z += __shfl_xor(a1.z, o); a1.w += __shfl_xor(a1.w, o);
        a2.x += __shfl_xor(a2.x, o); a2.y += __shfl_xor(a2.y, o);
        a2.z += __shfl_xor(a2.z, o); a2.w += __shfl_xor(a2.w, o);
        a3.x += __shfl_xor(a3.x, o); a3.y += __shfl_xor(a3.y, o);
        a3.z += __shfl_xor(a3.z, o); a3.w += __shfl_xor(a3.w, o);
    }
    if (eg == 0) {
        a0.x *= rs.x; a0.y *= rs.x; a0.z *= rs.x; a0.w *= rs.x;
        a1.x *= rs.y; a1.y *= rs.y; a1.z *= rs.y; a1.w *= rs.y;
        a2.x *= rs.z; a2.y *= rs.z; a2.z *= rs.z; a2.w *= rs.z;
        a3.x *= rs.w; a3.y *= rs.w; a3.z *= rs.w; a3.w *= rs.w;
        size_t b = (size_t)n * 128 + l15 * 2;
        *(uint2*)&aggx_bf[b +  0] = f4_to_bf4(a0);
        *(uint2*)&aggx_bf[b + 32] = f4_to_bf4(a1);
        *(uint2*)&aggx_bf[b + 64] = f4_to_bf4(a2);
        *(uint2*)&aggx_bf[b + 96] = f4_to_bf4(a3);
    }
}

// ---------- GAT2: fused softmax + bf16 gather (depth-4 pipeline) ----------
__global__ __launch_bounds__(256)
void gat2_fused(const int* __restrict__ off, const int* __restrict__ csr_src,
                const float* __restrict__ es, const float* __restrict__ ed,
                const unsigned* __restrict__ H2bf, const float* __restrict__ bias,
                unsigned* __restrict__ outbf, float* __restrict__ alpha_fb) {
    __shared__ float elds[4][CAP * 4];
    __shared__ int   sidx[4][CAP];
    int wav = threadIdx.x >> 6, lane = threadIdx.x & 63;
    int n = blockIdx.x * 4 + wav;
    bool active = n < N_NODES;
    int p0 = 0, p1 = 0;
    float4 ed4 = make_float4(0.f, 0.f, 0.f, 0.f);
    if (active) { p0 = off[n]; p1 = off[n + 1]; ed4 = *(const float4*)&ed[n * 4]; }
    float4 sum = make_float4(0.f, 0.f, 0.f, 0.f);
    for (int p = p0 + lane; p < p1; p += 64) {
        int s = csr_src[p];
        float4 e4 = *(const float4*)&es[s * 4];
        e4.x += ed4.x; e4.y += ed4.y; e4.z += ed4.z; e4.w += ed4.w;
        e4.x = e4.x > 0.f ? e4.x : 0.2f * e4.x;
        e4.y = e4.y > 0.f ? e4.y : 0.2f * e4.y;
        e4.z = e4.z > 0.f ? e4.z : 0.2f * e4.z;
        e4.w = e4.w > 0.f ? e4.w : 0.2f * e4.w;
        e4.x = __expf(e4.x); e4.y = __expf(e4.y); e4.z = __expf(e4.z); e4.w = __expf(e4.w);
        int q = p - p0;
        if (q < CAP) { *(float4*)&elds[wav][q * 4] = e4; sidx[wav][q] = s; }
        else         *(float4*)&alpha_fb[(size_t)p * 4] = e4;
        sum.x += e4.x; sum.y += e4.y; sum.z += e4.z; sum.w += e4.w;
    }
#pragma unroll
    for (int o = 1; o < 64; o <<= 1) {
        sum.x += __shfl_xor(sum.x, o); sum.y += __shfl_xor(sum.y, o);
        sum.z += __shfl_xor(sum.z, o); sum.w += __shfl_xor(sum.w, o);
    }
    if (!active) return;
    int half = lane >> 5, l = lane & 31;
    int hh = l >> 3;
    float sh = (hh == 0) ? sum.x : (hh == 1) ? sum.y : (hh == 2) ? sum.z : sum.w;
    float rsh = sh > 0.f ? 1.f / sh : 0.f;
    int deg = p1 - p0;
    float acc[8];
#pragma unroll
    for (int j = 0; j < 8; j++) acc[j] = 0.f;
    auto fetch = [&](int qq, float& al, uint4& rr) {
        al = 0.f;
        rr = make_uint4(0, 0, 0, 0);
        if (qq < deg) {
            int s;
            if (qq < CAP) { s = sidx[wav][qq]; al = elds[wav][qq * 4 + hh]; }
            else { s = csr_src[p0 + qq]; al = alpha_fb[(size_t)(p0 + qq) * 4 + hh]; }
            rr = *(const uint4*)&H2bf[(size_t)s * 128 + l * 4];
        }
    };
    int q = half;
    float aA, aB, aC;
    uint4 rA, rB, rC;
    fetch(q, aA, rA);
    fetch(q + 2, aB, rB);
    fetch(q + 4, aC, rC);
    while (q < deg) {
        float aD; uint4 rD;
        fetch(q + 6, aD, rD);
        float4 f0 = bf4_to_f4(make_uint2(rA.x, rA.y));
        float4 f1 = bf4_to_f4(make_uint2(rA.z, rA.w));
        acc[0] += aA * f0.x; acc[1] += aA * f0.y; acc[2] += aA * f0.z; acc[3] += aA * f0.w;
        acc[4] += aA * f1.x; acc[5] += aA * f1.y; acc[6] += aA * f1.z; acc[7] += aA * f1.w;
        aA = aB; rA = rB; aB = aC; rB = rC; aC = aD; rC = rD;
        q += 2;
    }
#pragma unroll
    for (int j = 0; j < 8; j++) acc[j] += __shfl_xor(acc[j], 32);
    if (half == 0) {
        float4 b0 = *(const float4*)&bias[l * 8];
        float4 b1 = *(const float4*)&bias[l * 8 + 4];
        float4 o0, o1;
        o0.x = fmaxf(acc[0] * rsh + b0.x, 0.f);
        o0.y = fmaxf(acc[1] * rsh + b0.y, 0.f);
        o0.z = fmaxf(acc[2] * rsh + b0.z, 0.f);
        o0.w = fmaxf(acc[3] * rsh + b0.w, 0.f);
        o1.x = fmaxf(acc[4] * rsh + b1.x, 0.f);
        o1.y = fmaxf(acc[5] * rsh + b1.y, 0.f);
        o1.z = fmaxf(acc[6] * rsh + b1.z, 0.f);
        o1.w = fmaxf(acc[7] * rsh + b1.w, 0.f);
        uint2 w0 = f4_to_bf4(o0), w1 = f4_to_bf4(o1);
        uint4 w = make_uint4(w0.x, w0.y, w1.x, w1.y);
        *(uint4*)&outbf[(size_t)n * 128 + l * 4] = w;
    }
}

// ---------- label prop: LDS idx+weight staging, depth-4 pipeline ----------
__global__ __launch_bounds__(256)
void lp_csr(const int* __restrict__ off, const int* __restrict__ csr_src,
            const float* __restrict__ dis, const unsigned* __restrict__ in_bf,
            const unsigned* __restrict__ res_bf, unsigned* __restrict__ out_bf) {
    __shared__ int   widx[4][CAP];
    __shared__ float wwt[4][CAP];
    int wav = threadIdx.x >> 6, lane = threadIdx.x & 63;
    int n = blockIdx.x * 4 + wav;
    if (n >= N_NODES) return;
    int p0 = off[n], p1 = off[n + 1];
    int deg = p1 - p0;
    float disd = dis[n];
    for (int q = lane; q < deg && q < CAP; q += 64) {
        int s = csr_src[p0 + q];
        widx[wav][q] = s;
        wwt[wav][q] = dis[s] * disd;
    }
    int half = lane >> 5, l = lane & 31;
    float acc[8];
#pragma unroll
    for (int j = 0; j < 8; j++) acc[j] = 0.f;
    auto fetch = [&](int qq, float& nw, uint4& rr) {
        nw = 0.f;
        rr = make_uint4(0, 0, 0, 0);
        if (qq < deg) {
            int s;
            if (qq < CAP) { s = widx[wav][qq]; nw = wwt[wav][qq]; }
            else { s = csr_src[p0 + qq]; nw = dis[s] * disd; }
            rr = *(const uint4*)&in_bf[(size_t)s * 128 + l * 4];
        }
    };
    int q = half;
    float nA, nB, nC;
    uint4 rA, rB, rC;
    fetch(q, nA, rA);
    fetch(q + 2, nB, rB);
    fetch(q + 4, nC, rC);
    while (q < deg) {
        float nD; uint4 rD;
        fetch(q + 6, nD, rD);
        float4 f0 = bf4_to_f4(make_uint2(rA.x, rA.y));
        float4 f1 = bf4_to_f4(make_uint2(rA.z, rA.w));
        acc[0] += nA * f0.x; acc[1] += nA * f0.y; acc[2] += nA * f0.z; acc[3] += nA * f0.w;
        acc[4] += nA * f1.x; acc[5] += nA * f1.y; acc[6] += nA * f1.z; acc[7] += nA * f1.w;
        nA = nB; rA = rB; nB = nC; rB = rC; nC = nD; rC = rD;
        q += 2;
    }
#pragma unroll
    for (int j = 0; j < 8; j++) acc[j] += __shfl_xor(acc[j], 32);
    if (half == 0) {
        uint4 rr = *(const uint4*)&res_bf[(size_t)n * 128 + l * 4];
        float4 r0 = bf4_to_f4(make_uint2(rr.x, rr.y));
        float4 r1 = bf4_to_f4(make_uint2(rr.z, rr.w));
        float4 o0, o1;
        o0.x = fminf(fmaxf(0.5f * acc[0] + 0.5f * r0.x, 0.f), 1.f);
        o0.y = fminf(fmaxf(0.5f * acc[1] + 0.5f * r0.y, 0.f), 1.f);
        o0.z = fminf(fmaxf(0.5f * acc[2] + 0.5f * r0.z, 0.f), 1.f);
        o0.w = fminf(fmaxf(0.5f * acc[3] + 0.5f * r0.w, 0.f), 1.f);
        o1.x = fminf(fmaxf(0.5f * acc[4] + 0.5f * r1.x, 0.f), 1.f);
        o1.y = fminf(fmaxf(0.5f * acc[5] + 0.5f * r1.y, 0.f), 1.f);
        o1.z = fminf(fmaxf(0.5f * acc[6] + 0.5f * r1.z, 0.f), 1.f);
        o1.w = fminf(fmaxf(0.5f * acc[7] + 0.5f * r1.w, 0.f), 1.f);
        uint2 w0 = f4_to_bf4(o0), w1 = f4_to_bf4(o1);
        uint4 w = make_uint4(w0.x, w0.y, w1.x, w1.y);
        *(uint4*)&out_bf[(size_t)n * 128 + l * 4] = w;
    }
}

// ---------- pooling ----------
__global__ void pool_partial(const float* __restrict__ buf, const int* __restrict__ gstart,
                             float* __restrict__ psum, int C, int colOff) {
    int g = blockIdx.x, q = blockIdx.y;
    int n0 = gstart[g], n1 = gstart[g + 1];
    int len = n1 - n0;
    int ns = n0 + (len * q) / 4, ne = n0 + (len * (q + 1)) / 4;
    int cp = threadIdx.x % C;
    int np = threadIdx.x / C;
    int NP = 256 / C;
    float s = 0.f;
    for (int n = ns + np; n < ne; n += NP) s += buf[(size_t)n * C + cp];
    atomicAdd(&psum[g * JK + colOff + cp], s);
}
__global__ void pool_bf(const unsigned* __restrict__ buf, const int* __restrict__ gstart,
                        float* __restrict__ psum, int colOff) {
    int g = blockIdx.x, q = blockIdx.y;
    int n0 = gstart[g], n1 = gstart[g + 1];
    int len = n1 - n0;
    int ns = n0 + (len * q) / 4, ne = n0 + (len * (q + 1)) / 4;
    int cp = threadIdx.x & 127;
    int np = threadIdx.x >> 7;
    float s0 = 0.f, s1 = 0.f;
    for (int n = ns + np; n < ne; n += 2) {
        unsigned u = buf[(size_t)n * 128 + cp];
        s0 += __uint_as_float(u << 16);
        s1 += __uint_as_float(u & 0xffff0000u);
    }
    atomicAdd(&psum[g * JK + colOff + cp * 2 + 0], s0);
    atomicAdd(&psum[g * JK + colOff + cp * 2 + 1], s1);
}
__global__ void gmean_kernel(const float* __restrict__ psum, const int* __restrict__ gstart,
                             float* __restrict__ g) {
    int i = blockIdx.x * blockDim.x + threadIdx.x;
    if (i >= N_GRAPHS * JK) return;
    int gi = i / JK;
    int len = gstart[gi + 1] - gstart[gi];
    g[i] = psum[i] / (float)(len > 1 ? len : 1);
}

// ---------- MLP head ----------
__global__ __launch_bounds__(64)
void head_d1(const float* __restrict__ gbuf, const float* __restrict__ W,
             const float* __restrict__ bias, float* __restrict__ out) {
    __shared__ float zin[JK];
    int g = blockIdx.y, mc = blockIdx.x, lane = threadIdx.x;
    for (int k = lane; k < JK; k += 64) zin[k] = gbuf[g * JK + k];
    __syncthreads();
    int m = mc * 64 + lane;
    float acc = bias[m];
#pragma unroll 8
    for (int k = 0; k < JK; k++) acc += zin[k] * W[k * 256 + m];
    out[g * 256 + m] = fmaxf(acc, 0.f);
}

__global__ __launch_bounds__(256)
void head_rest(const float* __restrict__ t1, const float* __restrict__ clin,
               const float* __restrict__ pp_w2, const float* __restrict__ pp_b2,
               const float* __restrict__ cl_w1, const float* __restrict__ cl_b1,
               const float* __restrict__ cl_w2, const float* __restrict__ cl_b2,
               const float* __restrict__ h_w1, const float* __restrict__ h_b1,
               const float* __restrict__ h_w2, const float* __restrict__ h_b2,
               const float* __restrict__ h_w3, const float* __restrict__ h_b3,
               float* __restrict__ out) {
    __shared__ float z1[256];
    __shared__ float zcl[32];
    __shared__ float zc[64];
    __shared__ float z[160];
    __shared__ float z3[64];
    __shared__ float z4[32];
    __shared__ float part[128];
    int g = blockIdx.x, t = threadIdx.x;
    z1[t] = t1[g * 256 + t];
    if (t < 32) zcl[t] = clin[g * 32 + t];
    __syncthreads();
    int m = t & 127, half = t >> 7;
    {
        float acc = 0.f;
        int k0 = half * 128;
#pragma unroll 8
        for (int k = k0; k < k0 + 128; k++) acc += z1[k] * pp_w2[k * 128 + m];
        if (half) part[m] = acc;
        __syncthreads();
        if (!half) z[m] = acc + part[m] + pp_b2[m];
    }
    if (t < 64) {
        float acc = cl_b1[t];
#pragma unroll
        for (int k = 0; k < 32; k++) acc += zcl[k] * cl_w1[k * 64 + t];
        zc[t] = fmaxf(acc, 0.f);
    }
    __syncthreads();
    if (t < 32) {
        float acc = cl_b2[t];
#pragma unroll
        for (int k = 0; k < 64; k++) acc += zc[k] * cl_w2[k * 32 + t];
        z[128 + t] = acc;
    }
    __syncthreads();
    if (t < 64) {
        float acc = h_b1[t];
#pragma unroll 8
        for (int k = 0; k < 160; k++) acc += z[k] * h_w1[k * 64 + t];
        z3[t] = fmaxf(acc, 0.f);
    }
    __syncthreads();
    if (t < 32) {
        float acc = h_b2[t];
#pragma unroll
        for (int k = 0; k < 64; k++) acc += z3[k] * h_w2[k * 32 + t];
        z4[t] = fmaxf(acc, 0.f);
    }
    __syncthreads();
    if (t < 2) {
        float acc = h_b3[t];
#pragma unroll
        for (int k = 0; k < 32; k++) acc += z4[k] * h_w3[k * 2 + t];
        out[g * 2 + t] = acc;
    }
}

// ---------- launch ----------
extern "C" void kernel_launch(void* const* d_in, const int* in_sizes, int n_in,
                              void* d_out, int out_size, void* d_ws, size_t ws_size,
                              hipStream_t stream) {
    const float* x     = (const float*)d_in[0];
    const int*   ei    = (const int*)d_in[1];
    const int*   batch = (const int*)d_in[2];
    const float* clin  = (const float*)d_in[3];
    const float* W1  = (const float*)d_in[4];
    const float* a1s = (const float*)d_in[5];
    const float* a1d = (const float*)d_in[6];
    const float* b1  = (const float*)d_in[7];
    const float* W2  = (const float*)d_in[8];
    const float* a2s = (const float*)d_in[9];
    const float* a2d = (const float*)d_in[10];
    const float* b2  = (const float*)d_in[11];
    const float* pp_w1 = (const float*)d_in[12];
    const float* pp_b1 = (const float*)d_in[13];
    const float* pp_w2 = (const float*)d_in[14];
    const float* pp_b2 = (const float*)d_in[15];
    const float* cl_w1 = (const float*)d_in[16];
    const float* cl_b1 = (const float*)d_in[17];
    const float* cl_w2 = (const float*)d_in[18];
    const float* cl_b2 = (const float*)d_in[19];
    const float* h_w1  = (const float*)d_in[20];
    const float* h_b1  = (const float*)d_in[21];
    const float* h_w2  = (const float*)d_in[22];
    const float* h_b2  = (const float*)d_in[23];
    const float* h_w3  = (const float*)d_in[24];
    const float* h_b3  = (const float*)d_in[25];

    const int* src = ei;
    const int* dst = ei + N_EDGES;

    char* p = (char*)d_ws;
    auto carve = [&](size_t bytes) -> char* {
        char* r = p;
        p += (bytes + 255) & ~(size_t)255;
        return r;
    };
    const size_t NBH = (size_t)N_NODES * 256 * 2;    // bf16 node buffer
    unsigned* abf  = (unsigned*)carve(NBH);          // aggx, later h2_final
    unsigned* bf1  = (unsigned*)carve(NBH);
    unsigned* bf2  = (unsigned*)carve(NBH);
    unsigned* bf3  = (unsigned*)carve(NBH);
    unsigned* xbf  = (unsigned*)carve((size_t)N_NODES * 32 * 4);  // bf16 x copy
    float* alpha_fb  = (float*)carve((size_t)N_EDGES * 4 * 4);
    int*   csr_src   = (int*)carve((size_t)N_EDGES * 4);
    int*   off       = (int*)carve((size_t)(N_NODES + 1) * 4);
    int*   deg       = (int*)carve((size_t)N_NODES * 4);
    int*   cursor    = (int*)carve((size_t)N_NODES * 4);
    int*   bsum      = (int*)carve((size_t)NSB * 4);
    int*   bpre      = (int*)carve((size_t)NSB * 4);
    float* dis       = (float*)carve((size_t)N_NODES * 4);
    float* es        = (float*)carve((size_t)N_NODES * 4 * 4);
    float* ed        = (float*)carve((size_t)N_NODES * 4 * 4);
    float* wes1      = (float*)carve((size_t)64 * 4 * 4);
    float* wed1      = (float*)carve((size_t)64 * 4 * 4);
    float* wes2      = (float*)carve((size_t)256 * 4 * 4);
    float* wed2      = (float*)carve((size_t)256 * 4 * 4);
    unsigned short* W1T = (unsigned short*)carve((size_t)256 * 64 * 2);
    unsigned short* W2T = (unsigned short*)carve((size_t)256 * 256 * 2);
    int*   gstart    = (int*)carve((size_t)(N_GRAPHS + 1) * 4);
    float* psum      = (float*)carve((size_t)N_GRAPHS * JK * 4);
    float* gbuf      = (float*)carve((size_t)N_GRAPHS * JK * 4);
    float* t1        = (float*)carve((size_t)N_GRAPHS * 256 * 4);

    const int TB = 256;
    const int gE     = (N_EDGES + TB - 1) / TB;
    const int gNwave = (N_NODES * 64 + TB - 1) / TB;
    const int gFuse  = (N_NODES + 3) / 4;
    const int gRow   = (N_NODES + 63) / 64;
    const int gPrep  = (S7 + TB - 1) / TB;

    // ---- CSR + degree + fused misc prep ----
    hipMemsetAsync(deg, 0, (size_t)N_NODES * 4, stream);
    hipMemsetAsync(cursor, 0, (size_t)N_NODES * 4, stream);
    hipMemsetAsync(psum, 0, (size_t)N_GRAPHS * JK * 4, stream);
    deg_kernel<<<gE, TB, 0, stream>>>(dst, deg);
    prep_misc<<<gPrep, TB, 0, stream>>>(deg, dis, batch, gstart,
                                        W1, a1s, a1d, wes1, wed1,
                                        W2, a2s, a2d, wes2, wed2,
                                        W1T, W2T, x, xbf);
    scan_bsum<<<NSB, 256, 0, stream>>>(deg, bsum);
    scan_bpre<<<1, 256, 0, stream>>>(bsum, bpre, &off[N_NODES]);
    scan_off<<<NSB, 256, 0, stream>>>(deg, bpre, off);
    csr_fill<<<gE, TB, 0, stream>>>(src, dst, off, cursor, csr_src);

    // ---- GAT layer 1 ----
    esed_x<<<gNwave, TB, 0, stream>>>(x, wes1, wed1, es, ed);
    gat1_fused<<<gFuse, TB, 0, stream>>>(off, csr_src, es, ed, xbf, abf, alpha_fb);
    mfma_gemm<64, 64><<<dim3(gRow, 4), 256, 0, stream>>>(
        (const unsigned short*)abf, 256, W1T, bf1, 256, N_NODES, b1, 1,
        64, 64 * 64, 64);                                   // bf1 = h1a

    // ---- label prop 1 (residual = bf1) ----
    lp_csr<<<gFuse, TB, 0, stream>>>(off, csr_src, dis, bf1, bf1, bf2);
    lp_csr<<<gFuse, TB, 0, stream>>>(off, csr_src, dis, bf2, bf1, bf3);   // bf3 = h1

    pool_bf<<<dim3(N_GRAPHS, 4), TB, 0, stream>>>(bf3, gstart, psum, 64);

    // ---- GAT layer 2 ----
    mfma_gemm<256, 256><<<dim3(gRow, 1), 256, 0, stream>>>(
        (const unsigned short*)bf3, 256, W2T, bf1, 256, N_NODES, nullptr, 0,
        0, 0, 0);                                           // bf1 = h2
    esed_h<<<gNwave, TB, 0, stream>>>(bf3, wes2, wed2, es, ed);
    gat2_fused<<<gFuse, TB, 0, stream>>>(off, csr_src, es, ed, bf1, b2, bf2, alpha_fb); // bf2 = h2a

    // ---- label prop 2 (residual = bf2) ----
    lp_csr<<<gFuse, TB, 0, stream>>>(off, csr_src, dis, bf2, bf2, bf1);
    lp_csr<<<gFuse, TB, 0, stream>>>(off, csr_src, dis, bf1, bf2, abf);   // abf = h2_final

    // ---- pooling (x fp32, h2 bf16) + mean ----
    pool_partial<<<dim3(N_GRAPHS, 4), TB, 0, stream>>>(x, gstart, psum, 64, 0);
    pool_bf<<<dim3(N_GRAPHS, 4), TB, 0, stream>>>(abf, gstart, psum, 320);
    gmean_kernel<<<(N_GRAPHS * JK + TB - 1) / TB, TB, 0, stream>>>(psum, gstart, gbuf);

    // ---- MLP head ----
    head_d1<<<dim3(4, N_GRAPHS), 64, 0, stream>>>(gbuf, pp_w1, pp_b1, t1);
    head_rest<<<N_GRAPHS, 256, 0, stream>>>(t1, clin, pp_w2, pp_b2, cl_w1, cl_b1,
                                            cl_w2, cl_b2, h_w1, h_b1, h_w2, h_b2,
                                            h_w3, h_b3, (float*)d_out);
}

// Round 12
// 769.672 us; speedup vs baseline: 22.6860x; 1.0190x over previous
//
#include <hip/hip_runtime.h>

#define N_NODES 50000
#define N_EDGES 800000
#define N_GRAPHS 128
#define JK 576              // 64 + 256 + 256
#define CAP 96              // max cached in-degree (Poisson(16), max~45; fallback exists)
#define NSB ((N_NODES + 255) / 256)   // scan blocks = 196

typedef __attribute__((ext_vector_type(8))) short bf16x8;
typedef __attribute__((ext_vector_type(4))) float f32x4;

// ---------- bf16 pack/unpack helpers ----------
__device__ __forceinline__ unsigned f2_to_bf2(float a, float b) {
    unsigned ua = __float_as_uint(a), ub = __float_as_uint(b);
    ua = (ua + 0x7fffu + ((ua >> 16) & 1u)) >> 16;       // RNE
    ub = (ub + 0x7fffu + ((ub >> 16) & 1u)) >> 16;
    return ua | (ub << 16);
}
__device__ __forceinline__ uint2 f4_to_bf4(float4 v) {
    return make_uint2(f2_to_bf2(v.x, v.y), f2_to_bf2(v.z, v.w));
}
__device__ __forceinline__ float4 bf4_to_f4(uint2 u) {
    float4 r;
    r.x = __uint_as_float(u.x << 16);
    r.y = __uint_as_float(u.x & 0xffff0000u);
    r.z = __uint_as_float(u.y << 16);
    r.w = __uint_as_float(u.y & 0xffff0000u);
    return r;
}

// ---------- MFMA GEMM: bf16 out = A_bf16 @ B (BT n-major bf16), fp32 acc ----------
template<int BN, int KK>
__global__ __launch_bounds__(256)
void mfma_gemm(const unsigned short* __restrict__ Abf, int lda,
               const unsigned short* __restrict__ BT,
               unsigned* __restrict__ Cbf, int ldc,
               int M, const float* __restrict__ bias, int relu,
               int a_off, int b_off, int c_off) {
    __shared__ unsigned short As[64][32];
    __shared__ unsigned short Bs[BN][32];
    const int t = threadIdx.x;
    const int wav = t >> 6, lane = t & 63;
    const int quad = lane >> 4, l15 = lane & 15;
    const int m0 = blockIdx.x * 64;
    const int head = blockIdx.y;
    Abf += (size_t)head * a_off;
    BT  += (size_t)head * b_off;
    const float* bptr = bias ? bias + (size_t)head * c_off : nullptr;
    unsigned* cbf = Cbf + (((size_t)head * c_off) >> 1);

    f32x4 acc[BN / 16];
#pragma unroll
    for (int i = 0; i < BN / 16; i++) acc[i] = (f32x4){0.f, 0.f, 0.f, 0.f};

    const int arow = t >> 2, aseg = t & 3;
    for (int k0 = 0; k0 < KK; k0 += 32) {
        uint4 av = make_uint4(0, 0, 0, 0);
        int gm = m0 + arow;
        if (gm < M) av = *(const uint4*)&Abf[(size_t)gm * lda + k0 + aseg * 8];
        uint4 bv[BN == 256 ? 4 : 1];
        if (BN == 256) {
            const unsigned short* srcb = &BT[(size_t)t * KK + k0];
#pragma unroll
            for (int j = 0; j < 4; j++) bv[j] = *(const uint4*)&srcb[j * 8];
        } else {
            bv[0] = *(const uint4*)&BT[(size_t)arow * KK + k0 + aseg * 8];
        }
        __syncthreads();
        *(uint4*)&As[arow][aseg * 8] = av;
        if (BN == 256) {
#pragma unroll
            for (int j = 0; j < 4; j++) *(uint4*)&Bs[t][j * 8] = bv[j];
        } else {
            *(uint4*)&Bs[arow][aseg * 8] = bv[0];
        }
        __syncthreads();
        bf16x8 afrag = *(const bf16x8*)&As[wav * 16 + l15][quad * 8];
#pragma unroll
        for (int nt = 0; nt < BN / 16; nt++) {
            bf16x8 bfrag = *(const bf16x8*)&Bs[nt * 16 + l15][quad * 8];
            acc[nt] = __builtin_amdgcn_mfma_f32_16x16x32_bf16(afrag, bfrag, acc[nt], 0, 0, 0);
        }
    }
    int rbase = m0 + wav * 16 + quad * 4;
#pragma unroll
    for (int nt = 0; nt < BN / 16; nt++) {
        int col = nt * 16 + l15;
        float bb = bptr ? bptr[col] : 0.f;
#pragma unroll
        for (int r = 0; r < 4; r++) {
            int row = rbase + r;
            float v = acc[nt][r] + bb;
            if (relu) v = fmaxf(v, 0.f);
            float vp = __shfl_xor(v, 1);
            if (row < M && !(l15 & 1))
                cbf[((size_t)row * ldc + col) >> 1] = f2_to_bf2(v, vp);
        }
    }
}

// ---------- degree + graph bounds (fused) ----------
__global__ void deg_kernel(const int* __restrict__ dst, int* __restrict__ deg,
                           const int* __restrict__ batch, int* __restrict__ gstart) {
    int t = blockIdx.x * blockDim.x + threadIdx.x;
    if (t < N_EDGES) {
        atomicAdd(&deg[dst[t]], 1);
    } else if (t < N_EDGES + N_NODES) {
        int n = t - N_EDGES;
        int b = batch[n];
        int prev = (n == 0) ? -1 : batch[n - 1];
        for (int g = prev + 1; g <= b; g++) gstart[g] = n;
        if (n == N_NODES - 1)
            for (int g = b + 1; g <= N_GRAPHS; g++) gstart[g] = N_NODES;
    }
}

// ---- fused misc prep: dis | prep_w1 | prep_w2 | W1T | W2T | xbf | pool(x) ----
#define S1 50000
#define S2 50256
#define S3 51280
#define S4 67664
#define S5 133200
#define S6 1733200            // S5 + 50000*32  (xbf pairs)
#define S7 (S6 + 131072)      // + 128 graphs * 4 quarters * 256 threads (x pooling)
__global__ void prep_misc(const int* __restrict__ deg, float* __restrict__ dis,
                          const float* __restrict__ W1, const float* __restrict__ a1s,
                          const float* __restrict__ a1d, float* __restrict__ wes1,
                          float* __restrict__ wed1,
                          const float* __restrict__ W2, const float* __restrict__ a2s,
                          const float* __restrict__ a2d, float* __restrict__ wes2,
                          float* __restrict__ wed2,
                          unsigned short* __restrict__ W1T, unsigned short* __restrict__ W2T,
                          const float* __restrict__ x, unsigned* __restrict__ xbf,
                          const int* __restrict__ gstart, float* __restrict__ psum) {
    int i = blockIdx.x * blockDim.x + threadIdx.x;
    if (i >= S7) return;
    if (i >= S6) {                       // pool x -> psum[:, 0:64]
        int t2 = i - S6;
        int g = t2 >> 10, rem = t2 & 1023;
        int q = rem >> 8, tid = rem & 255;
        int cp = tid & 63, np = tid >> 6;
        int n0 = gstart[g], n1 = gstart[g + 1];
        int len = n1 - n0;
        int ns = n0 + (len * q) / 4, ne = n0 + (len * (q + 1)) / 4;
        float s = 0.f;
        for (int n = ns + np; n < ne; n += 4) s += x[(size_t)n * 64 + cp];
        atomicAdd(&psum[g * JK + cp], s);
    } else if (i >= S5) {                // x -> bf16 (pairs)
        int j = i - S5;
        float2 v = *(const float2*)&x[(size_t)j * 2];
        xbf[j] = f2_to_bf2(v.x, v.y);
    } else if (i >= S4) {                // W2T
        int t2 = i - S4;
        int n = t2 >> 8, c = t2 & 255;
        unsigned u = __float_as_uint(W2[(size_t)c * 256 + n]);
        u = (u + 0x7fffu + ((u >> 16) & 1u)) >> 16;
        W2T[t2] = (unsigned short)u;
    } else if (i >= S3) {                // W1T
        int t2 = i - S3;
        int n = t2 >> 6, c = t2 & 63;
        unsigned u = __float_as_uint(W1[(size_t)c * 256 + n]);
        u = (u + 0x7fffu + ((u >> 16) & 1u)) >> 16;
        W1T[t2] = (unsigned short)u;
    } else if (i >= S2) {                // prep_w2
        int t2 = i - S2;
        int c = t2 >> 2, h = t2 & 3;
        float se = 0.f, sd = 0.f;
        for (int j = 0; j < 64; j++) {
            float w = W2[(size_t)c * 256 + h * 64 + j];
            se += w * a2s[h * 64 + j];
            sd += w * a2d[h * 64 + j];
        }
        wes2[c * 4 + h] = se;
        wed2[c * 4 + h] = sd;
    } else if (i >= S1) {                // prep_w1
        int t2 = i - S1;
        int c = t2 >> 2, h = t2 & 3;
        float se = 0.f, sd = 0.f;
        for (int j = 0; j < 64; j++) {
            float w = W1[(size_t)c * 256 + h * 64 + j];
            se += w * a1s[h * 64 + j];
            sd += w * a1d[h * 64 + j];
        }
        wes1[c * 4 + h] = se;
        wed1[c * 4 + h] = sd;
    } else {                             // dis
        int d = deg[i];
        dis[i] = d > 0 ? rsqrtf((float)d) : 0.f;
    }
}
// ---- hierarchical scan ----
__global__ __launch_bounds__(256) void scan_bsum(const int* __restrict__ deg,
                                                 int* __restrict__ bsum) {
    __shared__ int sd[256];
    int n = blockIdx.x * 256 + threadIdx.x;
    sd[threadIdx.x] = (n < N_NODES) ? deg[n] : 0;
    __syncthreads();
    for (int o = 128; o > 0; o >>= 1) {
        if (threadIdx.x < o) sd[threadIdx.x] += sd[threadIdx.x + o];
        __syncthreads();
    }
    if (threadIdx.x == 0) bsum[blockIdx.x] = sd[0];
}
__global__ __launch_bounds__(256) void scan_bpre(const int* __restrict__ bsum,
                                                 int* __restrict__ bpre,
                                                 int* __restrict__ off_last) {
    __shared__ int sd[256];
    int t = threadIdx.x;
    int v = (t < NSB) ? bsum[t] : 0;
    sd[t] = v;
    __syncthreads();
    for (int o = 1; o < 256; o <<= 1) {
        int u = (t >= o) ? sd[t - o] : 0;
        __syncthreads();
        sd[t] += u;
        __syncthreads();
    }
    if (t < NSB) bpre[t] = sd[t] - v;
    if (t == 255) *off_last = sd[255];
}
__global__ __launch_bounds__(256) void scan_off(const int* __restrict__ deg,
                                                const int* __restrict__ bpre,
                                                int* __restrict__ off) {
    __shared__ int sd[256];
    int n = blockIdx.x * 256 + threadIdx.x;
    int t = threadIdx.x;
    int v = (n < N_NODES) ? deg[n] : 0;
    sd[t] = v;
    __syncthreads();
    for (int o = 1; o < 256; o <<= 1) {
        int u = (t >= o) ? sd[t - o] : 0;
        __syncthreads();
        sd[t] += u;
        __syncthreads();
    }
    if (n < N_NODES) off[n] = bpre[blockIdx.x] + sd[t] - v;
}
__global__ void csr_fill(const int* __restrict__ src, const int* __restrict__ dst,
                         const int* __restrict__ off, int* __restrict__ cursor,
                         int* __restrict__ csr_src) {
    int e = blockIdx.x * blockDim.x + threadIdx.x;
    if (e >= N_EDGES) return;
    int s = src[e], d = dst[e];
    int pos = off[d] + atomicAdd(&cursor[d], 1);
    csr_src[pos] = s;
}

// ---------- es/ed from K=64 fp32 input (x) ----------
__global__ void esed_x(const float* __restrict__ X, const float* __restrict__ wes,
                       const float* __restrict__ wed, float* __restrict__ es,
                       float* __restrict__ ed) {
    int gid = blockIdx.x * blockDim.x + threadIdx.x;
    int n = gid >> 6, lane = threadIdx.x & 63;
    if (n >= N_NODES) return;
    float xv = X[(size_t)n * 64 + lane];
    float4 a = *(const float4*)&wes[lane * 4];
    float4 b = *(const float4*)&wed[lane * 4];
    float4 ps = make_float4(xv * a.x, xv * a.y, xv * a.z, xv * a.w);
    float4 pd = make_float4(xv * b.x, xv * b.y, xv * b.z, xv * b.w);
#pragma unroll
    for (int o = 1; o < 64; o <<= 1) {
        ps.x += __shfl_xor(ps.x, o); ps.y += __shfl_xor(ps.y, o);
        ps.z += __shfl_xor(ps.z, o); ps.w += __shfl_xor(ps.w, o);
        pd.x += __shfl_xor(pd.x, o); pd.y += __shfl_xor(pd.y, o);
        pd.z += __shfl_xor(pd.z, o); pd.w += __shfl_xor(pd.w, o);
    }
    if (lane == 0) {
        *(float4*)&es[n * 4] = ps;
        *(float4*)&ed[n * 4] = pd;
    }
}

// ---------- GAT1: fused softmax + bf16-x aggregation (depth-4 pipeline) ----------
__global__ __launch_bounds__(256)
void gat1_fused(const int* __restrict__ off, const int* __restrict__ csr_src,
                const float* __restrict__ es, const float* __restrict__ ed,
                const unsigned* __restrict__ xbf, unsigned* __restrict__ aggx_bf,
                float* __restrict__ alpha_fb) {
    __shared__ float elds[4][CAP * 4];
    __shared__ int   sidx[4][CAP];
    int wav = threadIdx.x >> 6, lane = threadIdx.x & 63;
    int n = blockIdx.x * 4 + wav;
    bool active = n < N_NODES;
    int p0 = 0, p1 = 0;
    float4 ed4 = make_float4(0.f, 0.f, 0.f, 0.f);
    if (active) { p0 = off[n]; p1 = off[n + 1]; ed4 = *(const float4*)&ed[n * 4]; }
    float4 sum = make_float4(0.f, 0.f, 0.f, 0.f);
    for (int p = p0 + lane; p < p1; p += 64) {
        int s = csr_src[p];
        float4 e4 = *(const float4*)&es[s * 4];
        e4.x += ed4.x; e4.y += ed4.y; e4.z += ed4.z; e4.w += ed4.w;
        e4.x = e4.x > 0.f ? e4.x : 0.2f * e4.x;
        e4.y = e4.y > 0.f ? e4.y : 0.2f * e4.y;
        e4.z = e4.z > 0.f ? e4.z : 0.2f * e4.z;
        e4.w = e4.w > 0.f ? e4.w : 0.2f * e4.w;
        e4.x = __expf(e4.x); e4.y = __expf(e4.y); e4.z = __expf(e4.z); e4.w = __expf(e4.w);
        int q = p - p0;
        if (q < CAP) { *(float4*)&elds[wav][q * 4] = e4; sidx[wav][q] = s; }
        else         *(float4*)&alpha_fb[(size_t)p * 4] = e4;
        sum.x += e4.x; sum.y += e4.y; sum.z += e4.z; sum.w += e4.w;
    }
#pragma unroll
    for (int o = 1; o < 64; o <<= 1) {
        sum.x += __shfl_xor(sum.x, o); sum.y += __shfl_xor(sum.y, o);
        sum.z += __shfl_xor(sum.z, o); sum.w += __shfl_xor(sum.w, o);
    }
    float4 rs;
    rs.x = sum.x > 0.f ? 1.f / sum.x : 0.f;
    rs.y = sum.y > 0.f ? 1.f / sum.y : 0.f;
    rs.z = sum.z > 0.f ? 1.f / sum.z : 0.f;
    rs.w = sum.w > 0.f ? 1.f / sum.w : 0.f;
    if (!active) return;
    int eg = lane >> 4, l15 = lane & 15;
    int deg = p1 - p0;
    float4 a0 = make_float4(0.f, 0.f, 0.f, 0.f);
    float4 a1 = a0, a2 = a0, a3 = a0;
    auto fetch = [&](int qq, float4& e4, float4& xv) {
        e4 = make_float4(0.f, 0.f, 0.f, 0.f);
        xv = e4;
        if (qq < deg) {
            int s;
            if (qq < CAP) { s = sidx[wav][qq]; e4 = *(const float4*)&elds[wav][qq * 4]; }
            else { s = csr_src[p0 + qq]; e4 = *(const float4*)&alpha_fb[(size_t)(p0 + qq) * 4]; }
            xv = bf4_to_f4(*(const uint2*)&xbf[(size_t)s * 32 + l15 * 2]);
        }
    };
    int q = eg;
    float4 eA, xA, eB, xB, eC, xC;
    fetch(q, eA, xA);
    fetch(q + 4, eB, xB);
    fetch(q + 8, eC, xC);
    while (q < deg) {
        float4 eD, xD;
        fetch(q + 12, eD, xD);
        a0.x += eA.x * xA.x; a0.y += eA.x * xA.y; a0.z += eA.x * xA.z; a0.w += eA.x * xA.w;
        a1.x += eA.y * xA.x; a1.y += eA.y * xA.y; a1.z += eA.y * xA.z; a1.w += eA.y * xA.w;
        a2.x += eA.z * xA.x; a2.y += eA.z * xA.y; a2.z += eA.z * xA.z; a2.w += eA.z * xA.w;
        a3.x += eA.w * xA.x; a3.y += eA.w * xA.y; a3.z += eA.w * xA.z; a3.w += eA.w * xA.w;
        eA = eB; xA = xB; eB = eC; xB = xC; eC = eD; xC = xD;
        q += 4;
    }
#pragma unroll
    for (int o = 16; o < 64; o <<= 1) {
        a0.x += __shfl_xor(a0.x, o); a0.y += __shfl_xor(a0.y, o);
        a0.z += __shfl_xor(a0.z, o); a0.w += __shfl_xor(a0.w, o);
        a1.x += __shfl_xor(a1.x, o); a1.y += __shfl_xor(a1.y, o);
        a1.z += __shfl_xor(a1.z, o); a1.w += __shfl_xor(a1.w, o);
        a2.x += __shfl_xor(a2.x, o); a2.y += __shfl_xor(a2.y, o);
        a2.z += __shfl_xor(a2.z, o); a2.w += __shfl_xor(a2.w, o);
        a3.x += __shfl_xor(a3.x, o); a3.y += __shfl_xor(a3.y, o);
        a3.z += __shfl_xor(a3.z, o); a3.w += __shfl_xor(a3.w, o);
    }
    if (eg == 0) {
        a0.x *= rs.x; a0.y *= rs.x; a0.z *= rs.x; a0.w *= rs.x;
        a1.x *= rs.y; a1.y *= rs.y; a1.z *= rs.y; a1.w *= rs.y;
        a2.x *= rs.z; a2.y *= rs.z; a2.z *= rs.z; a2.w *= rs.z;
        a3.x *= rs.w; a3.y *= rs.w; a3.z *= rs.w; a3.w *= rs.w;
        size_t b = (size_t)n * 128 + l15 * 2;
        *(uint2*)&aggx_bf[b +  0] = f4_to_bf4(a0);
        *(uint2*)&aggx_bf[b + 32] = f4_to_bf4(a1);
        *(uint2*)&aggx_bf[b + 64] = f4_to_bf4(a2);
        *(uint2*)&aggx_bf[b + 96] = f4_to_bf4(a3);
    }
}

// ---------- GAT2: fused softmax + bf16 gather (depth-4 pipeline) ----------
__global__ __launch_bounds__(256)
void gat2_fused(const int* __restrict__ off, const int* __restrict__ csr_src,
                const float* __restrict__ es, const float* __restrict__ ed,
                const unsigned* __restrict__ H2bf, const float* __restrict__ bias,
                unsigned* __restrict__ outbf, float* __restrict__ alpha_fb) {
    __shared__ float elds[4][CAP * 4];
    __shared__ int   sidx[4][CAP];
    int wav = threadIdx.x >> 6, lane = threadIdx.x & 63;
    int n = blockIdx.x * 4 + wav;
    bool active = n < N_NODES;
    int p0 = 0, p1 = 0;
    float4 ed4 = make_float4(0.f, 0.f, 0.f, 0.f);
    if (active) { p0 = off[n]; p1 = off[n + 1]; ed4 = *(const float4*)&ed[n * 4]; }
    float4 sum = make_float4(0.f, 0.f, 0.f, 0.f);
    for (int p = p0 + lane; p < p1; p += 64) {
        int s = csr_src[p];
        float4 e4 = *(const float4*)&es[s * 4];
        e4.x += ed4.x; e4.y += ed4.y; e4.z += ed4.z; e4.w += ed4.w;
        e4.x = e4.x > 0.f ? e4.x : 0.2f * e4.x;
        e4.y = e4.y > 0.f ? e4.y : 0.2f * e4.y;
        e4.z = e4.z > 0.f ? e4.z : 0.2f * e4.z;
        e4.w = e4.w > 0.f ? e4.w : 0.2f * e4.w;
        e4.x = __expf(e4.x); e4.y = __expf(e4.y); e4.z = __expf(e4.z); e4.w = __expf(e4.w);
        int q = p - p0;
        if (q < CAP) { *(float4*)&elds[wav][q * 4] = e4; sidx[wav][q] = s; }
        else         *(float4*)&alpha_fb[(size_t)p * 4] = e4;
        sum.x += e4.x; sum.y += e4.y; sum.z += e4.z; sum.w += e4.w;
    }
#pragma unroll
    for (int o = 1; o < 64; o <<= 1) {
        sum.x += __shfl_xor(sum.x, o); sum.y += __shfl_xor(sum.y, o);
        sum.z += __shfl_xor(sum.z, o); sum.w += __shfl_xor(sum.w, o);
    }
    if (!active) return;
    int half = lane >> 5, l = lane & 31;
    int hh = l >> 3;
    float sh = (hh == 0) ? sum.x : (hh == 1) ? sum.y : (hh == 2) ? sum.z : sum.w;
    float rsh = sh > 0.f ? 1.f / sh : 0.f;
    int deg = p1 - p0;
    float acc[8];
#pragma unroll
    for (int j = 0; j < 8; j++) acc[j] = 0.f;
    auto fetch = [&](int qq, float& al, uint4& rr) {
        al = 0.f;
        rr = make_uint4(0, 0, 0, 0);
        if (qq < deg) {
            int s;
            if (qq < CAP) { s = sidx[wav][qq]; al = elds[wav][qq * 4 + hh]; }
            else { s = csr_src[p0 + qq]; al = alpha_fb[(size_t)(p0 + qq) * 4 + hh]; }
            rr = *(const uint4*)&H2bf[(size_t)s * 128 + l * 4];
        }
    };
    int q = half;
    float aA, aB, aC;
    uint4 rA, rB, rC;
    fetch(q, aA, rA);
    fetch(q + 2, aB, rB);
    fetch(q + 4, aC, rC);
    while (q < deg) {
        float aD; uint4 rD;
        fetch(q + 6, aD, rD);
        float4 f0 = bf4_to_f4(make_uint2(rA.x, rA.y));
        float4 f1 = bf4_to_f4(make_uint2(rA.z, rA.w));
        acc[0] += aA * f0.x; acc[1] += aA * f0.y; acc[2] += aA * f0.z; acc[3] += aA * f0.w;
        acc[4] += aA * f1.x; acc[5] += aA * f1.y; acc[6] += aA * f1.z; acc[7] += aA * f1.w;
        aA = aB; rA = rB; aB = aC; rB = rC; aC = aD; rC = rD;
        q += 2;
    }
#pragma unroll
    for (int j = 0; j < 8; j++) acc[j] += __shfl_xor(acc[j], 32);
    if (half == 0) {
        float4 b0 = *(const float4*)&bias[l * 8];
        float4 b1 = *(const float4*)&bias[l * 8 + 4];
        float4 o0, o1;
        o0.x = fmaxf(acc[0] * rsh + b0.x, 0.f);
        o0.y = fmaxf(acc[1] * rsh + b0.y, 0.f);
        o0.z = fmaxf(acc[2] * rsh + b0.z, 0.f);
        o0.w = fmaxf(acc[3] * rsh + b0.w, 0.f);
        o1.x = fmaxf(acc[4] * rsh + b1.x, 0.f);
        o1.y = fmaxf(acc[5] * rsh + b1.y, 0.f);
        o1.z = fmaxf(acc[6] * rsh + b1.z, 0.f);
        o1.w = fmaxf(acc[7] * rsh + b1.w, 0.f);
        uint2 w0 = f4_to_bf4(o0), w1 = f4_to_bf4(o1);
        uint4 w = make_uint4(w0.x, w0.y, w1.x, w1.y);
        *(uint4*)&outbf[(size_t)n * 128 + l * 4] = w;
    }
}

// ---------- label prop: LDS staging, depth-4 pipeline; optional fused esed ----------
template<int FUSE_ESED>
__global__ __launch_bounds__(256)
void lp_csr_t(const int* __restrict__ off, const int* __restrict__ csr_src,
              const float* __restrict__ dis, const unsigned* __restrict__ in_bf,
              const unsigned* __restrict__ res_bf, unsigned* __restrict__ out_bf,
              const float* __restrict__ wes, const float* __restrict__ wed,
              float* __restrict__ es, float* __restrict__ ed) {
    __shared__ int   widx[4][CAP];
    __shared__ float wwt[4][CAP];
    int wav = threadIdx.x >> 6, lane = threadIdx.x & 63;
    int n = blockIdx.x * 4 + wav;
    if (n >= N_NODES) return;
    int p0 = off[n], p1 = off[n + 1];
    int deg = p1 - p0;
    float disd = dis[n];
    for (int q = lane; q < deg && q < CAP; q += 64) {
        int s = csr_src[p0 + q];
        widx[wav][q] = s;
        wwt[wav][q] = dis[s] * disd;
    }
    int half = lane >> 5, l = lane & 31;
    float acc[8];
#pragma unroll
    for (int j = 0; j < 8; j++) acc[j] = 0.f;
    auto fetch = [&](int qq, float& nw, uint4& rr) {
        nw = 0.f;
        rr = make_uint4(0, 0, 0, 0);
        if (qq < deg) {
            int s;
            if (qq < CAP) { s = widx[wav][qq]; nw = wwt[wav][qq]; }
            else { s = csr_src[p0 + qq]; nw = dis[s] * disd; }
            rr = *(const uint4*)&in_bf[(size_t)s * 128 + l * 4];
        }
    };
    int q = half;
    float nA, nB, nC;
    uint4 rA, rB, rC;
    fetch(q, nA, rA);
    fetch(q + 2, nB, rB);
    fetch(q + 4, nC, rC);
    while (q < deg) {
        float nD; uint4 rD;
        fetch(q + 6, nD, rD);
        float4 f0 = bf4_to_f4(make_uint2(rA.x, rA.y));
        float4 f1 = bf4_to_f4(make_uint2(rA.z, rA.w));
        acc[0] += nA * f0.x; acc[1] += nA * f0.y; acc[2] += nA * f0.z; acc[3] += nA * f0.w;
        acc[4] += nA * f1.x; acc[5] += nA * f1.y; acc[6] += nA * f1.z; acc[7] += nA * f1.w;
        nA = nB; rA = rB; nB = nC; rB = rC; nC = nD; rC = rD;
        q += 2;
    }
#pragma unroll
    for (int j = 0; j < 8; j++) acc[j] += __shfl_xor(acc[j], 32);
    if (half == 0) {
        uint4 rr = *(const uint4*)&res_bf[(size_t)n * 128 + l * 4];
        float4 r0 = bf4_to_f4(make_uint2(rr.x, rr.y));
        float4 r1 = bf4_to_f4(make_uint2(rr.z, rr.w));
        float4 o0, o1;
        o0.x = fminf(fmaxf(0.5f * acc[0] + 0.5f * r0.x, 0.f), 1.f);
        o0.y = fminf(fmaxf(0.5f * acc[1] + 0.5f * r0.y, 0.f), 1.f);
        o0.z = fminf(fmaxf(0.5f * acc[2] + 0.5f * r0.z, 0.f), 1.f);
        o0.w = fminf(fmaxf(0.5f * acc[3] + 0.5f * r0.w, 0.f), 1.f);
        o1.x = fminf(fmaxf(0.5f * acc[4] + 0.5f * r1.x, 0.f), 1.f);
        o1.y = fminf(fmaxf(0.5f * acc[5] + 0.5f * r1.y, 0.f), 1.f);
        o1.z = fminf(fmaxf(0.5f * acc[6] + 0.5f * r1.z, 0.f), 1.f);
        o1.w = fminf(fmaxf(0.5f * acc[7] + 0.5f * r1.w, 0.f), 1.f);
        uint2 w0 = f4_to_bf4(o0), w1 = f4_to_bf4(o1);
        uint4 w = make_uint4(w0.x, w0.y, w1.x, w1.y);
        *(uint4*)&out_bf[(size_t)n * 128 + l * 4] = w;
        if (FUSE_ESED) {
            // es/ed for next GAT layer from this row (lanes 0..31, 8 feats each)
            float vv[8] = {o0.x, o0.y, o0.z, o0.w, o1.x, o1.y, o1.z, o1.w};
            float4 ps = make_float4(0.f, 0.f, 0.f, 0.f);
            float4 pd = make_float4(0.f, 0.f, 0.f, 0.f);
#pragma unroll
            for (int j = 0; j < 8; j++) {
                int c = l * 8 + j;
                float4 a = *(const float4*)&wes[c * 4];
                float4 b = *(const float4*)&wed[c * 4];
                ps.x += vv[j] * a.x; ps.y += vv[j] * a.y; ps.z += vv[j] * a.z; ps.w += vv[j] * a.w;
                pd.x += vv[j] * b.x; pd.y += vv[j] * b.y; pd.z += vv[j] * b.z; pd.w += vv[j] * b.w;
            }
#pragma unroll
            for (int o = 1; o < 32; o <<= 1) {
                ps.x += __shfl_xor(ps.x, o); ps.y += __shfl_xor(ps.y, o);
                ps.z += __shfl_xor(ps.z, o); ps.w += __shfl_xor(ps.w, o);
                pd.x += __shfl_xor(pd.x, o); pd.y += __shfl_xor(pd.y, o);
                pd.z += __shfl_xor(pd.z, o); pd.w += __shfl_xor(pd.w, o);
            }
            if (l == 0) {
                *(float4*)&es[n * 4] = ps;
                *(float4*)&ed[n * 4] = pd;
            }
        }
    }
}

// ---------- bf16 pool ----------
__global__ void pool_bf(const unsigned* __restrict__ buf, const int* __restrict__ gstart,
                        float* __restrict__ psum, int colOff) {
    int g = blockIdx.x, q = blockIdx.y;
    int n0 = gstart[g], n1 = gstart[g + 1];
    int len = n1 - n0;
    int ns = n0 + (len * q) / 4, ne = n0 + (len * (q + 1)) / 4;
    int cp = threadIdx.x & 127;
    int np = threadIdx.x >> 7;
    float s0 = 0.f, s1 = 0.f;
    for (int n = ns + np; n < ne; n += 2) {
        unsigned u = buf[(size_t)n * 128 + cp];
        s0 += __uint_as_float(u << 16);
        s1 += __uint_as_float(u & 0xffff0000u);
    }
    atomicAdd(&psum[g * JK + colOff + cp * 2 + 0], s0);
    atomicAdd(&psum[g * JK + colOff + cp * 2 + 1], s1);
}

// ---------- full MLP head: one block per graph ----------
__global__ __launch_bounds__(256)
void head_all(const float* __restrict__ psum, const int* __restrict__ gstart,
              const float* __restrict__ clin,
              const float* __restrict__ pp_w1, const float* __restrict__ pp_b1,
              const float* __restrict__ pp_w2, const float* __restrict__ pp_b2,
              const float* __restrict__ cl_w1, const float* __restrict__ cl_b1,
              const float* __restrict__ cl_w2, const float* __restrict__ cl_b2,
              const float* __restrict__ h_w1, const float* __restrict__ h_b1,
              const float* __restrict__ h_w2, const float* __restrict__ h_b2,
              const float* __restrict__ h_w3, const float* __restrict__ h_b3,
              float* __restrict__ out) {
    __shared__ float zin[JK];
    __shared__ float z1[256];
    __shared__ float zcl[32];
    __shared__ float zc[64];
    __shared__ float z[160];
    __shared__ float z3[64];
    __shared__ float z4[32];
    __shared__ float part[128];
    int g = blockIdx.x, t = threadIdx.x;
    int len = gstart[g + 1] - gstart[g];
    float inv = 1.f / (float)(len > 1 ? len : 1);
    for (int k = t; k < JK; k += 256) zin[k] = psum[g * JK + k] * inv;
    if (t < 32) zcl[t] = clin[g * 32 + t];
    __syncthreads();
    // d1: 256 outputs, K=576, relu
    {
        float acc = pp_b1[t];
#pragma unroll 8
        for (int k = 0; k < JK; k++) acc += zin[k] * pp_w1[k * 256 + t];
        z1[t] = fmaxf(acc, 0.f);
    }
    __syncthreads();
    int m = t & 127, half = t >> 7;
    {
        float acc = 0.f;
        int k0 = half * 128;
#pragma unroll 8
        for (int k = k0; k < k0 + 128; k++) acc += z1[k] * pp_w2[k * 128 + m];
        if (half) part[m] = acc;
        __syncthreads();
        if (!half) z[m] = acc + part[m] + pp_b2[m];
    }
    if (t < 64) {
        float acc = cl_b1[t];
#pragma unroll
        for (int k = 0; k < 32; k++) acc += zcl[k] * cl_w1[k * 64 + t];
        zc[t] = fmaxf(acc, 0.f);
    }
    __syncthreads();
    if (t < 32) {
        float acc = cl_b2[t];
#pragma unroll
        for (int k = 0; k < 64; k++) acc += zc[k] * cl_w2[k * 32 + t];
        z[128 + t] = acc;
    }
    __syncthreads();
    if (t < 64) {
        float acc = h_b1[t];
#pragma unroll 8
        for (int k = 0; k < 160; k++) acc += z[k] * h_w1[k * 64 + t];
        z3[t] = fmaxf(acc, 0.f);
    }
    __syncthreads();
    if (t < 32) {
        float acc = h_b2[t];
#pragma unroll
        for (int k = 0; k < 64; k++) acc += z3[k] * h_w2[k * 32 + t];
        z4[t] = fmaxf(acc, 0.f);
    }
    __syncthreads();
    if (t < 2) {
        float acc = h_b3[t];
#pragma unroll
        for (int k = 0; k < 32; k++) acc += z4[k] * h_w3[k * 2 + t];
        out[g * 2 + t] = acc;
    }
}

// ---------- launch ----------
extern "C" void kernel_launch(void* const* d_in, const int* in_sizes, int n_in,
                              void* d_out, int out_size, void* d_ws, size_t ws_size,
                              hipStream_t stream) {
    const float* x     = (const float*)d_in[0];
    const int*   ei    = (const int*)d_in[1];
    const int*   batch = (const int*)d_in[2];
    const float* clin  = (const float*)d_in[3];
    const float* W1  = (const float*)d_in[4];
    const float* a1s = (const float*)d_in[5];
    const float* a1d = (const float*)d_in[6];
    const float* b1  = (const float*)d_in[7];
    const float* W2  = (const float*)d_in[8];
    const float* a2s = (const float*)d_in[9];
    const float* a2d = (const float*)d_in[10];
    const float* b2  = (const float*)d_in[11];
    const float* pp_w1 = (const float*)d_in[12];
    const float* pp_b1 = (const float*)d_in[13];
    const float* pp_w2 = (const float*)d_in[14];
    const float* pp_b2 = (const float*)d_in[15];
    const float* cl_w1 = (const float*)d_in[16];
    const float* cl_b1 = (const float*)d_in[17];
    const float* cl_w2 = (const float*)d_in[18];
    const float* cl_b2 = (const float*)d_in[19];
    const float* h_w1  = (const float*)d_in[20];
    const float* h_b1  = (const float*)d_in[21];
    const float* h_w2  = (const float*)d_in[22];
    const float* h_b2  = (const float*)d_in[23];
    const float* h_w3  = (const float*)d_in[24];
    const float* h_b3  = (const float*)d_in[25];

    const int* src = ei;
    const int* dst = ei + N_EDGES;

    char* p = (char*)d_ws;
    auto carve = [&](size_t bytes) -> char* {
        char* r = p;
        p += (bytes + 255) & ~(size_t)255;
        return r;
    };
    const size_t NBH = (size_t)N_NODES * 256 * 2;    // bf16 node buffer
    unsigned* abf  = (unsigned*)carve(NBH);          // aggx, later h2_final
    unsigned* bf1  = (unsigned*)carve(NBH);
    unsigned* bf2  = (unsigned*)carve(NBH);
    unsigned* bf3  = (unsigned*)carve(NBH);
    unsigned* xbf  = (unsigned*)carve((size_t)N_NODES * 32 * 4);  // bf16 x copy
    float* alpha_fb  = (float*)carve((size_t)N_EDGES * 4 * 4);
    int*   csr_src   = (int*)carve((size_t)N_EDGES * 4);
    int*   off       = (int*)carve((size_t)(N_NODES + 1) * 4);
    int*   deg       = (int*)carve((size_t)N_NODES * 4);
    int*   cursor    = (int*)carve((size_t)N_NODES * 4);
    int*   bsum      = (int*)carve((size_t)NSB * 4);
    int*   bpre      = (int*)carve((size_t)NSB * 4);
    float* dis       = (float*)carve((size_t)N_NODES * 4);
    float* es        = (float*)carve((size_t)N_NODES * 4 * 4);
    float* ed        = (float*)carve((size_t)N_NODES * 4 * 4);
    float* wes1      = (float*)carve((size_t)64 * 4 * 4);
    float* wed1      = (float*)carve((size_t)64 * 4 * 4);
    float* wes2      = (float*)carve((size_t)256 * 4 * 4);
    float* wed2      = (float*)carve((size_t)256 * 4 * 4);
    unsigned short* W1T = (unsigned short*)carve((size_t)256 * 64 * 2);
    unsigned short* W2T = (unsigned short*)carve((size_t)256 * 256 * 2);
    int*   gstart    = (int*)carve((size_t)(N_GRAPHS + 1) * 4);
    float* psum      = (float*)carve((size_t)N_GRAPHS * JK * 4);

    const int TB = 256;
    const int gE     = (N_EDGES + TB - 1) / TB;
    const int gDeg   = (N_EDGES + N_NODES + TB - 1) / TB;
    const int gNwave = (N_NODES * 64 + TB - 1) / TB;
    const int gFuse  = (N_NODES + 3) / 4;
    const int gRow   = (N_NODES + 63) / 64;
    const int gPrep  = (S7 + TB - 1) / TB;

    // ---- CSR + degree + bounds + fused misc prep (incl. x pooling) ----
    hipMemsetAsync(deg, 0, (size_t)N_NODES * 4, stream);
    hipMemsetAsync(cursor, 0, (size_t)N_NODES * 4, stream);
    hipMemsetAsync(psum, 0, (size_t)N_GRAPHS * JK * 4, stream);
    deg_kernel<<<gDeg, TB, 0, stream>>>(dst, deg, batch, gstart);
    prep_misc<<<gPrep, TB, 0, stream>>>(deg, dis,
                                        W1, a1s, a1d, wes1, wed1,
                                        W2, a2s, a2d, wes2, wed2,
                                        W1T, W2T, x, xbf, gstart, psum);
    scan_bsum<<<NSB, 256, 0, stream>>>(deg, bsum);
    scan_bpre<<<1, 256, 0, stream>>>(bsum, bpre, &off[N_NODES]);
    scan_off<<<NSB, 256, 0, stream>>>(deg, bpre, off);
    csr_fill<<<gE, TB, 0, stream>>>(src, dst, off, cursor, csr_src);

    // ---- GAT layer 1 ----
    esed_x<<<gNwave, TB, 0, stream>>>(x, wes1, wed1, es, ed);
    gat1_fused<<<gFuse, TB, 0, stream>>>(off, csr_src, es, ed, xbf, abf, alpha_fb);
    mfma_gemm<64, 64><<<dim3(gRow, 4), 256, 0, stream>>>(
        (const unsigned short*)abf, 256, W1T, bf1, 256, N_NODES, b1, 1,
        64, 64 * 64, 64);                                   // bf1 = h1a

    // ---- label prop 1 (residual = bf1); 2nd step fuses esed for layer 2 ----
    lp_csr_t<0><<<gFuse, TB, 0, stream>>>(off, csr_src, dis, bf1, bf1, bf2,
                                          nullptr, nullptr, nullptr, nullptr);
    lp_csr_t<1><<<gFuse, TB, 0, stream>>>(off, csr_src, dis, bf2, bf1, bf3,
                                          wes2, wed2, es, ed);   // bf3 = h1, es/ed ready

    pool_bf<<<dim3(N_GRAPHS, 4), TB, 0, stream>>>(bf3, gstart, psum, 64);

    // ---- GAT layer 2 ----
    mfma_gemm<256, 256><<<dim3(gRow, 1), 256, 0, stream>>>(
        (const unsigned short*)bf3, 256, W2T, bf1, 256, N_NODES, nullptr, 0,
        0, 0, 0);                                           // bf1 = h2
    gat2_fused<<<gFuse, TB, 0, stream>>>(off, csr_src, es, ed, bf1, b2, bf2, alpha_fb); // bf2 = h2a

    // ---- label prop 2 (residual = bf2) ----
    lp_csr_t<0><<<gFuse, TB, 0, stream>>>(off, csr_src, dis, bf2, bf2, bf1,
                                          nullptr, nullptr, nullptr, nullptr);
    lp_csr_t<0><<<gFuse, TB, 0, stream>>>(off, csr_src, dis, bf1, bf2, abf,
                                          nullptr, nullptr, nullptr, nullptr);  // abf = h2_final

    // ---- pooling (h2) + full head ----
    pool_bf<<<dim3(N_GRAPHS, 4), TB, 0, stream>>>(abf, gstart, psum, 320);
    head_all<<<N_GRAPHS, 256, 0, stream>>>(psum, gstart, clin,
                                           pp_w1, pp_b1, pp_w2, pp_b2,
                                           cl_w1, cl_b1, cl_w2, cl_b2,
                                           h_w1, h_b1, h_w2, h_b2, h_w3, h_b3,
                                           (float*)d_out);
}

// Round 13
// 763.541 us; speedup vs baseline: 22.8681x; 1.0080x over previous
//
#include <hip/hip_runtime.h>

#define N_NODES 50000
#define N_EDGES 800000
#define N_GRAPHS 128
#define JK 576              // 64 + 256 + 256
#define CAP 192             // reverted 96->192: single-variable A/B on lp regression
#define NSB ((N_NODES + 255) / 256)   // scan blocks = 196

typedef __attribute__((ext_vector_type(8))) short bf16x8;
typedef __attribute__((ext_vector_type(4))) float f32x4;

// ---------- bf16 pack/unpack helpers ----------
__device__ __forceinline__ unsigned f2_to_bf2(float a, float b) {
    unsigned ua = __float_as_uint(a), ub = __float_as_uint(b);
    ua = (ua + 0x7fffu + ((ua >> 16) & 1u)) >> 16;       // RNE
    ub = (ub + 0x7fffu + ((ub >> 16) & 1u)) >> 16;
    return ua | (ub << 16);
}
__device__ __forceinline__ uint2 f4_to_bf4(float4 v) {
    return make_uint2(f2_to_bf2(v.x, v.y), f2_to_bf2(v.z, v.w));
}
__device__ __forceinline__ float4 bf4_to_f4(uint2 u) {
    float4 r;
    r.x = __uint_as_float(u.x << 16);
    r.y = __uint_as_float(u.x & 0xffff0000u);
    r.z = __uint_as_float(u.y << 16);
    r.w = __uint_as_float(u.y & 0xffff0000u);
    return r;
}

// ---------- MFMA GEMM: bf16 out = A_bf16 @ B (BT n-major bf16), fp32 acc ----------
template<int BN, int KK>
__global__ __launch_bounds__(256)
void mfma_gemm(const unsigned short* __restrict__ Abf, int lda,
               const unsigned short* __restrict__ BT,
               unsigned* __restrict__ Cbf, int ldc,
               int M, const float* __restrict__ bias, int relu,
               int a_off, int b_off, int c_off) {
    __shared__ unsigned short As[64][32];
    __shared__ unsigned short Bs[BN][32];
    const int t = threadIdx.x;
    const int wav = t >> 6, lane = t & 63;
    const int quad = lane >> 4, l15 = lane & 15;
    const int m0 = blockIdx.x * 64;
    const int head = blockIdx.y;
    Abf += (size_t)head * a_off;
    BT  += (size_t)head * b_off;
    const float* bptr = bias ? bias + (size_t)head * c_off : nullptr;
    unsigned* cbf = Cbf + (((size_t)head * c_off) >> 1);

    f32x4 acc[BN / 16];
#pragma unroll
    for (int i = 0; i < BN / 16; i++) acc[i] = (f32x4){0.f, 0.f, 0.f, 0.f};

    const int arow = t >> 2, aseg = t & 3;
    for (int k0 = 0; k0 < KK; k0 += 32) {
        uint4 av = make_uint4(0, 0, 0, 0);
        int gm = m0 + arow;
        if (gm < M) av = *(const uint4*)&Abf[(size_t)gm * lda + k0 + aseg * 8];
        uint4 bv[BN == 256 ? 4 : 1];
        if (BN == 256) {
            const unsigned short* srcb = &BT[(size_t)t * KK + k0];
#pragma unroll
            for (int j = 0; j < 4; j++) bv[j] = *(const uint4*)&srcb[j * 8];
        } else {
            bv[0] = *(const uint4*)&BT[(size_t)arow * KK + k0 + aseg * 8];
        }
        __syncthreads();
        *(uint4*)&As[arow][aseg * 8] = av;
        if (BN == 256) {
#pragma unroll
            for (int j = 0; j < 4; j++) *(uint4*)&Bs[t][j * 8] = bv[j];
        } else {
            *(uint4*)&Bs[arow][aseg * 8] = bv[0];
        }
        __syncthreads();
        bf16x8 afrag = *(const bf16x8*)&As[wav * 16 + l15][quad * 8];
#pragma unroll
        for (int nt = 0; nt < BN / 16; nt++) {
            bf16x8 bfrag = *(const bf16x8*)&Bs[nt * 16 + l15][quad * 8];
            acc[nt] = __builtin_amdgcn_mfma_f32_16x16x32_bf16(afrag, bfrag, acc[nt], 0, 0, 0);
        }
    }
    int rbase = m0 + wav * 16 + quad * 4;
#pragma unroll
    for (int nt = 0; nt < BN / 16; nt++) {
        int col = nt * 16 + l15;
        float bb = bptr ? bptr[col] : 0.f;
#pragma unroll
        for (int r = 0; r < 4; r++) {
            int row = rbase + r;
            float v = acc[nt][r] + bb;
            if (relu) v = fmaxf(v, 0.f);
            float vp = __shfl_xor(v, 1);
            if (row < M && !(l15 & 1))
                cbf[((size_t)row * ldc + col) >> 1] = f2_to_bf2(v, vp);
        }
    }
}

// ---------- degree + graph bounds (fused) ----------
__global__ void deg_kernel(const int* __restrict__ dst, int* __restrict__ deg,
                           const int* __restrict__ batch, int* __restrict__ gstart) {
    int t = blockIdx.x * blockDim.x + threadIdx.x;
    if (t < N_EDGES) {
        atomicAdd(&deg[dst[t]], 1);
    } else if (t < N_EDGES + N_NODES) {
        int n = t - N_EDGES;
        int b = batch[n];
        int prev = (n == 0) ? -1 : batch[n - 1];
        for (int g = prev + 1; g <= b; g++) gstart[g] = n;
        if (n == N_NODES - 1)
            for (int g = b + 1; g <= N_GRAPHS; g++) gstart[g] = N_NODES;
    }
}

// ---- fused misc prep: dis | prep_w1 | prep_w2 | W1T | W2T | xbf | pool(x) ----
#define S1 50000
#define S2 50256
#define S3 51280
#define S4 67664
#define S5 133200
#define S6 1733200            // S5 + 50000*32  (xbf pairs)
#define S7 (S6 + 131072)      // + 128 graphs * 4 quarters * 256 threads (x pooling)
__global__ void prep_misc(const int* __restrict__ deg, float* __restrict__ dis,
                          const float* __restrict__ W1, const float* __restrict__ a1s,
                          const float* __restrict__ a1d, float* __restrict__ wes1,
                          float* __restrict__ wed1,
                          const float* __restrict__ W2, const float* __restrict__ a2s,
                          const float* __restrict__ a2d, float* __restrict__ wes2,
                          float* __restrict__ wed2,
                          unsigned short* __restrict__ W1T, unsigned short* __restrict__ W2T,
                          const float* __restrict__ x, unsigned* __restrict__ xbf,
                          const int* __restrict__ gstart, float* __restrict__ psum) {
    int i = blockIdx.x * blockDim.x + threadIdx.x;
    if (i >= S7) return;
    if (i >= S6) {                       // pool x -> psum[:, 0:64]
        int t2 = i - S6;
        int g = t2 >> 10, rem = t2 & 1023;
        int q = rem >> 8, tid = rem & 255;
        int cp = tid & 63, np = tid >> 6;
        int n0 = gstart[g], n1 = gstart[g + 1];
        int len = n1 - n0;
        int ns = n0 + (len * q) / 4, ne = n0 + (len * (q + 1)) / 4;
        float s = 0.f;
        for (int n = ns + np; n < ne; n += 4) s += x[(size_t)n * 64 + cp];
        atomicAdd(&psum[g * JK + cp], s);
    } else if (i >= S5) {                // x -> bf16 (pairs)
        int j = i - S5;
        float2 v = *(const float2*)&x[(size_t)j * 2];
        xbf[j] = f2_to_bf2(v.x, v.y);
    } else if (i >= S4) {                // W2T
        int t2 = i - S4;
        int n = t2 >> 8, c = t2 & 255;
        unsigned u = __float_as_uint(W2[(size_t)c * 256 + n]);
        u = (u + 0x7fffu + ((u >> 16) & 1u)) >> 16;
        W2T[t2] = (unsigned short)u;
    } else if (i >= S3) {                // W1T
        int t2 = i - S3;
        int n = t2 >> 6, c = t2 & 63;
        unsigned u = __float_as_uint(W1[(size_t)c * 256 + n]);
        u = (u + 0x7fffu + ((u >> 16) & 1u)) >> 16;
        W1T[t2] = (unsigned short)u;
    } else if (i >= S2) {                // prep_w2
        int t2 = i - S2;
        int c = t2 >> 2, h = t2 & 3;
        float se = 0.f, sd = 0.f;
        for (int j = 0; j < 64; j++) {
            float w = W2[(size_t)c * 256 + h * 64 + j];
            se += w * a2s[h * 64 + j];
            sd += w * a2d[h * 64 + j];
        }
        wes2[c * 4 + h] = se;
        wed2[c * 4 + h] = sd;
    } else if (i >= S1) {                // prep_w1
        int t2 = i - S1;
        int c = t2 >> 2, h = t2 & 3;
        float se = 0.f, sd = 0.f;
        for (int j = 0; j < 64; j++) {
            float w = W1[(size_t)c * 256 + h * 64 + j];
            se += w * a1s[h * 64 + j];
            sd += w * a1d[h * 64 + j];
        }
        wes1[c * 4 + h] = se;
        wed1[c * 4 + h] = sd;
    } else {                             // dis
        int d = deg[i];
        dis[i] = d > 0 ? rsqrtf((float)d) : 0.f;
    }
}
// ---- hierarchical scan ----
__global__ __launch_bounds__(256) void scan_bsum(const int* __restrict__ deg,
                                                 int* __restrict__ bsum) {
    __shared__ int sd[256];
    int n = blockIdx.x * 256 + threadIdx.x;
    sd[threadIdx.x] = (n < N_NODES) ? deg[n] : 0;
    __syncthreads();
    for (int o = 128; o > 0; o >>= 1) {
        if (threadIdx.x < o) sd[threadIdx.x] += sd[threadIdx.x + o];
        __syncthreads();
    }
    if (threadIdx.x == 0) bsum[blockIdx.x] = sd[0];
}
__global__ __launch_bounds__(256) void scan_bpre(const int* __restrict__ bsum,
                                                 int* __restrict__ bpre,
                                                 int* __restrict__ off_last) {
    __shared__ int sd[256];
    int t = threadIdx.x;
    int v = (t < NSB) ? bsum[t] : 0;
    sd[t] = v;
    __syncthreads();
    for (int o = 1; o < 256; o <<= 1) {
        int u = (t >= o) ? sd[t - o] : 0;
        __syncthreads();
        sd[t] += u;
        __syncthreads();
    }
    if (t < NSB) bpre[t] = sd[t] - v;
    if (t == 255) *off_last = sd[255];
}
__global__ __launch_bounds__(256) void scan_off(const int* __restrict__ deg,
                                                const int* __restrict__ bpre,
                                                int* __restrict__ off) {
    __shared__ int sd[256];
    int n = blockIdx.x * 256 + threadIdx.x;
    int t = threadIdx.x;
    int v = (n < N_NODES) ? deg[n] : 0;
    sd[t] = v;
    __syncthreads();
    for (int o = 1; o < 256; o <<= 1) {
        int u = (t >= o) ? sd[t - o] : 0;
        __syncthreads();
        sd[t] += u;
        __syncthreads();
    }
    if (n < N_NODES) off[n] = bpre[blockIdx.x] + sd[t] - v;
}
__global__ void csr_fill(const int* __restrict__ src, const int* __restrict__ dst,
                         const int* __restrict__ off, int* __restrict__ cursor,
                         int* __restrict__ csr_src) {
    int e = blockIdx.x * blockDim.x + threadIdx.x;
    if (e >= N_EDGES) return;
    int s = src[e], d = dst[e];
    int pos = off[d] + atomicAdd(&cursor[d], 1);
    csr_src[pos] = s;
}

// ---------- es/ed from K=64 fp32 input (x) ----------
__global__ void esed_x(const float* __restrict__ X, const float* __restrict__ wes,
                       const float* __restrict__ wed, float* __restrict__ es,
                       float* __restrict__ ed) {
    int gid = blockIdx.x * blockDim.x + threadIdx.x;
    int n = gid >> 6, lane = threadIdx.x & 63;
    if (n >= N_NODES) return;
    float xv = X[(size_t)n * 64 + lane];
    float4 a = *(const float4*)&wes[lane * 4];
    float4 b = *(const float4*)&wed[lane * 4];
    float4 ps = make_float4(xv * a.x, xv * a.y, xv * a.z, xv * a.w);
    float4 pd = make_float4(xv * b.x, xv * b.y, xv * b.z, xv * b.w);
#pragma unroll
    for (int o = 1; o < 64; o <<= 1) {
        ps.x += __shfl_xor(ps.x, o); ps.y += __shfl_xor(ps.y, o);
        ps.z += __shfl_xor(ps.z, o); ps.w += __shfl_xor(ps.w, o);
        pd.x += __shfl_xor(pd.x, o); pd.y += __shfl_xor(pd.y, o);
        pd.z += __shfl_xor(pd.z, o); pd.w += __shfl_xor(pd.w, o);
    }
    if (lane == 0) {
        *(float4*)&es[n * 4] = ps;
        *(float4*)&ed[n * 4] = pd;
    }
}

// ---------- GAT1: fused softmax + bf16-x aggregation (depth-4 pipeline) ----------
__global__ __launch_bounds__(256)
void gat1_fused(const int* __restrict__ off, const int* __restrict__ csr_src,
                const float* __restrict__ es, const float* __restrict__ ed,
                const unsigned* __restrict__ xbf, unsigned* __restrict__ aggx_bf,
                float* __restrict__ alpha_fb) {
    __shared__ float elds[4][CAP * 4];
    __shared__ int   sidx[4][CAP];
    int wav = threadIdx.x >> 6, lane = threadIdx.x & 63;
    int n = blockIdx.x * 4 + wav;
    bool active = n < N_NODES;
    int p0 = 0, p1 = 0;
    float4 ed4 = make_float4(0.f, 0.f, 0.f, 0.f);
    if (active) { p0 = off[n]; p1 = off[n + 1]; ed4 = *(const float4*)&ed[n * 4]; }
    float4 sum = make_float4(0.f, 0.f, 0.f, 0.f);
    for (int p = p0 + lane; p < p1; p += 64) {
        int s = csr_src[p];
        float4 e4 = *(const float4*)&es[s * 4];
        e4.x += ed4.x; e4.y += ed4.y; e4.z += ed4.z; e4.w += ed4.w;
        e4.x = e4.x > 0.f ? e4.x : 0.2f * e4.x;
        e4.y = e4.y > 0.f ? e4.y : 0.2f * e4.y;
        e4.z = e4.z > 0.f ? e4.z : 0.2f * e4.z;
        e4.w = e4.w > 0.f ? e4.w : 0.2f * e4.w;
        e4.x = __expf(e4.x); e4.y = __expf(e4.y); e4.z = __expf(e4.z); e4.w = __expf(e4.w);
        int q = p - p0;
        if (q < CAP) { *(float4*)&elds[wav][q * 4] = e4; sidx[wav][q] = s; }
        else         *(float4*)&alpha_fb[(size_t)p * 4] = e4;
        sum.x += e4.x; sum.y += e4.y; sum.z += e4.z; sum.w += e4.w;
    }
#pragma unroll
    for (int o = 1; o < 64; o <<= 1) {
        sum.x += __shfl_xor(sum.x, o); sum.y += __shfl_xor(sum.y, o);
        sum.z += __shfl_xor(sum.z, o); sum.w += __shfl_xor(sum.w, o);
    }
    float4 rs;
    rs.x = sum.x > 0.f ? 1.f / sum.x : 0.f;
    rs.y = sum.y > 0.f ? 1.f / sum.y : 0.f;
    rs.z = sum.z > 0.f ? 1.f / sum.z : 0.f;
    rs.w = sum.w > 0.f ? 1.f / sum.w : 0.f;
    if (!active) return;
    int eg = lane >> 4, l15 = lane & 15;
    int deg = p1 - p0;
    float4 a0 = make_float4(0.f, 0.f, 0.f, 0.f);
    float4 a1 = a0, a2 = a0, a3 = a0;
    auto fetch = [&](int qq, float4& e4, float4& xv) {
        e4 = make_float4(0.f, 0.f, 0.f, 0.f);
        xv = e4;
        if (qq < deg) {
            int s;
            if (qq < CAP) { s = sidx[wav][qq]; e4 = *(const float4*)&elds[wav][qq * 4]; }
            else { s = csr_src[p0 + qq]; e4 = *(const float4*)&alpha_fb[(size_t)(p0 + qq) * 4]; }
            xv = bf4_to_f4(*(const uint2*)&xbf[(size_t)s * 32 + l15 * 2]);
        }
    };
    int q = eg;
    float4 eA, xA, eB, xB, eC, xC;
    fetch(q, eA, xA);
    fetch(q + 4, eB, xB);
    fetch(q + 8, eC, xC);
    while (q < deg) {
        float4 eD, xD;
        fetch(q + 12, eD, xD);
        a0.x += eA.x * xA.x; a0.y += eA.x * xA.y; a0.z += eA.x * xA.z; a0.w += eA.x * xA.w;
        a1.x += eA.y * xA.x; a1.y += eA.y * xA.y; a1.z += eA.y * xA.z; a1.w += eA.y * xA.w;
        a2.x += eA.z * xA.x; a2.y += eA.z * xA.y; a2.z += eA.z * xA.z; a2.w += eA.z * xA.w;
        a3.x += eA.w * xA.x; a3.y += eA.w * xA.y; a3.z += eA.w * xA.z; a3.w += eA.w * xA.w;
        eA = eB; xA = xB; eB = eC; xB = xC; eC = eD; xC = xD;
        q += 4;
    }
#pragma unroll
    for (int o = 16; o < 64; o <<= 1) {
        a0.x += __shfl_xor(a0.x, o); a0.y += __shfl_xor(a0.y, o);
        a0.z += __shfl_xor(a0.z, o); a0.w += __shfl_xor(a0.w, o);
        a1.x += __shfl_xor(a1.x, o); a1.y += __shfl_xor(a1.y, o);
        a1.z += __shfl_xor(a1.z, o); a1.w += __shfl_xor(a1.w, o);
        a2.x += __shfl_xor(a2.x, o); a2.y += __shfl_xor(a2.y, o);
        a2.z += __shfl_xor(a2.z, o); a2.w += __shfl_xor(a2.w, o);
        a3.x += __shfl_xor(a3.x, o); a3.y += __shfl_xor(a3.y, o);
        a3.z += __shfl_xor(a3.z, o); a3.w += __shfl_xor(a3.w, o);
    }
    if (eg == 0) {
        a0.x *= rs.x; a0.y *= rs.x; a0.z *= rs.x; a0.w *= rs.x;
        a1.x *= rs.y; a1.y *= rs.y; a1.z *= rs.y; a1.w *= rs.y;
        a2.x *= rs.z; a2.y *= rs.z; a2.z *= rs.z; a2.w *= rs.z;
        a3.x *= rs.w; a3.y *= rs.w; a3.z *= rs.w; a3.w *= rs.w;
        size_t b = (size_t)n * 128 + l15 * 2;
        *(uint2*)&aggx_bf[b +  0] = f4_to_bf4(a0);
        *(uint2*)&aggx_bf[b + 32] = f4_to_bf4(a1);
        *(uint2*)&aggx_bf[b + 64] = f4_to_bf4(a2);
        *(uint2*)&aggx_bf[b + 96] = f4_to_bf4(a3);
    }
}

// ---------- GAT2: fused softmax + bf16 gather (depth-4 pipeline) ----------
__global__ __launch_bounds__(256)
void gat2_fused(const int* __restrict__ off, const int* __restrict__ csr_src,
                const float* __restrict__ es, const float* __restrict__ ed,
                const unsigned* __restrict__ H2bf, const float* __restrict__ bias,
                unsigned* __restrict__ outbf, float* __restrict__ alpha_fb) {
    __shared__ float elds[4][CAP * 4];
    __shared__ int   sidx[4][CAP];
    int wav = threadIdx.x >> 6, lane = threadIdx.x & 63;
    int n = blockIdx.x * 4 + wav;
    bool active = n < N_NODES;
    int p0 = 0, p1 = 0;
    float4 ed4 = make_float4(0.f, 0.f, 0.f, 0.f);
    if (active) { p0 = off[n]; p1 = off[n + 1]; ed4 = *(const float4*)&ed[n * 4]; }
    float4 sum = make_float4(0.f, 0.f, 0.f, 0.f);
    for (int p = p0 + lane; p < p1; p += 64) {
        int s = csr_src[p];
        float4 e4 = *(const float4*)&es[s * 4];
        e4.x += ed4.x; e4.y += ed4.y; e4.z += ed4.z; e4.w += ed4.w;
        e4.x = e4.x > 0.f ? e4.x : 0.2f * e4.x;
        e4.y = e4.y > 0.f ? e4.y : 0.2f * e4.y;
        e4.z = e4.z > 0.f ? e4.z : 0.2f * e4.z;
        e4.w = e4.w > 0.f ? e4.w : 0.2f * e4.w;
        e4.x = __expf(e4.x); e4.y = __expf(e4.y); e4.z = __expf(e4.z); e4.w = __expf(e4.w);
        int q = p - p0;
        if (q < CAP) { *(float4*)&elds[wav][q * 4] = e4; sidx[wav][q] = s; }
        else         *(float4*)&alpha_fb[(size_t)p * 4] = e4;
        sum.x += e4.x; sum.y += e4.y; sum.z += e4.z; sum.w += e4.w;
    }
#pragma unroll
    for (int o = 1; o < 64; o <<= 1) {
        sum.x += __shfl_xor(sum.x, o); sum.y += __shfl_xor(sum.y, o);
        sum.z += __shfl_xor(sum.z, o); sum.w += __shfl_xor(sum.w, o);
    }
    if (!active) return;
    int half = lane >> 5, l = lane & 31;
    int hh = l >> 3;
    float sh = (hh == 0) ? sum.x : (hh == 1) ? sum.y : (hh == 2) ? sum.z : sum.w;
    float rsh = sh > 0.f ? 1.f / sh : 0.f;
    int deg = p1 - p0;
    float acc[8];
#pragma unroll
    for (int j = 0; j < 8; j++) acc[j] = 0.f;
    auto fetch = [&](int qq, float& al, uint4& rr) {
        al = 0.f;
        rr = make_uint4(0, 0, 0, 0);
        if (qq < deg) {
            int s;
            if (qq < CAP) { s = sidx[wav][qq]; al = elds[wav][qq * 4 + hh]; }
            else { s = csr_src[p0 + qq]; al = alpha_fb[(size_t)(p0 + qq) * 4 + hh]; }
            rr = *(const uint4*)&H2bf[(size_t)s * 128 + l * 4];
        }
    };
    int q = half;
    float aA, aB, aC;
    uint4 rA, rB, rC;
    fetch(q, aA, rA);
    fetch(q + 2, aB, rB);
    fetch(q + 4, aC, rC);
    while (q < deg) {
        float aD; uint4 rD;
        fetch(q + 6, aD, rD);
        float4 f0 = bf4_to_f4(make_uint2(rA.x, rA.y));
        float4 f1 = bf4_to_f4(make_uint2(rA.z, rA.w));
        acc[0] += aA * f0.x; acc[1] += aA * f0.y; acc[2] += aA * f0.z; acc[3] += aA * f0.w;
        acc[4] += aA * f1.x; acc[5] += aA * f1.y; acc[6] += aA * f1.z; acc[7] += aA * f1.w;
        aA = aB; rA = rB; aB = aC; rB = rC; aC = aD; rC = rD;
        q += 2;
    }
#pragma unroll
    for (int j = 0; j < 8; j++) acc[j] += __shfl_xor(acc[j], 32);
    if (half == 0) {
        float4 b0 = *(const float4*)&bias[l * 8];
        float4 b1 = *(const float4*)&bias[l * 8 + 4];
        float4 o0, o1;
        o0.x = fmaxf(acc[0] * rsh + b0.x, 0.f);
        o0.y = fmaxf(acc[1] * rsh + b0.y, 0.f);
        o0.z = fmaxf(acc[2] * rsh + b0.z, 0.f);
        o0.w = fmaxf(acc[3] * rsh + b0.w, 0.f);
        o1.x = fmaxf(acc[4] * rsh + b1.x, 0.f);
        o1.y = fmaxf(acc[5] * rsh + b1.y, 0.f);
        o1.z = fmaxf(acc[6] * rsh + b1.z, 0.f);
        o1.w = fmaxf(acc[7] * rsh + b1.w, 0.f);
        uint2 w0 = f4_to_bf4(o0), w1 = f4_to_bf4(o1);
        uint4 w = make_uint4(w0.x, w0.y, w1.x, w1.y);
        *(uint4*)&outbf[(size_t)n * 128 + l * 4] = w;
    }
}

// ---------- label prop: LDS staging, depth-4 pipeline; optional fused esed ----------
template<int FUSE_ESED>
__global__ __launch_bounds__(256)
void lp_csr_t(const int* __restrict__ off, const int* __restrict__ csr_src,
              const float* __restrict__ dis, const unsigned* __restrict__ in_bf,
              const unsigned* __restrict__ res_bf, unsigned* __restrict__ out_bf,
              const float* __restrict__ wes, const float* __restrict__ wed,
              float* __restrict__ es, float* __restrict__ ed) {
    __shared__ int   widx[4][CAP];
    __shared__ float wwt[4][CAP];
    int wav = threadIdx.x >> 6, lane = threadIdx.x & 63;
    int n = blockIdx.x * 4 + wav;
    if (n >= N_NODES) return;
    int p0 = off[n], p1 = off[n + 1];
    int deg = p1 - p0;
    float disd = dis[n];
    for (int q = lane; q < deg && q < CAP; q += 64) {
        int s = csr_src[p0 + q];
        widx[wav][q] = s;
        wwt[wav][q] = dis[s] * disd;
    }
    int half = lane >> 5, l = lane & 31;
    float acc[8];
#pragma unroll
    for (int j = 0; j < 8; j++) acc[j] = 0.f;
    auto fetch = [&](int qq, float& nw, uint4& rr) {
        nw = 0.f;
        rr = make_uint4(0, 0, 0, 0);
        if (qq < deg) {
            int s;
            if (qq < CAP) { s = widx[wav][qq]; nw = wwt[wav][qq]; }
            else { s = csr_src[p0 + qq]; nw = dis[s] * disd; }
            rr = *(const uint4*)&in_bf[(size_t)s * 128 + l * 4];
        }
    };
    int q = half;
    float nA, nB, nC;
    uint4 rA, rB, rC;
    fetch(q, nA, rA);
    fetch(q + 2, nB, rB);
    fetch(q + 4, nC, rC);
    while (q < deg) {
        float nD; uint4 rD;
        fetch(q + 6, nD, rD);
        float4 f0 = bf4_to_f4(make_uint2(rA.x, rA.y));
        float4 f1 = bf4_to_f4(make_uint2(rA.z, rA.w));
        acc[0] += nA * f0.x; acc[1] += nA * f0.y; acc[2] += nA * f0.z; acc[3] += nA * f0.w;
        acc[4] += nA * f1.x; acc[5] += nA * f1.y; acc[6] += nA * f1.z; acc[7] += nA * f1.w;
        nA = nB; rA = rB; nB = nC; rB = rC; nC = nD; rC = rD;
        q += 2;
    }
#pragma unroll
    for (int j = 0; j < 8; j++) acc[j] += __shfl_xor(acc[j], 32);
    if (half == 0) {
        uint4 rr = *(const uint4*)&res_bf[(size_t)n * 128 + l * 4];
        float4 r0 = bf4_to_f4(make_uint2(rr.x, rr.y));
        float4 r1 = bf4_to_f4(make_uint2(rr.z, rr.w));
        float4 o0, o1;
        o0.x = fminf(fmaxf(0.5f * acc[0] + 0.5f * r0.x, 0.f), 1.f);
        o0.y = fminf(fmaxf(0.5f * acc[1] + 0.5f * r0.y, 0.f), 1.f);
        o0.z = fminf(fmaxf(0.5f * acc[2] + 0.5f * r0.z, 0.f), 1.f);
        o0.w = fminf(fmaxf(0.5f * acc[3] + 0.5f * r0.w, 0.f), 1.f);
        o1.x = fminf(fmaxf(0.5f * acc[4] + 0.5f * r1.x, 0.f), 1.f);
        o1.y = fminf(fmaxf(0.5f * acc[5] + 0.5f * r1.y, 0.f), 1.f);
        o1.z = fminf(fmaxf(0.5f * acc[6] + 0.5f * r1.z, 0.f), 1.f);
        o1.w = fminf(fmaxf(0.5f * acc[7] + 0.5f * r1.w, 0.f), 1.f);
        uint2 w0 = f4_to_bf4(o0), w1 = f4_to_bf4(o1);
        uint4 w = make_uint4(w0.x, w0.y, w1.x, w1.y);
        *(uint4*)&out_bf[(size_t)n * 128 + l * 4] = w;
        if (FUSE_ESED) {
            float vv[8] = {o0.x, o0.y, o0.z, o0.w, o1.x, o1.y, o1.z, o1.w};
            float4 ps = make_float4(0.f, 0.f, 0.f, 0.f);
            float4 pd = make_float4(0.f, 0.f, 0.f, 0.f);
#pragma unroll
            for (int j = 0; j < 8; j++) {
                int c = l * 8 + j;
                float4 a = *(const float4*)&wes[c * 4];
                float4 b = *(const float4*)&wed[c * 4];
                ps.x += vv[j] * a.x; ps.y += vv[j] * a.y; ps.z += vv[j] * a.z; ps.w += vv[j] * a.w;
                pd.x += vv[j] * b.x; pd.y += vv[j] * b.y; pd.z += vv[j] * b.z; pd.w += vv[j] * b.w;
            }
#pragma unroll
            for (int o = 1; o < 32; o <<= 1) {
                ps.x += __shfl_xor(ps.x, o); ps.y += __shfl_xor(ps.y, o);
                ps.z += __shfl_xor(ps.z, o); ps.w += __shfl_xor(ps.w, o);
                pd.x += __shfl_xor(pd.x, o); pd.y += __shfl_xor(pd.y, o);
                pd.z += __shfl_xor(pd.z, o); pd.w += __shfl_xor(pd.w, o);
            }
            if (l == 0) {
                *(float4*)&es[n * 4] = ps;
                *(float4*)&ed[n * 4] = pd;
            }
        }
    }
}

// ---------- bf16 pool ----------
__global__ void pool_bf(const unsigned* __restrict__ buf, const int* __restrict__ gstart,
                        float* __restrict__ psum, int colOff) {
    int g = blockIdx.x, q = blockIdx.y;
    int n0 = gstart[g], n1 = gstart[g + 1];
    int len = n1 - n0;
    int ns = n0 + (len * q) / 4, ne = n0 + (len * (q + 1)) / 4;
    int cp = threadIdx.x & 127;
    int np = threadIdx.x >> 7;
    float s0 = 0.f, s1 = 0.f;
    for (int n = ns + np; n < ne; n += 2) {
        unsigned u = buf[(size_t)n * 128 + cp];
        s0 += __uint_as_float(u << 16);
        s1 += __uint_as_float(u & 0xffff0000u);
    }
    atomicAdd(&psum[g * JK + colOff + cp * 2 + 0], s0);
    atomicAdd(&psum[g * JK + colOff + cp * 2 + 1], s1);
}

// ---------- full MLP head: one block per graph ----------
__global__ __launch_bounds__(256)
void head_all(const float* __restrict__ psum, const int* __restrict__ gstart,
              const float* __restrict__ clin,
              const float* __restrict__ pp_w1, const float* __restrict__ pp_b1,
              const float* __restrict__ pp_w2, const float* __restrict__ pp_b2,
              const float* __restrict__ cl_w1, const float* __restrict__ cl_b1,
              const float* __restrict__ cl_w2, const float* __restrict__ cl_b2,
              const float* __restrict__ h_w1, const float* __restrict__ h_b1,
              const float* __restrict__ h_w2, const float* __restrict__ h_b2,
              const float* __restrict__ h_w3, const float* __restrict__ h_b3,
              float* __restrict__ out) {
    __shared__ float zin[JK];
    __shared__ float z1[256];
    __shared__ float zcl[32];
    __shared__ float zc[64];
    __shared__ float z[160];
    __shared__ float z3[64];
    __shared__ float z4[32];
    __shared__ float part[128];
    int g = blockIdx.x, t = threadIdx.x;
    int len = gstart[g + 1] - gstart[g];
    float inv = 1.f / (float)(len > 1 ? len : 1);
    for (int k = t; k < JK; k += 256) zin[k] = psum[g * JK + k] * inv;
    if (t < 32) zcl[t] = clin[g * 32 + t];
    __syncthreads();
    {
        float acc = pp_b1[t];
#pragma unroll 8
        for (int k = 0; k < JK; k++) acc += zin[k] * pp_w1[k * 256 + t];
        z1[t] = fmaxf(acc, 0.f);
    }
    __syncthreads();
    int m = t & 127, half = t >> 7;
    {
        float acc = 0.f;
        int k0 = half * 128;
#pragma unroll 8
        for (int k = k0; k < k0 + 128; k++) acc += z1[k] * pp_w2[k * 128 + m];
        if (half) part[m] = acc;
        __syncthreads();
        if (!half) z[m] = acc + part[m] + pp_b2[m];
    }
    if (t < 64) {
        float acc = cl_b1[t];
#pragma unroll
        for (int k = 0; k < 32; k++) acc += zcl[k] * cl_w1[k * 64 + t];
        zc[t] = fmaxf(acc, 0.f);
    }
    __syncthreads();
    if (t < 32) {
        float acc = cl_b2[t];
#pragma unroll
        for (int k = 0; k < 64; k++) acc += zc[k] * cl_w2[k * 32 + t];
        z[128 + t] = acc;
    }
    __syncthreads();
    if (t < 64) {
        float acc = h_b1[t];
#pragma unroll 8
        for (int k = 0; k < 160; k++) acc += z[k] * h_w1[k * 64 + t];
        z3[t] = fmaxf(acc, 0.f);
    }
    __syncthreads();
    if (t < 32) {
        float acc = h_b2[t];
#pragma unroll
        for (int k = 0; k < 64; k++) acc += z3[k] * h_w2[k * 32 + t];
        z4[t] = fmaxf(acc, 0.f);
    }
    __syncthreads();
    if (t < 2) {
        float acc = h_b3[t];
#pragma unroll
        for (int k = 0; k < 32; k++) acc += z4[k] * h_w3[k * 2 + t];
        out[g * 2 + t] = acc;
    }
}

// ---------- launch ----------
extern "C" void kernel_launch(void* const* d_in, const int* in_sizes, int n_in,
                              void* d_out, int out_size, void* d_ws, size_t ws_size,
                              hipStream_t stream) {
    const float* x     = (const float*)d_in[0];
    const int*   ei    = (const int*)d_in[1];
    const int*   batch = (const int*)d_in[2];
    const float* clin  = (const float*)d_in[3];
    const float* W1  = (const float*)d_in[4];
    const float* a1s = (const float*)d_in[5];
    const float* a1d = (const float*)d_in[6];
    const float* b1  = (const float*)d_in[7];
    const float* W2  = (const float*)d_in[8];
    const float* a2s = (const float*)d_in[9];
    const float* a2d = (const float*)d_in[10];
    const float* b2  = (const float*)d_in[11];
    const float* pp_w1 = (const float*)d_in[12];
    const float* pp_b1 = (const float*)d_in[13];
    const float* pp_w2 = (const float*)d_in[14];
    const float* pp_b2 = (const float*)d_in[15];
    const float* cl_w1 = (const float*)d_in[16];
    const float* cl_b1 = (const float*)d_in[17];
    const float* cl_w2 = (const float*)d_in[18];
    const float* cl_b2 = (const float*)d_in[19];
    const float* h_w1  = (const float*)d_in[20];
    const float* h_b1  = (const float*)d_in[21];
    const float* h_w2  = (const float*)d_in[22];
    const float* h_b2  = (const float*)d_in[23];
    const float* h_w3  = (const float*)d_in[24];
    const float* h_b3  = (const float*)d_in[25];

    const int* src = ei;
    const int* dst = ei + N_EDGES;

    char* p = (char*)d_ws;
    auto carve = [&](size_t bytes) -> char* {
        char* r = p;
        p += (bytes + 255) & ~(size_t)255;
        return r;
    };
    const size_t NBH = (size_t)N_NODES * 256 * 2;    // bf16 node buffer
    unsigned* abf  = (unsigned*)carve(NBH);          // aggx, later h2_final
    unsigned* bf1  = (unsigned*)carve(NBH);
    unsigned* bf2  = (unsigned*)carve(NBH);
    unsigned* bf3  = (unsigned*)carve(NBH);
    unsigned* xbf  = (unsigned*)carve((size_t)N_NODES * 32 * 4);  // bf16 x copy
    float* alpha_fb  = (float*)carve((size_t)N_EDGES * 4 * 4);
    int*   csr_src   = (int*)carve((size_t)N_EDGES * 4);
    int*   off       = (int*)carve((size_t)(N_NODES + 1) * 4);
    int*   deg       = (int*)carve((size_t)N_NODES * 4);
    int*   cursor    = (int*)carve((size_t)N_NODES * 4);
    int*   bsum      = (int*)carve((size_t)NSB * 4);
    int*   bpre      = (int*)carve((size_t)NSB * 4);
    float* dis       = (float*)carve((size_t)N_NODES * 4);
    float* es        = (float*)carve((size_t)N_NODES * 4 * 4);
    float* ed        = (float*)carve((size_t)N_NODES * 4 * 4);
    float* wes1      = (float*)carve((size_t)64 * 4 * 4);
    float* wed1      = (float*)carve((size_t)64 * 4 * 4);
    float* wes2      = (float*)carve((size_t)256 * 4 * 4);
    float* wed2      = (float*)carve((size_t)256 * 4 * 4);
    unsigned short* W1T = (unsigned short*)carve((size_t)256 * 64 * 2);
    unsigned short* W2T = (unsigned short*)carve((size_t)256 * 256 * 2);
    int*   gstart    = (int*)carve((size_t)(N_GRAPHS + 1) * 4);
    float* psum      = (float*)carve((size_t)N_GRAPHS * JK * 4);

    const int TB = 256;
    const int gE     = (N_EDGES + TB - 1) / TB;
    const int gDeg   = (N_EDGES + N_NODES + TB - 1) / TB;
    const int gNwave = (N_NODES * 64 + TB - 1) / TB;
    const int gFuse  = (N_NODES + 3) / 4;
    const int gRow   = (N_NODES + 63) / 64;
    const int gPrep  = (S7 + TB - 1) / TB;

    // ---- CSR + degree + bounds + fused misc prep (incl. x pooling) ----
    hipMemsetAsync(deg, 0, (size_t)N_NODES * 4, stream);
    hipMemsetAsync(cursor, 0, (size_t)N_NODES * 4, stream);
    hipMemsetAsync(psum, 0, (size_t)N_GRAPHS * JK * 4, stream);
    deg_kernel<<<gDeg, TB, 0, stream>>>(dst, deg, batch, gstart);
    prep_misc<<<gPrep, TB, 0, stream>>>(deg, dis,
                                        W1, a1s, a1d, wes1, wed1,
                                        W2, a2s, a2d, wes2, wed2,
                                        W1T, W2T, x, xbf, gstart, psum);
    scan_bsum<<<NSB, 256, 0, stream>>>(deg, bsum);
    scan_bpre<<<1, 256, 0, stream>>>(bsum, bpre, &off[N_NODES]);
    scan_off<<<NSB, 256, 0, stream>>>(deg, bpre, off);
    csr_fill<<<gE, TB, 0, stream>>>(src, dst, off, cursor, csr_src);

    // ---- GAT layer 1 ----
    esed_x<<<gNwave, TB, 0, stream>>>(x, wes1, wed1, es, ed);
    gat1_fused<<<gFuse, TB, 0, stream>>>(off, csr_src, es, ed, xbf, abf, alpha_fb);
    mfma_gemm<64, 64><<<dim3(gRow, 4), 256, 0, stream>>>(
        (const unsigned short*)abf, 256, W1T, bf1, 256, N_NODES, b1, 1,
        64, 64 * 64, 64);                                   // bf1 = h1a

    // ---- label prop 1 (residual = bf1); 2nd step fuses esed for layer 2 ----
    lp_csr_t<0><<<gFuse, TB, 0, stream>>>(off, csr_src, dis, bf1, bf1, bf2,
                                          nullptr, nullptr, nullptr, nullptr);
    lp_csr_t<1><<<gFuse, TB, 0, stream>>>(off, csr_src, dis, bf2, bf1, bf3,
                                          wes2, wed2, es, ed);   // bf3 = h1, es/ed ready

    pool_bf<<<dim3(N_GRAPHS, 4), TB, 0, stream>>>(bf3, gstart, psum, 64);

    // ---- GAT layer 2 ----
    mfma_gemm<256, 256><<<dim3(gRow, 1), 256, 0, stream>>>(
        (const unsigned short*)bf3, 256, W2T, bf1, 256, N_NODES, nullptr, 0,
        0, 0, 0);                                           // bf1 = h2
    gat2_fused<<<gFuse, TB, 0, stream>>>(off, csr_src, es, ed, bf1, b2, bf2, alpha_fb); // bf2 = h2a

    // ---- label prop 2 (residual = bf2) ----
    lp_csr_t<0><<<gFuse, TB, 0, stream>>>(off, csr_src, dis, bf2, bf2, bf1,
                                          nullptr, nullptr, nullptr, nullptr);
    lp_csr_t<0><<<gFuse, TB, 0, stream>>>(off, csr_src, dis, bf1, bf2, abf,
                                          nullptr, nullptr, nullptr, nullptr);  // abf = h2_final

    // ---- pooling (h2) + full head ----
    pool_bf<<<dim3(N_GRAPHS, 4), TB, 0, stream>>>(abf, gstart, psum, 320);
    head_all<<<N_GRAPHS, 256, 0, stream>>>(psum, gstart, clin,
                                           pp_w1, pp_b1, pp_w2, pp_b2,
                                           cl_w1, cl_b1, cl_w2, cl_b2,
                                           h_w1, h_b1, h_w2, h_b2, h_w3, h_b3,
                                           (float*)d_out);
}